// Round 1
// baseline (453.285 us; speedup 1.0000x reference)
//
#include <hip/hip_runtime.h>
#include <float.h>
#include <stdint.h>
#include <stddef.h>

#define NB 16
#define NQ 4000
#define NG 300
#define NC 81
#define NQW 125  // NQ/32

__device__ __forceinline__ bool lexlt(float v1, int i1, float v2, int i2) {
  return (v1 < v2) || (v1 == v2 && i1 < i2);
}

// ---------------- K1: per-row fg mask: any(in_box) | any(in_ctr) ----------------
__global__ void fg_kernel(const float* __restrict__ boxes, const float* __restrict__ gtb,
                          int* __restrict__ fgv) {
#pragma clang fp contract(off)
  const int b = blockIdx.y;
  const int q = blockIdx.x * 256 + threadIdx.x;
  __shared__ float sg[NG * 4];
  for (int i = threadIdx.x; i < NG * 4; i += 256) sg[i] = gtb[b * NG * 4 + i];
  __syncthreads();
  if (q >= NQ) return;
  const float4 pb = reinterpret_cast<const float4*>(boxes)[b * NQ + q];
  const float ax = (pb.x + pb.z) * 0.5f;
  const float ay = (pb.y + pb.w) * 0.5f;
  bool anyb = false, anyc = false;
  for (int g = 0; g < NG; ++g) {
    const float gx0 = sg[g*4+0], gy0 = sg[g*4+1], gx1 = sg[g*4+2], gy1 = sg[g*4+3];
    const float gcx = (gx0 + gx1) * 0.5f, gcy = (gy0 + gy1) * 0.5f;
    const float gw0 = gx1 - gx0, gh0 = gy1 - gy0;
    const float xg0 = gcx - 0.5f*gw0, yg0 = gcy - 0.5f*gh0;
    const float xg1 = gcx + 0.5f*gw0, yg1 = gcy + 0.5f*gh0;
    anyb = anyb || ((ax > xg0) && (ax < xg1) && (ay > yg0) && (ay < yg1));
    const float cw = xg1 - xg0, ch = yg1 - yg0;
    anyc = anyc || ((ax > gcx - 2.5f*cw) && (ax < gcx + 2.5f*cw) &&
                    (ay > gcy - 2.5f*ch) && (ay < gcy + 2.5f*ch));
  }
  fgv[b * NQ + q] = (anyb || anyc) ? 1 : 0;
}

// ---------------- K2: focal class cost table, transposed (B,C,Q) ----------------
__global__ void cls_kernel(const float* __restrict__ logits, float* __restrict__ cct) {
#pragma clang fp contract(off)
  const int b = blockIdx.z, c = blockIdx.y;
  const int q = blockIdx.x * 256 + threadIdx.x;
  if (q >= NQ) return;
  const float x = logits[((size_t)(b * NQ + q)) * NC + c];
  float p;
  if (x >= 0.f) p = 1.f / (1.f + expf(-x));
  else { const float e = expf(x); p = e / (1.f + e); }
  const float pos = 0.25f * ((1.f - p) * (1.f - p)) * (-logf(p + 1e-8f));
  const float neg = 0.75f * (p * p) * (-logf(1.f - p + 1e-8f));
  cct[((size_t)(b * NC + c)) * NQ + q] = pos - neg;
}

// ---------------- K3: cost (B,G,Q) + per-column top5 iou (dyn_k) + top5 cost -> m bits ----------------
__global__ void cost_kernel(const float* __restrict__ boxes, const float* __restrict__ gtb,
                            const int* __restrict__ labels, const float* __restrict__ imgsz,
                            const float* __restrict__ cct, const int* __restrict__ fgv,
                            float* __restrict__ cost, unsigned* __restrict__ mbits) {
#pragma clang fp contract(off)
  const int g = blockIdx.x, b = blockIdx.y, t = threadIdx.x;
  const float gx0 = gtb[(b*NG + g)*4 + 0];
  const float gy0 = gtb[(b*NG + g)*4 + 1];
  const float gx1 = gtb[(b*NG + g)*4 + 2];
  const float gy1 = gtb[(b*NG + g)*4 + 3];
  const int   lab = labels[b*NG + g];
  const float s0 = imgsz[b*4+0], s1 = imgsz[b*4+1], s2 = imgsz[b*4+2], s3 = imgsz[b*4+3];
  const float areaB = (gx1 - gx0) * (gy1 - gy0);
  const float ngx0 = gx0 / s0, ngy0 = gy0 / s1, ngx1 = gx1 / s2, ngy1 = gy1 / s3;
  const float gcx = (gx0 + gx1) * 0.5f, gcy = (gy0 + gy1) * 0.5f;
  const float gw0 = gx1 - gx0, gh0 = gy1 - gy0;
  const float xg0 = gcx - 0.5f*gw0, yg0 = gcy - 0.5f*gh0;
  const float xg1 = gcx + 0.5f*gw0, yg1 = gcy + 0.5f*gh0;
  const float cw = xg1 - xg0, ch = yg1 - yg0;
  const float cxlo = gcx - 2.5f*cw, cxhi = gcx + 2.5f*cw;
  const float cylo = gcy - 2.5f*ch, cyhi = gcy + 2.5f*ch;
  const float* __restrict__ ccls = cct + ((size_t)(b*NC + lab)) * NQ;
  float* __restrict__ crow = cost + ((size_t)(b*NG + g)) * NQ;
  unsigned* __restrict__ mrow = mbits + (b*NG + g) * NQW;
  for (int i = t; i < NQW; i += 256) mrow[i] = 0u;

  float tv[5]; int tq[5]; float sv[5];
#pragma unroll
  for (int i = 0; i < 5; ++i) { tv[i] = FLT_MAX; tq[i] = 0x7fffffff; sv[i] = -1.f; }

  for (int q = t; q < NQ; q += 256) {
    const float4 pb = reinterpret_cast<const float4*>(boxes)[b*NQ + q];
    const float areaA = (pb.z - pb.x) * (pb.w - pb.y);
    const float ltx = fmaxf(pb.x, gx0), lty = fmaxf(pb.y, gy0);
    const float rbx = fminf(pb.z, gx1), rby = fminf(pb.w, gy1);
    const float iw = fmaxf(rbx - ltx, 0.f), ih = fmaxf(rby - lty, 0.f);
    const float inter = iw * ih;
    const float uni = areaA + areaB - inter;
    const float iou = inter / uni;
    const float eltx = fminf(pb.x, gx0), elty = fminf(pb.y, gy0);
    const float erbx = fmaxf(pb.z, gx1), erby = fmaxf(pb.w, gy1);
    const float ew = fmaxf(erbx - eltx, 0.f), eh = fmaxf(erby - elty, 0.f);
    const float earea = ew * eh;
    const float giou = iou - (earea - uni) / earea;
    const float cbb = fabsf(pb.x/s0 - ngx0) + fabsf(pb.y/s1 - ngy0)
                    + fabsf(pb.z/s2 - ngx1) + fabsf(pb.w/s3 - ngy1);
    const float ax = (pb.x + pb.z) * 0.5f, ay = (pb.y + pb.w) * 0.5f;
    const bool inb = (ax > xg0) && (ax < xg1) && (ay > yg0) && (ay < yg1);
    const bool inc = (ax > cxlo) && (ax < cxhi) && (ay > cylo) && (ay < cyhi);
    const bool ibc = inb && inc;
    float cval = 5.0f * cbb + 2.0f * ccls[q];
    cval = cval + 2.0f * (-giou);
    cval = cval + (ibc ? 0.f : 100.f);
    cval = cval + (fgv[b*NQ + q] ? 0.f : 10000.f);
    crow[q] = cval;
    // top-5 largest iou (values only)
    if (iou > sv[4]) {
      sv[4] = iou;
#pragma unroll
      for (int j = 4; j >= 1; --j)
        if (sv[j] > sv[j-1]) { const float tmp = sv[j]; sv[j] = sv[j-1]; sv[j-1] = tmp; }
    }
    // top-5 smallest (cost, q) lexicographic (stable-rank semantics)
    if (lexlt(cval, q, tv[4], tq[4])) {
      tv[4] = cval; tq[4] = q;
#pragma unroll
      for (int j = 4; j >= 1; --j)
        if (lexlt(tv[j], tq[j], tv[j-1], tq[j-1])) {
          const float tf = tv[j]; tv[j] = tv[j-1]; tv[j-1] = tf;
          const int ti = tq[j]; tq[j] = tq[j-1]; tq[j-1] = ti;
        }
    }
  }

  __shared__ float Lv[256 * 5];
  __shared__ int   Lq[256 * 5];
  __shared__ float Li[256 * 5];
#pragma unroll
  for (int i = 0; i < 5; ++i) { Lv[t*5+i] = tv[i]; Lq[t*5+i] = tq[i]; Li[t*5+i] = sv[i]; }
  __syncthreads();
  for (int off = 128; off >= 1; off >>= 1) {
    if (t < off) {
      float ov[5]; int oq[5]; float iv[5];
      int i = 0, j = 0;
#pragma unroll
      for (int k = 0; k < 5; ++k) {
        const float a = Lv[t*5 + i];       const int aq = Lq[t*5 + i];
        const float b2 = Lv[(t+off)*5 + j]; const int bq2 = Lq[(t+off)*5 + j];
        if (lexlt(a, aq, b2, bq2)) { ov[k] = a; oq[k] = aq; ++i; }
        else                       { ov[k] = b2; oq[k] = bq2; ++j; }
      }
      int i2 = 0, j2 = 0;
#pragma unroll
      for (int k = 0; k < 5; ++k) {
        const float a = Li[t*5 + i2];
        const float b2 = Li[(t+off)*5 + j2];
        if (a >= b2) { iv[k] = a; ++i2; } else { iv[k] = b2; ++j2; }
      }
#pragma unroll
      for (int k = 0; k < 5; ++k) { Lv[t*5+k] = ov[k]; Lq[t*5+k] = oq[k]; Li[t*5+k] = iv[k]; }
    }
    __syncthreads();
  }
  if (t == 0) {
    float s = Li[0]; s += Li[1]; s += Li[2]; s += Li[3]; s += Li[4];  // descending order sum
    int k = (int)s; if (k < 1) k = 1; if (k > 5) k = 5;
    for (int i = 0; i < k; ++i) {
      const int q = Lq[i];
      mrow[q >> 5] |= 1u << (q & 31);
    }
  }
}

// ---------------- K4: row counts from bits ----------------
__global__ void rowcnt_kernel(const unsigned* __restrict__ mbits, int* __restrict__ rcnt) {
  const int idx = blockIdx.x * 256 + threadIdx.x;
  if (idx >= NB * NQ) return;
  const int b = idx / NQ, q = idx % NQ;
  const unsigned* base = mbits + b * NG * NQW + (q >> 5);
  const unsigned bit = 1u << (q & 31);
  int c = 0;
  for (int g = 0; g < NG; ++g) c += (base[g * NQW] & bit) ? 1 : 0;
  rcnt[idx] = c;
}

// ---------------- K5: initial multi fix (row -> one_hot(argmin_g cost)) ----------------
__global__ void multifix_kernel(const float* __restrict__ cost, unsigned* __restrict__ mbits,
                                int* __restrict__ rcnt, int* __restrict__ multi) {
  const int idx = blockIdx.x * 256 + threadIdx.x;
  if (idx >= NB * NQ) return;
  const int b = idx / NQ, q = idx % NQ;
  if (rcnt[idx] <= 1) { multi[idx] = 0; return; }
  multi[idx] = 1;
  const float* cc = cost + (size_t)b * NG * NQ + q;
  float best = FLT_MAX; int bg = 0;
  for (int g = 0; g < NG; ++g) {
    const float v = cc[(size_t)g * NQ];
    if (v < best) { best = v; bg = g; }
  }
  unsigned* base = mbits + b * NG * NQW + (q >> 5);
  const unsigned bit = 1u << (q & 31);
  for (int g = 0; g < NG; ++g) {
    const unsigned w = base[g * NQW];
    const bool mine = (w & bit) != 0;
    if (g == bg) { if (!mine) atomicOr(&base[g * NQW], bit); }
    else if (mine) atomicAnd(&base[g * NQW], ~bit);
  }
  rcnt[idx] = 1;
}

// ---------------- K6: column coverage counts ----------------
__global__ void colcov_kernel(const unsigned* __restrict__ mbits, int* __restrict__ ccov) {
  const int idx = blockIdx.x * 256 + threadIdx.x;
  if (idx >= NB * NG) return;
  const unsigned* row = mbits + idx * NQW;
  int c = 0;
  for (int i = 0; i < NQW; ++i) c += __popc(row[i]);
  ccov[idx] = c;
}

// ---------------- K7: the while-loop, one persistent block per image ----------------
__global__ __launch_bounds__(1024) void loop_kernel(
    const float* __restrict__ cost, unsigned* __restrict__ mbits,
    const int* __restrict__ rcnt_g, const int* __restrict__ ccov_g,
    const int* __restrict__ multi_g, int* __restrict__ pen_g) {
  const int b = blockIdx.x, t = threadIdx.x;
  __shared__ int s_pen[NQ];
  __shared__ int s_rcnt[NQ];
  __shared__ unsigned char s_multi[NQ];
  __shared__ int s_ccov[NG];
  __shared__ int s_unc[NG];
  __shared__ int s_pickq[NG];
  __shared__ int s_mq[800];
  __shared__ int s_mn, s_n, s_fix, s_sticky;

  for (int q = t; q < NQ; q += 1024) {
    s_pen[q] = 0;
    s_rcnt[q] = rcnt_g[b * NQ + q];
    s_multi[q] = (unsigned char)multi_g[b * NQ + q];
  }
  for (int g = t; g < NG; g += 1024) s_ccov[g] = ccov_g[b * NG + g];
  if (t == 0) { s_sticky = 0; s_mn = 0; }
  __syncthreads();
  for (int q = t; q < NQ; q += 1024)
    if (s_multi[q]) { const int i = atomicAdd(&s_mn, 1); s_mq[i] = q; }
  __syncthreads();

  unsigned* __restrict__ mb = mbits + b * NG * NQW;
  const float* __restrict__ cb = cost + (size_t)b * NG * NQ;
  const int lane = t & 63, wave = t >> 6;
  const int m_n = s_mn;

  for (int iter = 0; iter < 100; ++iter) {
    if (t == 0) { s_n = 0; s_fix = s_sticky; }
    __syncthreads();
    // gather uncovered columns (order irrelevant; per-column results independent)
    for (int g = t; g < NG; g += 1024)
      if (s_ccov[g] == 0) { const int i = atomicAdd(&s_n, 1); s_unc[i] = g; }
    __syncthreads();
    const int n = s_n;
    if (n == 0) break;
    // c += 1e5 for assigned rows (track count; replay sequential f32 adds on use)
    for (int q = t; q < NQ; q += 1024)
      if (s_rcnt[q] > 0) s_pen[q]++;
    __syncthreads();
    // argmin_q per uncovered column (ties -> smallest q)
    for (int ci = wave; ci < n; ci += 16) {
      const int g = s_unc[ci];
      const float* __restrict__ crow = cb + (size_t)g * NQ;
      float best = FLT_MAX; int bq = 0;
      for (int q = lane; q < NQ; q += 64) {
        float v = crow[q];
        const int p = s_pen[q];
        for (int r = 0; r < p; ++r) v += 100000.0f;  // match reference's sequential rounding
        if (v < best) { best = v; bq = q; }
      }
      for (int off = 32; off; off >>= 1) {
        const float ov = __shfl_down(best, off);
        const int oq = __shfl_down(bq, off);
        if (ov < best || (ov == best && oq < bq)) { best = ov; bq = oq; }
      }
      if (lane == 0) s_pickq[ci] = bq;
    }
    __syncthreads();
    // apply picks
    if (t < n) {
      const int g = s_unc[t], q = s_pickq[t];
      atomicOr(&mb[g * NQW + (q >> 5)], 1u << (q & 31));
      const int nc = atomicAdd(&s_rcnt[q], 1) + 1;
      s_ccov[g] = 1;
      if (nc > 1) { s_fix = 1; if (!s_multi[q]) s_sticky = 1; }
    }
    __syncthreads();
    // fix: rows in ORIGINAL multi set -> one_hot(argmin_g c[q,:]) with CURRENT penalties
    if (s_fix) {
      for (int mi = wave; mi < m_n; mi += 16) {
        const int q = s_mq[mi];
        const int p = s_pen[q];
        const float* __restrict__ base = cb + q;
        float best = FLT_MAX; int bg = 0;
        for (int g = lane; g < NG; g += 64) {
          float v = base[(size_t)g * NQ];
          for (int r = 0; r < p; ++r) v += 100000.0f;
          if (v < best) { best = v; bg = g; }
        }
        for (int off = 32; off; off >>= 1) {
          const float ov = __shfl_down(best, off);
          const int og = __shfl_down(bg, off);
          if (ov < best || (ov == best && og < bg)) { best = ov; bg = og; }
        }
        bg = __shfl(bg, 0);
        const unsigned bit = 1u << (q & 31);
        const int wofs = q >> 5;
        for (int g = lane; g < NG; g += 64) {
          const unsigned w = mb[g * NQW + wofs];
          const bool cur = (w & bit) != 0;
          const bool want = (g == bg);
          if (cur != want) {
            if (want) { atomicOr(&mb[g * NQW + wofs], bit); atomicAdd(&s_ccov[g], 1); }
            else      { atomicAnd(&mb[g * NQW + wofs], ~bit); atomicSub(&s_ccov[g], 1); }
          }
        }
        if (lane == 0) s_rcnt[q] = 1;
      }
    }
    __syncthreads();
  }
  for (int q = t; q < NQ; q += 1024) pen_g[b * NQ + q] = s_pen[q];
}

// ---------------- K8: matched_qidx = argmin_q (m ? c_final : inf), ties->first, empty->0 ----------------
__global__ void matched_kernel(const float* __restrict__ cost, const unsigned* __restrict__ mbits,
                               const int* __restrict__ pen_g, float* __restrict__ out_mq) {
  const int g = blockIdx.x, b = blockIdx.y, t = threadIdx.x;
  const float* __restrict__ crow = cost + ((size_t)(b*NG + g)) * NQ;
  const unsigned* __restrict__ mrow = mbits + (b*NG + g) * NQW;
  const int* __restrict__ pb = pen_g + b * NQ;
  float best = FLT_MAX; int bq = 0;
  for (int q = t; q < NQ; q += 256) {
    if ((mrow[q >> 5] >> (q & 31)) & 1u) {
      float v = crow[q];
      const int p = pb[q];
      for (int r = 0; r < p; ++r) v += 100000.0f;
      if (v < best) { best = v; bq = q; }
    }
  }
  __shared__ float rv[256];
  __shared__ int rq[256];
  rv[t] = best; rq[t] = bq;
  __syncthreads();
  for (int off = 128; off; off >>= 1) {
    if (t < off) {
      if (lexlt(rv[t + off], rq[t + off], rv[t], rq[t])) { rv[t] = rv[t + off]; rq[t] = rq[t + off]; }
    }
    __syncthreads();
  }
  if (t == 0) out_mq[b * NG + g] = (float)rq[0];
}

// ---------------- K9: expand bits -> m floats (overwrites cost scratch), selected, gt_idx ----------------
__global__ void out_kernel(const unsigned* __restrict__ mbits, float* __restrict__ out_m,
                           float* __restrict__ out_sel, float* __restrict__ out_gti) {
  const int q = blockIdx.x, b = blockIdx.y, t = threadIdx.x;
  __shared__ int firstg;
  if (t == 0) firstg = 0x7fffffff;
  __syncthreads();
  const unsigned* __restrict__ base = mbits + b * NG * NQW + (q >> 5);
  const unsigned bit = 1u << (q & 31);
  float* __restrict__ orow = out_m + ((size_t)(b * NQ + q)) * NG;
  for (int g = t; g < NG; g += 128) {
    const bool s = (base[g * NQW] & bit) != 0;
    orow[g] = s ? 1.f : 0.f;
    if (s) atomicMin(&firstg, g);
  }
  __syncthreads();
  if (t == 0) {
    const bool sel = (firstg != 0x7fffffff);
    out_sel[b * NQ + q] = sel ? 1.f : 0.f;
    out_gti[b * NQ + q] = sel ? (float)firstg : 0.f;
  }
}

extern "C" void kernel_launch(void* const* d_in, const int* in_sizes, int n_in,
                              void* d_out, int out_size, void* d_ws, size_t ws_size,
                              hipStream_t stream) {
  const float* logits = (const float*)d_in[0];
  const float* boxes  = (const float*)d_in[1];
  const int*   labels = (const int*)d_in[2];
  const float* gtb    = (const float*)d_in[3];
  const float* imgsz  = (const float*)d_in[4];

  float* out = (float*)d_out;
  float* out_m   = out;                                   // B*Q*G
  float* out_sel = out + (size_t)NB * NQ * NG;            // B*Q
  float* out_gti = out_sel + (size_t)NB * NQ;             // B*Q
  float* out_mq  = out_gti + (size_t)NB * NQ;             // B*G

  // workspace layout
  char* w = (char*)d_ws;
  const size_t need = sizeof(float) * (size_t)NB * NC * NQ
                    + sizeof(unsigned) * (size_t)NB * NG * NQW
                    + sizeof(int) * (size_t)NB * NQ * 4
                    + sizeof(int) * (size_t)NB * NG;
  if (ws_size < need) return;  // loud failure rather than corruption
  float*    cct   = (float*)w;    w += sizeof(float) * (size_t)NB * NC * NQ;
  unsigned* mbits = (unsigned*)w; w += sizeof(unsigned) * (size_t)NB * NG * NQW;
  int* fgv   = (int*)w; w += sizeof(int) * (size_t)NB * NQ;
  int* rcnt  = (int*)w; w += sizeof(int) * (size_t)NB * NQ;
  int* multi = (int*)w; w += sizeof(int) * (size_t)NB * NQ;
  int* pen   = (int*)w; w += sizeof(int) * (size_t)NB * NQ;
  int* ccov  = (int*)w; w += sizeof(int) * (size_t)NB * NG;

  // cost matrix (B,G,Q) lives in the d_out m-region; overwritten by out_kernel at the end
  float* cost = out_m;

  fg_kernel<<<dim3((NQ + 255) / 256, NB), 256, 0, stream>>>(boxes, gtb, fgv);
  cls_kernel<<<dim3((NQ + 255) / 256, NC, NB), 256, 0, stream>>>(logits, cct);
  cost_kernel<<<dim3(NG, NB), 256, 0, stream>>>(boxes, gtb, labels, imgsz, cct, fgv, cost, mbits);
  rowcnt_kernel<<<(NB * NQ + 255) / 256, 256, 0, stream>>>(mbits, rcnt);
  multifix_kernel<<<(NB * NQ + 255) / 256, 256, 0, stream>>>(cost, mbits, rcnt, multi);
  colcov_kernel<<<(NB * NG + 255) / 256, 256, 0, stream>>>(mbits, ccov);
  loop_kernel<<<NB, 1024, 0, stream>>>(cost, mbits, rcnt, ccov, multi, pen);
  matched_kernel<<<dim3(NG, NB), 256, 0, stream>>>(cost, mbits, pen, out_mq);
  out_kernel<<<dim3(NQ, NB), 128, 0, stream>>>(mbits, out_m, out_sel, out_gti);
}

// Round 2
// 444.929 us; speedup vs baseline: 1.0188x; 1.0188x over previous
//
#include <hip/hip_runtime.h>
#include <float.h>
#include <stdint.h>
#include <stddef.h>

#define NB 16
#define NQ 4000
#define NG 300
#define NC 81
#define NQW 125  // NQ/32

__device__ __forceinline__ bool lexlt(float v1, int i1, float v2, int i2) {
  return (v1 < v2) || (v1 == v2 && i1 < i2);
}

// Exact replica of p sequential f32 adds of 1e5 (numpy semantics), in O(#binade crossings).
// Between power-of-2 boundaries the sum is exactly representable (value and 1e5 are both
// multiples of the current ulp <= 1), so only crossing steps round.
__device__ __forceinline__ float penalized(float v, int p) {
  if (p <= 0) return v;
  if (p <= 12) {
    float x = v;
    for (int r = 0; r < p; ++r) x += 100000.0f;
    return x;
  }
  double x = (double)v;
  x = (double)(float)(x + 100000.0);  // first add always rounds
  int k = 1;
  while (k < p) {
    double B = 131072.0;
    while (B <= x) B += B;            // next pow2 strictly above x
    double room = B - x;
    int j = (int)(room * 1e-5);
    while (j > 0 && x + (double)j * 100000.0 >= B) --j;
    if (j > p - k) j = p - k;
    if (j > 0) { x += (double)j * 100000.0; k += j; }  // exact, no rounding
    if (k < p) { x = (double)(float)(x + 100000.0); ++k; }  // crossing step rounds
  }
  return (float)x;
}

// ---------------- K1: prep — fg mask, normalized box, center/area, zero rcnt ----------------
__global__ void prep_kernel(const float* __restrict__ boxes, const float* __restrict__ gtb,
                            const float* __restrict__ imgsz,
                            float4* __restrict__ prepN, float4* __restrict__ prepM,
                            int* __restrict__ rcnt) {
#pragma clang fp contract(off)
  const int b = blockIdx.y;
  const int q = blockIdx.x * 256 + threadIdx.x;
  __shared__ float sg[NG * 4];
  for (int i = threadIdx.x; i < NG * 4; i += 256) sg[i] = gtb[b * NG * 4 + i];
  __syncthreads();
  if (q >= NQ) return;
  const float4 pb = reinterpret_cast<const float4*>(boxes)[b * NQ + q];
  const float s0 = imgsz[b*4+0], s1 = imgsz[b*4+1], s2 = imgsz[b*4+2], s3 = imgsz[b*4+3];
  const float ax = (pb.x + pb.z) * 0.5f;
  const float ay = (pb.y + pb.w) * 0.5f;
  bool anyb = false, anyc = false;
  for (int g = 0; g < NG; ++g) {
    const float gx0 = sg[g*4+0], gy0 = sg[g*4+1], gx1 = sg[g*4+2], gy1 = sg[g*4+3];
    const float gcx = (gx0 + gx1) * 0.5f, gcy = (gy0 + gy1) * 0.5f;
    const float gw0 = gx1 - gx0, gh0 = gy1 - gy0;
    const float xg0 = gcx - 0.5f*gw0, yg0 = gcy - 0.5f*gh0;
    const float xg1 = gcx + 0.5f*gw0, yg1 = gcy + 0.5f*gh0;
    anyb = anyb || ((ax > xg0) && (ax < xg1) && (ay > yg0) && (ay < yg1));
    const float cw = xg1 - xg0, ch = yg1 - yg0;
    anyc = anyc || ((ax > gcx - 2.5f*cw) && (ax < gcx + 2.5f*cw) &&
                    (ay > gcy - 2.5f*ch) && (ay < gcy + 2.5f*ch));
  }
  const int idx = b * NQ + q;
  prepN[idx] = make_float4(pb.x / s0, pb.y / s1, pb.z / s2, pb.w / s3);
  prepM[idx] = make_float4(ax, ay, (pb.z - pb.x) * (pb.w - pb.y),
                           (anyb || anyc) ? 0.f : 10000.f);
  rcnt[idx] = 0;
}

// ---------------- K2: focal class cost table, transposed (B,C,Q), tiled ----------------
#define QT 64
__global__ void cls_kernel(const float* __restrict__ logits, float* __restrict__ cct) {
#pragma clang fp contract(off)
  const int b = blockIdx.y, q0 = blockIdx.x * QT, t = threadIdx.x;
  __shared__ float tile[QT * NC];
  const int nq = (NQ - q0 < QT) ? (NQ - q0) : QT;
  const float* __restrict__ src = logits + ((size_t)(b * NQ + q0)) * NC;
  for (int i = t; i < nq * NC; i += 256) {
    const float x = src[i];
    float p;
    if (x >= 0.f) p = 1.f / (1.f + expf(-x));
    else { const float e = expf(x); p = e / (1.f + e); }
    const float pos = 0.25f * ((1.f - p) * (1.f - p)) * (-logf(p + 1e-8f));
    const float neg = 0.75f * (p * p) * (-logf(1.f - p + 1e-8f));
    tile[i] = pos - neg;
  }
  __syncthreads();
  for (int i = t; i < NC * QT; i += 256) {
    const int c = i >> 6;           // i / QT
    const int ql = i & (QT - 1);    // i % QT
    if (ql < nq) cct[((size_t)(b * NC + c)) * NQ + q0 + ql] = tile[ql * NC + c];
  }
}

// ---------------- K3: cost (B,G,Q) + per-column top5 (cost,iou) -> m bits + rcnt ----------------
__global__ __launch_bounds__(256) void cost_kernel(
    const float* __restrict__ boxes, const float4* __restrict__ prepN,
    const float4* __restrict__ prepM, const float* __restrict__ gtb,
    const int* __restrict__ labels, const float* __restrict__ imgsz,
    const float* __restrict__ cct, float* __restrict__ cost,
    unsigned* __restrict__ mbits, int* __restrict__ rcnt) {
#pragma clang fp contract(off)
  const int g = blockIdx.x, b = blockIdx.y, t = threadIdx.x;
  const float gx0 = gtb[(b*NG + g)*4 + 0];
  const float gy0 = gtb[(b*NG + g)*4 + 1];
  const float gx1 = gtb[(b*NG + g)*4 + 2];
  const float gy1 = gtb[(b*NG + g)*4 + 3];
  const int   lab = labels[b*NG + g];
  const float s0 = imgsz[b*4+0], s1 = imgsz[b*4+1], s2 = imgsz[b*4+2], s3 = imgsz[b*4+3];
  const float areaB = (gx1 - gx0) * (gy1 - gy0);
  const float ngx0 = gx0 / s0, ngy0 = gy0 / s1, ngx1 = gx1 / s2, ngy1 = gy1 / s3;
  const float gcx = (gx0 + gx1) * 0.5f, gcy = (gy0 + gy1) * 0.5f;
  const float gw0 = gx1 - gx0, gh0 = gy1 - gy0;
  const float xg0 = gcx - 0.5f*gw0, yg0 = gcy - 0.5f*gh0;
  const float xg1 = gcx + 0.5f*gw0, yg1 = gcy + 0.5f*gh0;
  const float cw = xg1 - xg0, ch = yg1 - yg0;
  const float cxlo = gcx - 2.5f*cw, cxhi = gcx + 2.5f*cw;
  const float cylo = gcy - 2.5f*ch, cyhi = gcy + 2.5f*ch;
  const float* __restrict__ ccls = cct + ((size_t)(b*NC + lab)) * NQ;
  float* __restrict__ crow = cost + ((size_t)(b*NG + g)) * NQ;
  unsigned* __restrict__ mrow = mbits + (b*NG + g) * NQW;
  for (int i = t; i < NQW; i += 256) mrow[i] = 0u;

  float tv[5]; int tq[5]; float sv[5];
#pragma unroll
  for (int i = 0; i < 5; ++i) { tv[i] = FLT_MAX; tq[i] = 0x7fffffff; sv[i] = -1.f; }

  for (int q = t; q < NQ; q += 256) {
    const float4 pb = reinterpret_cast<const float4*>(boxes)[b*NQ + q];
    const float4 nb = prepN[b*NQ + q];
    const float4 pm = prepM[b*NQ + q];
    const float areaA = pm.z;
    const float ltx = fmaxf(pb.x, gx0), lty = fmaxf(pb.y, gy0);
    const float rbx = fminf(pb.z, gx1), rby = fminf(pb.w, gy1);
    const float iw = fmaxf(rbx - ltx, 0.f), ih = fmaxf(rby - lty, 0.f);
    const float inter = iw * ih;
    const float uni = areaA + areaB - inter;
    const float iou = inter / uni;
    const float eltx = fminf(pb.x, gx0), elty = fminf(pb.y, gy0);
    const float erbx = fmaxf(pb.z, gx1), erby = fmaxf(pb.w, gy1);
    const float ew = fmaxf(erbx - eltx, 0.f), eh = fmaxf(erby - elty, 0.f);
    const float earea = ew * eh;
    const float giou = iou - (earea - uni) / earea;
    const float cbb = fabsf(nb.x - ngx0) + fabsf(nb.y - ngy0)
                    + fabsf(nb.z - ngx1) + fabsf(nb.w - ngy1);
    const bool inb = (pm.x > xg0) && (pm.x < xg1) && (pm.y > yg0) && (pm.y < yg1);
    const bool inc = (pm.x > cxlo) && (pm.x < cxhi) && (pm.y > cylo) && (pm.y < cyhi);
    const bool ibc = inb && inc;
    float cval = 5.0f * cbb + 2.0f * ccls[q];
    cval = cval + 2.0f * (-giou);
    cval = cval + (ibc ? 0.f : 100.f);
    cval = cval + pm.w;
    crow[q] = cval;
    if (iou > sv[4]) {
      sv[4] = iou;
#pragma unroll
      for (int j = 4; j >= 1; --j)
        if (sv[j] > sv[j-1]) { const float tmp = sv[j]; sv[j] = sv[j-1]; sv[j-1] = tmp; }
    }
    if (lexlt(cval, q, tv[4], tq[4])) {
      tv[4] = cval; tq[4] = q;
#pragma unroll
      for (int j = 4; j >= 1; --j)
        if (lexlt(tv[j], tq[j], tv[j-1], tq[j-1])) {
          const float tf = tv[j]; tv[j] = tv[j-1]; tv[j-1] = tf;
          const int ti = tq[j]; tq[j] = tq[j-1]; tq[j-1] = ti;
        }
    }
  }

  // in-register wave merge (6 shuffle rounds, no barriers); lane0 of each wave valid
#pragma unroll
  for (int off = 32; off >= 1; off >>= 1) {
    float pv[5]; int pq[5]; float pi[5];
#pragma unroll
    for (int i = 0; i < 5; ++i) {
      pv[i] = __shfl_down(tv[i], off);
      pq[i] = __shfl_down(tq[i], off);
      pi[i] = __shfl_down(sv[i], off);
    }
#pragma unroll
    for (int i = 0; i < 5; ++i) {
      if (lexlt(pv[i], pq[i], tv[4], tq[4])) {
        tv[4] = pv[i]; tq[4] = pq[i];
#pragma unroll
        for (int j = 4; j >= 1; --j)
          if (lexlt(tv[j], tq[j], tv[j-1], tq[j-1])) {
            const float tf = tv[j]; tv[j] = tv[j-1]; tv[j-1] = tf;
            const int ti = tq[j]; tq[j] = tq[j-1]; tq[j-1] = ti;
          }
      }
      if (pi[i] > sv[4]) {
        sv[4] = pi[i];
#pragma unroll
        for (int j = 4; j >= 1; --j)
          if (sv[j] > sv[j-1]) { const float tmp = sv[j]; sv[j] = sv[j-1]; sv[j-1] = tmp; }
      }
    }
  }

  __shared__ float Wv[4*5];
  __shared__ int   Wq[4*5];
  __shared__ float Wi[4*5];
  const int lane = t & 63, wave = t >> 6;
  if (lane == 0) {
#pragma unroll
    for (int i = 0; i < 5; ++i) { Wv[wave*5+i] = tv[i]; Wq[wave*5+i] = tq[i]; Wi[wave*5+i] = sv[i]; }
  }
  __syncthreads();
  if (t == 0) {
    // top-5 iou sum (selection over 20, descending)
    float s = 0.f;
    for (int k = 0; k < 5; ++k) {
      float bestv = -2.f; int bi = 0;
      for (int i = 0; i < 20; ++i) if (Wi[i] > bestv) { bestv = Wi[i]; bi = i; }
      Wi[bi] = -2.f;
      s += bestv;
    }
    int k = (int)s; if (k < 1) k = 1; if (k > 5) k = 5;
    // top-k (cost,q) lex selection over 20
    for (int i = 0; i < k; ++i) {
      float bestv = FLT_MAX; int bestq = 0x7fffffff; int bi = 0;
      for (int j = 0; j < 20; ++j)
        if (lexlt(Wv[j], Wq[j], bestv, bestq)) { bestv = Wv[j]; bestq = Wq[j]; bi = j; }
      Wv[bi] = FLT_MAX; Wq[bi] = 0x7fffffff;
      mrow[bestq >> 5] |= 1u << (bestq & 31);
      atomicAdd(&rcnt[b * NQ + bestq], 1);
    }
  }
}

// ---------------- K5: initial multi fix (row -> one_hot(argmin_g cost)) ----------------
__global__ void multifix_kernel(const float* __restrict__ cost, unsigned* __restrict__ mbits,
                                int* __restrict__ rcnt, int* __restrict__ multi) {
  const int idx = blockIdx.x * 256 + threadIdx.x;
  if (idx >= NB * NQ) return;
  const int b = idx / NQ, q = idx % NQ;
  if (rcnt[idx] <= 1) { multi[idx] = 0; return; }
  multi[idx] = 1;
  const float* cc = cost + (size_t)b * NG * NQ + q;
  float best = FLT_MAX; int bg = 0;
  for (int g = 0; g < NG; ++g) {
    const float v = cc[(size_t)g * NQ];
    if (v < best) { best = v; bg = g; }
  }
  unsigned* base = mbits + b * NG * NQW + (q >> 5);
  const unsigned bit = 1u << (q & 31);
  for (int g = 0; g < NG; ++g) {
    const unsigned w = base[g * NQW];
    const bool mine = (w & bit) != 0;
    if (g == bg) { if (!mine) atomicOr(&base[g * NQW], bit); }
    else if (mine) atomicAnd(&base[g * NQW], ~bit);
  }
  rcnt[idx] = 1;
}

// ---------------- K6: column coverage counts ----------------
__global__ void colcov_kernel(const unsigned* __restrict__ mbits, int* __restrict__ ccov) {
  const int idx = blockIdx.x * 256 + threadIdx.x;
  if (idx >= NB * NG) return;
  const unsigned* row = mbits + idx * NQW;
  int c = 0;
  for (int i = 0; i < NQW; ++i) c += __popc(row[i]);
  ccov[idx] = c;
}

// ---------------- K7: the while-loop, one persistent block per image ----------------
// Key invariant: rows never assigned keep pen==0 forever, and >=2500 of 4000 rows are never
// assigned (sum dyn_k <= 1500). Penalized values are >= 99989 > max raw cost (~10400), so the
// per-column argmin is always achieved among pen==0 rows at RAW cost — no replay needed there.
__global__ __launch_bounds__(1024) void loop_kernel(
    const float* __restrict__ cost, unsigned* __restrict__ mbits,
    const int* __restrict__ rcnt_g, const int* __restrict__ ccov_g,
    const int* __restrict__ multi_g, int* __restrict__ pen_g) {
  const int b = blockIdx.x, t = threadIdx.x;
  __shared__ int s_pen[NQ];
  __shared__ int s_rcnt[NQ];
  __shared__ unsigned char s_multi[NQ];
  __shared__ int s_ccov[NG];
  __shared__ int s_unc[NG];
  __shared__ int s_pickq[NG];
  __shared__ int s_mq[800];   // multi rows <= sum(dyn_k)/2 <= 750
  __shared__ int s_mn, s_n, s_fix, s_sticky;

  for (int q = t; q < NQ; q += 1024) {
    s_pen[q] = 0;
    s_rcnt[q] = rcnt_g[b * NQ + q];
    s_multi[q] = (unsigned char)multi_g[b * NQ + q];
  }
  for (int g = t; g < NG; g += 1024) s_ccov[g] = ccov_g[b * NG + g];
  if (t == 0) { s_sticky = 0; s_mn = 0; }
  __syncthreads();
  for (int q = t; q < NQ; q += 1024)
    if (s_multi[q]) { const int i = atomicAdd(&s_mn, 1); s_mq[i] = q; }
  __syncthreads();

  unsigned* __restrict__ mb = mbits + b * NG * NQW;
  const float* __restrict__ cb = cost + (size_t)b * NG * NQ;
  const int lane = t & 63, wave = t >> 6;
  const int m_n = s_mn;

  for (int iter = 0; iter < 100; ++iter) {
    if (t == 0) { s_n = 0; s_fix = s_sticky; }
    __syncthreads();
    for (int g = t; g < NG; g += 1024)
      if (s_ccov[g] == 0) { const int i = atomicAdd(&s_n, 1); s_unc[i] = g; }
    __syncthreads();
    const int n = s_n;
    if (n == 0) break;
    for (int q = t; q < NQ; q += 1024)
      if (s_rcnt[q] > 0) s_pen[q]++;
    __syncthreads();
    // argmin_q per uncovered column — pen==0 rows only, raw cost (exact; see invariant)
    for (int ci = wave; ci < n; ci += 16) {
      const int g = s_unc[ci];
      const float* __restrict__ crow = cb + (size_t)g * NQ;
      float best = FLT_MAX; int bq = 0x7fffffff;
      for (int q = lane; q < NQ; q += 64) {
        if (s_pen[q] == 0) {
          const float v = crow[q];
          if (v < best) { best = v; bq = q; }
        }
      }
      for (int off = 32; off; off >>= 1) {
        const float ov = __shfl_down(best, off);
        const int oq = __shfl_down(bq, off);
        if (ov < best || (ov == best && oq < bq)) { best = ov; bq = oq; }
      }
      if (lane == 0) s_pickq[ci] = bq;
    }
    __syncthreads();
    if (t < n) {
      const int g = s_unc[t], q = s_pickq[t];
      atomicOr(&mb[g * NQW + (q >> 5)], 1u << (q & 31));
      const int nc = atomicAdd(&s_rcnt[q], 1) + 1;
      s_ccov[g] = 1;
      if (nc > 1) { s_fix = 1; if (!s_multi[q]) s_sticky = 1; }
    }
    __syncthreads();
    if (s_fix) {
      for (int mi = wave; mi < m_n; mi += 16) {
        const int q = s_mq[mi];
        const int p = s_pen[q];
        const float* __restrict__ base = cb + q;
        float best = FLT_MAX; int bg = 0;
        for (int g = lane; g < NG; g += 64) {
          const float v = penalized(base[(size_t)g * NQ], p);
          if (v < best) { best = v; bg = g; }
        }
        for (int off = 32; off; off >>= 1) {
          const float ov = __shfl_down(best, off);
          const int og = __shfl_down(bg, off);
          if (ov < best || (ov == best && og < bg)) { best = ov; bg = og; }
        }
        bg = __shfl(bg, 0);
        const unsigned bit = 1u << (q & 31);
        const int wofs = q >> 5;
        for (int g = lane; g < NG; g += 64) {
          const unsigned w = mb[g * NQW + wofs];
          const bool cur = (w & bit) != 0;
          const bool want = (g == bg);
          if (cur != want) {
            if (want) { atomicOr(&mb[g * NQW + wofs], bit); atomicAdd(&s_ccov[g], 1); }
            else      { atomicAnd(&mb[g * NQW + wofs], ~bit); atomicSub(&s_ccov[g], 1); }
          }
        }
        if (lane == 0) s_rcnt[q] = 1;
      }
    }
    __syncthreads();
  }
  for (int q = t; q < NQ; q += 1024) pen_g[b * NQ + q] = s_pen[q];
}

// ---------------- K8: matched_qidx ----------------
__global__ void matched_kernel(const float* __restrict__ cost, const unsigned* __restrict__ mbits,
                               const int* __restrict__ pen_g, float* __restrict__ out_mq) {
  const int g = blockIdx.x, b = blockIdx.y, t = threadIdx.x;
  const float* __restrict__ crow = cost + ((size_t)(b*NG + g)) * NQ;
  const unsigned* __restrict__ mrow = mbits + (b*NG + g) * NQW;
  const int* __restrict__ pb = pen_g + b * NQ;
  float best = FLT_MAX; int bq = 0;
  for (int q = t; q < NQ; q += 256) {
    if ((mrow[q >> 5] >> (q & 31)) & 1u) {
      const float v = penalized(crow[q], pb[q]);
      if (v < best) { best = v; bq = q; }
    }
  }
  __shared__ float rv[256];
  __shared__ int rq[256];
  rv[t] = best; rq[t] = bq;
  __syncthreads();
  for (int off = 128; off; off >>= 1) {
    if (t < off) {
      if (lexlt(rv[t + off], rq[t + off], rv[t], rq[t])) { rv[t] = rv[t + off]; rq[t] = rq[t + off]; }
    }
    __syncthreads();
  }
  if (t == 0) out_mq[b * NG + g] = (float)rq[0];
}

// ---------------- K9: expand bits -> m floats, selected, gt_idx ----------------
__global__ void out_kernel(const unsigned* __restrict__ mbits, float* __restrict__ out_m,
                           float* __restrict__ out_sel, float* __restrict__ out_gti) {
  const int qw = blockIdx.x;   // 0..NQW-1, covers 32 q each
  const int b = blockIdx.y, t = threadIdx.x;
  __shared__ unsigned w[NG];
  for (int g = t; g < NG; g += 256) w[g] = mbits[(b*NG + g) * NQW + qw];
  __syncthreads();
  const int qbase = qw * 32;
  float* __restrict__ om = out_m + ((size_t)(b * NQ + qbase)) * NG;
  for (int idx = t; idx < 32 * NG; idx += 256) {
    const int qi = idx / NG, g = idx - qi * NG;
    om[idx] = ((w[g] >> qi) & 1u) ? 1.f : 0.f;
  }
  if (t < 32) {
    int fgi = -1;
    for (int g = 0; g < NG; ++g) if ((w[g] >> t) & 1u) { fgi = g; break; }
    out_sel[b * NQ + qbase + t] = (fgi >= 0) ? 1.f : 0.f;
    out_gti[b * NQ + qbase + t] = (fgi >= 0) ? (float)fgi : 0.f;
  }
}

extern "C" void kernel_launch(void* const* d_in, const int* in_sizes, int n_in,
                              void* d_out, int out_size, void* d_ws, size_t ws_size,
                              hipStream_t stream) {
  const float* logits = (const float*)d_in[0];
  const float* boxes  = (const float*)d_in[1];
  const int*   labels = (const int*)d_in[2];
  const float* gtb    = (const float*)d_in[3];
  const float* imgsz  = (const float*)d_in[4];

  float* out = (float*)d_out;
  float* out_m   = out;                                   // B*Q*G
  float* out_sel = out + (size_t)NB * NQ * NG;            // B*Q
  float* out_gti = out_sel + (size_t)NB * NQ;             // B*Q
  float* out_mq  = out_gti + (size_t)NB * NQ;             // B*G

  char* w = (char*)d_ws;
  const size_t szPrep = sizeof(float4) * (size_t)NB * NQ;
  const size_t szCct  = sizeof(float) * (size_t)NB * NC * NQ;
  const size_t szBits = sizeof(unsigned) * (size_t)NB * NG * NQW;
  const size_t szIntQ = sizeof(int) * (size_t)NB * NQ;
  const size_t szIntG = sizeof(int) * (size_t)NB * NG;
  const size_t need = 2*szPrep + szCct + szBits + 3*szIntQ + szIntG;
  if (ws_size < need) return;
  float4* prepN = (float4*)w; w += szPrep;
  float4* prepM = (float4*)w; w += szPrep;
  float*    cct   = (float*)w;    w += szCct;
  unsigned* mbits = (unsigned*)w; w += szBits;
  int* rcnt  = (int*)w; w += szIntQ;
  int* multi = (int*)w; w += szIntQ;
  int* pen   = (int*)w; w += szIntQ;
  int* ccov  = (int*)w; w += szIntG;

  // cost matrix (B,G,Q) lives in the d_out m-region; overwritten by out_kernel at the end
  float* cost = out_m;

  prep_kernel<<<dim3((NQ + 255) / 256, NB), 256, 0, stream>>>(boxes, gtb, imgsz, prepN, prepM, rcnt);
  cls_kernel<<<dim3((NQ + QT - 1) / QT, NB), 256, 0, stream>>>(logits, cct);
  cost_kernel<<<dim3(NG, NB), 256, 0, stream>>>(boxes, prepN, prepM, gtb, labels, imgsz, cct, cost, mbits, rcnt);
  multifix_kernel<<<(NB * NQ + 255) / 256, 256, 0, stream>>>(cost, mbits, rcnt, multi);
  colcov_kernel<<<(NB * NG + 255) / 256, 256, 0, stream>>>(mbits, ccov);
  loop_kernel<<<NB, 1024, 0, stream>>>(cost, mbits, rcnt, ccov, multi, pen);
  matched_kernel<<<dim3(NG, NB), 256, 0, stream>>>(cost, mbits, pen, out_mq);
  out_kernel<<<dim3(NQW, NB), 256, 0, stream>>>(mbits, out_m, out_sel, out_gti);
}

// Round 3
// 427.265 us; speedup vs baseline: 1.0609x; 1.0413x over previous
//
#include <hip/hip_runtime.h>
#include <float.h>
#include <stdint.h>
#include <stddef.h>

#define NB 16
#define NQ 4000
#define NG 300
#define NC 81
#define NQW 125  // NQ/32
#define GSPLIT 4
#define GCHUNK 75   // NG / GSPLIT
#define GSUB 15     // transpose tile width; GCHUNK = 5*GSUB

__device__ __forceinline__ bool lexlt(float v1, int i1, float v2, int i2) {
  return (v1 < v2) || (v1 == v2 && i1 < i2);
}

// Exact replica of p sequential f32 adds of 1e5 (numpy semantics), in O(#binade crossings).
__device__ __forceinline__ float penalized(float v, int p) {
  if (p <= 0) return v;
  if (p <= 12) {
    float x = v;
    for (int r = 0; r < p; ++r) x += 100000.0f;
    return x;
  }
  double x = (double)v;
  x = (double)(float)(x + 100000.0);
  int k = 1;
  while (k < p) {
    double B = 131072.0;
    while (B <= x) B += B;
    double room = B - x;
    int j = (int)(room * 1e-5);
    while (j > 0 && x + (double)j * 100000.0 >= B) --j;
    if (j > p - k) j = p - k;
    if (j > 0) { x += (double)j * 100000.0; k += j; }
    if (k < p) { x = (double)(float)(x + 100000.0); ++k; }
  }
  return (float)x;
}

// ---------------- K1: prep — fg mask, normalized box, center/area, zero rcnt ----------------
__global__ void prep_kernel(const float* __restrict__ boxes, const float* __restrict__ gtb,
                            const float* __restrict__ imgsz,
                            float4* __restrict__ prepN, float4* __restrict__ prepM,
                            int* __restrict__ rcnt) {
#pragma clang fp contract(off)
  const int b = blockIdx.y;
  const int q = blockIdx.x * 256 + threadIdx.x;
  __shared__ float sg[NG * 4];
  for (int i = threadIdx.x; i < NG * 4; i += 256) sg[i] = gtb[b * NG * 4 + i];
  __syncthreads();
  if (q >= NQ) return;
  const float4 pb = reinterpret_cast<const float4*>(boxes)[b * NQ + q];
  const float s0 = imgsz[b*4+0], s1 = imgsz[b*4+1], s2 = imgsz[b*4+2], s3 = imgsz[b*4+3];
  const float ax = (pb.x + pb.z) * 0.5f;
  const float ay = (pb.y + pb.w) * 0.5f;
  bool anyb = false, anyc = false;
  for (int g = 0; g < NG; ++g) {
    const float gx0 = sg[g*4+0], gy0 = sg[g*4+1], gx1 = sg[g*4+2], gy1 = sg[g*4+3];
    const float gcx = (gx0 + gx1) * 0.5f, gcy = (gy0 + gy1) * 0.5f;
    const float gw0 = gx1 - gx0, gh0 = gy1 - gy0;
    const float xg0 = gcx - 0.5f*gw0, yg0 = gcy - 0.5f*gh0;
    const float xg1 = gcx + 0.5f*gw0, yg1 = gcy + 0.5f*gh0;
    anyb = anyb || ((ax > xg0) && (ax < xg1) && (ay > yg0) && (ay < yg1));
    const float cw = xg1 - xg0, ch = yg1 - yg0;
    anyc = anyc || ((ax > gcx - 2.5f*cw) && (ax < gcx + 2.5f*cw) &&
                    (ay > gcy - 2.5f*ch) && (ay < gcy + 2.5f*ch));
  }
  const int idx = b * NQ + q;
  prepN[idx] = make_float4(pb.x / s0, pb.y / s1, pb.z / s2, pb.w / s3);
  prepM[idx] = make_float4(ax, ay, (pb.z - pb.x) * (pb.w - pb.y),
                           (anyb || anyc) ? 0.f : 10000.f);
  rcnt[idx] = 0;
}

// ---------------- K1b: per-gt derived params (computed once, broadcast later) ----------------
// layout per (b,g): 5 float4s:
//  [0] xg0,yg0,xg1,yg1  (fp-roundtripped box)   [1] cxlo,cxhi,cylo,cyhi
//  [2] ngx0,ngy0,ngx1,ngy1                      [3] gx0,gy0,gx1,gy1 (original)
//  [4] areaB, lab(bits), 0, 0
__global__ void gprep_kernel(const float* __restrict__ gtb, const int* __restrict__ labels,
                             const float* __restrict__ imgsz, float4* __restrict__ gp) {
#pragma clang fp contract(off)
  const int idx = blockIdx.x * 256 + threadIdx.x;
  if (idx >= NB * NG) return;
  const int b = idx / NG;
  const float gx0 = gtb[idx*4 + 0];
  const float gy0 = gtb[idx*4 + 1];
  const float gx1 = gtb[idx*4 + 2];
  const float gy1 = gtb[idx*4 + 3];
  const float s0 = imgsz[b*4+0], s1 = imgsz[b*4+1], s2 = imgsz[b*4+2], s3 = imgsz[b*4+3];
  const float areaB = (gx1 - gx0) * (gy1 - gy0);
  const float gcx = (gx0 + gx1) * 0.5f, gcy = (gy0 + gy1) * 0.5f;
  const float gw0 = gx1 - gx0, gh0 = gy1 - gy0;
  const float xg0 = gcx - 0.5f*gw0, yg0 = gcy - 0.5f*gh0;
  const float xg1 = gcx + 0.5f*gw0, yg1 = gcy + 0.5f*gh0;
  const float cw = xg1 - xg0, ch = yg1 - yg0;
  gp[idx*5+0] = make_float4(xg0, yg0, xg1, yg1);
  gp[idx*5+1] = make_float4(gcx - 2.5f*cw, gcx + 2.5f*cw, gcy - 2.5f*ch, gcy + 2.5f*ch);
  gp[idx*5+2] = make_float4(gx0 / s0, gy0 / s1, gx1 / s2, gy1 / s3);
  gp[idx*5+3] = make_float4(gx0, gy0, gx1, gy1);
  gp[idx*5+4] = make_float4(areaB, __int_as_float(labels[idx]), 0.f, 0.f);
}

// ---------------- K2: focal class cost table, transposed (B,C,Q), tiled ----------------
#define QT 64
__global__ void cls_kernel(const float* __restrict__ logits, float* __restrict__ cct) {
#pragma clang fp contract(off)
  const int b = blockIdx.y, q0 = blockIdx.x * QT, t = threadIdx.x;
  __shared__ float tile[QT * NC];
  const int nq = (NQ - q0 < QT) ? (NQ - q0) : QT;
  const float* __restrict__ src = logits + ((size_t)(b * NQ + q0)) * NC;
  for (int i = t; i < nq * NC; i += 256) {
    const float x = src[i];
    float p;
    if (x >= 0.f) p = 1.f / (1.f + expf(-x));
    else { const float e = expf(x); p = e / (1.f + e); }
    const float pos = 0.25f * ((1.f - p) * (1.f - p)) * (-logf(p + 1e-8f));
    const float neg = 0.75f * (p * p) * (-logf(1.f - p + 1e-8f));
    tile[i] = pos - neg;
  }
  __syncthreads();
  for (int i = t; i < NC * QT; i += 256) {
    const int c = i >> 6;
    const int ql = i & (QT - 1);
    if (ql < nq) cct[((size_t)(b * NC + c)) * NQ + q0 + ql] = tile[ql * NC + c];
  }
}

// ---------------- K3a: featurize — q-resident registers, loop over g ----------------
template<int USET>
__global__ __launch_bounds__(256) void costA_kernel(
    const float* __restrict__ boxes, const float4* __restrict__ prepN,
    const float4* __restrict__ prepM, const float4* __restrict__ gp,
    const float* __restrict__ cct, float* __restrict__ cost, float* __restrict__ costT) {
#pragma clang fp contract(off)
  const int b = blockIdx.z, t = threadIdx.x;
  const int q0 = blockIdx.x * 256, gl0 = blockIdx.y * GCHUNK;
  __shared__ float4 sgp[GCHUNK * 5];
  __shared__ float tile[USET ? 256 * GSUB : 1];
  for (int i = t; i < GCHUNK * 5; i += 256) sgp[i] = gp[(size_t)(b*NG + gl0) * 5 + i];
  const int q = q0 + t;
  const bool qv = q < NQ;
  float4 pb = make_float4(0.f, 0.f, 1.f, 1.f);
  float4 nb = make_float4(0.f, 0.f, 0.f, 0.f);
  float4 pm = make_float4(0.f, 0.f, 1.f, 0.f);
  if (qv) {
    pb = reinterpret_cast<const float4*>(boxes)[b*NQ + q];
    nb = prepN[b*NQ + q];
    pm = prepM[b*NQ + q];
  }
  const float areaA = pm.z;
  __syncthreads();
  for (int c = 0; c < GCHUNK / GSUB; ++c) {
    for (int gg = 0; gg < GSUB; ++gg) {
      const int gi = c * GSUB + gg, g = gl0 + gi;
      const float4 A0 = sgp[gi*5+0];
      const float4 A1 = sgp[gi*5+1];
      const float4 A2 = sgp[gi*5+2];
      const float4 A3 = sgp[gi*5+3];
      const float4 A4 = sgp[gi*5+4];
      const int lab = __float_as_int(A4.y);
      const float ccls = qv ? cct[((size_t)(b*NC + lab)) * NQ + q] : 0.f;
      // iou / giou (identical op order to verified version)
      const float ltx = fmaxf(pb.x, A3.x), lty = fmaxf(pb.y, A3.y);
      const float rbx = fminf(pb.z, A3.z), rby = fminf(pb.w, A3.w);
      const float iw = fmaxf(rbx - ltx, 0.f), ih = fmaxf(rby - lty, 0.f);
      const float inter = iw * ih;
      const float uni = areaA + A4.x - inter;
      const float iou = inter / uni;
      const float eltx = fminf(pb.x, A3.x), elty = fminf(pb.y, A3.y);
      const float erbx = fmaxf(pb.z, A3.z), erby = fmaxf(pb.w, A3.w);
      const float ew = fmaxf(erbx - eltx, 0.f), eh = fmaxf(erby - elty, 0.f);
      const float earea = ew * eh;
      const float giou = iou - (earea - uni) / earea;
      const float cbb = fabsf(nb.x - A2.x) + fabsf(nb.y - A2.y)
                      + fabsf(nb.z - A2.z) + fabsf(nb.w - A2.w);
      const bool inb = (pm.x > A0.x) && (pm.x < A0.z) && (pm.y > A0.y) && (pm.y < A0.w);
      const bool inc = (pm.x > A1.x) && (pm.x < A1.y) && (pm.y > A1.z) && (pm.y < A1.w);
      const bool ibc = inb && inc;
      float cval = 5.0f * cbb + 2.0f * ccls;
      cval = cval + 2.0f * (-giou);
      cval = cval + (ibc ? 0.f : 100.f);
      cval = cval + pm.w;
      if (qv) cost[((size_t)(b*NG + g)) * NQ + q] = cval;
      if (USET) tile[t * GSUB + gg] = cval;
    }
    if (USET) {
      __syncthreads();
      for (int i = t; i < 256 * GSUB; i += 256) {
        const int qq = i / GSUB, gg2 = i - qq * GSUB;
        if (q0 + qq < NQ)
          costT[((size_t)(b*NQ + q0 + qq)) * NG + gl0 + c * GSUB + gg2] = tile[qq * GSUB + gg2];
      }
      __syncthreads();
    }
  }
}

// ---------------- K3b: per-(b,g) top-5 (cost,q) + top-5 iou -> dyn_k, m bits, rcnt ----------------
__global__ __launch_bounds__(64) void topk_kernel(
    const float* __restrict__ boxes, const float4* __restrict__ gp,
    const float* __restrict__ cost, unsigned* __restrict__ mbits, int* __restrict__ rcnt) {
#pragma clang fp contract(off)
  const int g = blockIdx.x, b = blockIdx.y, lane = threadIdx.x;
  const float4 A3 = gp[(size_t)(b*NG + g) * 5 + 3];
  const float areaB = gp[(size_t)(b*NG + g) * 5 + 4].x;
  const float* __restrict__ crow = cost + ((size_t)(b*NG + g)) * NQ;
  unsigned* __restrict__ mrow = mbits + (b*NG + g) * NQW;
  for (int i = lane; i < NQW; i += 64) mrow[i] = 0u;

  float tv[5]; int tq[5]; float sv[5];
#pragma unroll
  for (int i = 0; i < 5; ++i) { tv[i] = FLT_MAX; tq[i] = 0x7fffffff; sv[i] = -1.f; }

  for (int q = lane; q < NQ; q += 64) {
    const float cval = crow[q];
    const float4 pb = reinterpret_cast<const float4*>(boxes)[b*NQ + q];
    const float areaA = (pb.z - pb.x) * (pb.w - pb.y);
    const float ltx = fmaxf(pb.x, A3.x), lty = fmaxf(pb.y, A3.y);
    const float rbx = fminf(pb.z, A3.z), rby = fminf(pb.w, A3.w);
    const float iw = fmaxf(rbx - ltx, 0.f), ih = fmaxf(rby - lty, 0.f);
    const float inter = iw * ih;
    const float uni = areaA + areaB - inter;
    const float iou = inter / uni;
    if (iou > sv[4]) {
      sv[4] = iou;
#pragma unroll
      for (int j = 4; j >= 1; --j)
        if (sv[j] > sv[j-1]) { const float tmp = sv[j]; sv[j] = sv[j-1]; sv[j-1] = tmp; }
    }
    if (lexlt(cval, q, tv[4], tq[4])) {
      tv[4] = cval; tq[4] = q;
#pragma unroll
      for (int j = 4; j >= 1; --j)
        if (lexlt(tv[j], tq[j], tv[j-1], tq[j-1])) {
          const float tf = tv[j]; tv[j] = tv[j-1]; tv[j-1] = tf;
          const int ti = tq[j]; tq[j] = tq[j-1]; tq[j-1] = ti;
        }
    }
  }

#pragma unroll
  for (int off = 32; off >= 1; off >>= 1) {
    float pv[5]; int pq[5]; float pi[5];
#pragma unroll
    for (int i = 0; i < 5; ++i) {
      pv[i] = __shfl_down(tv[i], off);
      pq[i] = __shfl_down(tq[i], off);
      pi[i] = __shfl_down(sv[i], off);
    }
#pragma unroll
    for (int i = 0; i < 5; ++i) {
      if (lexlt(pv[i], pq[i], tv[4], tq[4])) {
        tv[4] = pv[i]; tq[4] = pq[i];
#pragma unroll
        for (int j = 4; j >= 1; --j)
          if (lexlt(tv[j], tq[j], tv[j-1], tq[j-1])) {
            const float tf = tv[j]; tv[j] = tv[j-1]; tv[j-1] = tf;
            const int ti = tq[j]; tq[j] = tq[j-1]; tq[j-1] = ti;
          }
      }
      if (pi[i] > sv[4]) {
        sv[4] = pi[i];
#pragma unroll
        for (int j = 4; j >= 1; --j)
          if (sv[j] > sv[j-1]) { const float tmp = sv[j]; sv[j] = sv[j-1]; sv[j-1] = tmp; }
      }
    }
  }
  __syncthreads();  // drain mrow clears before lane0's read-modify-write
  if (lane == 0) {
    float s = sv[0]; s += sv[1]; s += sv[2]; s += sv[3]; s += sv[4];  // descending order
    int k = (int)s; if (k < 1) k = 1; if (k > 5) k = 5;
    for (int i = 0; i < k; ++i) {
      const int q = tq[i];
      mrow[q >> 5] |= 1u << (q & 31);
      atomicAdd(&rcnt[b * NQ + q], 1);
    }
  }
}

// ---------------- K5: initial multi fix (row -> one_hot(argmin_g cost)) ----------------
__global__ void multifix_kernel(const float* __restrict__ cost, const float* __restrict__ costT,
                                int useT, unsigned* __restrict__ mbits,
                                int* __restrict__ rcnt, int* __restrict__ multi) {
  const int idx = blockIdx.x * 256 + threadIdx.x;
  if (idx >= NB * NQ) return;
  const int b = idx / NQ, q = idx % NQ;
  if (rcnt[idx] <= 1) { multi[idx] = 0; return; }
  multi[idx] = 1;
  float best = FLT_MAX; int bg = 0;
  if (useT) {
    const float* __restrict__ r = costT + ((size_t)(b*NQ + q)) * NG;
    for (int g = 0; g < NG; ++g) {
      const float v = r[g];
      if (v < best) { best = v; bg = g; }
    }
  } else {
    const float* cc = cost + (size_t)b * NG * NQ + q;
    for (int g = 0; g < NG; ++g) {
      const float v = cc[(size_t)g * NQ];
      if (v < best) { best = v; bg = g; }
    }
  }
  unsigned* base = mbits + b * NG * NQW + (q >> 5);
  const unsigned bit = 1u << (q & 31);
  for (int g = 0; g < NG; ++g) {
    const unsigned w = base[g * NQW];
    const bool mine = (w & bit) != 0;
    if (g == bg) { if (!mine) atomicOr(&base[g * NQW], bit); }
    else if (mine) atomicAnd(&base[g * NQW], ~bit);
  }
  rcnt[idx] = 1;
}

// ---------------- K6: column coverage counts ----------------
__global__ void colcov_kernel(const unsigned* __restrict__ mbits, int* __restrict__ ccov) {
  const int idx = blockIdx.x * 256 + threadIdx.x;
  if (idx >= NB * NG) return;
  const unsigned* row = mbits + idx * NQW;
  int c = 0;
  for (int i = 0; i < NQW; ++i) c += __popc(row[i]);
  ccov[idx] = c;
}

// ---------------- K7: the while-loop, one persistent block per image ----------------
__global__ __launch_bounds__(1024) void loop_kernel(
    const float* __restrict__ cost, const float* __restrict__ costT, int useT,
    unsigned* __restrict__ mbits,
    const int* __restrict__ rcnt_g, const int* __restrict__ ccov_g,
    const int* __restrict__ multi_g, int* __restrict__ pen_g) {
  const int b = blockIdx.x, t = threadIdx.x;
  __shared__ int s_pen[NQ];
  __shared__ int s_rcnt[NQ];
  __shared__ unsigned char s_multi[NQ];
  __shared__ int s_ccov[NG];
  __shared__ int s_unc[NG];
  __shared__ int s_pickq[NG];
  __shared__ int s_mq[800];
  __shared__ int s_mn, s_n, s_fix, s_sticky;

  for (int q = t; q < NQ; q += 1024) {
    s_pen[q] = 0;
    s_rcnt[q] = rcnt_g[b * NQ + q];
    s_multi[q] = (unsigned char)multi_g[b * NQ + q];
  }
  for (int g = t; g < NG; g += 1024) s_ccov[g] = ccov_g[b * NG + g];
  if (t == 0) { s_sticky = 0; s_mn = 0; }
  __syncthreads();
  for (int q = t; q < NQ; q += 1024)
    if (s_multi[q]) { const int i = atomicAdd(&s_mn, 1); s_mq[i] = q; }
  __syncthreads();

  unsigned* __restrict__ mb = mbits + b * NG * NQW;
  const float* __restrict__ cb = cost + (size_t)b * NG * NQ;
  const int lane = t & 63, wave = t >> 6;
  const int m_n = s_mn;

  for (int iter = 0; iter < 100; ++iter) {
    if (t == 0) { s_n = 0; s_fix = s_sticky; }
    __syncthreads();
    for (int g = t; g < NG; g += 1024)
      if (s_ccov[g] == 0) { const int i = atomicAdd(&s_n, 1); s_unc[i] = g; }
    __syncthreads();
    const int n = s_n;
    if (n == 0) break;
    for (int q = t; q < NQ; q += 1024)
      if (s_rcnt[q] > 0) s_pen[q]++;
    __syncthreads();
    // argmin_q per uncovered column — pen==0 rows only, raw cost (exact; penalty >= 99989 > max raw ~10160)
    for (int ci = wave; ci < n; ci += 16) {
      const int g = s_unc[ci];
      const float* __restrict__ crow = cb + (size_t)g * NQ;
      float best = FLT_MAX; int bq = 0x7fffffff;
      for (int q = lane; q < NQ; q += 64) {
        if (s_pen[q] == 0) {
          const float v = crow[q];
          if (v < best) { best = v; bq = q; }
        }
      }
      for (int off = 32; off; off >>= 1) {
        const float ov = __shfl_down(best, off);
        const int oq = __shfl_down(bq, off);
        if (ov < best || (ov == best && oq < bq)) { best = ov; bq = oq; }
      }
      if (lane == 0) s_pickq[ci] = bq;
    }
    __syncthreads();
    if (t < n) {
      const int g = s_unc[t], q = s_pickq[t];
      atomicOr(&mb[g * NQW + (q >> 5)], 1u << (q & 31));
      const int nc = atomicAdd(&s_rcnt[q], 1) + 1;
      s_ccov[g] = 1;
      if (nc > 1) { s_fix = 1; if (!s_multi[q]) s_sticky = 1; }
    }
    __syncthreads();
    if (s_fix) {
      for (int mi = wave; mi < m_n; mi += 16) {
        const int q = s_mq[mi];
        const int p = s_pen[q];
        const float* __restrict__ rowT = costT + ((size_t)(b*NQ + q)) * NG;
        const float* __restrict__ base = cb + q;
        float best = FLT_MAX; int bg = 0;
        for (int g = lane; g < NG; g += 64) {
          const float raw = useT ? rowT[g] : base[(size_t)g * NQ];
          const float v = penalized(raw, p);
          if (v < best) { best = v; bg = g; }
        }
        for (int off = 32; off; off >>= 1) {
          const float ov = __shfl_down(best, off);
          const int og = __shfl_down(bg, off);
          if (ov < best || (ov == best && og < bg)) { best = ov; bg = og; }
        }
        bg = __shfl(bg, 0);
        const unsigned bit = 1u << (q & 31);
        const int wofs = q >> 5;
        for (int g = lane; g < NG; g += 64) {
          const unsigned w = mb[g * NQW + wofs];
          const bool cur = (w & bit) != 0;
          const bool want = (g == bg);
          if (cur != want) {
            if (want) { atomicOr(&mb[g * NQW + wofs], bit); atomicAdd(&s_ccov[g], 1); }
            else      { atomicAnd(&mb[g * NQW + wofs], ~bit); atomicSub(&s_ccov[g], 1); }
          }
        }
        if (lane == 0) s_rcnt[q] = 1;
      }
    }
    __syncthreads();
  }
  for (int q = t; q < NQ; q += 1024) pen_g[b * NQ + q] = s_pen[q];
}

// ---------------- K8: matched_qidx ----------------
__global__ void matched_kernel(const float* __restrict__ cost, const unsigned* __restrict__ mbits,
                               const int* __restrict__ pen_g, float* __restrict__ out_mq) {
  const int g = blockIdx.x, b = blockIdx.y, t = threadIdx.x;
  const float* __restrict__ crow = cost + ((size_t)(b*NG + g)) * NQ;
  const unsigned* __restrict__ mrow = mbits + (b*NG + g) * NQW;
  const int* __restrict__ pb = pen_g + b * NQ;
  float best = FLT_MAX; int bq = 0;
  for (int q = t; q < NQ; q += 256) {
    if ((mrow[q >> 5] >> (q & 31)) & 1u) {
      const float v = penalized(crow[q], pb[q]);
      if (v < best) { best = v; bq = q; }
    }
  }
  __shared__ float rv[256];
  __shared__ int rq[256];
  rv[t] = best; rq[t] = bq;
  __syncthreads();
  for (int off = 128; off; off >>= 1) {
    if (t < off) {
      if (lexlt(rv[t + off], rq[t + off], rv[t], rq[t])) { rv[t] = rv[t + off]; rq[t] = rq[t + off]; }
    }
    __syncthreads();
  }
  if (t == 0) out_mq[b * NG + g] = (float)rq[0];
}

// ---------------- K9: expand bits -> m floats, selected, gt_idx ----------------
__global__ void out_kernel(const unsigned* __restrict__ mbits, float* __restrict__ out_m,
                           float* __restrict__ out_sel, float* __restrict__ out_gti) {
  const int qw = blockIdx.x;
  const int b = blockIdx.y, t = threadIdx.x;
  __shared__ unsigned w[NG];
  for (int g = t; g < NG; g += 256) w[g] = mbits[(b*NG + g) * NQW + qw];
  __syncthreads();
  const int qbase = qw * 32;
  float* __restrict__ om = out_m + ((size_t)(b * NQ + qbase)) * NG;
  for (int idx = t; idx < 32 * NG; idx += 256) {
    const int qi = idx / NG, g = idx - qi * NG;
    om[idx] = ((w[g] >> qi) & 1u) ? 1.f : 0.f;
  }
  if (t < 32) {
    int fgi = -1;
    for (int g = 0; g < NG; ++g) if ((w[g] >> t) & 1u) { fgi = g; break; }
    out_sel[b * NQ + qbase + t] = (fgi >= 0) ? 1.f : 0.f;
    out_gti[b * NQ + qbase + t] = (fgi >= 0) ? (float)fgi : 0.f;
  }
}

extern "C" void kernel_launch(void* const* d_in, const int* in_sizes, int n_in,
                              void* d_out, int out_size, void* d_ws, size_t ws_size,
                              hipStream_t stream) {
  const float* logits = (const float*)d_in[0];
  const float* boxes  = (const float*)d_in[1];
  const int*   labels = (const int*)d_in[2];
  const float* gtb    = (const float*)d_in[3];
  const float* imgsz  = (const float*)d_in[4];

  float* out = (float*)d_out;
  float* out_m   = out;                                   // B*Q*G
  float* out_sel = out + (size_t)NB * NQ * NG;            // B*Q
  float* out_gti = out_sel + (size_t)NB * NQ;             // B*Q
  float* out_mq  = out_gti + (size_t)NB * NQ;             // B*G

  char* w = (char*)d_ws;
  const size_t szPrep = sizeof(float4) * (size_t)NB * NQ;
  const size_t szGp   = sizeof(float4) * (size_t)NB * NG * 5;
  const size_t szCct  = sizeof(float) * (size_t)NB * NC * NQ;
  const size_t szBits = sizeof(unsigned) * (size_t)NB * NG * NQW;
  const size_t szIntQ = sizeof(int) * (size_t)NB * NQ;
  const size_t szIntG = sizeof(int) * (size_t)NB * NG;
  const size_t szCT   = sizeof(float) * (size_t)NB * NQ * NG;
  const size_t base_need = 2*szPrep + szGp + szCct + szBits + 3*szIntQ + szIntG;
  if (ws_size < base_need) return;
  const int useT = (ws_size >= base_need + szCT) ? 1 : 0;

  float4* prepN = (float4*)w; w += szPrep;
  float4* prepM = (float4*)w; w += szPrep;
  float4* gp    = (float4*)w; w += szGp;
  float*    cct   = (float*)w;    w += szCct;
  unsigned* mbits = (unsigned*)w; w += szBits;
  int* rcnt  = (int*)w; w += szIntQ;
  int* multi = (int*)w; w += szIntQ;
  int* pen   = (int*)w; w += szIntQ;
  int* ccov  = (int*)w; w += szIntG;
  float* costT = (float*)w;  // valid only if useT

  float* cost = out_m;  // (B,G,Q) in the d_out m-region; overwritten by out_kernel at the end

  prep_kernel<<<dim3((NQ + 255) / 256, NB), 256, 0, stream>>>(boxes, gtb, imgsz, prepN, prepM, rcnt);
  gprep_kernel<<<(NB * NG + 255) / 256, 256, 0, stream>>>(gtb, labels, imgsz, gp);
  cls_kernel<<<dim3((NQ + QT - 1) / QT, NB), 256, 0, stream>>>(logits, cct);
  if (useT)
    costA_kernel<1><<<dim3((NQ + 255) / 256, GSPLIT, NB), 256, 0, stream>>>(boxes, prepN, prepM, gp, cct, cost, costT);
  else
    costA_kernel<0><<<dim3((NQ + 255) / 256, GSPLIT, NB), 256, 0, stream>>>(boxes, prepN, prepM, gp, cct, cost, costT);
  topk_kernel<<<dim3(NG, NB), 64, 0, stream>>>(boxes, gp, cost, mbits, rcnt);
  multifix_kernel<<<(NB * NQ + 255) / 256, 256, 0, stream>>>(cost, costT, useT, mbits, rcnt, multi);
  colcov_kernel<<<(NB * NG + 255) / 256, 256, 0, stream>>>(mbits, ccov);
  loop_kernel<<<NB, 1024, 0, stream>>>(cost, costT, useT, mbits, rcnt, ccov, multi, pen);
  matched_kernel<<<dim3(NG, NB), 256, 0, stream>>>(cost, mbits, pen, out_mq);
  out_kernel<<<dim3(NQW, NB), 256, 0, stream>>>(mbits, out_m, out_sel, out_gti);
}

// Round 4
// 337.717 us; speedup vs baseline: 1.3422x; 1.2652x over previous
//
#include <hip/hip_runtime.h>
#include <float.h>
#include <stdint.h>
#include <stddef.h>

#define NB 16
#define NQ 4000
#define NG 300
#define NC 81
#define NQW 125  // NQ/32
#define NGW 10   // ceil(NG/32)
#define MAXM 768 // multi rows per image <= sum(dyn_k)/2 <= 750
#define GSPLIT 4
#define GCHUNK 75   // NG / GSPLIT
#define GSUB 15     // transpose tile width; GCHUNK = 5*GSUB

__device__ __forceinline__ bool lexlt(float v1, int i1, float v2, int i2) {
  return (v1 < v2) || (v1 == v2 && i1 < i2);
}

// Exact replica of p sequential f32 adds of 1e5 (numpy semantics), in O(#binade crossings).
__device__ __forceinline__ float penalized(float v, int p) {
  if (p <= 0) return v;
  if (p <= 12) {
    float x = v;
    for (int r = 0; r < p; ++r) x += 100000.0f;
    return x;
  }
  double x = (double)v;
  x = (double)(float)(x + 100000.0);
  int k = 1;
  while (k < p) {
    double B = 131072.0;
    while (B <= x) B += B;
    double room = B - x;
    int j = (int)(room * 1e-5);
    while (j > 0 && x + (double)j * 100000.0 >= B) --j;
    if (j > p - k) j = p - k;
    if (j > 0) { x += (double)j * 100000.0; k += j; }
    if (k < p) { x = (double)(float)(x + 100000.0); ++k; }
  }
  return (float)x;
}

// ---------------- K1: prep — fg mask, normalized box, center/area; zero rcnt/mbitsT/mcount ----------------
__global__ void prep_kernel(const float* __restrict__ boxes, const float* __restrict__ gtb,
                            const float* __restrict__ imgsz,
                            float4* __restrict__ prepN, float4* __restrict__ prepM,
                            int* __restrict__ rcnt, unsigned* __restrict__ mbitsT,
                            int* __restrict__ mcount) {
#pragma clang fp contract(off)
  const int b = blockIdx.y;
  const int q = blockIdx.x * 256 + threadIdx.x;
  const int tid = (blockIdx.y * gridDim.x + blockIdx.x) * 256 + threadIdx.x;
  const int nthreads = gridDim.x * gridDim.y * 256;
  for (int i = tid; i < NB * NQ * NGW; i += nthreads) mbitsT[i] = 0u;
  if (tid < NB) mcount[tid] = 0;
  __shared__ float sg[NG * 4];
  for (int i = threadIdx.x; i < NG * 4; i += 256) sg[i] = gtb[b * NG * 4 + i];
  __syncthreads();
  if (q >= NQ) return;
  const float4 pb = reinterpret_cast<const float4*>(boxes)[b * NQ + q];
  const float s0 = imgsz[b*4+0], s1 = imgsz[b*4+1], s2 = imgsz[b*4+2], s3 = imgsz[b*4+3];
  const float ax = (pb.x + pb.z) * 0.5f;
  const float ay = (pb.y + pb.w) * 0.5f;
  bool anyb = false, anyc = false;
  for (int g = 0; g < NG; ++g) {
    const float gx0 = sg[g*4+0], gy0 = sg[g*4+1], gx1 = sg[g*4+2], gy1 = sg[g*4+3];
    const float gcx = (gx0 + gx1) * 0.5f, gcy = (gy0 + gy1) * 0.5f;
    const float gw0 = gx1 - gx0, gh0 = gy1 - gy0;
    const float xg0 = gcx - 0.5f*gw0, yg0 = gcy - 0.5f*gh0;
    const float xg1 = gcx + 0.5f*gw0, yg1 = gcy + 0.5f*gh0;
    anyb = anyb || ((ax > xg0) && (ax < xg1) && (ay > yg0) && (ay < yg1));
    const float cw = xg1 - xg0, ch = yg1 - yg0;
    anyc = anyc || ((ax > gcx - 2.5f*cw) && (ax < gcx + 2.5f*cw) &&
                    (ay > gcy - 2.5f*ch) && (ay < gcy + 2.5f*ch));
  }
  const int idx = b * NQ + q;
  prepN[idx] = make_float4(pb.x / s0, pb.y / s1, pb.z / s2, pb.w / s3);
  prepM[idx] = make_float4(ax, ay, (pb.z - pb.x) * (pb.w - pb.y),
                           (anyb || anyc) ? 0.f : 10000.f);
  rcnt[idx] = 0;
}

// ---------------- K1b: per-gt derived params ----------------
__global__ void gprep_kernel(const float* __restrict__ gtb, const int* __restrict__ labels,
                             const float* __restrict__ imgsz, float4* __restrict__ gp) {
#pragma clang fp contract(off)
  const int idx = blockIdx.x * 256 + threadIdx.x;
  if (idx >= NB * NG) return;
  const int b = idx / NG;
  const float gx0 = gtb[idx*4 + 0];
  const float gy0 = gtb[idx*4 + 1];
  const float gx1 = gtb[idx*4 + 2];
  const float gy1 = gtb[idx*4 + 3];
  const float s0 = imgsz[b*4+0], s1 = imgsz[b*4+1], s2 = imgsz[b*4+2], s3 = imgsz[b*4+3];
  const float areaB = (gx1 - gx0) * (gy1 - gy0);
  const float gcx = (gx0 + gx1) * 0.5f, gcy = (gy0 + gy1) * 0.5f;
  const float gw0 = gx1 - gx0, gh0 = gy1 - gy0;
  const float xg0 = gcx - 0.5f*gw0, yg0 = gcy - 0.5f*gh0;
  const float xg1 = gcx + 0.5f*gw0, yg1 = gcy + 0.5f*gh0;
  const float cw = xg1 - xg0, ch = yg1 - yg0;
  gp[idx*5+0] = make_float4(xg0, yg0, xg1, yg1);
  gp[idx*5+1] = make_float4(gcx - 2.5f*cw, gcx + 2.5f*cw, gcy - 2.5f*ch, gcy + 2.5f*ch);
  gp[idx*5+2] = make_float4(gx0 / s0, gy0 / s1, gx1 / s2, gy1 / s3);
  gp[idx*5+3] = make_float4(gx0, gy0, gx1, gy1);
  gp[idx*5+4] = make_float4(areaB, __int_as_float(labels[idx]), 0.f, 0.f);
}

// ---------------- K2: focal class cost table, transposed (B,C,Q), tiled ----------------
#define QT 64
__global__ void cls_kernel(const float* __restrict__ logits, float* __restrict__ cct) {
#pragma clang fp contract(off)
  const int b = blockIdx.y, q0 = blockIdx.x * QT, t = threadIdx.x;
  __shared__ float tile[QT * NC];
  const int nq = (NQ - q0 < QT) ? (NQ - q0) : QT;
  const float* __restrict__ src = logits + ((size_t)(b * NQ + q0)) * NC;
  for (int i = t; i < nq * NC; i += 256) {
    const float x = src[i];
    float p;
    if (x >= 0.f) p = 1.f / (1.f + expf(-x));
    else { const float e = expf(x); p = e / (1.f + e); }
    const float pos = 0.25f * ((1.f - p) * (1.f - p)) * (-logf(p + 1e-8f));
    const float neg = 0.75f * (p * p) * (-logf(1.f - p + 1e-8f));
    tile[i] = pos - neg;
  }
  __syncthreads();
  for (int i = t; i < NC * QT; i += 256) {
    const int c = i >> 6;
    const int ql = i & (QT - 1);
    if (ql < nq) cct[((size_t)(b * NC + c)) * NQ + q0 + ql] = tile[ql * NC + c];
  }
}

// ---------------- K3a: featurize — q-resident registers, loop over g ----------------
template<int USET>
__global__ __launch_bounds__(256) void costA_kernel(
    const float* __restrict__ boxes, const float4* __restrict__ prepN,
    const float4* __restrict__ prepM, const float4* __restrict__ gp,
    const float* __restrict__ cct, float* __restrict__ cost, float* __restrict__ costT) {
#pragma clang fp contract(off)
  const int b = blockIdx.z, t = threadIdx.x;
  const int q0 = blockIdx.x * 256, gl0 = blockIdx.y * GCHUNK;
  __shared__ float4 sgp[GCHUNK * 5];
  __shared__ float tile[USET ? 256 * GSUB : 1];
  for (int i = t; i < GCHUNK * 5; i += 256) sgp[i] = gp[(size_t)(b*NG + gl0) * 5 + i];
  const int q = q0 + t;
  const bool qv = q < NQ;
  float4 pb = make_float4(0.f, 0.f, 1.f, 1.f);
  float4 nb = make_float4(0.f, 0.f, 0.f, 0.f);
  float4 pm = make_float4(0.f, 0.f, 1.f, 0.f);
  if (qv) {
    pb = reinterpret_cast<const float4*>(boxes)[b*NQ + q];
    nb = prepN[b*NQ + q];
    pm = prepM[b*NQ + q];
  }
  const float areaA = pm.z;
  __syncthreads();
  for (int c = 0; c < GCHUNK / GSUB; ++c) {
    for (int gg = 0; gg < GSUB; ++gg) {
      const int gi = c * GSUB + gg, g = gl0 + gi;
      const float4 A0 = sgp[gi*5+0];
      const float4 A1 = sgp[gi*5+1];
      const float4 A2 = sgp[gi*5+2];
      const float4 A3 = sgp[gi*5+3];
      const float4 A4 = sgp[gi*5+4];
      const int lab = __float_as_int(A4.y);
      const float ccls = qv ? cct[((size_t)(b*NC + lab)) * NQ + q] : 0.f;
      const float ltx = fmaxf(pb.x, A3.x), lty = fmaxf(pb.y, A3.y);
      const float rbx = fminf(pb.z, A3.z), rby = fminf(pb.w, A3.w);
      const float iw = fmaxf(rbx - ltx, 0.f), ih = fmaxf(rby - lty, 0.f);
      const float inter = iw * ih;
      const float uni = areaA + A4.x - inter;
      const float iou = inter / uni;
      const float eltx = fminf(pb.x, A3.x), elty = fminf(pb.y, A3.y);
      const float erbx = fmaxf(pb.z, A3.z), erby = fmaxf(pb.w, A3.w);
      const float ew = fmaxf(erbx - eltx, 0.f), eh = fmaxf(erby - elty, 0.f);
      const float earea = ew * eh;
      const float giou = iou - (earea - uni) / earea;
      const float cbb = fabsf(nb.x - A2.x) + fabsf(nb.y - A2.y)
                      + fabsf(nb.z - A2.z) + fabsf(nb.w - A2.w);
      const bool inb = (pm.x > A0.x) && (pm.x < A0.z) && (pm.y > A0.y) && (pm.y < A0.w);
      const bool inc = (pm.x > A1.x) && (pm.x < A1.y) && (pm.y > A1.z) && (pm.y < A1.w);
      const bool ibc = inb && inc;
      float cval = 5.0f * cbb + 2.0f * ccls;
      cval = cval + 2.0f * (-giou);
      cval = cval + (ibc ? 0.f : 100.f);
      cval = cval + pm.w;
      if (qv) cost[((size_t)(b*NG + g)) * NQ + q] = cval;
      if (USET) tile[t * GSUB + gg] = cval;
    }
    if (USET) {
      __syncthreads();
      for (int i = t; i < 256 * GSUB; i += 256) {
        const int qq = i / GSUB, gg2 = i - qq * GSUB;
        if (q0 + qq < NQ)
          costT[((size_t)(b*NQ + q0 + qq)) * NG + gl0 + c * GSUB + gg2] = tile[qq * GSUB + gg2];
      }
      __syncthreads();
    }
  }
}

// ---------------- K3b: per-(b,g) top-5 -> dyn_k, m bits (both layouts), rcnt ----------------
__global__ __launch_bounds__(64) void topk_kernel(
    const float* __restrict__ boxes, const float4* __restrict__ gp,
    const float* __restrict__ cost, unsigned* __restrict__ mbits,
    unsigned* __restrict__ mbitsT, int* __restrict__ rcnt) {
#pragma clang fp contract(off)
  const int g = blockIdx.x, b = blockIdx.y, lane = threadIdx.x;
  const float4 A3 = gp[(size_t)(b*NG + g) * 5 + 3];
  const float areaB = gp[(size_t)(b*NG + g) * 5 + 4].x;
  const float* __restrict__ crow = cost + ((size_t)(b*NG + g)) * NQ;
  unsigned* __restrict__ mrow = mbits + (b*NG + g) * NQW;
  for (int i = lane; i < NQW; i += 64) mrow[i] = 0u;

  float tv[5]; int tq[5]; float sv[5];
#pragma unroll
  for (int i = 0; i < 5; ++i) { tv[i] = FLT_MAX; tq[i] = 0x7fffffff; sv[i] = -1.f; }

  for (int q = lane; q < NQ; q += 64) {
    const float cval = crow[q];
    const float4 pb = reinterpret_cast<const float4*>(boxes)[b*NQ + q];
    const float areaA = (pb.z - pb.x) * (pb.w - pb.y);
    const float ltx = fmaxf(pb.x, A3.x), lty = fmaxf(pb.y, A3.y);
    const float rbx = fminf(pb.z, A3.z), rby = fminf(pb.w, A3.w);
    const float iw = fmaxf(rbx - ltx, 0.f), ih = fmaxf(rby - lty, 0.f);
    const float inter = iw * ih;
    const float uni = areaA + areaB - inter;
    const float iou = inter / uni;
    if (iou > sv[4]) {
      sv[4] = iou;
#pragma unroll
      for (int j = 4; j >= 1; --j)
        if (sv[j] > sv[j-1]) { const float tmp = sv[j]; sv[j] = sv[j-1]; sv[j-1] = tmp; }
    }
    if (lexlt(cval, q, tv[4], tq[4])) {
      tv[4] = cval; tq[4] = q;
#pragma unroll
      for (int j = 4; j >= 1; --j)
        if (lexlt(tv[j], tq[j], tv[j-1], tq[j-1])) {
          const float tf = tv[j]; tv[j] = tv[j-1]; tv[j-1] = tf;
          const int ti = tq[j]; tq[j] = tq[j-1]; tq[j-1] = ti;
        }
    }
  }

#pragma unroll
  for (int off = 32; off >= 1; off >>= 1) {
    float pv[5]; int pq[5]; float pi[5];
#pragma unroll
    for (int i = 0; i < 5; ++i) {
      pv[i] = __shfl_down(tv[i], off);
      pq[i] = __shfl_down(tq[i], off);
      pi[i] = __shfl_down(sv[i], off);
    }
#pragma unroll
    for (int i = 0; i < 5; ++i) {
      if (lexlt(pv[i], pq[i], tv[4], tq[4])) {
        tv[4] = pv[i]; tq[4] = pq[i];
#pragma unroll
        for (int j = 4; j >= 1; --j)
          if (lexlt(tv[j], tq[j], tv[j-1], tq[j-1])) {
            const float tf = tv[j]; tv[j] = tv[j-1]; tv[j-1] = tf;
            const int ti = tq[j]; tq[j] = tq[j-1]; tq[j-1] = ti;
          }
      }
      if (pi[i] > sv[4]) {
        sv[4] = pi[i];
#pragma unroll
        for (int j = 4; j >= 1; --j)
          if (sv[j] > sv[j-1]) { const float tmp = sv[j]; sv[j] = sv[j-1]; sv[j-1] = tmp; }
      }
    }
  }
  __syncthreads();
  if (lane == 0) {
    float s = sv[0]; s += sv[1]; s += sv[2]; s += sv[3]; s += sv[4];
    int k = (int)s; if (k < 1) k = 1; if (k > 5) k = 5;
    for (int i = 0; i < k; ++i) {
      const int q = tq[i];
      mrow[q >> 5] |= 1u << (q & 31);
      atomicOr(&mbitsT[((size_t)(b*NQ + q)) * NGW + (g >> 5)], 1u << (g & 31));
      atomicAdd(&rcnt[b * NQ + q], 1);
    }
  }
}

// ---------------- K4: compact multi rows ----------------
__global__ void compact_kernel(const int* __restrict__ rcnt, int* __restrict__ multi,
                               int* __restrict__ mlist, int* __restrict__ mcount) {
  const int idx = blockIdx.x * 256 + threadIdx.x;
  if (idx >= NB * NQ) return;
  const int b = idx / NQ, q = idx - b * NQ;
  if (rcnt[idx] > 1) {
    multi[idx] = 1;
    const int pos = atomicAdd(&mcount[b], 1);
    if (pos < MAXM) mlist[b * MAXM + pos] = q;
  } else multi[idx] = 0;
}

// ---------------- K5: multifix — one wave per multi row ----------------
template<int USET>
__global__ __launch_bounds__(256) void multifix_kernel(
    const float* __restrict__ cost, const float* __restrict__ costT,
    unsigned* __restrict__ mbits, unsigned* __restrict__ mbitsT,
    int* __restrict__ rcnt, const int* __restrict__ mlist, const int* __restrict__ mcount) {
  const int b = blockIdx.y;
  const int gw = blockIdx.x * 4 + (threadIdx.x >> 6);
  const int nw = gridDim.x * 4;
  const int lane = threadIdx.x & 63;
  int mn = mcount[b]; if (mn > MAXM) mn = MAXM;
  for (int i = gw; i < mn; i += nw) {
    const int q = mlist[b * MAXM + i];
    float best = FLT_MAX; int bg = 0;
    for (int g = lane; g < NG; g += 64) {
      const float v = USET ? costT[((size_t)(b*NQ + q)) * NG + g]
                           : cost[((size_t)(b*NG + g)) * NQ + q];
      if (v < best) { best = v; bg = g; }
    }
    for (int off = 32; off; off >>= 1) {
      const float ov = __shfl_down(best, off);
      const int og = __shfl_down(bg, off);
      if (ov < best || (ov == best && og < bg)) { best = ov; bg = og; }
    }
    bg = __shfl(bg, 0);
    unsigned* __restrict__ trow = mbitsT + (size_t)(b*NQ + q) * NGW;
    const unsigned qbit = 1u << (q & 31);
    const int qw = q >> 5;
    if (lane < NGW) {
      const unsigned wv = trow[lane];
      const unsigned want = ((bg >> 5) == lane) ? (1u << (bg & 31)) : 0u;
      unsigned clr = wv & ~want;
      while (clr) {
        const int gb = __ffs(clr) - 1; clr &= clr - 1;
        atomicAnd(&mbits[(b*NG + lane*32 + gb) * NQW + qw], ~qbit);
      }
      if (want & ~wv) atomicOr(&mbits[(b*NG + bg) * NQW + qw], qbit);
      trow[lane] = want;
    }
    if (lane == 0) rcnt[b * NQ + q] = 1;
  }
}

// ---------------- K6: column coverage counts ----------------
__global__ void colcov_kernel(const unsigned* __restrict__ mbits, int* __restrict__ ccov) {
  const int idx = blockIdx.x * 256 + threadIdx.x;
  if (idx >= NB * NG) return;
  const unsigned* row = mbits + idx * NQW;
  int c = 0;
  for (int i = 0; i < NQW; ++i) c += __popc(row[i]);
  ccov[idx] = c;
}

// ---------------- K7: the while-loop, one persistent block per image ----------------
// Rows never assigned keep pen==0 (>=2500 of 4000); penalized >= 99989 > max raw ~10160,
// so uncovered-column argmin only needs pen==0 rows at raw cost.
template<int USET>
__global__ __launch_bounds__(1024) void loop_kernel(
    const float* __restrict__ cost, const float* __restrict__ costT,
    unsigned* __restrict__ mbits, unsigned* __restrict__ mbitsT,
    const int* __restrict__ rcnt_g, const int* __restrict__ ccov_g,
    const int* __restrict__ multi_g, const int* __restrict__ mlist,
    const int* __restrict__ mcount, int* __restrict__ pen_g) {
  const int b = blockIdx.x, t = threadIdx.x;
  __shared__ int s_pen[NQ];
  __shared__ int s_rcnt[NQ];
  __shared__ unsigned char s_multi[NQ];
  __shared__ short s_qmi[NQ];
  __shared__ int s_ccov[NG];
  __shared__ int s_unc[NG];
  __shared__ int s_pickq[NG];
  __shared__ int s_mq[MAXM];
  __shared__ unsigned s_mrow[MAXM][NGW];
  __shared__ int s_n, s_fix, s_sticky;

  int m_n = mcount[b]; if (m_n > MAXM) m_n = MAXM;
  for (int q = t; q < NQ; q += 1024) {
    s_pen[q] = 0;
    s_rcnt[q] = rcnt_g[b * NQ + q];
    s_multi[q] = (unsigned char)multi_g[b * NQ + q];
    s_qmi[q] = -1;
  }
  for (int i = t; i < m_n; i += 1024) s_mq[i] = mlist[b * MAXM + i];
  for (int g = t; g < NG; g += 1024) s_ccov[g] = ccov_g[b * NG + g];
  if (t == 0) s_sticky = 0;
  __syncthreads();
  for (int i = t; i < m_n; i += 1024) s_qmi[s_mq[i]] = (short)i;
  unsigned* __restrict__ mbT = mbitsT + (size_t)b * NQ * NGW;
  for (int i = t; i < m_n * NGW; i += 1024) {
    const int mi = i / NGW, w2 = i - mi * NGW;
    s_mrow[mi][w2] = mbT[(size_t)s_mq[mi] * NGW + w2];
  }
  __syncthreads();

  unsigned* __restrict__ mb = mbits + b * NG * NQW;
  const float* __restrict__ cb = cost + (size_t)b * NG * NQ;
  const float* __restrict__ cbT = costT + (size_t)b * NQ * NG;
  const int lane = t & 63, wave = t >> 6;

  for (int iter = 0; iter < 100; ++iter) {
    if (t == 0) { s_n = 0; s_fix = s_sticky; }
    __syncthreads();
    for (int g = t; g < NG; g += 1024)
      if (s_ccov[g] == 0) { const int i = atomicAdd(&s_n, 1); s_unc[i] = g; }
    __syncthreads();
    const int n = s_n;
    if (n == 0) break;
    for (int q = t; q < NQ; q += 1024)
      if (s_rcnt[q] > 0) s_pen[q]++;
    __syncthreads();
    for (int ci = wave; ci < n; ci += 16) {
      const int g = s_unc[ci];
      const float* __restrict__ crow = cb + (size_t)g * NQ;
      float best = FLT_MAX; int bq = 0x7fffffff;
      for (int q = lane; q < NQ; q += 64) {
        if (s_pen[q] == 0) {
          const float v = crow[q];
          if (v < best) { best = v; bq = q; }
        }
      }
      for (int off = 32; off; off >>= 1) {
        const float ov = __shfl_down(best, off);
        const int oq = __shfl_down(bq, off);
        if (ov < best || (ov == best && oq < bq)) { best = ov; bq = oq; }
      }
      if (lane == 0) s_pickq[ci] = bq;
    }
    __syncthreads();
    if (t < n) {
      const int g = s_unc[t], q = s_pickq[t];
      atomicOr(&mb[g * NQW + (q >> 5)], 1u << (q & 31));
      const int mi2 = s_qmi[q];
      if (mi2 >= 0) atomicOr(&s_mrow[mi2][g >> 5], 1u << (g & 31));
      else atomicOr(&mbT[(size_t)q * NGW + (g >> 5)], 1u << (g & 31));
      const int nc = atomicAdd(&s_rcnt[q], 1) + 1;
      s_ccov[g] = 1;
      if (nc > 1) { s_fix = 1; if (!s_multi[q]) s_sticky = 1; }
    }
    __syncthreads();
    if (s_fix) {
      for (int mi = wave; mi < m_n; mi += 16) {
        const int q = s_mq[mi];
        const int p = s_pen[q];
        float best = FLT_MAX; int bg = 0;
        for (int g = lane; g < NG; g += 64) {
          const float raw = USET ? cbT[(size_t)q * NG + g] : cb[(size_t)g * NQ + q];
          const float v = penalized(raw, p);
          if (v < best) { best = v; bg = g; }
        }
        for (int off = 32; off; off >>= 1) {
          const float ov = __shfl_down(best, off);
          const int og = __shfl_down(bg, off);
          if (ov < best || (ov == best && og < bg)) { best = ov; bg = og; }
        }
        bg = __shfl(bg, 0);
        const unsigned qbit = 1u << (q & 31);
        const int qw = q >> 5;
        if (lane < NGW) {
          const unsigned wv = s_mrow[mi][lane];
          const unsigned want = ((bg >> 5) == lane) ? (1u << (bg & 31)) : 0u;
          unsigned clr = wv & ~want;
          while (clr) {
            const int gb = __ffs(clr) - 1; clr &= clr - 1;
            const int g = lane * 32 + gb;
            atomicAnd(&mb[g * NQW + qw], ~qbit);
            atomicSub(&s_ccov[g], 1);
          }
          if (want & ~wv) {
            atomicOr(&mb[bg * NQW + qw], qbit);
            atomicAdd(&s_ccov[bg], 1);
          }
          s_mrow[mi][lane] = want;
        }
        if (lane == 0) s_rcnt[q] = 1;
      }
    }
    __syncthreads();
  }
  // write back multi rows' bit-rows + penalties
  __syncthreads();
  for (int i = t; i < m_n * NGW; i += 1024) {
    const int mi = i / NGW, w2 = i - mi * NGW;
    mbT[(size_t)s_mq[mi] * NGW + w2] = s_mrow[mi][w2];
  }
  for (int q = t; q < NQ; q += 1024) pen_g[b * NQ + q] = s_pen[q];
}

// ---------------- K8: matched_qidx ----------------
__global__ void matched_kernel(const float* __restrict__ cost, const unsigned* __restrict__ mbits,
                               const int* __restrict__ pen_g, float* __restrict__ out_mq) {
  const int g = blockIdx.x, b = blockIdx.y, t = threadIdx.x;
  const float* __restrict__ crow = cost + ((size_t)(b*NG + g)) * NQ;
  const unsigned* __restrict__ mrow = mbits + (b*NG + g) * NQW;
  const int* __restrict__ pb = pen_g + b * NQ;
  float best = FLT_MAX; int bq = 0;
  for (int q = t; q < NQ; q += 256) {
    if ((mrow[q >> 5] >> (q & 31)) & 1u) {
      const float v = penalized(crow[q], pb[q]);
      if (v < best) { best = v; bq = q; }
    }
  }
  __shared__ float rv[256];
  __shared__ int rq[256];
  rv[t] = best; rq[t] = bq;
  __syncthreads();
  for (int off = 128; off; off >>= 1) {
    if (t < off) {
      if (lexlt(rv[t + off], rq[t + off], rv[t], rq[t])) { rv[t] = rv[t + off]; rq[t] = rq[t + off]; }
    }
    __syncthreads();
  }
  if (t == 0) out_mq[b * NG + g] = (float)rq[0];
}

// ---------------- K9: expand mbitsT rows -> m floats, selected, gt_idx ----------------
__global__ void out_kernel(const unsigned* __restrict__ mbitsT, float* __restrict__ out_m,
                           float* __restrict__ out_sel, float* __restrict__ out_gti) {
  const int b = blockIdx.y, t = threadIdx.x;
  const int q0 = blockIdx.x * 8;
  __shared__ unsigned wds[8 * NGW];
  if (t < 8 * NGW) wds[t] = mbitsT[((size_t)(b*NQ + q0)) * NGW + t];
  __syncthreads();
  float* __restrict__ om = out_m + ((size_t)(b*NQ + q0)) * NG;
  for (int i = t; i < 8 * NG; i += 256) {
    const int qi = i / NG, g = i - qi * NG;
    om[i] = ((wds[qi*NGW + (g >> 5)] >> (g & 31)) & 1u) ? 1.f : 0.f;
  }
  if (t < 8) {
    int fgi = -1;
    for (int w = 0; w < NGW; ++w) {
      const unsigned v = wds[t*NGW + w];
      if (v) { fgi = w*32 + __ffs(v) - 1; break; }
    }
    out_sel[b*NQ + q0 + t] = (fgi >= 0) ? 1.f : 0.f;
    out_gti[b*NQ + q0 + t] = (fgi >= 0) ? (float)fgi : 0.f;
  }
}

extern "C" void kernel_launch(void* const* d_in, const int* in_sizes, int n_in,
                              void* d_out, int out_size, void* d_ws, size_t ws_size,
                              hipStream_t stream) {
  const float* logits = (const float*)d_in[0];
  const float* boxes  = (const float*)d_in[1];
  const int*   labels = (const int*)d_in[2];
  const float* gtb    = (const float*)d_in[3];
  const float* imgsz  = (const float*)d_in[4];

  float* out = (float*)d_out;
  float* out_m   = out;                                   // B*Q*G
  float* out_sel = out + (size_t)NB * NQ * NG;            // B*Q
  float* out_gti = out_sel + (size_t)NB * NQ;             // B*Q
  float* out_mq  = out_gti + (size_t)NB * NQ;             // B*G

  char* w = (char*)d_ws;
  const size_t szPrep = sizeof(float4) * (size_t)NB * NQ;
  const size_t szGp   = sizeof(float4) * (size_t)NB * NG * 5;
  const size_t szCct  = sizeof(float) * (size_t)NB * NC * NQ;
  const size_t szBits = sizeof(unsigned) * (size_t)NB * NG * NQW;
  const size_t szBitsT= sizeof(unsigned) * (size_t)NB * NQ * NGW;
  const size_t szIntQ = sizeof(int) * (size_t)NB * NQ;
  const size_t szIntG = sizeof(int) * (size_t)NB * NG;
  const size_t szML   = sizeof(int) * (size_t)NB * MAXM;
  const size_t szMC   = sizeof(int) * 64;
  const size_t szCT   = sizeof(float) * (size_t)NB * NQ * NG;
  const size_t base_need = 2*szPrep + szGp + szCct + szBits + szBitsT + 3*szIntQ + szIntG + szML + szMC;
  if (ws_size < base_need) return;
  const int useT = (ws_size >= base_need + szCT) ? 1 : 0;

  float4* prepN = (float4*)w; w += szPrep;
  float4* prepM = (float4*)w; w += szPrep;
  float4* gp    = (float4*)w; w += szGp;
  float*    cct   = (float*)w;    w += szCct;
  unsigned* mbits = (unsigned*)w; w += szBits;
  unsigned* mbitsT= (unsigned*)w; w += szBitsT;
  int* rcnt  = (int*)w; w += szIntQ;
  int* multi = (int*)w; w += szIntQ;
  int* pen   = (int*)w; w += szIntQ;
  int* ccov  = (int*)w; w += szIntG;
  int* mlist = (int*)w; w += szML;
  int* mcount= (int*)w; w += szMC;
  float* costT = (float*)w;  // valid only if useT

  float* cost = out_m;  // (B,G,Q) in the d_out m-region; overwritten by out_kernel at the end

  prep_kernel<<<dim3((NQ + 255) / 256, NB), 256, 0, stream>>>(boxes, gtb, imgsz, prepN, prepM, rcnt, mbitsT, mcount);
  gprep_kernel<<<(NB * NG + 255) / 256, 256, 0, stream>>>(gtb, labels, imgsz, gp);
  cls_kernel<<<dim3((NQ + QT - 1) / QT, NB), 256, 0, stream>>>(logits, cct);
  if (useT)
    costA_kernel<1><<<dim3((NQ + 255) / 256, GSPLIT, NB), 256, 0, stream>>>(boxes, prepN, prepM, gp, cct, cost, costT);
  else
    costA_kernel<0><<<dim3((NQ + 255) / 256, GSPLIT, NB), 256, 0, stream>>>(boxes, prepN, prepM, gp, cct, cost, costT);
  topk_kernel<<<dim3(NG, NB), 64, 0, stream>>>(boxes, gp, cost, mbits, mbitsT, rcnt);
  compact_kernel<<<(NB * NQ + 255) / 256, 256, 0, stream>>>(rcnt, multi, mlist, mcount);
  if (useT)
    multifix_kernel<1><<<dim3(12, NB), 256, 0, stream>>>(cost, costT, mbits, mbitsT, rcnt, mlist, mcount);
  else
    multifix_kernel<0><<<dim3(12, NB), 256, 0, stream>>>(cost, costT, mbits, mbitsT, rcnt, mlist, mcount);
  colcov_kernel<<<(NB * NG + 255) / 256, 256, 0, stream>>>(mbits, ccov);
  if (useT)
    loop_kernel<1><<<NB, 1024, 0, stream>>>(cost, costT, mbits, mbitsT, rcnt, ccov, multi, mlist, mcount, pen);
  else
    loop_kernel<0><<<NB, 1024, 0, stream>>>(cost, costT, mbits, mbitsT, rcnt, ccov, multi, mlist, mcount, pen);
  matched_kernel<<<dim3(NG, NB), 256, 0, stream>>>(cost, mbits, pen, out_mq);
  out_kernel<<<dim3(NQ / 8, NB), 256, 0, stream>>>(mbitsT, out_m, out_sel, out_gti);
}

// Round 5
// 319.050 us; speedup vs baseline: 1.4207x; 1.0585x over previous
//
#include <hip/hip_runtime.h>
#include <float.h>
#include <stdint.h>
#include <stddef.h>

#define NB 16
#define NQ 4000
#define NG 300
#define NC 81
#define NQW 125  // NQ/32
#define NGW 10   // ceil(NG/32)
#define MAXM 768 // multi rows per image <= sum(dyn_k)/2 <= 750
#define GSPLIT 4
#define GCHUNK 75   // NG / GSPLIT
#define GSUB 15     // transpose tile width; GCHUNK = 5*GSUB

typedef unsigned long long u64t;

__device__ __forceinline__ bool lexlt(float v1, int i1, float v2, int i2) {
  return (v1 < v2) || (v1 == v2 && i1 < i2);
}
__device__ __forceinline__ u64t umin64(u64t a, u64t b) { return a < b ? a : b; }
__device__ __forceinline__ u64t umax64(u64t a, u64t b) { return a > b ? a : b; }

// Exact replica of p sequential f32 adds of 1e5 (numpy semantics), in O(#binade crossings).
__device__ __forceinline__ float penalized(float v, int p) {
  if (p <= 0) return v;
  if (p <= 12) {
    float x = v;
    for (int r = 0; r < p; ++r) x += 100000.0f;
    return x;
  }
  double x = (double)v;
  x = (double)(float)(x + 100000.0);
  int k = 1;
  while (k < p) {
    double B = 131072.0;
    while (B <= x) B += B;
    double room = B - x;
    int j = (int)(room * 1e-5);
    while (j > 0 && x + (double)j * 100000.0 >= B) --j;
    if (j > p - k) j = p - k;
    if (j > 0) { x += (double)j * 100000.0; k += j; }
    if (k < p) { x = (double)(float)(x + 100000.0); ++k; }
  }
  return (float)x;
}

// ---------------- K1: prep — fg mask, normalized box, center/area; zero rcnt/mbitsT/mcount ----------------
__global__ void prep_kernel(const float* __restrict__ boxes, const float* __restrict__ gtb,
                            const float* __restrict__ imgsz,
                            float4* __restrict__ prepN, float4* __restrict__ prepM,
                            int* __restrict__ rcnt, unsigned* __restrict__ mbitsT,
                            int* __restrict__ mcount) {
#pragma clang fp contract(off)
  const int b = blockIdx.y;
  const int q = blockIdx.x * 256 + threadIdx.x;
  const int tid = (blockIdx.y * gridDim.x + blockIdx.x) * 256 + threadIdx.x;
  const int nthreads = gridDim.x * gridDim.y * 256;
  for (int i = tid; i < NB * NQ * NGW; i += nthreads) mbitsT[i] = 0u;
  if (tid < NB) mcount[tid] = 0;
  __shared__ float sg[NG * 4];
  for (int i = threadIdx.x; i < NG * 4; i += 256) sg[i] = gtb[b * NG * 4 + i];
  __syncthreads();
  if (q >= NQ) return;
  const float4 pb = reinterpret_cast<const float4*>(boxes)[b * NQ + q];
  const float s0 = imgsz[b*4+0], s1 = imgsz[b*4+1], s2 = imgsz[b*4+2], s3 = imgsz[b*4+3];
  const float ax = (pb.x + pb.z) * 0.5f;
  const float ay = (pb.y + pb.w) * 0.5f;
  bool anyb = false, anyc = false;
  for (int g = 0; g < NG; ++g) {
    const float gx0 = sg[g*4+0], gy0 = sg[g*4+1], gx1 = sg[g*4+2], gy1 = sg[g*4+3];
    const float gcx = (gx0 + gx1) * 0.5f, gcy = (gy0 + gy1) * 0.5f;
    const float gw0 = gx1 - gx0, gh0 = gy1 - gy0;
    const float xg0 = gcx - 0.5f*gw0, yg0 = gcy - 0.5f*gh0;
    const float xg1 = gcx + 0.5f*gw0, yg1 = gcy + 0.5f*gh0;
    anyb = anyb || ((ax > xg0) && (ax < xg1) && (ay > yg0) && (ay < yg1));
    const float cw = xg1 - xg0, ch = yg1 - yg0;
    anyc = anyc || ((ax > gcx - 2.5f*cw) && (ax < gcx + 2.5f*cw) &&
                    (ay > gcy - 2.5f*ch) && (ay < gcy + 2.5f*ch));
  }
  const int idx = b * NQ + q;
  prepN[idx] = make_float4(pb.x / s0, pb.y / s1, pb.z / s2, pb.w / s3);
  prepM[idx] = make_float4(ax, ay, (pb.z - pb.x) * (pb.w - pb.y),
                           (anyb || anyc) ? 0.f : 10000.f);
  rcnt[idx] = 0;
}

// ---------------- K1b: per-gt derived params ----------------
__global__ void gprep_kernel(const float* __restrict__ gtb, const int* __restrict__ labels,
                             const float* __restrict__ imgsz, float4* __restrict__ gp) {
#pragma clang fp contract(off)
  const int idx = blockIdx.x * 256 + threadIdx.x;
  if (idx >= NB * NG) return;
  const int b = idx / NG;
  const float gx0 = gtb[idx*4 + 0];
  const float gy0 = gtb[idx*4 + 1];
  const float gx1 = gtb[idx*4 + 2];
  const float gy1 = gtb[idx*4 + 3];
  const float s0 = imgsz[b*4+0], s1 = imgsz[b*4+1], s2 = imgsz[b*4+2], s3 = imgsz[b*4+3];
  const float areaB = (gx1 - gx0) * (gy1 - gy0);
  const float gcx = (gx0 + gx1) * 0.5f, gcy = (gy0 + gy1) * 0.5f;
  const float gw0 = gx1 - gx0, gh0 = gy1 - gy0;
  const float xg0 = gcx - 0.5f*gw0, yg0 = gcy - 0.5f*gh0;
  const float xg1 = gcx + 0.5f*gw0, yg1 = gcy + 0.5f*gh0;
  const float cw = xg1 - xg0, ch = yg1 - yg0;
  gp[idx*5+0] = make_float4(xg0, yg0, xg1, yg1);
  gp[idx*5+1] = make_float4(gcx - 2.5f*cw, gcx + 2.5f*cw, gcy - 2.5f*ch, gcy + 2.5f*ch);
  gp[idx*5+2] = make_float4(gx0 / s0, gy0 / s1, gx1 / s2, gy1 / s3);
  gp[idx*5+3] = make_float4(gx0, gy0, gx1, gy1);
  gp[idx*5+4] = make_float4(areaB, __int_as_float(labels[idx]), 0.f, 0.f);
}

// ---------------- K2: focal class cost table, transposed (B,C,Q), tiled ----------------
#define QT 64
__global__ void cls_kernel(const float* __restrict__ logits, float* __restrict__ cct) {
#pragma clang fp contract(off)
  const int b = blockIdx.y, q0 = blockIdx.x * QT, t = threadIdx.x;
  __shared__ float tile[QT * NC];
  const int nq = (NQ - q0 < QT) ? (NQ - q0) : QT;
  const float* __restrict__ src = logits + ((size_t)(b * NQ + q0)) * NC;
  for (int i = t; i < nq * NC; i += 256) {
    const float x = src[i];
    float p;
    if (x >= 0.f) p = 1.f / (1.f + expf(-x));
    else { const float e = expf(x); p = e / (1.f + e); }
    const float pos = 0.25f * ((1.f - p) * (1.f - p)) * (-logf(p + 1e-8f));
    const float neg = 0.75f * (p * p) * (-logf(1.f - p + 1e-8f));
    tile[i] = pos - neg;
  }
  __syncthreads();
  for (int i = t; i < NC * QT; i += 256) {
    const int c = i >> 6;
    const int ql = i & (QT - 1);
    if (ql < nq) cct[((size_t)(b * NC + c)) * NQ + q0 + ql] = tile[ql * NC + c];
  }
}

// ---------------- K3a: featurize — q-resident registers, loop over g ----------------
template<int USET>
__global__ __launch_bounds__(256) void costA_kernel(
    const float* __restrict__ boxes, const float4* __restrict__ prepN,
    const float4* __restrict__ prepM, const float4* __restrict__ gp,
    const float* __restrict__ cct, float* __restrict__ cost, float* __restrict__ costT) {
#pragma clang fp contract(off)
  const int b = blockIdx.z, t = threadIdx.x;
  const int q0 = blockIdx.x * 256, gl0 = blockIdx.y * GCHUNK;
  __shared__ float4 sgp[GCHUNK * 5];
  __shared__ float tile[USET ? 256 * GSUB : 1];
  for (int i = t; i < GCHUNK * 5; i += 256) sgp[i] = gp[(size_t)(b*NG + gl0) * 5 + i];
  const int q = q0 + t;
  const bool qv = q < NQ;
  float4 pb = make_float4(0.f, 0.f, 1.f, 1.f);
  float4 nb = make_float4(0.f, 0.f, 0.f, 0.f);
  float4 pm = make_float4(0.f, 0.f, 1.f, 0.f);
  if (qv) {
    pb = reinterpret_cast<const float4*>(boxes)[b*NQ + q];
    nb = prepN[b*NQ + q];
    pm = prepM[b*NQ + q];
  }
  const float areaA = pm.z;
  __syncthreads();
  for (int c = 0; c < GCHUNK / GSUB; ++c) {
    for (int gg = 0; gg < GSUB; ++gg) {
      const int gi = c * GSUB + gg, g = gl0 + gi;
      const float4 A0 = sgp[gi*5+0];
      const float4 A1 = sgp[gi*5+1];
      const float4 A2 = sgp[gi*5+2];
      const float4 A3 = sgp[gi*5+3];
      const float4 A4 = sgp[gi*5+4];
      const int lab = __float_as_int(A4.y);
      const float ccls = qv ? cct[((size_t)(b*NC + lab)) * NQ + q] : 0.f;
      const float ltx = fmaxf(pb.x, A3.x), lty = fmaxf(pb.y, A3.y);
      const float rbx = fminf(pb.z, A3.z), rby = fminf(pb.w, A3.w);
      const float iw = fmaxf(rbx - ltx, 0.f), ih = fmaxf(rby - lty, 0.f);
      const float inter = iw * ih;
      const float uni = areaA + A4.x - inter;
      const float iou = inter / uni;
      const float eltx = fminf(pb.x, A3.x), elty = fminf(pb.y, A3.y);
      const float erbx = fmaxf(pb.z, A3.z), erby = fmaxf(pb.w, A3.w);
      const float ew = fmaxf(erbx - eltx, 0.f), eh = fmaxf(erby - elty, 0.f);
      const float earea = ew * eh;
      const float giou = iou - (earea - uni) / earea;
      const float cbb = fabsf(nb.x - A2.x) + fabsf(nb.y - A2.y)
                      + fabsf(nb.z - A2.z) + fabsf(nb.w - A2.w);
      const bool inb = (pm.x > A0.x) && (pm.x < A0.z) && (pm.y > A0.y) && (pm.y < A0.w);
      const bool inc = (pm.x > A1.x) && (pm.x < A1.y) && (pm.y > A1.z) && (pm.y < A1.w);
      const bool ibc = inb && inc;
      float cval = 5.0f * cbb + 2.0f * ccls;
      cval = cval + 2.0f * (-giou);
      cval = cval + (ibc ? 0.f : 100.f);
      cval = cval + pm.w;
      if (qv) cost[((size_t)(b*NG + g)) * NQ + q] = cval;
      if (USET) tile[t * GSUB + gg] = cval;
    }
    if (USET) {
      __syncthreads();
      for (int i = t; i < 256 * GSUB; i += 256) {
        const int qq = i / GSUB, gg2 = i - qq * GSUB;
        if (q0 + qq < NQ)
          costT[((size_t)(b*NQ + q0 + qq)) * NG + gl0 + c * GSUB + gg2] = tile[qq * GSUB + gg2];
      }
      __syncthreads();
    }
  }
}

// ---------------- K3b: per-(b,g) top-5 — branchless u64-key chains ----------------
// 5-smallest-of-union trick: for ascending a[5], b[5], the 5 smallest of a∪b are
// {min(a_i, b_{4-i})}; re-sort with a 10-CE insertion network (correct by construction).
__device__ __forceinline__ void sort5_asc(u64t* c) {
#define CEA(i,j) { const u64t lo = umin64(c[i], c[j]); c[j] = umax64(c[i], c[j]); c[i] = lo; }
  CEA(0,1)
  CEA(1,2) CEA(0,1)
  CEA(2,3) CEA(1,2) CEA(0,1)
  CEA(3,4) CEA(2,3) CEA(1,2) CEA(0,1)
#undef CEA
}
__device__ __forceinline__ void sort5_desc(float* c) {
#define CED(i,j) { const float hi = fmaxf(c[i], c[j]); c[j] = fminf(c[i], c[j]); c[i] = hi; }
  CED(0,1)
  CED(1,2) CED(0,1)
  CED(2,3) CED(1,2) CED(0,1)
  CED(3,4) CED(2,3) CED(1,2) CED(0,1)
#undef CED
}
__device__ __forceinline__ void merge5_keys(u64t* a, const u64t* o) {
  u64t c[5];
#pragma unroll
  for (int i = 0; i < 5; ++i) c[i] = umin64(a[i], o[4 - i]);
  sort5_asc(c);
#pragma unroll
  for (int i = 0; i < 5; ++i) a[i] = c[i];
}
__device__ __forceinline__ void merge5_iou(float* a, const float* o) {
  float c[5];
#pragma unroll
  for (int i = 0; i < 5; ++i) c[i] = fmaxf(a[i], o[4 - i]);
  sort5_desc(c);
#pragma unroll
  for (int i = 0; i < 5; ++i) a[i] = c[i];
}

__global__ __launch_bounds__(128) void topk_kernel(
    const float* __restrict__ boxes, const float4* __restrict__ gp,
    const float* __restrict__ cost, unsigned* __restrict__ mbits,
    unsigned* __restrict__ mbitsT, int* __restrict__ rcnt) {
#pragma clang fp contract(off)
  const int g = blockIdx.x, b = blockIdx.y, t = threadIdx.x;
  const int lane = t & 63, wave = t >> 6;
  const float4 A3 = gp[(size_t)(b*NG + g) * 5 + 3];
  const float areaB = gp[(size_t)(b*NG + g) * 5 + 4].x;
  const float* __restrict__ crow = cost + ((size_t)(b*NG + g)) * NQ;
  unsigned* __restrict__ mrow = mbits + (b*NG + g) * NQW;
  for (int i = t; i < NQW; i += 128) mrow[i] = 0u;

  u64t kk[5]; float sv[5];
#pragma unroll
  for (int i = 0; i < 5; ++i) { kk[i] = ~0ull; sv[i] = -1.f; }

  for (int q = t; q < NQ; q += 128) {
    const float cval = crow[q] + 0.0f;  // canonicalize -0 -> +0
    const unsigned bits = __float_as_uint(cval);
    const unsigned mono = (bits & 0x80000000u) ? ~bits : (bits | 0x80000000u);
    u64t key = ((u64t)mono << 32) | (unsigned)q;
#pragma unroll
    for (int j = 0; j < 5; ++j) {       // branchless bubble: kk stays sorted ascending
      const u64t a = kk[j];
      kk[j] = umin64(a, key);
      key = umax64(a, key);
    }
    const float4 pb = reinterpret_cast<const float4*>(boxes)[b*NQ + q];
    const float areaA = (pb.z - pb.x) * (pb.w - pb.y);
    const float ltx = fmaxf(pb.x, A3.x), lty = fmaxf(pb.y, A3.y);
    const float rbx = fminf(pb.z, A3.z), rby = fminf(pb.w, A3.w);
    const float iw = fmaxf(rbx - ltx, 0.f), ih = fmaxf(rby - lty, 0.f);
    const float inter = iw * ih;
    const float uni = areaA + areaB - inter;
    float x = inter / uni;
#pragma unroll
    for (int j = 0; j < 5; ++j) {       // sv sorted descending
      const float a = sv[j];
      sv[j] = fmaxf(a, x);
      x = fminf(a, x);
    }
  }

#pragma unroll
  for (int off = 32; off >= 1; off >>= 1) {
    u64t ok[5]; float ov[5];
#pragma unroll
    for (int i = 0; i < 5; ++i) {
      const unsigned klo = __shfl_down((unsigned)(kk[i] & 0xffffffffu), off);
      const unsigned khi = __shfl_down((unsigned)(kk[i] >> 32), off);
      ok[i] = ((u64t)khi << 32) | klo;
      ov[i] = __shfl_down(sv[i], off);
    }
    merge5_keys(kk, ok);
    merge5_iou(sv, ov);
  }

  __shared__ u64t Lk[2][5];
  __shared__ float Ls[2][5];
  if (lane == 0) {
#pragma unroll
    for (int i = 0; i < 5; ++i) { Lk[wave][i] = kk[i]; Ls[wave][i] = sv[i]; }
  }
  __syncthreads();
  if (t == 0) {
    u64t fk[5]; float fs[5];
    u64t o2[5]; float s2[5];
#pragma unroll
    for (int i = 0; i < 5; ++i) { fk[i] = Lk[0][i]; fs[i] = Ls[0][i]; o2[i] = Lk[1][i]; s2[i] = Ls[1][i]; }
    merge5_keys(fk, o2);
    merge5_iou(fs, s2);
    float s = fs[0]; s += fs[1]; s += fs[2]; s += fs[3]; s += fs[4];  // descending order sum
    int k = (int)s; if (k < 1) k = 1; if (k > 5) k = 5;
    for (int i = 0; i < k; ++i) {
      const int q = (int)(fk[i] & 0xffffffffu);
      mrow[q >> 5] |= 1u << (q & 31);
      atomicOr(&mbitsT[((size_t)(b*NQ + q)) * NGW + (g >> 5)], 1u << (g & 31));
      atomicAdd(&rcnt[b * NQ + q], 1);
    }
  }
}

// ---------------- K4: compact multi rows ----------------
__global__ void compact_kernel(const int* __restrict__ rcnt, int* __restrict__ multi,
                               int* __restrict__ mlist, int* __restrict__ mcount) {
  const int idx = blockIdx.x * 256 + threadIdx.x;
  if (idx >= NB * NQ) return;
  const int b = idx / NQ, q = idx - b * NQ;
  if (rcnt[idx] > 1) {
    multi[idx] = 1;
    const int pos = atomicAdd(&mcount[b], 1);
    if (pos < MAXM) mlist[b * MAXM + pos] = q;
  } else multi[idx] = 0;
}

// ---------------- K5: multifix — one wave per multi row ----------------
template<int USET>
__global__ __launch_bounds__(256) void multifix_kernel(
    const float* __restrict__ cost, const float* __restrict__ costT,
    unsigned* __restrict__ mbits, unsigned* __restrict__ mbitsT,
    int* __restrict__ rcnt, const int* __restrict__ mlist, const int* __restrict__ mcount) {
  const int b = blockIdx.y;
  const int gw = blockIdx.x * 4 + (threadIdx.x >> 6);
  const int nw = gridDim.x * 4;
  const int lane = threadIdx.x & 63;
  int mn = mcount[b]; if (mn > MAXM) mn = MAXM;
  for (int i = gw; i < mn; i += nw) {
    const int q = mlist[b * MAXM + i];
    float best = FLT_MAX; int bg = 0;
    for (int g = lane; g < NG; g += 64) {
      const float v = USET ? costT[((size_t)(b*NQ + q)) * NG + g]
                           : cost[((size_t)(b*NG + g)) * NQ + q];
      if (v < best) { best = v; bg = g; }
    }
    for (int off = 32; off; off >>= 1) {
      const float ov = __shfl_down(best, off);
      const int og = __shfl_down(bg, off);
      if (ov < best || (ov == best && og < bg)) { best = ov; bg = og; }
    }
    bg = __shfl(bg, 0);
    unsigned* __restrict__ trow = mbitsT + (size_t)(b*NQ + q) * NGW;
    const unsigned qbit = 1u << (q & 31);
    const int qw = q >> 5;
    if (lane < NGW) {
      const unsigned wv = trow[lane];
      const unsigned want = ((bg >> 5) == lane) ? (1u << (bg & 31)) : 0u;
      unsigned clr = wv & ~want;
      while (clr) {
        const int gb = __ffs(clr) - 1; clr &= clr - 1;
        atomicAnd(&mbits[(b*NG + lane*32 + gb) * NQW + qw], ~qbit);
      }
      if (want & ~wv) atomicOr(&mbits[(b*NG + bg) * NQW + qw], qbit);
      trow[lane] = want;
    }
    if (lane == 0) rcnt[b * NQ + q] = 1;
  }
}

// ---------------- K6: column coverage counts ----------------
__global__ void colcov_kernel(const unsigned* __restrict__ mbits, int* __restrict__ ccov) {
  const int idx = blockIdx.x * 256 + threadIdx.x;
  if (idx >= NB * NG) return;
  const unsigned* row = mbits + idx * NQW;
  int c = 0;
  for (int i = 0; i < NQW; ++i) c += __popc(row[i]);
  ccov[idx] = c;
}

// ---------------- K7: the while-loop, one persistent block per image ----------------
// Rows never assigned keep pen==0 (>=2500 of 4000); penalized >= 99989 > max raw ~10160,
// so uncovered-column argmin only needs pen==0 rows at raw cost.
template<int USET>
__global__ __launch_bounds__(1024) void loop_kernel(
    const float* __restrict__ cost, const float* __restrict__ costT,
    unsigned* __restrict__ mbits, unsigned* __restrict__ mbitsT,
    const int* __restrict__ rcnt_g, const int* __restrict__ ccov_g,
    const int* __restrict__ multi_g, const int* __restrict__ mlist,
    const int* __restrict__ mcount, int* __restrict__ pen_g) {
  const int b = blockIdx.x, t = threadIdx.x;
  __shared__ int s_pen[NQ];
  __shared__ int s_rcnt[NQ];
  __shared__ unsigned char s_multi[NQ];
  __shared__ short s_qmi[NQ];
  __shared__ int s_ccov[NG];
  __shared__ int s_unc[NG];
  __shared__ int s_pickq[NG];
  __shared__ int s_mq[MAXM];
  __shared__ unsigned s_mrow[MAXM][NGW];
  __shared__ int s_n, s_fix, s_sticky;

  int m_n = mcount[b]; if (m_n > MAXM) m_n = MAXM;
  for (int q = t; q < NQ; q += 1024) {
    s_pen[q] = 0;
    s_rcnt[q] = rcnt_g[b * NQ + q];
    s_multi[q] = (unsigned char)multi_g[b * NQ + q];
    s_qmi[q] = -1;
  }
  for (int i = t; i < m_n; i += 1024) s_mq[i] = mlist[b * MAXM + i];
  for (int g = t; g < NG; g += 1024) s_ccov[g] = ccov_g[b * NG + g];
  if (t == 0) s_sticky = 0;
  __syncthreads();
  for (int i = t; i < m_n; i += 1024) s_qmi[s_mq[i]] = (short)i;
  unsigned* __restrict__ mbT = mbitsT + (size_t)b * NQ * NGW;
  for (int i = t; i < m_n * NGW; i += 1024) {
    const int mi = i / NGW, w2 = i - mi * NGW;
    s_mrow[mi][w2] = mbT[(size_t)s_mq[mi] * NGW + w2];
  }
  __syncthreads();

  unsigned* __restrict__ mb = mbits + b * NG * NQW;
  const float* __restrict__ cb = cost + (size_t)b * NG * NQ;
  const float* __restrict__ cbT = costT + (size_t)b * NQ * NG;
  const int lane = t & 63, wave = t >> 6;

  for (int iter = 0; iter < 100; ++iter) {
    if (t == 0) { s_n = 0; s_fix = s_sticky; }
    __syncthreads();
    for (int g = t; g < NG; g += 1024)
      if (s_ccov[g] == 0) { const int i = atomicAdd(&s_n, 1); s_unc[i] = g; }
    __syncthreads();
    const int n = s_n;
    if (n == 0) break;
    for (int q = t; q < NQ; q += 1024)
      if (s_rcnt[q] > 0) s_pen[q]++;
    __syncthreads();
    for (int ci = wave; ci < n; ci += 16) {
      const int g = s_unc[ci];
      const float* __restrict__ crow = cb + (size_t)g * NQ;
      float best = FLT_MAX; int bq = 0x7fffffff;
      for (int q = lane; q < NQ; q += 64) {
        if (s_pen[q] == 0) {
          const float v = crow[q];
          if (v < best) { best = v; bq = q; }
        }
      }
      for (int off = 32; off; off >>= 1) {
        const float ov = __shfl_down(best, off);
        const int oq = __shfl_down(bq, off);
        if (ov < best || (ov == best && oq < bq)) { best = ov; bq = oq; }
      }
      if (lane == 0) s_pickq[ci] = bq;
    }
    __syncthreads();
    if (t < n) {
      const int g = s_unc[t], q = s_pickq[t];
      atomicOr(&mb[g * NQW + (q >> 5)], 1u << (q & 31));
      const int mi2 = s_qmi[q];
      if (mi2 >= 0) atomicOr(&s_mrow[mi2][g >> 5], 1u << (g & 31));
      else atomicOr(&mbT[(size_t)q * NGW + (g >> 5)], 1u << (g & 31));
      const int nc = atomicAdd(&s_rcnt[q], 1) + 1;
      s_ccov[g] = 1;
      if (nc > 1) { s_fix = 1; if (!s_multi[q]) s_sticky = 1; }
    }
    __syncthreads();
    if (s_fix) {
      for (int mi = wave; mi < m_n; mi += 16) {
        const int q = s_mq[mi];
        const int p = s_pen[q];
        float best = FLT_MAX; int bg = 0;
        for (int g = lane; g < NG; g += 64) {
          const float raw = USET ? cbT[(size_t)q * NG + g] : cb[(size_t)g * NQ + q];
          const float v = penalized(raw, p);
          if (v < best) { best = v; bg = g; }
        }
        for (int off = 32; off; off >>= 1) {
          const float ov = __shfl_down(best, off);
          const int og = __shfl_down(bg, off);
          if (ov < best || (ov == best && og < bg)) { best = ov; bg = og; }
        }
        bg = __shfl(bg, 0);
        const unsigned qbit = 1u << (q & 31);
        const int qw = q >> 5;
        if (lane < NGW) {
          const unsigned wv = s_mrow[mi][lane];
          const unsigned want = ((bg >> 5) == lane) ? (1u << (bg & 31)) : 0u;
          unsigned clr = wv & ~want;
          while (clr) {
            const int gb = __ffs(clr) - 1; clr &= clr - 1;
            const int g = lane * 32 + gb;
            atomicAnd(&mb[g * NQW + qw], ~qbit);
            atomicSub(&s_ccov[g], 1);
          }
          if (want & ~wv) {
            atomicOr(&mb[bg * NQW + qw], qbit);
            atomicAdd(&s_ccov[bg], 1);
          }
          s_mrow[mi][lane] = want;
        }
        if (lane == 0) s_rcnt[q] = 1;
      }
    }
    __syncthreads();
  }
  __syncthreads();
  for (int i = t; i < m_n * NGW; i += 1024) {
    const int mi = i / NGW, w2 = i - mi * NGW;
    mbT[(size_t)s_mq[mi] * NGW + w2] = s_mrow[mi][w2];
  }
  for (int q = t; q < NQ; q += 1024) pen_g[b * NQ + q] = s_pen[q];
}

// ---------------- K8: matched_qidx ----------------
__global__ void matched_kernel(const float* __restrict__ cost, const unsigned* __restrict__ mbits,
                               const int* __restrict__ pen_g, float* __restrict__ out_mq) {
  const int g = blockIdx.x, b = blockIdx.y, t = threadIdx.x;
  const float* __restrict__ crow = cost + ((size_t)(b*NG + g)) * NQ;
  const unsigned* __restrict__ mrow = mbits + (b*NG + g) * NQW;
  const int* __restrict__ pb = pen_g + b * NQ;
  float best = FLT_MAX; int bq = 0;
  for (int q = t; q < NQ; q += 256) {
    if ((mrow[q >> 5] >> (q & 31)) & 1u) {
      const float v = penalized(crow[q], pb[q]);
      if (v < best) { best = v; bq = q; }
    }
  }
  __shared__ float rv[256];
  __shared__ int rq[256];
  rv[t] = best; rq[t] = bq;
  __syncthreads();
  for (int off = 128; off; off >>= 1) {
    if (t < off) {
      if (lexlt(rv[t + off], rq[t + off], rv[t], rq[t])) { rv[t] = rv[t + off]; rq[t] = rq[t + off]; }
    }
    __syncthreads();
  }
  if (t == 0) out_mq[b * NG + g] = (float)rq[0];
}

// ---------------- K9: expand mbitsT rows -> m floats, selected, gt_idx ----------------
__global__ void out_kernel(const unsigned* __restrict__ mbitsT, float* __restrict__ out_m,
                           float* __restrict__ out_sel, float* __restrict__ out_gti) {
  const int b = blockIdx.y, t = threadIdx.x;
  const int q0 = blockIdx.x * 8;
  __shared__ unsigned wds[8 * NGW];
  if (t < 8 * NGW) wds[t] = mbitsT[((size_t)(b*NQ + q0)) * NGW + t];
  __syncthreads();
  float* __restrict__ om = out_m + ((size_t)(b*NQ + q0)) * NG;
  for (int i = t; i < 8 * NG; i += 256) {
    const int qi = i / NG, g = i - qi * NG;
    om[i] = ((wds[qi*NGW + (g >> 5)] >> (g & 31)) & 1u) ? 1.f : 0.f;
  }
  if (t < 8) {
    int fgi = -1;
    for (int w = 0; w < NGW; ++w) {
      const unsigned v = wds[t*NGW + w];
      if (v) { fgi = w*32 + __ffs(v) - 1; break; }
    }
    out_sel[b*NQ + q0 + t] = (fgi >= 0) ? 1.f : 0.f;
    out_gti[b*NQ + q0 + t] = (fgi >= 0) ? (float)fgi : 0.f;
  }
}

extern "C" void kernel_launch(void* const* d_in, const int* in_sizes, int n_in,
                              void* d_out, int out_size, void* d_ws, size_t ws_size,
                              hipStream_t stream) {
  const float* logits = (const float*)d_in[0];
  const float* boxes  = (const float*)d_in[1];
  const int*   labels = (const int*)d_in[2];
  const float* gtb    = (const float*)d_in[3];
  const float* imgsz  = (const float*)d_in[4];

  float* out = (float*)d_out;
  float* out_m   = out;                                   // B*Q*G
  float* out_sel = out + (size_t)NB * NQ * NG;            // B*Q
  float* out_gti = out_sel + (size_t)NB * NQ;             // B*Q
  float* out_mq  = out_gti + (size_t)NB * NQ;             // B*G

  char* w = (char*)d_ws;
  const size_t szPrep = sizeof(float4) * (size_t)NB * NQ;
  const size_t szGp   = sizeof(float4) * (size_t)NB * NG * 5;
  const size_t szCct  = sizeof(float) * (size_t)NB * NC * NQ;
  const size_t szBits = sizeof(unsigned) * (size_t)NB * NG * NQW;
  const size_t szBitsT= sizeof(unsigned) * (size_t)NB * NQ * NGW;
  const size_t szIntQ = sizeof(int) * (size_t)NB * NQ;
  const size_t szIntG = sizeof(int) * (size_t)NB * NG;
  const size_t szML   = sizeof(int) * (size_t)NB * MAXM;
  const size_t szMC   = sizeof(int) * 64;
  const size_t szCT   = sizeof(float) * (size_t)NB * NQ * NG;
  const size_t base_need = 2*szPrep + szGp + szCct + szBits + szBitsT + 3*szIntQ + szIntG + szML + szMC;
  if (ws_size < base_need) return;
  const int useT = (ws_size >= base_need + szCT) ? 1 : 0;

  float4* prepN = (float4*)w; w += szPrep;
  float4* prepM = (float4*)w; w += szPrep;
  float4* gp    = (float4*)w; w += szGp;
  float*    cct   = (float*)w;    w += szCct;
  unsigned* mbits = (unsigned*)w; w += szBits;
  unsigned* mbitsT= (unsigned*)w; w += szBitsT;
  int* rcnt  = (int*)w; w += szIntQ;
  int* multi = (int*)w; w += szIntQ;
  int* pen   = (int*)w; w += szIntQ;
  int* ccov  = (int*)w; w += szIntG;
  int* mlist = (int*)w; w += szML;
  int* mcount= (int*)w; w += szMC;
  float* costT = (float*)w;  // valid only if useT

  float* cost = out_m;  // (B,G,Q) in the d_out m-region; overwritten by out_kernel at the end

  prep_kernel<<<dim3((NQ + 255) / 256, NB), 256, 0, stream>>>(boxes, gtb, imgsz, prepN, prepM, rcnt, mbitsT, mcount);
  gprep_kernel<<<(NB * NG + 255) / 256, 256, 0, stream>>>(gtb, labels, imgsz, gp);
  cls_kernel<<<dim3((NQ + QT - 1) / QT, NB), 256, 0, stream>>>(logits, cct);
  if (useT)
    costA_kernel<1><<<dim3((NQ + 255) / 256, GSPLIT, NB), 256, 0, stream>>>(boxes, prepN, prepM, gp, cct, cost, costT);
  else
    costA_kernel<0><<<dim3((NQ + 255) / 256, GSPLIT, NB), 256, 0, stream>>>(boxes, prepN, prepM, gp, cct, cost, costT);
  topk_kernel<<<dim3(NG, NB), 128, 0, stream>>>(boxes, gp, cost, mbits, mbitsT, rcnt);
  compact_kernel<<<(NB * NQ + 255) / 256, 256, 0, stream>>>(rcnt, multi, mlist, mcount);
  if (useT)
    multifix_kernel<1><<<dim3(12, NB), 256, 0, stream>>>(cost, costT, mbits, mbitsT, rcnt, mlist, mcount);
  else
    multifix_kernel<0><<<dim3(12, NB), 256, 0, stream>>>(cost, costT, mbits, mbitsT, rcnt, mlist, mcount);
  colcov_kernel<<<(NB * NG + 255) / 256, 256, 0, stream>>>(mbits, ccov);
  if (useT)
    loop_kernel<1><<<NB, 1024, 0, stream>>>(cost, costT, mbits, mbitsT, rcnt, ccov, multi, mlist, mcount, pen);
  else
    loop_kernel<0><<<NB, 1024, 0, stream>>>(cost, costT, mbits, mbitsT, rcnt, ccov, multi, mlist, mcount, pen);
  matched_kernel<<<dim3(NG, NB), 256, 0, stream>>>(cost, mbits, pen, out_mq);
  out_kernel<<<dim3(NQ / 8, NB), 256, 0, stream>>>(mbitsT, out_m, out_sel, out_gti);
}

// Round 6
// 304.104 us; speedup vs baseline: 1.4906x; 1.0491x over previous
//
#include <hip/hip_runtime.h>
#include <float.h>
#include <stdint.h>
#include <stddef.h>

#define NB 16
#define NQ 4000
#define NG 300
#define NC 81
#define NQW 125  // NQ/32
#define NGW 10   // ceil(NG/32)
#define MAXM 768 // multi rows per image <= sum(dyn_k)/2 <= 750 (provable bound)
#define GSPLIT 4
#define GCHUNK 75   // NG / GSPLIT

typedef unsigned long long u64t;

__device__ __forceinline__ bool lexlt(float v1, int i1, float v2, int i2) {
  return (v1 < v2) || (v1 == v2 && i1 < i2);
}
__device__ __forceinline__ u64t umin64(u64t a, u64t b) { return a < b ? a : b; }
__device__ __forceinline__ u64t umax64(u64t a, u64t b) { return a > b ? a : b; }

// Exact replica of p sequential f32 adds of 1e5 (numpy semantics), in O(#binade crossings).
__device__ __forceinline__ float penalized(float v, int p) {
  if (p <= 0) return v;
  if (p <= 12) {
    float x = v;
    for (int r = 0; r < p; ++r) x += 100000.0f;
    return x;
  }
  double x = (double)v;
  x = (double)(float)(x + 100000.0);
  int k = 1;
  while (k < p) {
    double B = 131072.0;
    while (B <= x) B += B;
    double room = B - x;
    int j = (int)(room * 1e-5);
    while (j > 0 && x + (double)j * 100000.0 >= B) --j;
    if (j > p - k) j = p - k;
    if (j > 0) { x += (double)j * 100000.0; k += j; }
    if (k < p) { x = (double)(float)(x + 100000.0); ++k; }
  }
  return (float)x;
}

// ---------------- K0: per-gt derived params ----------------
// layout per (b,g): 5 float4s:
//  [0] xg0,yg0,xg1,yg1 (fp-roundtripped box)  [1] cxlo,cxhi,cylo,cyhi
//  [2] ngx0,ngy0,ngx1,ngy1                    [3] gx0,gy0,gx1,gy1 (original)
//  [4] areaB, lab(bits), 0, 0
__global__ void gprep_kernel(const float* __restrict__ gtb, const int* __restrict__ labels,
                             const float* __restrict__ imgsz, float4* __restrict__ gp) {
#pragma clang fp contract(off)
  const int idx = blockIdx.x * 256 + threadIdx.x;
  if (idx >= NB * NG) return;
  const int b = idx / NG;
  const float gx0 = gtb[idx*4 + 0];
  const float gy0 = gtb[idx*4 + 1];
  const float gx1 = gtb[idx*4 + 2];
  const float gy1 = gtb[idx*4 + 3];
  const float s0 = imgsz[b*4+0], s1 = imgsz[b*4+1], s2 = imgsz[b*4+2], s3 = imgsz[b*4+3];
  const float areaB = (gx1 - gx0) * (gy1 - gy0);
  const float gcx = (gx0 + gx1) * 0.5f, gcy = (gy0 + gy1) * 0.5f;
  const float gw0 = gx1 - gx0, gh0 = gy1 - gy0;
  const float xg0 = gcx - 0.5f*gw0, yg0 = gcy - 0.5f*gh0;
  const float xg1 = gcx + 0.5f*gw0, yg1 = gcy + 0.5f*gh0;
  const float cw = xg1 - xg0, ch = yg1 - yg0;
  gp[idx*5+0] = make_float4(xg0, yg0, xg1, yg1);
  gp[idx*5+1] = make_float4(gcx - 2.5f*cw, gcx + 2.5f*cw, gcy - 2.5f*ch, gcy + 2.5f*ch);
  gp[idx*5+2] = make_float4(gx0 / s0, gy0 / s1, gx1 / s2, gy1 / s3);
  gp[idx*5+3] = make_float4(gx0, gy0, gx1, gy1);
  gp[idx*5+4] = make_float4(areaB, __int_as_float(labels[idx]), 0.f, 0.f);
}

// ---------------- K1: prep — fg mask via gp, normalized box, center/area; zero rcnt/mbitsT/mcount ----------------
__global__ void prep_kernel(const float* __restrict__ boxes, const float4* __restrict__ gp,
                            const float* __restrict__ imgsz,
                            float4* __restrict__ prepN, float4* __restrict__ prepM,
                            int* __restrict__ rcnt, unsigned* __restrict__ mbitsT,
                            int* __restrict__ mcount) {
#pragma clang fp contract(off)
  const int b = blockIdx.y;
  const int q = blockIdx.x * 256 + threadIdx.x;
  const int tid = (blockIdx.y * gridDim.x + blockIdx.x) * 256 + threadIdx.x;
  const int nthreads = gridDim.x * gridDim.y * 256;
  for (int i = tid; i < NB * NQ * NGW; i += nthreads) mbitsT[i] = 0u;
  if (tid < NB) mcount[tid] = 0;
  __shared__ float4 sA0[NG];
  __shared__ float4 sA1[NG];
  for (int i = threadIdx.x; i < NG; i += 256) {
    sA0[i] = gp[(size_t)(b*NG + i)*5 + 0];
    sA1[i] = gp[(size_t)(b*NG + i)*5 + 1];
  }
  __syncthreads();
  if (q >= NQ) return;
  const float4 pb = reinterpret_cast<const float4*>(boxes)[b * NQ + q];
  const float s0 = imgsz[b*4+0], s1 = imgsz[b*4+1], s2 = imgsz[b*4+2], s3 = imgsz[b*4+3];
  const float ax = (pb.x + pb.z) * 0.5f;
  const float ay = (pb.y + pb.w) * 0.5f;
  bool anyb = false, anyc = false;
  for (int g = 0; g < NG; ++g) {
    const float4 A0 = sA0[g];
    const float4 A1 = sA1[g];
    anyb = anyb || ((ax > A0.x) && (ax < A0.z) && (ay > A0.y) && (ay < A0.w));
    anyc = anyc || ((ax > A1.x) && (ax < A1.y) && (ay > A1.z) && (ay < A1.w));
  }
  const int idx = b * NQ + q;
  prepN[idx] = make_float4(pb.x / s0, pb.y / s1, pb.z / s2, pb.w / s3);
  prepM[idx] = make_float4(ax, ay, (pb.z - pb.x) * (pb.w - pb.y),
                           (anyb || anyc) ? 0.f : 10000.f);
  rcnt[idx] = 0;
}

// ---------------- K2: focal class cost table, transposed (B,C,Q), tiled ----------------
#define QT 64
__global__ void cls_kernel(const float* __restrict__ logits, float* __restrict__ cct) {
#pragma clang fp contract(off)
  const int b = blockIdx.y, q0 = blockIdx.x * QT, t = threadIdx.x;
  __shared__ float tile[QT * NC];
  const int nq = (NQ - q0 < QT) ? (NQ - q0) : QT;
  const float* __restrict__ src = logits + ((size_t)(b * NQ + q0)) * NC;
  for (int i = t; i < nq * NC; i += 256) {
    const float x = src[i];
    float p;
    if (x >= 0.f) p = 1.f / (1.f + expf(-x));
    else { const float e = expf(x); p = e / (1.f + e); }
    const float pos = 0.25f * ((1.f - p) * (1.f - p)) * (-logf(p + 1e-8f));
    const float neg = 0.75f * (p * p) * (-logf(1.f - p + 1e-8f));
    tile[i] = pos - neg;
  }
  __syncthreads();
  for (int i = t; i < NC * QT; i += 256) {
    const int c = i >> 6;
    const int ql = i & (QT - 1);
    if (ql < nq) cct[((size_t)(b * NC + c)) * NQ + q0 + ql] = tile[ql * NC + c];
  }
}

// ---------------- K3a: featurize — q-resident registers, loop over g, single layout ----------------
__global__ __launch_bounds__(256) void costA_kernel(
    const float* __restrict__ boxes, const float4* __restrict__ prepN,
    const float4* __restrict__ prepM, const float4* __restrict__ gp,
    const float* __restrict__ cct, float* __restrict__ cost) {
#pragma clang fp contract(off)
  const int b = blockIdx.z, t = threadIdx.x;
  const int q0 = blockIdx.x * 256, gl0 = blockIdx.y * GCHUNK;
  __shared__ float4 sgp[GCHUNK * 5];
  for (int i = t; i < GCHUNK * 5; i += 256) sgp[i] = gp[(size_t)(b*NG + gl0) * 5 + i];
  const int q = q0 + t;
  const bool qv = q < NQ;
  float4 pb = make_float4(0.f, 0.f, 1.f, 1.f);
  float4 nb = make_float4(0.f, 0.f, 0.f, 0.f);
  float4 pm = make_float4(0.f, 0.f, 1.f, 0.f);
  if (qv) {
    pb = reinterpret_cast<const float4*>(boxes)[b*NQ + q];
    nb = prepN[b*NQ + q];
    pm = prepM[b*NQ + q];
  }
  const float areaA = pm.z;
  __syncthreads();
  for (int gi = 0; gi < GCHUNK; ++gi) {
    const int g = gl0 + gi;
    const float4 A0 = sgp[gi*5+0];
    const float4 A1 = sgp[gi*5+1];
    const float4 A2 = sgp[gi*5+2];
    const float4 A3 = sgp[gi*5+3];
    const float4 A4 = sgp[gi*5+4];
    const int lab = __float_as_int(A4.y);
    const float ccls = qv ? cct[((size_t)(b*NC + lab)) * NQ + q] : 0.f;
    const float ltx = fmaxf(pb.x, A3.x), lty = fmaxf(pb.y, A3.y);
    const float rbx = fminf(pb.z, A3.z), rby = fminf(pb.w, A3.w);
    const float iw = fmaxf(rbx - ltx, 0.f), ih = fmaxf(rby - lty, 0.f);
    const float inter = iw * ih;
    const float uni = areaA + A4.x - inter;
    const float iou = inter / uni;
    const float eltx = fminf(pb.x, A3.x), elty = fminf(pb.y, A3.y);
    const float erbx = fmaxf(pb.z, A3.z), erby = fmaxf(pb.w, A3.w);
    const float ew = fmaxf(erbx - eltx, 0.f), eh = fmaxf(erby - elty, 0.f);
    const float earea = ew * eh;
    const float giou = iou - (earea - uni) / earea;
    const float cbb = fabsf(nb.x - A2.x) + fabsf(nb.y - A2.y)
                    + fabsf(nb.z - A2.z) + fabsf(nb.w - A2.w);
    const bool inb = (pm.x > A0.x) && (pm.x < A0.z) && (pm.y > A0.y) && (pm.y < A0.w);
    const bool inc = (pm.x > A1.x) && (pm.x < A1.y) && (pm.y > A1.z) && (pm.y < A1.w);
    const bool ibc = inb && inc;
    float cval = 5.0f * cbb + 2.0f * ccls;
    cval = cval + 2.0f * (-giou);
    cval = cval + (ibc ? 0.f : 100.f);
    cval = cval + pm.w;
    if (qv) cost[((size_t)(b*NG + g)) * NQ + q] = cval;
  }
}

// ---------------- K3b: per-(b,g) top-5 — branchless u64-key chains ----------------
__device__ __forceinline__ void sort5_asc(u64t* c) {
#define CEA(i,j) { const u64t lo = umin64(c[i], c[j]); c[j] = umax64(c[i], c[j]); c[i] = lo; }
  CEA(0,1)
  CEA(1,2) CEA(0,1)
  CEA(2,3) CEA(1,2) CEA(0,1)
  CEA(3,4) CEA(2,3) CEA(1,2) CEA(0,1)
#undef CEA
}
__device__ __forceinline__ void sort5_desc(float* c) {
#define CED(i,j) { const float hi = fmaxf(c[i], c[j]); c[j] = fminf(c[i], c[j]); c[i] = hi; }
  CED(0,1)
  CED(1,2) CED(0,1)
  CED(2,3) CED(1,2) CED(0,1)
  CED(3,4) CED(2,3) CED(1,2) CED(0,1)
#undef CED
}
__device__ __forceinline__ void merge5_keys(u64t* a, const u64t* o) {
  u64t c[5];
#pragma unroll
  for (int i = 0; i < 5; ++i) c[i] = umin64(a[i], o[4 - i]);
  sort5_asc(c);
#pragma unroll
  for (int i = 0; i < 5; ++i) a[i] = c[i];
}
__device__ __forceinline__ void merge5_iou(float* a, const float* o) {
  float c[5];
#pragma unroll
  for (int i = 0; i < 5; ++i) c[i] = fmaxf(a[i], o[4 - i]);
  sort5_desc(c);
#pragma unroll
  for (int i = 0; i < 5; ++i) a[i] = c[i];
}

__global__ __launch_bounds__(128) void topk_kernel(
    const float* __restrict__ boxes, const float4* __restrict__ gp,
    const float* __restrict__ cost, unsigned* __restrict__ mbits,
    unsigned* __restrict__ mbitsT, int* __restrict__ rcnt) {
#pragma clang fp contract(off)
  const int g = blockIdx.x, b = blockIdx.y, t = threadIdx.x;
  const int lane = t & 63, wave = t >> 6;
  const float4 A3 = gp[(size_t)(b*NG + g) * 5 + 3];
  const float areaB = gp[(size_t)(b*NG + g) * 5 + 4].x;
  const float* __restrict__ crow = cost + ((size_t)(b*NG + g)) * NQ;
  unsigned* __restrict__ mrow = mbits + (b*NG + g) * NQW;
  for (int i = t; i < NQW; i += 128) mrow[i] = 0u;

  u64t kk[5]; float sv[5];
#pragma unroll
  for (int i = 0; i < 5; ++i) { kk[i] = ~0ull; sv[i] = -1.f; }

  for (int q = t; q < NQ; q += 128) {
    const float cval = crow[q] + 0.0f;  // canonicalize -0 -> +0
    const unsigned bits = __float_as_uint(cval);
    const unsigned mono = (bits & 0x80000000u) ? ~bits : (bits | 0x80000000u);
    u64t key = ((u64t)mono << 32) | (unsigned)q;
#pragma unroll
    for (int j = 0; j < 5; ++j) {
      const u64t a = kk[j];
      kk[j] = umin64(a, key);
      key = umax64(a, key);
    }
    const float4 pb = reinterpret_cast<const float4*>(boxes)[b*NQ + q];
    const float areaA = (pb.z - pb.x) * (pb.w - pb.y);
    const float ltx = fmaxf(pb.x, A3.x), lty = fmaxf(pb.y, A3.y);
    const float rbx = fminf(pb.z, A3.z), rby = fminf(pb.w, A3.w);
    const float iw = fmaxf(rbx - ltx, 0.f), ih = fmaxf(rby - lty, 0.f);
    const float inter = iw * ih;
    const float uni = areaA + areaB - inter;
    float x = inter / uni;
#pragma unroll
    for (int j = 0; j < 5; ++j) {
      const float a = sv[j];
      sv[j] = fmaxf(a, x);
      x = fminf(a, x);
    }
  }

#pragma unroll
  for (int off = 32; off >= 1; off >>= 1) {
    u64t ok[5]; float ov[5];
#pragma unroll
    for (int i = 0; i < 5; ++i) {
      const unsigned klo = __shfl_down((unsigned)(kk[i] & 0xffffffffu), off);
      const unsigned khi = __shfl_down((unsigned)(kk[i] >> 32), off);
      ok[i] = ((u64t)khi << 32) | klo;
      ov[i] = __shfl_down(sv[i], off);
    }
    merge5_keys(kk, ok);
    merge5_iou(sv, ov);
  }

  __shared__ u64t Lk[2][5];
  __shared__ float Ls[2][5];
  if (lane == 0) {
#pragma unroll
    for (int i = 0; i < 5; ++i) { Lk[wave][i] = kk[i]; Ls[wave][i] = sv[i]; }
  }
  __syncthreads();
  if (t == 0) {
    u64t fk[5]; float fs[5];
    u64t o2[5]; float s2[5];
#pragma unroll
    for (int i = 0; i < 5; ++i) { fk[i] = Lk[0][i]; fs[i] = Ls[0][i]; o2[i] = Lk[1][i]; s2[i] = Ls[1][i]; }
    merge5_keys(fk, o2);
    merge5_iou(fs, s2);
    float s = fs[0]; s += fs[1]; s += fs[2]; s += fs[3]; s += fs[4];
    int k = (int)s; if (k < 1) k = 1; if (k > 5) k = 5;
    for (int i = 0; i < k; ++i) {
      const int q = (int)(fk[i] & 0xffffffffu);
      mrow[q >> 5] |= 1u << (q & 31);
      atomicOr(&mbitsT[((size_t)(b*NQ + q)) * NGW + (g >> 5)], 1u << (g & 31));
      atomicAdd(&rcnt[b * NQ + q], 1);
    }
  }
}

// ---------------- K4: compact multi rows ----------------
__global__ void compact_kernel(const int* __restrict__ rcnt,
                               int* __restrict__ mlist, int* __restrict__ mcount) {
  const int idx = blockIdx.x * 256 + threadIdx.x;
  if (idx >= NB * NQ) return;
  const int b = idx / NQ, q = idx - b * NQ;
  if (rcnt[idx] > 1) {
    const int pos = atomicAdd(&mcount[b], 1);
    if (pos < MAXM) mlist[b * MAXM + pos] = q;
  }
}

// ---------------- K4b: gather multi-row cost slices (coalesced writes, L3-resident reads) ----------------
__global__ __launch_bounds__(256) void gatherM_kernel(
    const float* __restrict__ cost, const int* __restrict__ mlist,
    const int* __restrict__ mcount, float* __restrict__ costM) {
  const int b = blockIdx.y;
  const int w = blockIdx.x * 4 + (threadIdx.x >> 6);
  const int nw = gridDim.x * 4;
  const int lane = threadIdx.x & 63;
  int mn = mcount[b]; if (mn > MAXM) mn = MAXM;
  const float* __restrict__ cb = cost + (size_t)b * NG * NQ;
  for (int i = w; i < mn; i += nw) {
    const int q = mlist[b * MAXM + i];
    float* __restrict__ dst = costM + ((size_t)b * MAXM + i) * NG;
    for (int g = lane; g < NG; g += 64) dst[g] = cb[(size_t)g * NQ + q];
  }
}

// ---------------- K5: multifix — one wave per multi row, reads costM ----------------
__global__ __launch_bounds__(256) void multifix_kernel(
    const float* __restrict__ costM,
    unsigned* __restrict__ mbits, unsigned* __restrict__ mbitsT,
    int* __restrict__ rcnt, const int* __restrict__ mlist, const int* __restrict__ mcount) {
  const int b = blockIdx.y;
  const int gw = blockIdx.x * 4 + (threadIdx.x >> 6);
  const int nw = gridDim.x * 4;
  const int lane = threadIdx.x & 63;
  int mn = mcount[b]; if (mn > MAXM) mn = MAXM;
  for (int i = gw; i < mn; i += nw) {
    const int q = mlist[b * MAXM + i];
    const float* __restrict__ row = costM + ((size_t)b * MAXM + i) * NG;
    float best = FLT_MAX; int bg = 0;
    for (int g = lane; g < NG; g += 64) {
      const float v = row[g];
      if (v < best) { best = v; bg = g; }
    }
    for (int off = 32; off; off >>= 1) {
      const float ov = __shfl_down(best, off);
      const int og = __shfl_down(bg, off);
      if (ov < best || (ov == best && og < bg)) { best = ov; bg = og; }
    }
    bg = __shfl(bg, 0);
    unsigned* __restrict__ trow = mbitsT + (size_t)(b*NQ + q) * NGW;
    const unsigned qbit = 1u << (q & 31);
    const int qw = q >> 5;
    if (lane < NGW) {
      const unsigned wv = trow[lane];
      const unsigned want = ((bg >> 5) == lane) ? (1u << (bg & 31)) : 0u;
      unsigned clr = wv & ~want;
      while (clr) {
        const int gb = __ffs(clr) - 1; clr &= clr - 1;
        atomicAnd(&mbits[(b*NG + lane*32 + gb) * NQW + qw], ~qbit);
      }
      if (want & ~wv) atomicOr(&mbits[(b*NG + bg) * NQW + qw], qbit);
      trow[lane] = want;
    }
    if (lane == 0) rcnt[b * NQ + q] = 1;
  }
}

// ---------------- K6: column coverage counts ----------------
__global__ void colcov_kernel(const unsigned* __restrict__ mbits, int* __restrict__ ccov) {
  const int idx = blockIdx.x * 256 + threadIdx.x;
  if (idx >= NB * NG) return;
  const unsigned* row = mbits + idx * NQW;
  int c = 0;
  for (int i = 0; i < NQW; ++i) c += __popc(row[i]);
  ccov[idx] = c;
}

// ---------------- K7: the while-loop, one persistent block per image ----------------
// Rows never assigned keep pen==0 (>=2500 of 4000); penalized >= 99989 > max raw ~10160,
// so uncovered-column argmin only needs pen==0 rows at raw cost.
__global__ __launch_bounds__(1024) void loop_kernel(
    const float* __restrict__ cost, const float* __restrict__ costM,
    unsigned* __restrict__ mbits, unsigned* __restrict__ mbitsT,
    const int* __restrict__ rcnt_g, const int* __restrict__ ccov_g,
    const int* __restrict__ mlist, const int* __restrict__ mcount,
    int* __restrict__ pen_g) {
  const int b = blockIdx.x, t = threadIdx.x;
  __shared__ int s_pen[NQ];
  __shared__ int s_rcnt[NQ];
  __shared__ short s_qmi[NQ];
  __shared__ int s_ccov[NG];
  __shared__ int s_unc[NG];
  __shared__ int s_pickq[NG];
  __shared__ int s_mq[MAXM];
  __shared__ unsigned s_mrow[MAXM][NGW];
  __shared__ int s_n, s_fix, s_sticky;

  int m_n = mcount[b]; if (m_n > MAXM) m_n = MAXM;
  for (int q = t; q < NQ; q += 1024) {
    s_pen[q] = 0;
    s_rcnt[q] = rcnt_g[b * NQ + q];
    s_qmi[q] = -1;
  }
  for (int i = t; i < m_n; i += 1024) s_mq[i] = mlist[b * MAXM + i];
  for (int g = t; g < NG; g += 1024) s_ccov[g] = ccov_g[b * NG + g];
  if (t == 0) s_sticky = 0;
  __syncthreads();
  for (int i = t; i < m_n; i += 1024) s_qmi[s_mq[i]] = (short)i;
  unsigned* __restrict__ mbT = mbitsT + (size_t)b * NQ * NGW;
  for (int i = t; i < m_n * NGW; i += 1024) {
    const int mi = i / NGW, w2 = i - mi * NGW;
    s_mrow[mi][w2] = mbT[(size_t)s_mq[mi] * NGW + w2];
  }
  __syncthreads();

  unsigned* __restrict__ mb = mbits + b * NG * NQW;
  const float* __restrict__ cb = cost + (size_t)b * NG * NQ;
  const float* __restrict__ cm = costM + (size_t)b * MAXM * NG;
  const int lane = t & 63, wave = t >> 6;

  for (int iter = 0; iter < 100; ++iter) {
    if (t == 0) { s_n = 0; s_fix = s_sticky; }
    __syncthreads();
    for (int g = t; g < NG; g += 1024)
      if (s_ccov[g] == 0) { const int i = atomicAdd(&s_n, 1); s_unc[i] = g; }
    __syncthreads();
    const int n = s_n;
    if (n == 0) break;
    for (int q = t; q < NQ; q += 1024)
      if (s_rcnt[q] > 0) s_pen[q]++;
    __syncthreads();
    for (int ci = wave; ci < n; ci += 16) {
      const int g = s_unc[ci];
      const float* __restrict__ crow = cb + (size_t)g * NQ;
      float best = FLT_MAX; int bq = 0x7fffffff;
      for (int q = lane; q < NQ; q += 64) {
        if (s_pen[q] == 0) {
          const float v = crow[q];
          if (v < best) { best = v; bq = q; }
        }
      }
      for (int off = 32; off; off >>= 1) {
        const float ov = __shfl_down(best, off);
        const int oq = __shfl_down(bq, off);
        if (ov < best || (ov == best && oq < bq)) { best = ov; bq = oq; }
      }
      if (lane == 0) s_pickq[ci] = bq;
    }
    __syncthreads();
    if (t < n) {
      const int g = s_unc[t], q = s_pickq[t];
      atomicOr(&mb[g * NQW + (q >> 5)], 1u << (q & 31));
      const int mi2 = s_qmi[q];
      if (mi2 >= 0) atomicOr(&s_mrow[mi2][g >> 5], 1u << (g & 31));
      else atomicOr(&mbT[(size_t)q * NGW + (g >> 5)], 1u << (g & 31));
      const int nc = atomicAdd(&s_rcnt[q], 1) + 1;
      s_ccov[g] = 1;
      if (nc > 1) { s_fix = 1; if (s_qmi[q] < 0) s_sticky = 1; }
    }
    __syncthreads();
    if (s_fix) {
      for (int mi = wave; mi < m_n; mi += 16) {
        const int q = s_mq[mi];
        const int p = s_pen[q];
        const float* __restrict__ row = cm + (size_t)mi * NG;
        float best = FLT_MAX; int bg = 0;
        for (int g = lane; g < NG; g += 64) {
          const float v = penalized(row[g], p);
          if (v < best) { best = v; bg = g; }
        }
        for (int off = 32; off; off >>= 1) {
          const float ov = __shfl_down(best, off);
          const int og = __shfl_down(bg, off);
          if (ov < best || (ov == best && og < bg)) { best = ov; bg = og; }
        }
        bg = __shfl(bg, 0);
        const unsigned qbit = 1u << (q & 31);
        const int qw = q >> 5;
        if (lane < NGW) {
          const unsigned wv = s_mrow[mi][lane];
          const unsigned want = ((bg >> 5) == lane) ? (1u << (bg & 31)) : 0u;
          unsigned clr = wv & ~want;
          while (clr) {
            const int gb = __ffs(clr) - 1; clr &= clr - 1;
            const int g = lane * 32 + gb;
            atomicAnd(&mb[g * NQW + qw], ~qbit);
            atomicSub(&s_ccov[g], 1);
          }
          if (want & ~wv) {
            atomicOr(&mb[bg * NQW + qw], qbit);
            atomicAdd(&s_ccov[bg], 1);
          }
          s_mrow[mi][lane] = want;
        }
        if (lane == 0) s_rcnt[q] = 1;
      }
    }
    __syncthreads();
  }
  __syncthreads();
  for (int i = t; i < m_n * NGW; i += 1024) {
    const int mi = i / NGW, w2 = i - mi * NGW;
    mbT[(size_t)s_mq[mi] * NGW + w2] = s_mrow[mi][w2];
  }
  for (int q = t; q < NQ; q += 1024) pen_g[b * NQ + q] = s_pen[q];
}

// ---------------- K8: matched_qidx ----------------
__global__ void matched_kernel(const float* __restrict__ cost, const unsigned* __restrict__ mbits,
                               const int* __restrict__ pen_g, float* __restrict__ out_mq) {
  const int g = blockIdx.x, b = blockIdx.y, t = threadIdx.x;
  const float* __restrict__ crow = cost + ((size_t)(b*NG + g)) * NQ;
  const unsigned* __restrict__ mrow = mbits + (b*NG + g) * NQW;
  const int* __restrict__ pb = pen_g + b * NQ;
  float best = FLT_MAX; int bq = 0;
  for (int q = t; q < NQ; q += 256) {
    if ((mrow[q >> 5] >> (q & 31)) & 1u) {
      const float v = penalized(crow[q], pb[q]);
      if (v < best) { best = v; bq = q; }
    }
  }
  __shared__ float rv[256];
  __shared__ int rq[256];
  rv[t] = best; rq[t] = bq;
  __syncthreads();
  for (int off = 128; off; off >>= 1) {
    if (t < off) {
      if (lexlt(rv[t + off], rq[t + off], rv[t], rq[t])) { rv[t] = rv[t + off]; rq[t] = rq[t + off]; }
    }
    __syncthreads();
  }
  if (t == 0) out_mq[b * NG + g] = (float)rq[0];
}

// ---------------- K9: expand mbitsT rows -> m floats (float4 stores), selected, gt_idx ----------------
__global__ void out_kernel(const unsigned* __restrict__ mbitsT, float* __restrict__ out_m,
                           float* __restrict__ out_sel, float* __restrict__ out_gti) {
  const int b = blockIdx.y, t = threadIdx.x;
  const int q0 = blockIdx.x * 8;
  __shared__ unsigned wds[8 * NGW];
  if (t < 8 * NGW) wds[t] = mbitsT[((size_t)(b*NQ + q0)) * NGW + t];
  __syncthreads();
  float4* __restrict__ om4 = reinterpret_cast<float4*>(out_m + ((size_t)(b*NQ + q0)) * NG);
  for (int j = t; j < 8 * (NG/4); j += 256) {   // 600 float4 per block
    const int qi = j / (NG/4);
    const int g0 = (j - qi * (NG/4)) * 4;
    const unsigned* wr = &wds[qi * NGW];
    float4 v;
    v.x = ((wr[(g0+0) >> 5] >> ((g0+0) & 31)) & 1u) ? 1.f : 0.f;
    v.y = ((wr[(g0+1) >> 5] >> ((g0+1) & 31)) & 1u) ? 1.f : 0.f;
    v.z = ((wr[(g0+2) >> 5] >> ((g0+2) & 31)) & 1u) ? 1.f : 0.f;
    v.w = ((wr[(g0+3) >> 5] >> ((g0+3) & 31)) & 1u) ? 1.f : 0.f;
    om4[j] = v;
  }
  if (t < 8) {
    int fgi = -1;
    for (int w = 0; w < NGW; ++w) {
      const unsigned v = wds[t*NGW + w];
      if (v) { fgi = w*32 + __ffs(v) - 1; break; }
    }
    out_sel[b*NQ + q0 + t] = (fgi >= 0) ? 1.f : 0.f;
    out_gti[b*NQ + q0 + t] = (fgi >= 0) ? (float)fgi : 0.f;
  }
}

extern "C" void kernel_launch(void* const* d_in, const int* in_sizes, int n_in,
                              void* d_out, int out_size, void* d_ws, size_t ws_size,
                              hipStream_t stream) {
  const float* logits = (const float*)d_in[0];
  const float* boxes  = (const float*)d_in[1];
  const int*   labels = (const int*)d_in[2];
  const float* gtb    = (const float*)d_in[3];
  const float* imgsz  = (const float*)d_in[4];

  float* out = (float*)d_out;
  float* out_m   = out;                                   // B*Q*G
  float* out_sel = out + (size_t)NB * NQ * NG;            // B*Q
  float* out_gti = out_sel + (size_t)NB * NQ;             // B*Q
  float* out_mq  = out_gti + (size_t)NB * NQ;             // B*G

  char* w = (char*)d_ws;
  const size_t szPrep = sizeof(float4) * (size_t)NB * NQ;
  const size_t szGp   = sizeof(float4) * (size_t)NB * NG * 5;
  const size_t szCct  = sizeof(float) * (size_t)NB * NC * NQ;
  const size_t szBits = sizeof(unsigned) * (size_t)NB * NG * NQW;
  const size_t szBitsT= sizeof(unsigned) * (size_t)NB * NQ * NGW;
  const size_t szIntQ = sizeof(int) * (size_t)NB * NQ;
  const size_t szIntG = sizeof(int) * (size_t)NB * NG;
  const size_t szML   = sizeof(int) * (size_t)NB * MAXM;
  const size_t szMC   = sizeof(int) * 64;
  const size_t szCM   = sizeof(float) * (size_t)NB * MAXM * NG;
  const size_t need = 2*szPrep + szGp + szCct + szBits + szBitsT + 2*szIntQ + szIntG + szML + szMC + szCM;
  if (ws_size < need) return;

  float4* prepN = (float4*)w; w += szPrep;
  float4* prepM = (float4*)w; w += szPrep;
  float4* gp    = (float4*)w; w += szGp;
  float*    cct   = (float*)w;    w += szCct;
  unsigned* mbits = (unsigned*)w; w += szBits;
  unsigned* mbitsT= (unsigned*)w; w += szBitsT;
  int* rcnt  = (int*)w; w += szIntQ;
  int* pen   = (int*)w; w += szIntQ;
  int* ccov  = (int*)w; w += szIntG;
  int* mlist = (int*)w; w += szML;
  int* mcount= (int*)w; w += szMC;
  float* costM = (float*)w; w += szCM;

  float* cost = out_m;  // (B,G,Q) in the d_out m-region; overwritten by out_kernel at the end

  gprep_kernel<<<(NB * NG + 255) / 256, 256, 0, stream>>>(gtb, labels, imgsz, gp);
  prep_kernel<<<dim3((NQ + 255) / 256, NB), 256, 0, stream>>>(boxes, gp, imgsz, prepN, prepM, rcnt, mbitsT, mcount);
  cls_kernel<<<dim3((NQ + QT - 1) / QT, NB), 256, 0, stream>>>(logits, cct);
  costA_kernel<<<dim3((NQ + 255) / 256, GSPLIT, NB), 256, 0, stream>>>(boxes, prepN, prepM, gp, cct, cost);
  topk_kernel<<<dim3(NG, NB), 128, 0, stream>>>(boxes, gp, cost, mbits, mbitsT, rcnt);
  compact_kernel<<<(NB * NQ + 255) / 256, 256, 0, stream>>>(rcnt, mlist, mcount);
  gatherM_kernel<<<dim3(12, NB), 256, 0, stream>>>(cost, mlist, mcount, costM);
  multifix_kernel<<<dim3(12, NB), 256, 0, stream>>>(costM, mbits, mbitsT, rcnt, mlist, mcount);
  colcov_kernel<<<(NB * NG + 255) / 256, 256, 0, stream>>>(mbits, ccov);
  loop_kernel<<<NB, 1024, 0, stream>>>(cost, costM, mbits, mbitsT, rcnt, ccov, mlist, mcount, pen);
  matched_kernel<<<dim3(NG, NB), 256, 0, stream>>>(cost, mbits, pen, out_mq);
  out_kernel<<<dim3(NQ / 8, NB), 256, 0, stream>>>(mbitsT, out_m, out_sel, out_gti);
}

// Round 7
// 297.953 us; speedup vs baseline: 1.5213x; 1.0206x over previous
//
#include <hip/hip_runtime.h>
#include <float.h>
#include <stdint.h>
#include <stddef.h>

#define NB 16
#define NQ 4000
#define NG 300
#define NC 81
#define NQW 125  // NQ/32
#define NGW 10   // ceil(NG/32)
#define MAXM 768 // multi rows per image <= sum(dyn_k)/2 <= 750 (provable bound)

typedef unsigned long long u64t;

__device__ __forceinline__ bool lexlt(float v1, int i1, float v2, int i2) {
  return (v1 < v2) || (v1 == v2 && i1 < i2);
}

// Exact replica of p sequential f32 adds of 1e5 (numpy semantics), in O(#binade crossings).
__device__ __forceinline__ float penalized(float v, int p) {
  if (p <= 0) return v;
  if (p <= 12) {
    float x = v;
    for (int r = 0; r < p; ++r) x += 100000.0f;
    return x;
  }
  double x = (double)v;
  x = (double)(float)(x + 100000.0);
  int k = 1;
  while (k < p) {
    double B = 131072.0;
    while (B <= x) B += B;
    double room = B - x;
    int j = (int)(room * 1e-5);
    while (j > 0 && x + (double)j * 100000.0 >= B) --j;
    if (j > p - k) j = p - k;
    if (j > 0) { x += (double)j * 100000.0; k += j; }
    if (k < p) { x = (double)(float)(x + 100000.0); ++k; }
  }
  return (float)x;
}

// ---------------- K0: per-gt derived params ----------------
__global__ void gprep_kernel(const float* __restrict__ gtb, const int* __restrict__ labels,
                             const float* __restrict__ imgsz, float4* __restrict__ gp) {
#pragma clang fp contract(off)
  const int idx = blockIdx.x * 256 + threadIdx.x;
  if (idx >= NB * NG) return;
  const int b = idx / NG;
  const float gx0 = gtb[idx*4 + 0];
  const float gy0 = gtb[idx*4 + 1];
  const float gx1 = gtb[idx*4 + 2];
  const float gy1 = gtb[idx*4 + 3];
  const float s0 = imgsz[b*4+0], s1 = imgsz[b*4+1], s2 = imgsz[b*4+2], s3 = imgsz[b*4+3];
  const float areaB = (gx1 - gx0) * (gy1 - gy0);
  const float gcx = (gx0 + gx1) * 0.5f, gcy = (gy0 + gy1) * 0.5f;
  const float gw0 = gx1 - gx0, gh0 = gy1 - gy0;
  const float xg0 = gcx - 0.5f*gw0, yg0 = gcy - 0.5f*gh0;
  const float xg1 = gcx + 0.5f*gw0, yg1 = gcy + 0.5f*gh0;
  const float cw = xg1 - xg0, ch = yg1 - yg0;
  gp[idx*5+0] = make_float4(xg0, yg0, xg1, yg1);
  gp[idx*5+1] = make_float4(gcx - 2.5f*cw, gcx + 2.5f*cw, gcy - 2.5f*ch, gcy + 2.5f*ch);
  gp[idx*5+2] = make_float4(gx0 / s0, gy0 / s1, gx1 / s2, gy1 / s3);
  gp[idx*5+3] = make_float4(gx0, gy0, gx1, gy1);
  gp[idx*5+4] = make_float4(areaB, __int_as_float(labels[idx]), 0.f, 0.f);
}

// ---------------- K1: prep — fg penalty via gp, normalized box; zero rcnt/mbitsT/mcount ----------------
__global__ void prep_kernel(const float* __restrict__ boxes, const float4* __restrict__ gp,
                            const float* __restrict__ imgsz,
                            float4* __restrict__ prepN, float* __restrict__ prepF,
                            int* __restrict__ rcnt, unsigned* __restrict__ mbitsT,
                            int* __restrict__ mcount) {
#pragma clang fp contract(off)
  const int b = blockIdx.y;
  const int q = blockIdx.x * 256 + threadIdx.x;
  const int tid = (blockIdx.y * gridDim.x + blockIdx.x) * 256 + threadIdx.x;
  const int nthreads = gridDim.x * gridDim.y * 256;
  for (int i = tid; i < NB * NQ * NGW; i += nthreads) mbitsT[i] = 0u;
  if (tid < NB) mcount[tid] = 0;
  __shared__ float4 sA0[NG];
  __shared__ float4 sA1[NG];
  for (int i = threadIdx.x; i < NG; i += 256) {
    sA0[i] = gp[(size_t)(b*NG + i)*5 + 0];
    sA1[i] = gp[(size_t)(b*NG + i)*5 + 1];
  }
  __syncthreads();
  if (q >= NQ) return;
  const float4 pb = reinterpret_cast<const float4*>(boxes)[b * NQ + q];
  const float s0 = imgsz[b*4+0], s1 = imgsz[b*4+1], s2 = imgsz[b*4+2], s3 = imgsz[b*4+3];
  const float ax = (pb.x + pb.z) * 0.5f;
  const float ay = (pb.y + pb.w) * 0.5f;
  bool anyb = false, anyc = false;
  for (int g = 0; g < NG; ++g) {
    const float4 A0 = sA0[g];
    const float4 A1 = sA1[g];
    anyb = anyb || ((ax > A0.x) && (ax < A0.z) && (ay > A0.y) && (ay < A0.w));
    anyc = anyc || ((ax > A1.x) && (ax < A1.y) && (ay > A1.z) && (ay < A1.w));
  }
  const int idx = b * NQ + q;
  prepN[idx] = make_float4(pb.x / s0, pb.y / s1, pb.z / s2, pb.w / s3);
  prepF[idx] = (anyb || anyc) ? 0.f : 10000.f;
  rcnt[idx] = 0;
}

// ---------------- K2: focal class cost table, transposed (B,C,Q), tiled ----------------
#define QT 64
__global__ void cls_kernel(const float* __restrict__ logits, float* __restrict__ cct) {
#pragma clang fp contract(off)
  const int b = blockIdx.y, q0 = blockIdx.x * QT, t = threadIdx.x;
  __shared__ float tile[QT * NC];
  const int nq = (NQ - q0 < QT) ? (NQ - q0) : QT;
  const float* __restrict__ src = logits + ((size_t)(b * NQ + q0)) * NC;
  for (int i = t; i < nq * NC; i += 256) {
    const float x = src[i];
    float p;
    if (x >= 0.f) p = 1.f / (1.f + expf(-x));
    else { const float e = expf(x); p = e / (1.f + e); }
    const float pos = 0.25f * ((1.f - p) * (1.f - p)) * (-logf(p + 1e-8f));
    const float neg = 0.75f * (p * p) * (-logf(1.f - p + 1e-8f));
    tile[i] = pos - neg;
  }
  __syncthreads();
  for (int i = t; i < NC * QT; i += 256) {
    const int c = i >> 6;
    const int ql = i & (QT - 1);
    if (ql < nq) cct[((size_t)(b * NC + c)) * NQ + q0 + ql] = tile[ql * NC + c];
  }
}

// ---------------- K3: FUSED cost + per-(b,g) top-5 ----------------
// u32 mono-key + index chains (pred-based, stable: strict-less keeps earlier=smaller-q).
// Cross-lane merges use explicit (key,idx) lex compare.
struct KV { unsigned k[5]; int i[5]; };

__device__ __forceinline__ void kv_sortnet(unsigned* k, int* i) {
  // 10-CE insertion network for 5 elements, lex (k,i) ascending
#define CE(a,b) { \
    const bool pr = (k[b] < k[a]) || (k[b] == k[a] && i[b] < i[a]); \
    const unsigned tk = pr ? k[b] : k[a]; const unsigned uk = pr ? k[a] : k[b]; \
    const int ti = pr ? i[b] : i[a]; const int ui = pr ? i[a] : i[b]; \
    k[a] = tk; k[b] = uk; i[a] = ti; i[b] = ui; }
  CE(0,1)
  CE(1,2) CE(0,1)
  CE(2,3) CE(1,2) CE(0,1)
  CE(3,4) CE(2,3) CE(1,2) CE(0,1)
#undef CE
}
__device__ __forceinline__ void kv_merge(unsigned* ak, int* ai, const unsigned* bk, const int* bi) {
  unsigned ck[5]; int ci[5];
#pragma unroll
  for (int j = 0; j < 5; ++j) {
    const unsigned ka = ak[j], kb = bk[4 - j];
    const int ia = ai[j], ib = bi[4 - j];
    const bool pr = (kb < ka) || (kb == ka && ib < ia);
    ck[j] = pr ? kb : ka; ci[j] = pr ? ib : ia;
  }
  kv_sortnet(ck, ci);
#pragma unroll
  for (int j = 0; j < 5; ++j) { ak[j] = ck[j]; ai[j] = ci[j]; }
}
__device__ __forceinline__ void sort5_desc(float* c) {
#define CED(a,b) { const float hi = fmaxf(c[a], c[b]); c[b] = fminf(c[a], c[b]); c[a] = hi; }
  CED(0,1)
  CED(1,2) CED(0,1)
  CED(2,3) CED(1,2) CED(0,1)
  CED(3,4) CED(2,3) CED(1,2) CED(0,1)
#undef CED
}
__device__ __forceinline__ void merge5_iou(float* a, const float* o) {
  float c[5];
#pragma unroll
  for (int j = 0; j < 5; ++j) c[j] = fmaxf(a[j], o[4 - j]);
  sort5_desc(c);
#pragma unroll
  for (int j = 0; j < 5; ++j) a[j] = c[j];
}

__global__ __launch_bounds__(128) void cost_topk_kernel(
    const float* __restrict__ boxes, const float4* __restrict__ prepN,
    const float* __restrict__ prepF, const float4* __restrict__ gp,
    const float* __restrict__ cct, float* __restrict__ cost,
    unsigned* __restrict__ mbits, unsigned* __restrict__ mbitsT, int* __restrict__ rcnt) {
#pragma clang fp contract(off)
  const int g = blockIdx.x, b = blockIdx.y, t = threadIdx.x;
  const int lane = t & 63, wave = t >> 6;
  const float4 A0 = gp[(size_t)(b*NG + g) * 5 + 0];
  const float4 A1 = gp[(size_t)(b*NG + g) * 5 + 1];
  const float4 A2 = gp[(size_t)(b*NG + g) * 5 + 2];
  const float4 A3 = gp[(size_t)(b*NG + g) * 5 + 3];
  const float4 A4 = gp[(size_t)(b*NG + g) * 5 + 4];
  const int lab = __float_as_int(A4.y);
  const float areaB = A4.x;
  const float* __restrict__ ccls = cct + ((size_t)(b*NC + lab)) * NQ;
  float* __restrict__ crow = cost + ((size_t)(b*NG + g)) * NQ;
  unsigned* __restrict__ mrow = mbits + (b*NG + g) * NQW;
  for (int i = t; i < NQW; i += 128) mrow[i] = 0u;

  unsigned mk[5]; int mi[5]; float sv[5];
#pragma unroll
  for (int j = 0; j < 5; ++j) { mk[j] = 0xffffffffu; mi[j] = 0x7fffffff; sv[j] = -1.f; }

  for (int q = t; q < NQ; q += 128) {
    const float4 pb = reinterpret_cast<const float4*>(boxes)[b*NQ + q];
    const float4 nb = prepN[b*NQ + q];
    const float fpen = prepF[b*NQ + q];
    const float ax = (pb.x + pb.z) * 0.5f;
    const float ay = (pb.y + pb.w) * 0.5f;
    const float areaA = (pb.z - pb.x) * (pb.w - pb.y);
    // iou / giou — identical op order to verified version
    const float ltx = fmaxf(pb.x, A3.x), lty = fmaxf(pb.y, A3.y);
    const float rbx = fminf(pb.z, A3.z), rby = fminf(pb.w, A3.w);
    const float iw = fmaxf(rbx - ltx, 0.f), ih = fmaxf(rby - lty, 0.f);
    const float inter = iw * ih;
    const float uni = areaA + areaB - inter;
    const float iou = inter / uni;
    const float eltx = fminf(pb.x, A3.x), elty = fminf(pb.y, A3.y);
    const float erbx = fmaxf(pb.z, A3.z), erby = fmaxf(pb.w, A3.w);
    const float ew = fmaxf(erbx - eltx, 0.f), eh = fmaxf(erby - elty, 0.f);
    const float earea = ew * eh;
    const float giou = iou - (earea - uni) / earea;
    const float cbb = fabsf(nb.x - A2.x) + fabsf(nb.y - A2.y)
                    + fabsf(nb.z - A2.z) + fabsf(nb.w - A2.w);
    const bool inb = (ax > A0.x) && (ax < A0.z) && (ay > A0.y) && (ay < A0.w);
    const bool inc = (ax > A1.x) && (ax < A1.y) && (ay > A1.z) && (ay < A1.w);
    const bool ibc = inb && inc;
    float cval = 5.0f * cbb + 2.0f * ccls[q];
    cval = cval + 2.0f * (-giou);
    cval = cval + (ibc ? 0.f : 100.f);
    cval = cval + fpen;
    crow[q] = cval;
    // mono map (after -0 canonicalization via +0.0f)
    const unsigned bits = __float_as_uint(cval + 0.0f);
    unsigned key = (bits & 0x80000000u) ? ~bits : (bits | 0x80000000u);
    int qidx = q;
#pragma unroll
    for (int j = 0; j < 5; ++j) {   // stable branchless bubble (ties keep existing)
      const unsigned a = mk[j];
      const bool pr = key < a;
      mk[j] = pr ? key : a;
      const int ii = mi[j];
      mi[j] = pr ? qidx : ii;
      key = pr ? a : key;
      qidx = pr ? ii : qidx;
    }
    float x = iou;
#pragma unroll
    for (int j = 0; j < 5; ++j) {   // sv sorted descending
      const float a = sv[j];
      sv[j] = fmaxf(a, x);
      x = fminf(a, x);
    }
  }

#pragma unroll
  for (int off = 32; off >= 1; off >>= 1) {
    unsigned ok[5]; int oi[5]; float ov[5];
#pragma unroll
    for (int j = 0; j < 5; ++j) {
      ok[j] = __shfl_down(mk[j], off);
      oi[j] = __shfl_down(mi[j], off);
      ov[j] = __shfl_down(sv[j], off);
    }
    kv_merge(mk, mi, ok, oi);
    merge5_iou(sv, ov);
  }

  __shared__ unsigned Lk[2][5];
  __shared__ int Li[2][5];
  __shared__ float Ls[2][5];
  if (lane == 0) {
#pragma unroll
    for (int j = 0; j < 5; ++j) { Lk[wave][j] = mk[j]; Li[wave][j] = mi[j]; Ls[wave][j] = sv[j]; }
  }
  __syncthreads();
  if (t == 0) {
    unsigned fk[5]; int fi[5]; float fs[5];
    unsigned o2[5]; int i2[5]; float s2[5];
#pragma unroll
    for (int j = 0; j < 5; ++j) {
      fk[j] = Lk[0][j]; fi[j] = Li[0][j]; fs[j] = Ls[0][j];
      o2[j] = Lk[1][j]; i2[j] = Li[1][j]; s2[j] = Ls[1][j];
    }
    kv_merge(fk, fi, o2, i2);
    merge5_iou(fs, s2);
    float s = fs[0]; s += fs[1]; s += fs[2]; s += fs[3]; s += fs[4];  // descending order sum
    int k = (int)s; if (k < 1) k = 1; if (k > 5) k = 5;
    for (int j = 0; j < k; ++j) {
      const int q = fi[j];
      mrow[q >> 5] |= 1u << (q & 31);
      atomicOr(&mbitsT[((size_t)(b*NQ + q)) * NGW + (g >> 5)], 1u << (g & 31));
      atomicAdd(&rcnt[b * NQ + q], 1);
    }
  }
}

// ---------------- K4: compact multi rows ----------------
__global__ void compact_kernel(const int* __restrict__ rcnt,
                               int* __restrict__ mlist, int* __restrict__ mcount) {
  const int idx = blockIdx.x * 256 + threadIdx.x;
  if (idx >= NB * NQ) return;
  const int b = idx / NQ, q = idx - b * NQ;
  if (rcnt[idx] > 1) {
    const int pos = atomicAdd(&mcount[b], 1);
    if (pos < MAXM) mlist[b * MAXM + pos] = q;
  }
}

// ---------------- K4b: gather multi-row cost slices ----------------
__global__ __launch_bounds__(256) void gatherM_kernel(
    const float* __restrict__ cost, const int* __restrict__ mlist,
    const int* __restrict__ mcount, float* __restrict__ costM) {
  const int b = blockIdx.y;
  const int w = blockIdx.x * 4 + (threadIdx.x >> 6);
  const int nw = gridDim.x * 4;
  const int lane = threadIdx.x & 63;
  int mn = mcount[b]; if (mn > MAXM) mn = MAXM;
  const float* __restrict__ cb = cost + (size_t)b * NG * NQ;
  for (int i = w; i < mn; i += nw) {
    const int q = mlist[b * MAXM + i];
    float* __restrict__ dst = costM + ((size_t)b * MAXM + i) * NG;
    for (int g = lane; g < NG; g += 64) dst[g] = cb[(size_t)g * NQ + q];
  }
}

// ---------------- K5: multifix — one wave per multi row, reads costM ----------------
__global__ __launch_bounds__(256) void multifix_kernel(
    const float* __restrict__ costM,
    unsigned* __restrict__ mbits, unsigned* __restrict__ mbitsT,
    int* __restrict__ rcnt, const int* __restrict__ mlist, const int* __restrict__ mcount) {
  const int b = blockIdx.y;
  const int gw = blockIdx.x * 4 + (threadIdx.x >> 6);
  const int nw = gridDim.x * 4;
  const int lane = threadIdx.x & 63;
  int mn = mcount[b]; if (mn > MAXM) mn = MAXM;
  for (int i = gw; i < mn; i += nw) {
    const int q = mlist[b * MAXM + i];
    const float* __restrict__ row = costM + ((size_t)b * MAXM + i) * NG;
    float best = FLT_MAX; int bg = 0;
    for (int g = lane; g < NG; g += 64) {
      const float v = row[g];
      if (v < best) { best = v; bg = g; }
    }
    for (int off = 32; off; off >>= 1) {
      const float ov = __shfl_down(best, off);
      const int og = __shfl_down(bg, off);
      if (ov < best || (ov == best && og < bg)) { best = ov; bg = og; }
    }
    bg = __shfl(bg, 0);
    unsigned* __restrict__ trow = mbitsT + (size_t)(b*NQ + q) * NGW;
    const unsigned qbit = 1u << (q & 31);
    const int qw = q >> 5;
    if (lane < NGW) {
      const unsigned wv = trow[lane];
      const unsigned want = ((bg >> 5) == lane) ? (1u << (bg & 31)) : 0u;
      unsigned clr = wv & ~want;
      while (clr) {
        const int gb = __ffs(clr) - 1; clr &= clr - 1;
        atomicAnd(&mbits[(b*NG + lane*32 + gb) * NQW + qw], ~qbit);
      }
      if (want & ~wv) atomicOr(&mbits[(b*NG + bg) * NQW + qw], qbit);
      trow[lane] = want;
    }
    if (lane == 0) rcnt[b * NQ + q] = 1;
  }
}

// ---------------- K6: column coverage counts ----------------
__global__ void colcov_kernel(const unsigned* __restrict__ mbits, int* __restrict__ ccov) {
  const int idx = blockIdx.x * 256 + threadIdx.x;
  if (idx >= NB * NG) return;
  const unsigned* row = mbits + idx * NQW;
  int c = 0;
  for (int i = 0; i < NQW; ++i) c += __popc(row[i]);
  ccov[idx] = c;
}

// ---------------- K7: the while-loop, one persistent block per image ----------------
__global__ __launch_bounds__(1024) void loop_kernel(
    const float* __restrict__ cost, const float* __restrict__ costM,
    unsigned* __restrict__ mbits, unsigned* __restrict__ mbitsT,
    const int* __restrict__ rcnt_g, const int* __restrict__ ccov_g,
    const int* __restrict__ mlist, const int* __restrict__ mcount,
    int* __restrict__ pen_g) {
  const int b = blockIdx.x, t = threadIdx.x;
  __shared__ int s_pen[NQ];
  __shared__ int s_rcnt[NQ];
  __shared__ short s_qmi[NQ];
  __shared__ int s_ccov[NG];
  __shared__ int s_unc[NG];
  __shared__ int s_pickq[NG];
  __shared__ int s_mq[MAXM];
  __shared__ unsigned s_mrow[MAXM][NGW];
  __shared__ int s_n, s_fix, s_sticky;

  int m_n = mcount[b]; if (m_n > MAXM) m_n = MAXM;
  for (int q = t; q < NQ; q += 1024) {
    s_pen[q] = 0;
    s_rcnt[q] = rcnt_g[b * NQ + q];
    s_qmi[q] = -1;
  }
  for (int i = t; i < m_n; i += 1024) s_mq[i] = mlist[b * MAXM + i];
  for (int g = t; g < NG; g += 1024) s_ccov[g] = ccov_g[b * NG + g];
  if (t == 0) s_sticky = 0;
  __syncthreads();
  for (int i = t; i < m_n; i += 1024) s_qmi[s_mq[i]] = (short)i;
  unsigned* __restrict__ mbT = mbitsT + (size_t)b * NQ * NGW;
  for (int i = t; i < m_n * NGW; i += 1024) {
    const int mi = i / NGW, w2 = i - mi * NGW;
    s_mrow[mi][w2] = mbT[(size_t)s_mq[mi] * NGW + w2];
  }
  __syncthreads();

  unsigned* __restrict__ mb = mbits + b * NG * NQW;
  const float* __restrict__ cb = cost + (size_t)b * NG * NQ;
  const float* __restrict__ cm = costM + (size_t)b * MAXM * NG;
  const int lane = t & 63, wave = t >> 6;

  for (int iter = 0; iter < 100; ++iter) {
    if (t == 0) { s_n = 0; s_fix = s_sticky; }
    __syncthreads();
    for (int g = t; g < NG; g += 1024)
      if (s_ccov[g] == 0) { const int i = atomicAdd(&s_n, 1); s_unc[i] = g; }
    __syncthreads();
    const int n = s_n;
    if (n == 0) break;
    for (int q = t; q < NQ; q += 1024)
      if (s_rcnt[q] > 0) s_pen[q]++;
    __syncthreads();
    for (int ci = wave; ci < n; ci += 16) {
      const int g = s_unc[ci];
      const float* __restrict__ crow = cb + (size_t)g * NQ;
      float best = FLT_MAX; int bq = 0x7fffffff;
      for (int q = lane; q < NQ; q += 64) {
        if (s_pen[q] == 0) {
          const float v = crow[q];
          if (v < best) { best = v; bq = q; }
        }
      }
      for (int off = 32; off; off >>= 1) {
        const float ov = __shfl_down(best, off);
        const int oq = __shfl_down(bq, off);
        if (ov < best || (ov == best && oq < bq)) { best = ov; bq = oq; }
      }
      if (lane == 0) s_pickq[ci] = bq;
    }
    __syncthreads();
    if (t < n) {
      const int g = s_unc[t], q = s_pickq[t];
      atomicOr(&mb[g * NQW + (q >> 5)], 1u << (q & 31));
      const int mi2 = s_qmi[q];
      if (mi2 >= 0) atomicOr(&s_mrow[mi2][g >> 5], 1u << (g & 31));
      else atomicOr(&mbT[(size_t)q * NGW + (g >> 5)], 1u << (g & 31));
      const int nc = atomicAdd(&s_rcnt[q], 1) + 1;
      s_ccov[g] = 1;
      if (nc > 1) { s_fix = 1; if (s_qmi[q] < 0) s_sticky = 1; }
    }
    __syncthreads();
    if (s_fix) {
      for (int mi = wave; mi < m_n; mi += 16) {
        const int q = s_mq[mi];
        const int p = s_pen[q];
        const float* __restrict__ row = cm + (size_t)mi * NG;
        float best = FLT_MAX; int bg = 0;
        for (int g = lane; g < NG; g += 64) {
          const float v = penalized(row[g], p);
          if (v < best) { best = v; bg = g; }
        }
        for (int off = 32; off; off >>= 1) {
          const float ov = __shfl_down(best, off);
          const int og = __shfl_down(bg, off);
          if (ov < best || (ov == best && og < bg)) { best = ov; bg = og; }
        }
        bg = __shfl(bg, 0);
        const unsigned qbit = 1u << (q & 31);
        const int qw = q >> 5;
        if (lane < NGW) {
          const unsigned wv = s_mrow[mi][lane];
          const unsigned want = ((bg >> 5) == lane) ? (1u << (bg & 31)) : 0u;
          unsigned clr = wv & ~want;
          while (clr) {
            const int gb = __ffs(clr) - 1; clr &= clr - 1;
            const int g = lane * 32 + gb;
            atomicAnd(&mb[g * NQW + qw], ~qbit);
            atomicSub(&s_ccov[g], 1);
          }
          if (want & ~wv) {
            atomicOr(&mb[bg * NQW + qw], qbit);
            atomicAdd(&s_ccov[bg], 1);
          }
          s_mrow[mi][lane] = want;
        }
        if (lane == 0) s_rcnt[q] = 1;
      }
    }
    __syncthreads();
  }
  __syncthreads();
  for (int i = t; i < m_n * NGW; i += 1024) {
    const int mi = i / NGW, w2 = i - mi * NGW;
    mbT[(size_t)s_mq[mi] * NGW + w2] = s_mrow[mi][w2];
  }
  for (int q = t; q < NQ; q += 1024) pen_g[b * NQ + q] = s_pen[q];
}

// ---------------- K8: matched_qidx ----------------
__global__ void matched_kernel(const float* __restrict__ cost, const unsigned* __restrict__ mbits,
                               const int* __restrict__ pen_g, float* __restrict__ out_mq) {
  const int g = blockIdx.x, b = blockIdx.y, t = threadIdx.x;
  const float* __restrict__ crow = cost + ((size_t)(b*NG + g)) * NQ;
  const unsigned* __restrict__ mrow = mbits + (b*NG + g) * NQW;
  const int* __restrict__ pb = pen_g + b * NQ;
  float best = FLT_MAX; int bq = 0;
  for (int q = t; q < NQ; q += 256) {
    if ((mrow[q >> 5] >> (q & 31)) & 1u) {
      const float v = penalized(crow[q], pb[q]);
      if (v < best) { best = v; bq = q; }
    }
  }
  __shared__ float rv[256];
  __shared__ int rq[256];
  rv[t] = best; rq[t] = bq;
  __syncthreads();
  for (int off = 128; off; off >>= 1) {
    if (t < off) {
      if (lexlt(rv[t + off], rq[t + off], rv[t], rq[t])) { rv[t] = rv[t + off]; rq[t] = rq[t + off]; }
    }
    __syncthreads();
  }
  if (t == 0) out_mq[b * NG + g] = (float)rq[0];
}

// ---------------- K9: expand mbitsT rows -> m floats (float4 stores), selected, gt_idx ----------------
__global__ void out_kernel(const unsigned* __restrict__ mbitsT, float* __restrict__ out_m,
                           float* __restrict__ out_sel, float* __restrict__ out_gti) {
  const int b = blockIdx.y, t = threadIdx.x;
  const int q0 = blockIdx.x * 8;
  __shared__ unsigned wds[8 * NGW];
  if (t < 8 * NGW) wds[t] = mbitsT[((size_t)(b*NQ + q0)) * NGW + t];
  __syncthreads();
  float4* __restrict__ om4 = reinterpret_cast<float4*>(out_m + ((size_t)(b*NQ + q0)) * NG);
  for (int j = t; j < 8 * (NG/4); j += 256) {
    const int qi = j / (NG/4);
    const int g0 = (j - qi * (NG/4)) * 4;
    const unsigned* wr = &wds[qi * NGW];
    float4 v;
    v.x = ((wr[(g0+0) >> 5] >> ((g0+0) & 31)) & 1u) ? 1.f : 0.f;
    v.y = ((wr[(g0+1) >> 5] >> ((g0+1) & 31)) & 1u) ? 1.f : 0.f;
    v.z = ((wr[(g0+2) >> 5] >> ((g0+2) & 31)) & 1u) ? 1.f : 0.f;
    v.w = ((wr[(g0+3) >> 5] >> ((g0+3) & 31)) & 1u) ? 1.f : 0.f;
    om4[j] = v;
  }
  if (t < 8) {
    int fgi = -1;
    for (int w = 0; w < NGW; ++w) {
      const unsigned v = wds[t*NGW + w];
      if (v) { fgi = w*32 + __ffs(v) - 1; break; }
    }
    out_sel[b*NQ + q0 + t] = (fgi >= 0) ? 1.f : 0.f;
    out_gti[b*NQ + q0 + t] = (fgi >= 0) ? (float)fgi : 0.f;
  }
}

extern "C" void kernel_launch(void* const* d_in, const int* in_sizes, int n_in,
                              void* d_out, int out_size, void* d_ws, size_t ws_size,
                              hipStream_t stream) {
  const float* logits = (const float*)d_in[0];
  const float* boxes  = (const float*)d_in[1];
  const int*   labels = (const int*)d_in[2];
  const float* gtb    = (const float*)d_in[3];
  const float* imgsz  = (const float*)d_in[4];

  float* out = (float*)d_out;
  float* out_m   = out;                                   // B*Q*G
  float* out_sel = out + (size_t)NB * NQ * NG;            // B*Q
  float* out_gti = out_sel + (size_t)NB * NQ;             // B*Q
  float* out_mq  = out_gti + (size_t)NB * NQ;             // B*G

  char* w = (char*)d_ws;
  const size_t szPrep = sizeof(float4) * (size_t)NB * NQ;
  const size_t szF    = sizeof(float) * (size_t)NB * NQ;
  const size_t szGp   = sizeof(float4) * (size_t)NB * NG * 5;
  const size_t szCct  = sizeof(float) * (size_t)NB * NC * NQ;
  const size_t szBits = sizeof(unsigned) * (size_t)NB * NG * NQW;
  const size_t szBitsT= sizeof(unsigned) * (size_t)NB * NQ * NGW;
  const size_t szIntQ = sizeof(int) * (size_t)NB * NQ;
  const size_t szIntG = sizeof(int) * (size_t)NB * NG;
  const size_t szML   = sizeof(int) * (size_t)NB * MAXM;
  const size_t szMC   = sizeof(int) * 64;
  const size_t szCM   = sizeof(float) * (size_t)NB * MAXM * NG;
  const size_t need = szPrep + szF + szGp + szCct + szBits + szBitsT + 2*szIntQ + szIntG + szML + szMC + szCM;
  if (ws_size < need) return;

  float4* prepN = (float4*)w; w += szPrep;
  float*  prepF = (float*)w;  w += szF;
  float4* gp    = (float4*)w; w += szGp;
  float*    cct   = (float*)w;    w += szCct;
  unsigned* mbits = (unsigned*)w; w += szBits;
  unsigned* mbitsT= (unsigned*)w; w += szBitsT;
  int* rcnt  = (int*)w; w += szIntQ;
  int* pen   = (int*)w; w += szIntQ;
  int* ccov  = (int*)w; w += szIntG;
  int* mlist = (int*)w; w += szML;
  int* mcount= (int*)w; w += szMC;
  float* costM = (float*)w; w += szCM;

  float* cost = out_m;  // (B,G,Q) in the d_out m-region; overwritten by out_kernel at the end

  gprep_kernel<<<(NB * NG + 255) / 256, 256, 0, stream>>>(gtb, labels, imgsz, gp);
  prep_kernel<<<dim3((NQ + 255) / 256, NB), 256, 0, stream>>>(boxes, gp, imgsz, prepN, prepF, rcnt, mbitsT, mcount);
  cls_kernel<<<dim3((NQ + QT - 1) / QT, NB), 256, 0, stream>>>(logits, cct);
  cost_topk_kernel<<<dim3(NG, NB), 128, 0, stream>>>(boxes, prepN, prepF, gp, cct, cost, mbits, mbitsT, rcnt);
  compact_kernel<<<(NB * NQ + 255) / 256, 256, 0, stream>>>(rcnt, mlist, mcount);
  gatherM_kernel<<<dim3(12, NB), 256, 0, stream>>>(cost, mlist, mcount, costM);
  multifix_kernel<<<dim3(12, NB), 256, 0, stream>>>(costM, mbits, mbitsT, rcnt, mlist, mcount);
  colcov_kernel<<<(NB * NG + 255) / 256, 256, 0, stream>>>(mbits, ccov);
  loop_kernel<<<NB, 1024, 0, stream>>>(cost, costM, mbits, mbitsT, rcnt, ccov, mlist, mcount, pen);
  matched_kernel<<<dim3(NG, NB), 256, 0, stream>>>(cost, mbits, pen, out_mq);
  out_kernel<<<dim3(NQ / 8, NB), 256, 0, stream>>>(mbitsT, out_m, out_sel, out_gti);
}

// Round 8
// 279.531 us; speedup vs baseline: 1.6216x; 1.0659x over previous
//
#include <hip/hip_runtime.h>
#include <float.h>
#include <stdint.h>
#include <stddef.h>

#define NB 16
#define NQ 4000
#define NG 300
#define NC 81
#define NQW 125  // NQ/32
#define NGW 10   // ceil(NG/32)
#define MAXM 768 // multi rows per image <= sum(dyn_k)/2 <= 750 (provable bound)

__device__ __forceinline__ bool lexlt(float v1, int i1, float v2, int i2) {
  return (v1 < v2) || (v1 == v2 && i1 < i2);
}

// Exact replica of p sequential f32 adds of 1e5 (numpy semantics), in O(#binade crossings).
__device__ __forceinline__ float penalized(float v, int p) {
  if (p <= 0) return v;
  if (p <= 12) {
    float x = v;
    for (int r = 0; r < p; ++r) x += 100000.0f;
    return x;
  }
  double x = (double)v;
  x = (double)(float)(x + 100000.0);
  int k = 1;
  while (k < p) {
    double B = 131072.0;
    while (B <= x) B += B;
    double room = B - x;
    int j = (int)(room * 1e-5);
    while (j > 0 && x + (double)j * 100000.0 >= B) --j;
    if (j > p - k) j = p - k;
    if (j > 0) { x += (double)j * 100000.0; k += j; }
    if (k < p) { x = (double)(float)(x + 100000.0); ++k; }
  }
  return (float)x;
}

// ---------------- K0: per-gt derived params ----------------
__global__ void gprep_kernel(const float* __restrict__ gtb, const int* __restrict__ labels,
                             const float* __restrict__ imgsz, float4* __restrict__ gp) {
#pragma clang fp contract(off)
  const int idx = blockIdx.x * 256 + threadIdx.x;
  if (idx >= NB * NG) return;
  const int b = idx / NG;
  const float gx0 = gtb[idx*4 + 0];
  const float gy0 = gtb[idx*4 + 1];
  const float gx1 = gtb[idx*4 + 2];
  const float gy1 = gtb[idx*4 + 3];
  const float s0 = imgsz[b*4+0], s1 = imgsz[b*4+1], s2 = imgsz[b*4+2], s3 = imgsz[b*4+3];
  const float areaB = (gx1 - gx0) * (gy1 - gy0);
  const float gcx = (gx0 + gx1) * 0.5f, gcy = (gy0 + gy1) * 0.5f;
  const float gw0 = gx1 - gx0, gh0 = gy1 - gy0;
  const float xg0 = gcx - 0.5f*gw0, yg0 = gcy - 0.5f*gh0;
  const float xg1 = gcx + 0.5f*gw0, yg1 = gcy + 0.5f*gh0;
  const float cw = xg1 - xg0, ch = yg1 - yg0;
  gp[idx*5+0] = make_float4(xg0, yg0, xg1, yg1);
  gp[idx*5+1] = make_float4(gcx - 2.5f*cw, gcx + 2.5f*cw, gcy - 2.5f*ch, gcy + 2.5f*ch);
  gp[idx*5+2] = make_float4(gx0 / s0, gy0 / s1, gx1 / s2, gy1 / s3);
  gp[idx*5+3] = make_float4(gx0, gy0, gx1, gy1);
  gp[idx*5+4] = make_float4(areaB, __int_as_float(labels[idx]), 0.f, 0.f);
}

// ---------------- K1: prep — fg penalty via gp, normalized box; zero rcnt/mbitsT/mcount ----------------
__global__ void prep_kernel(const float* __restrict__ boxes, const float4* __restrict__ gp,
                            const float* __restrict__ imgsz,
                            float4* __restrict__ prepN, float* __restrict__ prepF,
                            int* __restrict__ rcnt, unsigned* __restrict__ mbitsT,
                            int* __restrict__ mcount) {
#pragma clang fp contract(off)
  const int b = blockIdx.y;
  const int q = blockIdx.x * 256 + threadIdx.x;
  const int tid = (blockIdx.y * gridDim.x + blockIdx.x) * 256 + threadIdx.x;
  const int nthreads = gridDim.x * gridDim.y * 256;
  for (int i = tid; i < NB * NQ * NGW; i += nthreads) mbitsT[i] = 0u;
  if (tid < NB) mcount[tid] = 0;
  __shared__ float4 sA0[NG];
  __shared__ float4 sA1[NG];
  for (int i = threadIdx.x; i < NG; i += 256) {
    sA0[i] = gp[(size_t)(b*NG + i)*5 + 0];
    sA1[i] = gp[(size_t)(b*NG + i)*5 + 1];
  }
  __syncthreads();
  if (q >= NQ) return;
  const float4 pb = reinterpret_cast<const float4*>(boxes)[b * NQ + q];
  const float s0 = imgsz[b*4+0], s1 = imgsz[b*4+1], s2 = imgsz[b*4+2], s3 = imgsz[b*4+3];
  const float ax = (pb.x + pb.z) * 0.5f;
  const float ay = (pb.y + pb.w) * 0.5f;
  bool anyb = false, anyc = false;
  for (int g = 0; g < NG; ++g) {
    const float4 A0 = sA0[g];
    const float4 A1 = sA1[g];
    anyb = anyb || ((ax > A0.x) && (ax < A0.z) && (ay > A0.y) && (ay < A0.w));
    anyc = anyc || ((ax > A1.x) && (ax < A1.y) && (ay > A1.z) && (ay < A1.w));
  }
  const int idx = b * NQ + q;
  prepN[idx] = make_float4(pb.x / s0, pb.y / s1, pb.z / s2, pb.w / s3);
  prepF[idx] = (anyb || anyc) ? 0.f : 10000.f;
  rcnt[idx] = 0;
}

// ---------------- K2: focal class cost table, transposed (B,C,Q), tiled ----------------
#define QT 64
__global__ void cls_kernel(const float* __restrict__ logits, float* __restrict__ cct) {
#pragma clang fp contract(off)
  const int b = blockIdx.y, q0 = blockIdx.x * QT, t = threadIdx.x;
  __shared__ float tile[QT * NC];
  const int nq = (NQ - q0 < QT) ? (NQ - q0) : QT;
  const float* __restrict__ src = logits + ((size_t)(b * NQ + q0)) * NC;
  for (int i = t; i < nq * NC; i += 256) {
    const float x = src[i];
    float p;
    if (x >= 0.f) p = 1.f / (1.f + expf(-x));
    else { const float e = expf(x); p = e / (1.f + e); }
    const float pos = 0.25f * ((1.f - p) * (1.f - p)) * (-logf(p + 1e-8f));
    const float neg = 0.75f * (p * p) * (-logf(1.f - p + 1e-8f));
    tile[i] = pos - neg;
  }
  __syncthreads();
  for (int i = t; i < NC * QT; i += 256) {
    const int c = i >> 6;
    const int ql = i & (QT - 1);
    if (ql < nq) cct[((size_t)(b * NC + c)) * NQ + q0 + ql] = tile[ql * NC + c];
  }
}

// ---------------- K3: FUSED cost + top-5, TWO gts per block ----------------
__device__ __forceinline__ void kv_sortnet(unsigned* k, int* i) {
#define CE(a,b) { \
    const bool pr = (k[b] < k[a]) || (k[b] == k[a] && i[b] < i[a]); \
    const unsigned tk = pr ? k[b] : k[a]; const unsigned uk = pr ? k[a] : k[b]; \
    const int ti = pr ? i[b] : i[a]; const int ui = pr ? i[a] : i[b]; \
    k[a] = tk; k[b] = uk; i[a] = ti; i[b] = ui; }
  CE(0,1)
  CE(1,2) CE(0,1)
  CE(2,3) CE(1,2) CE(0,1)
  CE(3,4) CE(2,3) CE(1,2) CE(0,1)
#undef CE
}
__device__ __forceinline__ void kv_merge(unsigned* ak, int* ai, const unsigned* bk, const int* bi) {
  unsigned ck[5]; int ci[5];
#pragma unroll
  for (int j = 0; j < 5; ++j) {
    const unsigned ka = ak[j], kb = bk[4 - j];
    const int ia = ai[j], ib = bi[4 - j];
    const bool pr = (kb < ka) || (kb == ka && ib < ia);
    ck[j] = pr ? kb : ka; ci[j] = pr ? ib : ia;
  }
  kv_sortnet(ck, ci);
#pragma unroll
  for (int j = 0; j < 5; ++j) { ak[j] = ck[j]; ai[j] = ci[j]; }
}
__device__ __forceinline__ void sort5_desc(float* c) {
#define CED(a,b) { const float hi = fmaxf(c[a], c[b]); c[b] = fminf(c[a], c[b]); c[a] = hi; }
  CED(0,1)
  CED(1,2) CED(0,1)
  CED(2,3) CED(1,2) CED(0,1)
  CED(3,4) CED(2,3) CED(1,2) CED(0,1)
#undef CED
}
__device__ __forceinline__ void merge5_iou(float* a, const float* o) {
  float c[5];
#pragma unroll
  for (int j = 0; j < 5; ++j) c[j] = fmaxf(a[j], o[4 - j]);
  sort5_desc(c);
#pragma unroll
  for (int j = 0; j < 5; ++j) a[j] = c[j];
}

__device__ __forceinline__ void compute_pair(
    const float4 pb, const float4 nb, const float fpen,
    const float ax, const float ay, const float areaA,
    const float4 A0, const float4 A1, const float4 A2, const float4 A3,
    const float areaB, const float cclsq, float& cval_o, float& iou_o) {
  const float ltx = fmaxf(pb.x, A3.x), lty = fmaxf(pb.y, A3.y);
  const float rbx = fminf(pb.z, A3.z), rby = fminf(pb.w, A3.w);
  const float iw = fmaxf(rbx - ltx, 0.f), ih = fmaxf(rby - lty, 0.f);
  const float inter = iw * ih;
  const float uni = areaA + areaB - inter;
  const float iou = inter / uni;
  const float eltx = fminf(pb.x, A3.x), elty = fminf(pb.y, A3.y);
  const float erbx = fmaxf(pb.z, A3.z), erby = fmaxf(pb.w, A3.w);
  const float ew = fmaxf(erbx - eltx, 0.f), eh = fmaxf(erby - elty, 0.f);
  const float earea = ew * eh;
  const float giou = iou - (earea - uni) / earea;
  const float cbb = fabsf(nb.x - A2.x) + fabsf(nb.y - A2.y)
                  + fabsf(nb.z - A2.z) + fabsf(nb.w - A2.w);
  const bool inb = (ax > A0.x) && (ax < A0.z) && (ay > A0.y) && (ay < A0.w);
  const bool inc = (ax > A1.x) && (ax < A1.y) && (ay > A1.z) && (ay < A1.w);
  const bool ibc = inb && inc;
  float cval = 5.0f * cbb + 2.0f * cclsq;
  cval = cval + 2.0f * (-giou);
  cval = cval + (ibc ? 0.f : 100.f);
  cval = cval + fpen;
  cval_o = cval;
  iou_o = iou;
}

__device__ __forceinline__ void chain_insert(unsigned* mk, int* mi, float* sv,
                                             const float cval, const float iou, const int q) {
  const unsigned bits = __float_as_uint(cval + 0.0f);  // canonicalize -0
  unsigned key = (bits & 0x80000000u) ? ~bits : (bits | 0x80000000u);
  int qi = q;
#pragma unroll
  for (int j = 0; j < 5; ++j) {   // stable branchless bubble (ties keep existing)
    const unsigned a = mk[j];
    const bool pr = key < a;
    mk[j] = pr ? key : a;
    const int ii = mi[j];
    mi[j] = pr ? qi : ii;
    key = pr ? a : key;
    qi = pr ? ii : qi;
  }
  float x = iou;
#pragma unroll
  for (int j = 0; j < 5; ++j) {
    const float a = sv[j];
    sv[j] = fmaxf(a, x);
    x = fminf(a, x);
  }
}

__device__ __forceinline__ void wave_merge(unsigned* mk, int* mi, float* sv) {
#pragma unroll
  for (int off = 32; off >= 1; off >>= 1) {
    unsigned ok[5]; int oi[5]; float ov[5];
#pragma unroll
    for (int j = 0; j < 5; ++j) {
      ok[j] = __shfl_down(mk[j], off);
      oi[j] = __shfl_down(mi[j], off);
      ov[j] = __shfl_down(sv[j], off);
    }
    kv_merge(mk, mi, ok, oi);
    merge5_iou(sv, ov);
  }
}

__global__ __launch_bounds__(256) void cost_topk_kernel(
    const float* __restrict__ boxes, const float4* __restrict__ prepN,
    const float* __restrict__ prepF, const float4* __restrict__ gp,
    const float* __restrict__ cct, float* __restrict__ cost,
    unsigned* __restrict__ mbits, unsigned* __restrict__ mbitsT,
    int* __restrict__ rcnt, int* __restrict__ ccov) {
#pragma clang fp contract(off)
  const int gpair = blockIdx.x, b = blockIdx.y, t = threadIdx.x;
  const int g0 = gpair * 2, g1 = g0 + 1;
  const int lane = t & 63, wave = t >> 6;
  const float4 A0a = gp[(size_t)(b*NG+g0)*5+0], A1a = gp[(size_t)(b*NG+g0)*5+1];
  const float4 A2a = gp[(size_t)(b*NG+g0)*5+2], A3a = gp[(size_t)(b*NG+g0)*5+3];
  const float4 A4a = gp[(size_t)(b*NG+g0)*5+4];
  const float4 A0b = gp[(size_t)(b*NG+g1)*5+0], A1b = gp[(size_t)(b*NG+g1)*5+1];
  const float4 A2b = gp[(size_t)(b*NG+g1)*5+2], A3b = gp[(size_t)(b*NG+g1)*5+3];
  const float4 A4b = gp[(size_t)(b*NG+g1)*5+4];
  const float* __restrict__ ccls0 = cct + ((size_t)(b*NC + __float_as_int(A4a.y))) * NQ;
  const float* __restrict__ ccls1 = cct + ((size_t)(b*NC + __float_as_int(A4b.y))) * NQ;
  float* __restrict__ crow0 = cost + ((size_t)(b*NG + g0)) * NQ;
  float* __restrict__ crow1 = cost + ((size_t)(b*NG + g1)) * NQ;
  unsigned* __restrict__ mrow0 = mbits + (b*NG + g0) * NQW;
  unsigned* __restrict__ mrow1 = mbits + (b*NG + g1) * NQW;
  for (int i = t; i < NQW; i += 256) { mrow0[i] = 0u; mrow1[i] = 0u; }

  unsigned mk0[5], mk1[5]; int mi0[5], mi1[5]; float sv0[5], sv1[5];
#pragma unroll
  for (int j = 0; j < 5; ++j) {
    mk0[j] = mk1[j] = 0xffffffffu; mi0[j] = mi1[j] = 0x7fffffff; sv0[j] = sv1[j] = -1.f;
  }

  for (int q = t; q < NQ; q += 256) {
    const float4 pb = reinterpret_cast<const float4*>(boxes)[b*NQ + q];
    const float4 nb = prepN[b*NQ + q];
    const float fpen = prepF[b*NQ + q];
    const float ax = (pb.x + pb.z) * 0.5f;
    const float ay = (pb.y + pb.w) * 0.5f;
    const float areaA = (pb.z - pb.x) * (pb.w - pb.y);
    float cv, io;
    compute_pair(pb, nb, fpen, ax, ay, areaA, A0a, A1a, A2a, A3a, A4a.x, ccls0[q], cv, io);
    crow0[q] = cv;
    chain_insert(mk0, mi0, sv0, cv, io, q);
    compute_pair(pb, nb, fpen, ax, ay, areaA, A0b, A1b, A2b, A3b, A4b.x, ccls1[q], cv, io);
    crow1[q] = cv;
    chain_insert(mk1, mi1, sv1, cv, io, q);
  }

  wave_merge(mk0, mi0, sv0);
  wave_merge(mk1, mi1, sv1);

  __shared__ unsigned Lk[2][4][5];
  __shared__ int Li[2][4][5];
  __shared__ float Ls[2][4][5];
  if (lane == 0) {
#pragma unroll
    for (int j = 0; j < 5; ++j) {
      Lk[0][wave][j] = mk0[j]; Li[0][wave][j] = mi0[j]; Ls[0][wave][j] = sv0[j];
      Lk[1][wave][j] = mk1[j]; Li[1][wave][j] = mi1[j]; Ls[1][wave][j] = sv1[j];
    }
  }
  __syncthreads();
  if (t < 2) {
    const int g = (t == 0) ? g0 : g1;
    unsigned* __restrict__ mrow = (t == 0) ? mrow0 : mrow1;
    unsigned fk[5]; int fi[5]; float fs[5];
#pragma unroll
    for (int j = 0; j < 5; ++j) { fk[j] = Lk[t][0][j]; fi[j] = Li[t][0][j]; fs[j] = Ls[t][0][j]; }
    for (int wv = 1; wv < 4; ++wv) {
      unsigned ok[5]; int oi[5]; float ov[5];
#pragma unroll
      for (int j = 0; j < 5; ++j) { ok[j] = Lk[t][wv][j]; oi[j] = Li[t][wv][j]; ov[j] = Ls[t][wv][j]; }
      kv_merge(fk, fi, ok, oi);
      merge5_iou(fs, ov);
    }
    float s = fs[0]; s += fs[1]; s += fs[2]; s += fs[3]; s += fs[4];  // descending order sum
    int k = (int)s; if (k < 1) k = 1; if (k > 5) k = 5;
    for (int j = 0; j < k; ++j) {
      const int q = fi[j];
      mrow[q >> 5] |= 1u << (q & 31);
      atomicOr(&mbitsT[((size_t)(b*NQ + q)) * NGW + (g >> 5)], 1u << (g & 31));
      atomicAdd(&rcnt[b * NQ + q], 1);
    }
    ccov[b * NG + g] = k;
  }
}

// ---------------- K4: compact multi rows ----------------
__global__ void compact_kernel(const int* __restrict__ rcnt,
                               int* __restrict__ mlist, int* __restrict__ mcount) {
  const int idx = blockIdx.x * 256 + threadIdx.x;
  if (idx >= NB * NQ) return;
  const int b = idx / NQ, q = idx - b * NQ;
  if (rcnt[idx] > 1) {
    const int pos = atomicAdd(&mcount[b], 1);
    if (pos < MAXM) mlist[b * MAXM + pos] = q;
  }
}

// ---------------- K4b: gather multi-row cost slices ----------------
__global__ __launch_bounds__(256) void gatherM_kernel(
    const float* __restrict__ cost, const int* __restrict__ mlist,
    const int* __restrict__ mcount, float* __restrict__ costM) {
  const int b = blockIdx.y;
  const int w = blockIdx.x * 4 + (threadIdx.x >> 6);
  const int nw = gridDim.x * 4;
  const int lane = threadIdx.x & 63;
  int mn = mcount[b]; if (mn > MAXM) mn = MAXM;
  const float* __restrict__ cb = cost + (size_t)b * NG * NQ;
  for (int i = w; i < mn; i += nw) {
    const int q = mlist[b * MAXM + i];
    float* __restrict__ dst = costM + ((size_t)b * MAXM + i) * NG;
    for (int g = lane; g < NG; g += 64) dst[g] = cb[(size_t)g * NQ + q];
  }
}

// ---------------- K5: multifix — one wave per multi row; maintains ccov ----------------
__global__ __launch_bounds__(256) void multifix_kernel(
    const float* __restrict__ costM,
    unsigned* __restrict__ mbits, unsigned* __restrict__ mbitsT,
    int* __restrict__ rcnt, const int* __restrict__ mlist, const int* __restrict__ mcount,
    int* __restrict__ ccov) {
  const int b = blockIdx.y;
  const int gw = blockIdx.x * 4 + (threadIdx.x >> 6);
  const int nw = gridDim.x * 4;
  const int lane = threadIdx.x & 63;
  int mn = mcount[b]; if (mn > MAXM) mn = MAXM;
  for (int i = gw; i < mn; i += nw) {
    const int q = mlist[b * MAXM + i];
    const float* __restrict__ row = costM + ((size_t)b * MAXM + i) * NG;
    float best = FLT_MAX; int bg = 0;
    for (int g = lane; g < NG; g += 64) {
      const float v = row[g];
      if (v < best) { best = v; bg = g; }
    }
    for (int off = 32; off; off >>= 1) {
      const float ov = __shfl_down(best, off);
      const int og = __shfl_down(bg, off);
      if (ov < best || (ov == best && og < bg)) { best = ov; bg = og; }
    }
    bg = __shfl(bg, 0);
    unsigned* __restrict__ trow = mbitsT + (size_t)(b*NQ + q) * NGW;
    const unsigned qbit = 1u << (q & 31);
    const int qw = q >> 5;
    if (lane < NGW) {
      const unsigned wv = trow[lane];
      const unsigned want = ((bg >> 5) == lane) ? (1u << (bg & 31)) : 0u;
      unsigned clr = wv & ~want;
      while (clr) {
        const int gb = __ffs(clr) - 1; clr &= clr - 1;
        const int g = lane*32 + gb;
        atomicAnd(&mbits[(b*NG + g) * NQW + qw], ~qbit);
        atomicSub(&ccov[b*NG + g], 1);
      }
      if (want & ~wv) {
        atomicOr(&mbits[(b*NG + bg) * NQW + qw], qbit);
        atomicAdd(&ccov[b*NG + bg], 1);
      }
      trow[lane] = want;
    }
    if (lane == 0) rcnt[b * NQ + q] = 1;
  }
}

// ---------------- K7: the while-loop, one persistent block per image ----------------
__global__ __launch_bounds__(1024) void loop_kernel(
    const float* __restrict__ cost, const float* __restrict__ costM,
    unsigned* __restrict__ mbits, unsigned* __restrict__ mbitsT,
    const int* __restrict__ rcnt_g, const int* __restrict__ ccov_g,
    const int* __restrict__ mlist, const int* __restrict__ mcount,
    int* __restrict__ pen_g) {
  const int b = blockIdx.x, t = threadIdx.x;
  __shared__ int s_pen[NQ];
  __shared__ int s_rcnt[NQ];
  __shared__ short s_qmi[NQ];
  __shared__ int s_ccov[NG];
  __shared__ int s_unc[NG];
  __shared__ int s_pickq[NG];
  __shared__ int s_mq[MAXM];
  __shared__ unsigned s_mrow[MAXM][NGW];
  __shared__ int s_n, s_fix, s_sticky;

  int m_n = mcount[b]; if (m_n > MAXM) m_n = MAXM;
  for (int q = t; q < NQ; q += 1024) {
    s_pen[q] = 0;
    s_rcnt[q] = rcnt_g[b * NQ + q];
    s_qmi[q] = -1;
  }
  for (int i = t; i < m_n; i += 1024) s_mq[i] = mlist[b * MAXM + i];
  for (int g = t; g < NG; g += 1024) s_ccov[g] = ccov_g[b * NG + g];
  if (t == 0) s_sticky = 0;
  __syncthreads();
  for (int i = t; i < m_n; i += 1024) s_qmi[s_mq[i]] = (short)i;
  unsigned* __restrict__ mbT = mbitsT + (size_t)b * NQ * NGW;
  for (int i = t; i < m_n * NGW; i += 1024) {
    const int mi = i / NGW, w2 = i - mi * NGW;
    s_mrow[mi][w2] = mbT[(size_t)s_mq[mi] * NGW + w2];
  }
  __syncthreads();

  unsigned* __restrict__ mb = mbits + b * NG * NQW;
  const float* __restrict__ cb = cost + (size_t)b * NG * NQ;
  const float* __restrict__ cm = costM + (size_t)b * MAXM * NG;
  const int lane = t & 63, wave = t >> 6;

  for (int iter = 0; iter < 100; ++iter) {
    if (t == 0) { s_n = 0; s_fix = s_sticky; }
    __syncthreads();
    for (int g = t; g < NG; g += 1024)
      if (s_ccov[g] == 0) { const int i = atomicAdd(&s_n, 1); s_unc[i] = g; }
    __syncthreads();
    const int n = s_n;
    if (n == 0) break;
    for (int q = t; q < NQ; q += 1024)
      if (s_rcnt[q] > 0) s_pen[q]++;
    __syncthreads();
    for (int ci = wave; ci < n; ci += 16) {
      const int g = s_unc[ci];
      const float* __restrict__ crow = cb + (size_t)g * NQ;
      float best = FLT_MAX; int bq = 0x7fffffff;
      for (int q = lane; q < NQ; q += 64) {
        if (s_pen[q] == 0) {
          const float v = crow[q];
          if (v < best) { best = v; bq = q; }
        }
      }
      for (int off = 32; off; off >>= 1) {
        const float ov = __shfl_down(best, off);
        const int oq = __shfl_down(bq, off);
        if (ov < best || (ov == best && oq < bq)) { best = ov; bq = oq; }
      }
      if (lane == 0) s_pickq[ci] = bq;
    }
    __syncthreads();
    if (t < n) {
      const int g = s_unc[t], q = s_pickq[t];
      atomicOr(&mb[g * NQW + (q >> 5)], 1u << (q & 31));
      const int mi2 = s_qmi[q];
      if (mi2 >= 0) atomicOr(&s_mrow[mi2][g >> 5], 1u << (g & 31));
      else atomicOr(&mbT[(size_t)q * NGW + (g >> 5)], 1u << (g & 31));
      const int nc = atomicAdd(&s_rcnt[q], 1) + 1;
      s_ccov[g] = 1;
      if (nc > 1) { s_fix = 1; if (s_qmi[q] < 0) s_sticky = 1; }
    }
    __syncthreads();
    if (s_fix) {
      for (int mi = wave; mi < m_n; mi += 16) {
        const int q = s_mq[mi];
        const int p = s_pen[q];
        const float* __restrict__ row = cm + (size_t)mi * NG;
        float best = FLT_MAX; int bg = 0;
        for (int g = lane; g < NG; g += 64) {
          const float v = penalized(row[g], p);
          if (v < best) { best = v; bg = g; }
        }
        for (int off = 32; off; off >>= 1) {
          const float ov = __shfl_down(best, off);
          const int og = __shfl_down(bg, off);
          if (ov < best || (ov == best && og < bg)) { best = ov; bg = og; }
        }
        bg = __shfl(bg, 0);
        const unsigned qbit = 1u << (q & 31);
        const int qw = q >> 5;
        if (lane < NGW) {
          const unsigned wv = s_mrow[mi][lane];
          const unsigned want = ((bg >> 5) == lane) ? (1u << (bg & 31)) : 0u;
          unsigned clr = wv & ~want;
          while (clr) {
            const int gb = __ffs(clr) - 1; clr &= clr - 1;
            const int g = lane * 32 + gb;
            atomicAnd(&mb[g * NQW + qw], ~qbit);
            atomicSub(&s_ccov[g], 1);
          }
          if (want & ~wv) {
            atomicOr(&mb[bg * NQW + qw], qbit);
            atomicAdd(&s_ccov[bg], 1);
          }
          s_mrow[mi][lane] = want;
        }
        if (lane == 0) s_rcnt[q] = 1;
      }
    }
    __syncthreads();
  }
  __syncthreads();
  for (int i = t; i < m_n * NGW; i += 1024) {
    const int mi = i / NGW, w2 = i - mi * NGW;
    mbT[(size_t)s_mq[mi] * NGW + w2] = s_mrow[mi][w2];
  }
  for (int q = t; q < NQ; q += 1024) pen_g[b * NQ + q] = s_pen[q];
}

// ---------------- K8: matched_qidx — bit-sparse, one wave per (b,g) ----------------
__global__ __launch_bounds__(256) void matched_kernel(
    const float* __restrict__ cost, const unsigned* __restrict__ mbits,
    const int* __restrict__ pen_g, float* __restrict__ out_mq) {
  const int b = blockIdx.y, t = threadIdx.x;
  const int g = blockIdx.x * 4 + (t >> 6);
  const int lane = t & 63;
  const float* __restrict__ crow = cost + ((size_t)(b*NG + g)) * NQ;
  const unsigned* __restrict__ mrow = mbits + (b*NG + g) * NQW;
  const int* __restrict__ pb = pen_g + b * NQ;
  float best = FLT_MAX; int bq = 0;
  for (int w = lane; w < NQW; w += 64) {
    unsigned word = mrow[w];
    while (word) {
      const int bit = __ffs(word) - 1; word &= word - 1;
      const int q = w * 32 + bit;
      const float v = penalized(crow[q], pb[q]);
      if (lexlt(v, q, best, bq)) { best = v; bq = q; }
    }
  }
  for (int off = 32; off; off >>= 1) {
    const float ov = __shfl_down(best, off);
    const int oq = __shfl_down(bq, off);
    if (lexlt(ov, oq, best, bq)) { best = ov; bq = oq; }
  }
  if (lane == 0) out_mq[b * NG + g] = (float)bq;
}

// ---------------- K9: expand mbitsT rows -> m floats (float4 stores), selected, gt_idx ----------------
__global__ void out_kernel(const unsigned* __restrict__ mbitsT, float* __restrict__ out_m,
                           float* __restrict__ out_sel, float* __restrict__ out_gti) {
  const int b = blockIdx.y, t = threadIdx.x;
  const int q0 = blockIdx.x * 8;
  __shared__ unsigned wds[8 * NGW];
  if (t < 8 * NGW) wds[t] = mbitsT[((size_t)(b*NQ + q0)) * NGW + t];
  __syncthreads();
  float4* __restrict__ om4 = reinterpret_cast<float4*>(out_m + ((size_t)(b*NQ + q0)) * NG);
  for (int j = t; j < 8 * (NG/4); j += 256) {
    const int qi = j / (NG/4);
    const int g0 = (j - qi * (NG/4)) * 4;
    const unsigned* wr = &wds[qi * NGW];
    float4 v;
    v.x = ((wr[(g0+0) >> 5] >> ((g0+0) & 31)) & 1u) ? 1.f : 0.f;
    v.y = ((wr[(g0+1) >> 5] >> ((g0+1) & 31)) & 1u) ? 1.f : 0.f;
    v.z = ((wr[(g0+2) >> 5] >> ((g0+2) & 31)) & 1u) ? 1.f : 0.f;
    v.w = ((wr[(g0+3) >> 5] >> ((g0+3) & 31)) & 1u) ? 1.f : 0.f;
    om4[j] = v;
  }
  if (t < 8) {
    int fgi = -1;
    for (int w = 0; w < NGW; ++w) {
      const unsigned v = wds[t*NGW + w];
      if (v) { fgi = w*32 + __ffs(v) - 1; break; }
    }
    out_sel[b*NQ + q0 + t] = (fgi >= 0) ? 1.f : 0.f;
    out_gti[b*NQ + q0 + t] = (fgi >= 0) ? (float)fgi : 0.f;
  }
}

extern "C" void kernel_launch(void* const* d_in, const int* in_sizes, int n_in,
                              void* d_out, int out_size, void* d_ws, size_t ws_size,
                              hipStream_t stream) {
  const float* logits = (const float*)d_in[0];
  const float* boxes  = (const float*)d_in[1];
  const int*   labels = (const int*)d_in[2];
  const float* gtb    = (const float*)d_in[3];
  const float* imgsz  = (const float*)d_in[4];

  float* out = (float*)d_out;
  float* out_m   = out;                                   // B*Q*G
  float* out_sel = out + (size_t)NB * NQ * NG;            // B*Q
  float* out_gti = out_sel + (size_t)NB * NQ;             // B*Q
  float* out_mq  = out_gti + (size_t)NB * NQ;             // B*G

  char* w = (char*)d_ws;
  const size_t szPrep = sizeof(float4) * (size_t)NB * NQ;
  const size_t szF    = sizeof(float) * (size_t)NB * NQ;
  const size_t szGp   = sizeof(float4) * (size_t)NB * NG * 5;
  const size_t szCct  = sizeof(float) * (size_t)NB * NC * NQ;
  const size_t szBits = sizeof(unsigned) * (size_t)NB * NG * NQW;
  const size_t szBitsT= sizeof(unsigned) * (size_t)NB * NQ * NGW;
  const size_t szIntQ = sizeof(int) * (size_t)NB * NQ;
  const size_t szIntG = sizeof(int) * (size_t)NB * NG;
  const size_t szML   = sizeof(int) * (size_t)NB * MAXM;
  const size_t szMC   = sizeof(int) * 64;
  const size_t szCM   = sizeof(float) * (size_t)NB * MAXM * NG;
  const size_t need = szPrep + szF + szGp + szCct + szBits + szBitsT + 2*szIntQ + szIntG + szML + szMC + szCM;
  if (ws_size < need) return;

  float4* prepN = (float4*)w; w += szPrep;
  float*  prepF = (float*)w;  w += szF;
  float4* gp    = (float4*)w; w += szGp;
  float*    cct   = (float*)w;    w += szCct;
  unsigned* mbits = (unsigned*)w; w += szBits;
  unsigned* mbitsT= (unsigned*)w; w += szBitsT;
  int* rcnt  = (int*)w; w += szIntQ;
  int* pen   = (int*)w; w += szIntQ;
  int* ccov  = (int*)w; w += szIntG;
  int* mlist = (int*)w; w += szML;
  int* mcount= (int*)w; w += szMC;
  float* costM = (float*)w; w += szCM;

  float* cost = out_m;  // (B,G,Q) in the d_out m-region; overwritten by out_kernel at the end

  gprep_kernel<<<(NB * NG + 255) / 256, 256, 0, stream>>>(gtb, labels, imgsz, gp);
  prep_kernel<<<dim3((NQ + 255) / 256, NB), 256, 0, stream>>>(boxes, gp, imgsz, prepN, prepF, rcnt, mbitsT, mcount);
  cls_kernel<<<dim3((NQ + QT - 1) / QT, NB), 256, 0, stream>>>(logits, cct);
  cost_topk_kernel<<<dim3(NG/2, NB), 256, 0, stream>>>(boxes, prepN, prepF, gp, cct, cost, mbits, mbitsT, rcnt, ccov);
  compact_kernel<<<(NB * NQ + 255) / 256, 256, 0, stream>>>(rcnt, mlist, mcount);
  gatherM_kernel<<<dim3(12, NB), 256, 0, stream>>>(cost, mlist, mcount, costM);
  multifix_kernel<<<dim3(12, NB), 256, 0, stream>>>(costM, mbits, mbitsT, rcnt, mlist, mcount, ccov);
  loop_kernel<<<NB, 1024, 0, stream>>>(cost, costM, mbits, mbitsT, rcnt, ccov, mlist, mcount, pen);
  matched_kernel<<<dim3(NG/4, NB), 256, 0, stream>>>(cost, mbits, pen, out_mq);
  out_kernel<<<dim3(NQ / 8, NB), 256, 0, stream>>>(mbitsT, out_m, out_sel, out_gti);
}

// Round 9
// 244.215 us; speedup vs baseline: 1.8561x; 1.1446x over previous
//
#include <hip/hip_runtime.h>
#include <float.h>
#include <stdint.h>
#include <stddef.h>

#define NB 16
#define NQ 4000
#define NG 300
#define NC 81
#define NQW 125  // NQ/32
#define NGW 10   // ceil(NG/32)
#define MAXM 768 // multi rows per image <= sum(dyn_k)/2 <= 750 (provable bound)

__device__ __forceinline__ bool lexlt(float v1, int i1, float v2, int i2) {
  return (v1 < v2) || (v1 == v2 && i1 < i2);
}

// Exact replica of p sequential f32 adds of 1e5 (numpy semantics), in O(#binade crossings).
__device__ __forceinline__ float penalized(float v, int p) {
  if (p <= 0) return v;
  if (p <= 12) {
    float x = v;
    for (int r = 0; r < p; ++r) x += 100000.0f;
    return x;
  }
  double x = (double)v;
  x = (double)(float)(x + 100000.0);
  int k = 1;
  while (k < p) {
    double B = 131072.0;
    while (B <= x) B += B;
    double room = B - x;
    int j = (int)(room * 1e-5);
    while (j > 0 && x + (double)j * 100000.0 >= B) --j;
    if (j > p - k) j = p - k;
    if (j > 0) { x += (double)j * 100000.0; k += j; }
    if (k < p) { x = (double)(float)(x + 100000.0); ++k; }
  }
  return (float)x;
}

// ---------------- K0: per-gt derived params ----------------
__global__ void gprep_kernel(const float* __restrict__ gtb, const int* __restrict__ labels,
                             const float* __restrict__ imgsz, float4* __restrict__ gp) {
#pragma clang fp contract(off)
  const int idx = blockIdx.x * 256 + threadIdx.x;
  if (idx >= NB * NG) return;
  const int b = idx / NG;
  const float gx0 = gtb[idx*4 + 0];
  const float gy0 = gtb[idx*4 + 1];
  const float gx1 = gtb[idx*4 + 2];
  const float gy1 = gtb[idx*4 + 3];
  const float s0 = imgsz[b*4+0], s1 = imgsz[b*4+1], s2 = imgsz[b*4+2], s3 = imgsz[b*4+3];
  const float areaB = (gx1 - gx0) * (gy1 - gy0);
  const float gcx = (gx0 + gx1) * 0.5f, gcy = (gy0 + gy1) * 0.5f;
  const float gw0 = gx1 - gx0, gh0 = gy1 - gy0;
  const float xg0 = gcx - 0.5f*gw0, yg0 = gcy - 0.5f*gh0;
  const float xg1 = gcx + 0.5f*gw0, yg1 = gcy + 0.5f*gh0;
  const float cw = xg1 - xg0, ch = yg1 - yg0;
  gp[idx*5+0] = make_float4(xg0, yg0, xg1, yg1);
  gp[idx*5+1] = make_float4(gcx - 2.5f*cw, gcx + 2.5f*cw, gcy - 2.5f*ch, gcy + 2.5f*ch);
  gp[idx*5+2] = make_float4(gx0 / s0, gy0 / s1, gx1 / s2, gy1 / s3);
  gp[idx*5+3] = make_float4(gx0, gy0, gx1, gy1);
  gp[idx*5+4] = make_float4(areaB, __int_as_float(labels[idx]), 0.f, 0.f);
}

// ---------------- K1: prep — fg penalty via gp (early break), normalized box; zero rcnt/mbitsT ----------------
__global__ void prep_kernel(const float* __restrict__ boxes, const float4* __restrict__ gp,
                            const float* __restrict__ imgsz,
                            float4* __restrict__ prepN, float* __restrict__ prepF,
                            int* __restrict__ rcnt, unsigned* __restrict__ mbitsT) {
#pragma clang fp contract(off)
  const int b = blockIdx.y;
  const int q = blockIdx.x * 256 + threadIdx.x;
  const int tid = (blockIdx.y * gridDim.x + blockIdx.x) * 256 + threadIdx.x;
  const int nthreads = gridDim.x * gridDim.y * 256;
  for (int i = tid; i < NB * NQ * NGW; i += nthreads) mbitsT[i] = 0u;
  __shared__ float4 sA0[NG];
  __shared__ float4 sA1[NG];
  for (int i = threadIdx.x; i < NG; i += 256) {
    sA0[i] = gp[(size_t)(b*NG + i)*5 + 0];
    sA1[i] = gp[(size_t)(b*NG + i)*5 + 1];
  }
  __syncthreads();
  if (q >= NQ) return;
  const float4 pb = reinterpret_cast<const float4*>(boxes)[b * NQ + q];
  const float s0 = imgsz[b*4+0], s1 = imgsz[b*4+1], s2 = imgsz[b*4+2], s3 = imgsz[b*4+3];
  const float ax = (pb.x + pb.z) * 0.5f;
  const float ay = (pb.y + pb.w) * 0.5f;
  bool fg = false;
  for (int g = 0; g < NG; ++g) {
    const float4 A0 = sA0[g];
    const float4 A1 = sA1[g];
    const bool inb = (ax > A0.x) && (ax < A0.z) && (ay > A0.y) && (ay < A0.w);
    const bool inc = (ax > A1.x) && (ax < A1.y) && (ay > A1.z) && (ay < A1.w);
    if (inb || inc) { fg = true; break; }   // fg = any(in_box) | any(in_ctr)
  }
  const int idx = b * NQ + q;
  prepN[idx] = make_float4(pb.x / s0, pb.y / s1, pb.z / s2, pb.w / s3);
  prepF[idx] = fg ? 0.f : 10000.f;
  rcnt[idx] = 0;
}

// ---------------- K2: focal class cost table, transposed (B,C,Q), tiled ----------------
#define QT 64
__global__ void cls_kernel(const float* __restrict__ logits, float* __restrict__ cct) {
#pragma clang fp contract(off)
  const int b = blockIdx.y, q0 = blockIdx.x * QT, t = threadIdx.x;
  __shared__ float tile[QT * NC];
  const int nq = (NQ - q0 < QT) ? (NQ - q0) : QT;
  const float* __restrict__ src = logits + ((size_t)(b * NQ + q0)) * NC;
  for (int i = t; i < nq * NC; i += 256) {
    const float x = src[i];
    float p;
    if (x >= 0.f) p = 1.f / (1.f + expf(-x));
    else { const float e = expf(x); p = e / (1.f + e); }
    const float pos = 0.25f * ((1.f - p) * (1.f - p)) * (-logf(p + 1e-8f));
    const float neg = 0.75f * (p * p) * (-logf(1.f - p + 1e-8f));
    tile[i] = pos - neg;
  }
  __syncthreads();
  for (int i = t; i < NC * QT; i += 256) {
    const int c = i >> 6;
    const int ql = i & (QT - 1);
    if (ql < nq) cct[((size_t)(b * NC + c)) * NQ + q0 + ql] = tile[ql * NC + c];
  }
}

// ---------------- K3: FUSED cost + per-(b,g) top-5 (1 GT per block, 128 thr) ----------------
__device__ __forceinline__ void kv_sortnet(unsigned* k, int* i) {
#define CE(a,b) { \
    const bool pr = (k[b] < k[a]) || (k[b] == k[a] && i[b] < i[a]); \
    const unsigned tk = pr ? k[b] : k[a]; const unsigned uk = pr ? k[a] : k[b]; \
    const int ti = pr ? i[b] : i[a]; const int ui = pr ? i[a] : i[b]; \
    k[a] = tk; k[b] = uk; i[a] = ti; i[b] = ui; }
  CE(0,1)
  CE(1,2) CE(0,1)
  CE(2,3) CE(1,2) CE(0,1)
  CE(3,4) CE(2,3) CE(1,2) CE(0,1)
#undef CE
}
__device__ __forceinline__ void kv_merge(unsigned* ak, int* ai, const unsigned* bk, const int* bi) {
  unsigned ck[5]; int ci[5];
#pragma unroll
  for (int j = 0; j < 5; ++j) {
    const unsigned ka = ak[j], kb = bk[4 - j];
    const int ia = ai[j], ib = bi[4 - j];
    const bool pr = (kb < ka) || (kb == ka && ib < ia);
    ck[j] = pr ? kb : ka; ci[j] = pr ? ib : ia;
  }
  kv_sortnet(ck, ci);
#pragma unroll
  for (int j = 0; j < 5; ++j) { ak[j] = ck[j]; ai[j] = ci[j]; }
}
__device__ __forceinline__ void sort5_desc(float* c) {
#define CED(a,b) { const float hi = fmaxf(c[a], c[b]); c[b] = fminf(c[a], c[b]); c[a] = hi; }
  CED(0,1)
  CED(1,2) CED(0,1)
  CED(2,3) CED(1,2) CED(0,1)
  CED(3,4) CED(2,3) CED(1,2) CED(0,1)
#undef CED
}
__device__ __forceinline__ void merge5_iou(float* a, const float* o) {
  float c[5];
#pragma unroll
  for (int j = 0; j < 5; ++j) c[j] = fmaxf(a[j], o[4 - j]);
  sort5_desc(c);
#pragma unroll
  for (int j = 0; j < 5; ++j) a[j] = c[j];
}

__global__ __launch_bounds__(128) void cost_topk_kernel(
    const float* __restrict__ boxes, const float4* __restrict__ prepN,
    const float* __restrict__ prepF, const float4* __restrict__ gp,
    const float* __restrict__ cct, float* __restrict__ cost,
    unsigned* __restrict__ mbits, unsigned* __restrict__ mbitsT,
    int* __restrict__ rcnt, int* __restrict__ ccov) {
#pragma clang fp contract(off)
  const int g = blockIdx.x, b = blockIdx.y, t = threadIdx.x;
  const int lane = t & 63, wave = t >> 6;
  const float4 A0 = gp[(size_t)(b*NG + g) * 5 + 0];
  const float4 A1 = gp[(size_t)(b*NG + g) * 5 + 1];
  const float4 A2 = gp[(size_t)(b*NG + g) * 5 + 2];
  const float4 A3 = gp[(size_t)(b*NG + g) * 5 + 3];
  const float4 A4 = gp[(size_t)(b*NG + g) * 5 + 4];
  const int lab = __float_as_int(A4.y);
  const float areaB = A4.x;
  const float* __restrict__ ccls = cct + ((size_t)(b*NC + lab)) * NQ;
  float* __restrict__ crow = cost + ((size_t)(b*NG + g)) * NQ;
  unsigned* __restrict__ mrow = mbits + (b*NG + g) * NQW;
  for (int i = t; i < NQW; i += 128) mrow[i] = 0u;

  unsigned mk[5]; int mi[5]; float sv[5];
#pragma unroll
  for (int j = 0; j < 5; ++j) { mk[j] = 0xffffffffu; mi[j] = 0x7fffffff; sv[j] = -1.f; }

  for (int q = t; q < NQ; q += 128) {
    const float4 pb = reinterpret_cast<const float4*>(boxes)[b*NQ + q];
    const float4 nb = prepN[b*NQ + q];
    const float fpen = prepF[b*NQ + q];
    const float ax = (pb.x + pb.z) * 0.5f;
    const float ay = (pb.y + pb.w) * 0.5f;
    const float areaA = (pb.z - pb.x) * (pb.w - pb.y);
    const float ltx = fmaxf(pb.x, A3.x), lty = fmaxf(pb.y, A3.y);
    const float rbx = fminf(pb.z, A3.z), rby = fminf(pb.w, A3.w);
    const float iw = fmaxf(rbx - ltx, 0.f), ih = fmaxf(rby - lty, 0.f);
    const float inter = iw * ih;
    const float uni = areaA + areaB - inter;
    const float iou = inter / uni;
    const float eltx = fminf(pb.x, A3.x), elty = fminf(pb.y, A3.y);
    const float erbx = fmaxf(pb.z, A3.z), erby = fmaxf(pb.w, A3.w);
    const float ew = fmaxf(erbx - eltx, 0.f), eh = fmaxf(erby - elty, 0.f);
    const float earea = ew * eh;
    const float giou = iou - (earea - uni) / earea;
    const float cbb = fabsf(nb.x - A2.x) + fabsf(nb.y - A2.y)
                    + fabsf(nb.z - A2.z) + fabsf(nb.w - A2.w);
    const bool inb = (ax > A0.x) && (ax < A0.z) && (ay > A0.y) && (ay < A0.w);
    const bool inc = (ax > A1.x) && (ax < A1.y) && (ay > A1.z) && (ay < A1.w);
    const bool ibc = inb && inc;
    float cval = 5.0f * cbb + 2.0f * ccls[q];
    cval = cval + 2.0f * (-giou);
    cval = cval + (ibc ? 0.f : 100.f);
    cval = cval + fpen;
    crow[q] = cval;
    const unsigned bits = __float_as_uint(cval + 0.0f);  // canonicalize -0
    unsigned key = (bits & 0x80000000u) ? ~bits : (bits | 0x80000000u);
    int qi = q;
#pragma unroll
    for (int j = 0; j < 5; ++j) {   // stable branchless bubble (ties keep existing)
      const unsigned a = mk[j];
      const bool pr = key < a;
      mk[j] = pr ? key : a;
      const int ii = mi[j];
      mi[j] = pr ? qi : ii;
      key = pr ? a : key;
      qi = pr ? ii : qi;
    }
    float x = iou;
#pragma unroll
    for (int j = 0; j < 5; ++j) {   // sv sorted descending
      const float a = sv[j];
      sv[j] = fmaxf(a, x);
      x = fminf(a, x);
    }
  }

#pragma unroll
  for (int off = 32; off >= 1; off >>= 1) {
    unsigned ok[5]; int oi[5]; float ov[5];
#pragma unroll
    for (int j = 0; j < 5; ++j) {
      ok[j] = __shfl_down(mk[j], off);
      oi[j] = __shfl_down(mi[j], off);
      ov[j] = __shfl_down(sv[j], off);
    }
    kv_merge(mk, mi, ok, oi);
    merge5_iou(sv, ov);
  }

  __shared__ unsigned Lk[2][5];
  __shared__ int Li[2][5];
  __shared__ float Ls[2][5];
  if (lane == 0) {
#pragma unroll
    for (int j = 0; j < 5; ++j) { Lk[wave][j] = mk[j]; Li[wave][j] = mi[j]; Ls[wave][j] = sv[j]; }
  }
  __syncthreads();
  if (t == 0) {
    unsigned fk[5]; int fi[5]; float fs[5];
    unsigned o2[5]; int i2[5]; float s2[5];
#pragma unroll
    for (int j = 0; j < 5; ++j) {
      fk[j] = Lk[0][j]; fi[j] = Li[0][j]; fs[j] = Ls[0][j];
      o2[j] = Lk[1][j]; i2[j] = Li[1][j]; s2[j] = Ls[1][j];
    }
    kv_merge(fk, fi, o2, i2);
    merge5_iou(fs, s2);
    float s = fs[0]; s += fs[1]; s += fs[2]; s += fs[3]; s += fs[4];  // descending order sum
    int k = (int)s; if (k < 1) k = 1; if (k > 5) k = 5;
    for (int j = 0; j < k; ++j) {
      const int q = fi[j];
      mrow[q >> 5] |= 1u << (q & 31);
      atomicOr(&mbitsT[((size_t)(b*NQ + q)) * NGW + (g >> 5)], 1u << (g & 31));
      atomicAdd(&rcnt[b * NQ + q], 1);
    }
    ccov[b * NG + g] = k;
  }
}

// ---------------- K7: fused compact+gather+multifix + while-loop, one block per image ----------------
__global__ __launch_bounds__(1024) void loop_kernel(
    const float* __restrict__ cost, float* __restrict__ costM,
    unsigned* __restrict__ mbits, unsigned* __restrict__ mbitsT,
    const int* __restrict__ rcnt_g, const int* __restrict__ ccov_g,
    int* __restrict__ pen_g) {
  const int b = blockIdx.x, t = threadIdx.x;
  __shared__ int s_pen[NQ];
  __shared__ int s_rcnt[NQ];
  __shared__ short s_qmi[NQ];
  __shared__ int s_ccov[NG];
  __shared__ int s_unc[NG];
  __shared__ int s_pickq[NG];
  __shared__ int s_mq[MAXM];
  __shared__ unsigned s_mrow[MAXM][NGW];
  __shared__ int s_mn, s_n, s_fix, s_sticky;

  const int lane = t & 63, wave = t >> 6;
  unsigned* __restrict__ mb = mbits + b * NG * NQW;
  unsigned* __restrict__ mbT = mbitsT + (size_t)b * NQ * NGW;
  const float* __restrict__ cb = cost + (size_t)b * NG * NQ;
  float* __restrict__ cm = costM + (size_t)b * MAXM * NG;

  if (t == 0) { s_mn = 0; s_sticky = 0; }
  for (int q = t; q < NQ; q += 1024) {
    s_pen[q] = 0;
    s_rcnt[q] = rcnt_g[b * NQ + q];
    s_qmi[q] = -1;
  }
  for (int g = t; g < NG; g += 1024) s_ccov[g] = ccov_g[b * NG + g];
  __syncthreads();
  // compact multi rows (rcnt>1) into s_mq
  for (int q = t; q < NQ; q += 1024)
    if (s_rcnt[q] > 1) { const int i = atomicAdd(&s_mn, 1); if (i < MAXM) s_mq[i] = q; }
  __syncthreads();
  int m_n = s_mn; if (m_n > MAXM) m_n = MAXM;
  for (int i = t; i < m_n; i += 1024) s_qmi[s_mq[i]] = (short)i;
  // gather costM rows (strided reads, coalesced-ish writes)
  for (int i = t; i < m_n * NG; i += 1024) {
    const int mi = i / NG, g = i - mi * NG;
    cm[i] = cb[(size_t)g * NQ + s_mq[mi]];
  }
  // load multi rows' bit-rows
  for (int i = t; i < m_n * NGW; i += 1024) {
    const int mi = i / NGW, w2 = i - mi * NGW;
    s_mrow[mi][w2] = mbT[(size_t)s_mq[mi] * NGW + w2];
  }
  __syncthreads();
  // multifix: one wave per multi row -> one-hot argmin_g
  for (int mi = wave; mi < m_n; mi += 16) {
    const int q = s_mq[mi];
    const float* __restrict__ row = cm + (size_t)mi * NG;
    float best = FLT_MAX; int bg = 0;
    for (int g = lane; g < NG; g += 64) {
      const float v = row[g];
      if (v < best) { best = v; bg = g; }
    }
    for (int off = 32; off; off >>= 1) {
      const float ov = __shfl_down(best, off);
      const int og = __shfl_down(bg, off);
      if (ov < best || (ov == best && og < bg)) { best = ov; bg = og; }
    }
    bg = __shfl(bg, 0);
    const unsigned qbit = 1u << (q & 31);
    const int qw = q >> 5;
    if (lane < NGW) {
      const unsigned wv = s_mrow[mi][lane];
      const unsigned want = ((bg >> 5) == lane) ? (1u << (bg & 31)) : 0u;
      unsigned clr = wv & ~want;
      while (clr) {
        const int gb = __ffs(clr) - 1; clr &= clr - 1;
        const int g = lane*32 + gb;
        atomicAnd(&mb[g * NQW + qw], ~qbit);
        atomicSub(&s_ccov[g], 1);
      }
      if (want & ~wv) {
        atomicOr(&mb[bg * NQW + qw], qbit);
        atomicAdd(&s_ccov[bg], 1);
      }
      s_mrow[mi][lane] = want;
    }
    if (lane == 0) s_rcnt[q] = 1;
  }
  __syncthreads();

  for (int iter = 0; iter < 100; ++iter) {
    if (t == 0) { s_n = 0; s_fix = s_sticky; }
    __syncthreads();
    for (int g = t; g < NG; g += 1024)
      if (s_ccov[g] == 0) { const int i = atomicAdd(&s_n, 1); s_unc[i] = g; }
    __syncthreads();
    const int n = s_n;
    if (n == 0) break;
    for (int q = t; q < NQ; q += 1024)
      if (s_rcnt[q] > 0) s_pen[q]++;
    __syncthreads();
    // argmin_q per uncovered column — pen==0 rows only at raw cost (penalized >= 99989 > max raw)
    for (int ci = wave; ci < n; ci += 16) {
      const int g = s_unc[ci];
      const float* __restrict__ crow = cb + (size_t)g * NQ;
      float best = FLT_MAX; int bq = 0x7fffffff;
      for (int q = lane; q < NQ; q += 64) {
        if (s_pen[q] == 0) {
          const float v = crow[q];
          if (v < best) { best = v; bq = q; }
        }
      }
      for (int off = 32; off; off >>= 1) {
        const float ov = __shfl_down(best, off);
        const int oq = __shfl_down(bq, off);
        if (ov < best || (ov == best && oq < bq)) { best = ov; bq = oq; }
      }
      if (lane == 0) s_pickq[ci] = bq;
    }
    __syncthreads();
    if (t < n) {
      const int g = s_unc[t], q = s_pickq[t];
      atomicOr(&mb[g * NQW + (q >> 5)], 1u << (q & 31));
      const int mi2 = s_qmi[q];
      if (mi2 >= 0) atomicOr(&s_mrow[mi2][g >> 5], 1u << (g & 31));
      else atomicOr(&mbT[(size_t)q * NGW + (g >> 5)], 1u << (g & 31));
      const int nc = atomicAdd(&s_rcnt[q], 1) + 1;
      s_ccov[g] = 1;
      if (nc > 1) { s_fix = 1; if (s_qmi[q] < 0) s_sticky = 1; }
    }
    __syncthreads();
    if (s_fix) {
      for (int mi = wave; mi < m_n; mi += 16) {
        const int q = s_mq[mi];
        const int p = s_pen[q];
        const float* __restrict__ row = cm + (size_t)mi * NG;
        float best = FLT_MAX; int bg = 0;
        for (int g = lane; g < NG; g += 64) {
          const float v = penalized(row[g], p);
          if (v < best) { best = v; bg = g; }
        }
        for (int off = 32; off; off >>= 1) {
          const float ov = __shfl_down(best, off);
          const int og = __shfl_down(bg, off);
          if (ov < best || (ov == best && og < bg)) { best = ov; bg = og; }
        }
        bg = __shfl(bg, 0);
        const unsigned qbit = 1u << (q & 31);
        const int qw = q >> 5;
        if (lane < NGW) {
          const unsigned wv = s_mrow[mi][lane];
          const unsigned want = ((bg >> 5) == lane) ? (1u << (bg & 31)) : 0u;
          unsigned clr = wv & ~want;
          while (clr) {
            const int gb = __ffs(clr) - 1; clr &= clr - 1;
            const int g = lane * 32 + gb;
            atomicAnd(&mb[g * NQW + qw], ~qbit);
            atomicSub(&s_ccov[g], 1);
          }
          if (want & ~wv) {
            atomicOr(&mb[bg * NQW + qw], qbit);
            atomicAdd(&s_ccov[bg], 1);
          }
          s_mrow[mi][lane] = want;
        }
        if (lane == 0) s_rcnt[q] = 1;
      }
    }
    __syncthreads();
  }
  __syncthreads();
  for (int i = t; i < m_n * NGW; i += 1024) {
    const int mi = i / NGW, w2 = i - mi * NGW;
    mbT[(size_t)s_mq[mi] * NGW + w2] = s_mrow[mi][w2];
  }
  for (int q = t; q < NQ; q += 1024) pen_g[b * NQ + q] = s_pen[q];
}

// ---------------- K8: matched_qidx — bit-sparse, one wave per (b,g) ----------------
__global__ __launch_bounds__(256) void matched_kernel(
    const float* __restrict__ cost, const unsigned* __restrict__ mbits,
    const int* __restrict__ pen_g, float* __restrict__ out_mq) {
  const int b = blockIdx.y, t = threadIdx.x;
  const int g = blockIdx.x * 4 + (t >> 6);
  const int lane = t & 63;
  const float* __restrict__ crow = cost + ((size_t)(b*NG + g)) * NQ;
  const unsigned* __restrict__ mrow = mbits + (b*NG + g) * NQW;
  const int* __restrict__ pb = pen_g + b * NQ;
  float best = FLT_MAX; int bq = 0;
  for (int w = lane; w < NQW; w += 64) {
    unsigned word = mrow[w];
    while (word) {
      const int bit = __ffs(word) - 1; word &= word - 1;
      const int q = w * 32 + bit;
      const float v = penalized(crow[q], pb[q]);
      if (lexlt(v, q, best, bq)) { best = v; bq = q; }
    }
  }
  for (int off = 32; off; off >>= 1) {
    const float ov = __shfl_down(best, off);
    const int oq = __shfl_down(bq, off);
    if (lexlt(ov, oq, best, bq)) { best = ov; bq = oq; }
  }
  if (lane == 0) out_mq[b * NG + g] = (float)bq;
}

// ---------------- K9: expand mbitsT rows -> m floats (float4 stores), selected, gt_idx ----------------
__global__ void out_kernel(const unsigned* __restrict__ mbitsT, float* __restrict__ out_m,
                           float* __restrict__ out_sel, float* __restrict__ out_gti) {
  const int b = blockIdx.y, t = threadIdx.x;
  const int q0 = blockIdx.x * 8;
  __shared__ unsigned wds[8 * NGW];
  if (t < 8 * NGW) wds[t] = mbitsT[((size_t)(b*NQ + q0)) * NGW + t];
  __syncthreads();
  float4* __restrict__ om4 = reinterpret_cast<float4*>(out_m + ((size_t)(b*NQ + q0)) * NG);
  for (int j = t; j < 8 * (NG/4); j += 256) {
    const int qi = j / (NG/4);
    const int g0 = (j - qi * (NG/4)) * 4;
    const unsigned* wr = &wds[qi * NGW];
    float4 v;
    v.x = ((wr[(g0+0) >> 5] >> ((g0+0) & 31)) & 1u) ? 1.f : 0.f;
    v.y = ((wr[(g0+1) >> 5] >> ((g0+1) & 31)) & 1u) ? 1.f : 0.f;
    v.z = ((wr[(g0+2) >> 5] >> ((g0+2) & 31)) & 1u) ? 1.f : 0.f;
    v.w = ((wr[(g0+3) >> 5] >> ((g0+3) & 31)) & 1u) ? 1.f : 0.f;
    om4[j] = v;
  }
  if (t < 8) {
    int fgi = -1;
    for (int w = 0; w < NGW; ++w) {
      const unsigned v = wds[t*NGW + w];
      if (v) { fgi = w*32 + __ffs(v) - 1; break; }
    }
    out_sel[b*NQ + q0 + t] = (fgi >= 0) ? 1.f : 0.f;
    out_gti[b*NQ + q0 + t] = (fgi >= 0) ? (float)fgi : 0.f;
  }
}

extern "C" void kernel_launch(void* const* d_in, const int* in_sizes, int n_in,
                              void* d_out, int out_size, void* d_ws, size_t ws_size,
                              hipStream_t stream) {
  const float* logits = (const float*)d_in[0];
  const float* boxes  = (const float*)d_in[1];
  const int*   labels = (const int*)d_in[2];
  const float* gtb    = (const float*)d_in[3];
  const float* imgsz  = (const float*)d_in[4];

  float* out = (float*)d_out;
  float* out_m   = out;                                   // B*Q*G
  float* out_sel = out + (size_t)NB * NQ * NG;            // B*Q
  float* out_gti = out_sel + (size_t)NB * NQ;             // B*Q
  float* out_mq  = out_gti + (size_t)NB * NQ;             // B*G

  char* w = (char*)d_ws;
  const size_t szPrep = sizeof(float4) * (size_t)NB * NQ;
  const size_t szF    = sizeof(float) * (size_t)NB * NQ;
  const size_t szGp   = sizeof(float4) * (size_t)NB * NG * 5;
  const size_t szCct  = sizeof(float) * (size_t)NB * NC * NQ;
  const size_t szBits = sizeof(unsigned) * (size_t)NB * NG * NQW;
  const size_t szBitsT= sizeof(unsigned) * (size_t)NB * NQ * NGW;
  const size_t szIntQ = sizeof(int) * (size_t)NB * NQ;
  const size_t szIntG = sizeof(int) * (size_t)NB * NG;
  const size_t szCM   = sizeof(float) * (size_t)NB * MAXM * NG;
  const size_t need = szPrep + szF + szGp + szCct + szBits + szBitsT + 2*szIntQ + szIntG + szCM;
  if (ws_size < need) return;

  float4* prepN = (float4*)w; w += szPrep;
  float*  prepF = (float*)w;  w += szF;
  float4* gp    = (float4*)w; w += szGp;
  float*    cct   = (float*)w;    w += szCct;
  unsigned* mbits = (unsigned*)w; w += szBits;
  unsigned* mbitsT= (unsigned*)w; w += szBitsT;
  int* rcnt  = (int*)w; w += szIntQ;
  int* pen   = (int*)w; w += szIntQ;
  int* ccov  = (int*)w; w += szIntG;
  float* costM = (float*)w; w += szCM;

  float* cost = out_m;  // (B,G,Q) in the d_out m-region; overwritten by out_kernel at the end

  gprep_kernel<<<(NB * NG + 255) / 256, 256, 0, stream>>>(gtb, labels, imgsz, gp);
  prep_kernel<<<dim3((NQ + 255) / 256, NB), 256, 0, stream>>>(boxes, gp, imgsz, prepN, prepF, rcnt, mbitsT);
  cls_kernel<<<dim3((NQ + QT - 1) / QT, NB), 256, 0, stream>>>(logits, cct);
  cost_topk_kernel<<<dim3(NG, NB), 128, 0, stream>>>(boxes, prepN, prepF, gp, cct, cost, mbits, mbitsT, rcnt, ccov);
  loop_kernel<<<NB, 1024, 0, stream>>>(cost, costM, mbits, mbitsT, rcnt, ccov, pen);
  matched_kernel<<<dim3(NG/4, NB), 256, 0, stream>>>(cost, mbits, pen, out_mq);
  out_kernel<<<dim3(NQ / 8, NB), 256, 0, stream>>>(mbitsT, out_m, out_sel, out_gti);
}

// Round 10
// 244.111 us; speedup vs baseline: 1.8569x; 1.0004x over previous
//
#include <hip/hip_runtime.h>
#include <float.h>
#include <stdint.h>
#include <stddef.h>

#define NB 16
#define NQ 4000
#define NG 300
#define NC 81
#define NQW 125  // NQ/32
#define NGW 10   // ceil(NG/32)
#define MAXM 768 // multi rows per image <= sum(dyn_k)/2 <= 750 (provable bound)

__device__ __forceinline__ bool lexlt(float v1, int i1, float v2, int i2) {
  return (v1 < v2) || (v1 == v2 && i1 < i2);
}

// Exact replica of p sequential f32 adds of 1e5 (numpy semantics), in O(#binade crossings).
__device__ __forceinline__ float penalized(float v, int p) {
  if (p <= 0) return v;
  if (p <= 12) {
    float x = v;
    for (int r = 0; r < p; ++r) x += 100000.0f;
    return x;
  }
  double x = (double)v;
  x = (double)(float)(x + 100000.0);
  int k = 1;
  while (k < p) {
    double B = 131072.0;
    while (B <= x) B += B;
    double room = B - x;
    int j = (int)(room * 1e-5);
    while (j > 0 && x + (double)j * 100000.0 >= B) --j;
    if (j > p - k) j = p - k;
    if (j > 0) { x += (double)j * 100000.0; k += j; }
    if (k < p) { x = (double)(float)(x + 100000.0); ++k; }
  }
  return (float)x;
}

// ---------------- K0: per-gt derived params ----------------
__global__ void gprep_kernel(const float* __restrict__ gtb, const int* __restrict__ labels,
                             const float* __restrict__ imgsz, float4* __restrict__ gp) {
#pragma clang fp contract(off)
  const int idx = blockIdx.x * 256 + threadIdx.x;
  if (idx >= NB * NG) return;
  const int b = idx / NG;
  const float gx0 = gtb[idx*4 + 0];
  const float gy0 = gtb[idx*4 + 1];
  const float gx1 = gtb[idx*4 + 2];
  const float gy1 = gtb[idx*4 + 3];
  const float s0 = imgsz[b*4+0], s1 = imgsz[b*4+1], s2 = imgsz[b*4+2], s3 = imgsz[b*4+3];
  const float areaB = (gx1 - gx0) * (gy1 - gy0);
  const float gcx = (gx0 + gx1) * 0.5f, gcy = (gy0 + gy1) * 0.5f;
  const float gw0 = gx1 - gx0, gh0 = gy1 - gy0;
  const float xg0 = gcx - 0.5f*gw0, yg0 = gcy - 0.5f*gh0;
  const float xg1 = gcx + 0.5f*gw0, yg1 = gcy + 0.5f*gh0;
  const float cw = xg1 - xg0, ch = yg1 - yg0;
  gp[idx*5+0] = make_float4(xg0, yg0, xg1, yg1);
  gp[idx*5+1] = make_float4(gcx - 2.5f*cw, gcx + 2.5f*cw, gcy - 2.5f*ch, gcy + 2.5f*ch);
  gp[idx*5+2] = make_float4(gx0 / s0, gy0 / s1, gx1 / s2, gy1 / s3);
  gp[idx*5+3] = make_float4(gx0, gy0, gx1, gy1);
  gp[idx*5+4] = make_float4(areaB, __int_as_float(labels[idx]), 0.f, 0.f);
}

// ---------------- K1: prep — fg penalty via gp (early break), normalized box; zero rcnt/mbitsT ----------------
__global__ void prep_kernel(const float* __restrict__ boxes, const float4* __restrict__ gp,
                            const float* __restrict__ imgsz,
                            float4* __restrict__ prepN, float* __restrict__ prepF,
                            int* __restrict__ rcnt, unsigned* __restrict__ mbitsT) {
#pragma clang fp contract(off)
  const int b = blockIdx.y;
  const int q = blockIdx.x * 256 + threadIdx.x;
  const int tid = (blockIdx.y * gridDim.x + blockIdx.x) * 256 + threadIdx.x;
  const int nthreads = gridDim.x * gridDim.y * 256;
  for (int i = tid; i < NB * NQ * NGW; i += nthreads) mbitsT[i] = 0u;
  __shared__ float4 sA0[NG];
  __shared__ float4 sA1[NG];
  for (int i = threadIdx.x; i < NG; i += 256) {
    sA0[i] = gp[(size_t)(b*NG + i)*5 + 0];
    sA1[i] = gp[(size_t)(b*NG + i)*5 + 1];
  }
  __syncthreads();
  if (q >= NQ) return;
  const float4 pb = reinterpret_cast<const float4*>(boxes)[b * NQ + q];
  const float s0 = imgsz[b*4+0], s1 = imgsz[b*4+1], s2 = imgsz[b*4+2], s3 = imgsz[b*4+3];
  const float ax = (pb.x + pb.z) * 0.5f;
  const float ay = (pb.y + pb.w) * 0.5f;
  bool fg = false;
  for (int g = 0; g < NG; ++g) {
    const float4 A0 = sA0[g];
    const float4 A1 = sA1[g];
    const bool inb = (ax > A0.x) && (ax < A0.z) && (ay > A0.y) && (ay < A0.w);
    const bool inc = (ax > A1.x) && (ax < A1.y) && (ay > A1.z) && (ay < A1.w);
    if (inb || inc) { fg = true; break; }   // fg = any(in_box) | any(in_ctr)
  }
  const int idx = b * NQ + q;
  prepN[idx] = make_float4(pb.x / s0, pb.y / s1, pb.z / s2, pb.w / s3);
  prepF[idx] = fg ? 0.f : 10000.f;
  rcnt[idx] = 0;
}

// ---------------- K2: focal class cost table, transposed (B,C,Q), tiled ----------------
#define QT 64
__global__ void cls_kernel(const float* __restrict__ logits, float* __restrict__ cct) {
#pragma clang fp contract(off)
  const int b = blockIdx.y, q0 = blockIdx.x * QT, t = threadIdx.x;
  __shared__ float tile[QT * NC];
  const int nq = (NQ - q0 < QT) ? (NQ - q0) : QT;
  const float* __restrict__ src = logits + ((size_t)(b * NQ + q0)) * NC;
  for (int i = t; i < nq * NC; i += 256) {
    const float x = src[i];
    float p;
    if (x >= 0.f) p = 1.f / (1.f + expf(-x));
    else { const float e = expf(x); p = e / (1.f + e); }
    const float pos = 0.25f * ((1.f - p) * (1.f - p)) * (-logf(p + 1e-8f));
    const float neg = 0.75f * (p * p) * (-logf(1.f - p + 1e-8f));
    tile[i] = pos - neg;
  }
  __syncthreads();
  for (int i = t; i < NC * QT; i += 256) {
    const int c = i >> 6;
    const int ql = i & (QT - 1);
    if (ql < nq) cct[((size_t)(b * NC + c)) * NQ + q0 + ql] = tile[ql * NC + c];
  }
}

// ---------------- K3: FUSED cost + per-(b,g) top-5 (1 GT per block, 128 thr) ----------------
__device__ __forceinline__ void kv_sortnet(unsigned* k, int* i) {
#define CE(a,b) { \
    const bool pr = (k[b] < k[a]) || (k[b] == k[a] && i[b] < i[a]); \
    const unsigned tk = pr ? k[b] : k[a]; const unsigned uk = pr ? k[a] : k[b]; \
    const int ti = pr ? i[b] : i[a]; const int ui = pr ? i[a] : i[b]; \
    k[a] = tk; k[b] = uk; i[a] = ti; i[b] = ui; }
  CE(0,1)
  CE(1,2) CE(0,1)
  CE(2,3) CE(1,2) CE(0,1)
  CE(3,4) CE(2,3) CE(1,2) CE(0,1)
#undef CE
}
__device__ __forceinline__ void kv_merge(unsigned* ak, int* ai, const unsigned* bk, const int* bi) {
  unsigned ck[5]; int ci[5];
#pragma unroll
  for (int j = 0; j < 5; ++j) {
    const unsigned ka = ak[j], kb = bk[4 - j];
    const int ia = ai[j], ib = bi[4 - j];
    const bool pr = (kb < ka) || (kb == ka && ib < ia);
    ck[j] = pr ? kb : ka; ci[j] = pr ? ib : ia;
  }
  kv_sortnet(ck, ci);
#pragma unroll
  for (int j = 0; j < 5; ++j) { ak[j] = ck[j]; ai[j] = ci[j]; }
}
__device__ __forceinline__ void sort5_desc(float* c) {
#define CED(a,b) { const float hi = fmaxf(c[a], c[b]); c[b] = fminf(c[a], c[b]); c[a] = hi; }
  CED(0,1)
  CED(1,2) CED(0,1)
  CED(2,3) CED(1,2) CED(0,1)
  CED(3,4) CED(2,3) CED(1,2) CED(0,1)
#undef CED
}
__device__ __forceinline__ void merge5_iou(float* a, const float* o) {
  float c[5];
#pragma unroll
  for (int j = 0; j < 5; ++j) c[j] = fmaxf(a[j], o[4 - j]);
  sort5_desc(c);
#pragma unroll
  for (int j = 0; j < 5; ++j) a[j] = c[j];
}

__global__ __launch_bounds__(128, 4) void cost_topk_kernel(
    const float* __restrict__ boxes, const float4* __restrict__ prepN,
    const float* __restrict__ prepF, const float4* __restrict__ gp,
    const float* __restrict__ cct, float* __restrict__ cost,
    unsigned* __restrict__ mbits, unsigned* __restrict__ mbitsT,
    int* __restrict__ rcnt, int* __restrict__ ccov) {
#pragma clang fp contract(off)
  const int g = blockIdx.x, b = blockIdx.y, t = threadIdx.x;
  const int lane = t & 63, wave = t >> 6;
  const float4 A0 = gp[(size_t)(b*NG + g) * 5 + 0];
  const float4 A1 = gp[(size_t)(b*NG + g) * 5 + 1];
  const float4 A2 = gp[(size_t)(b*NG + g) * 5 + 2];
  const float4 A3 = gp[(size_t)(b*NG + g) * 5 + 3];
  const float4 A4 = gp[(size_t)(b*NG + g) * 5 + 4];
  const int lab = __float_as_int(A4.y);
  const float areaB = A4.x;
  const float* __restrict__ ccls = cct + ((size_t)(b*NC + lab)) * NQ;
  float* __restrict__ crow = cost + ((size_t)(b*NG + g)) * NQ;
  unsigned* __restrict__ mrow = mbits + (b*NG + g) * NQW;
  for (int i = t; i < NQW; i += 128) mrow[i] = 0u;

  unsigned mk[5]; int mi[5]; float sv[5];
#pragma unroll
  for (int j = 0; j < 5; ++j) { mk[j] = 0xffffffffu; mi[j] = 0x7fffffff; sv[j] = -1.f; }

  for (int q = t; q < NQ; q += 128) {
    const float4 pb = reinterpret_cast<const float4*>(boxes)[b*NQ + q];
    const float4 nb = prepN[b*NQ + q];
    const float fpen = prepF[b*NQ + q];
    const float ax = (pb.x + pb.z) * 0.5f;
    const float ay = (pb.y + pb.w) * 0.5f;
    const float areaA = (pb.z - pb.x) * (pb.w - pb.y);
    const float ltx = fmaxf(pb.x, A3.x), lty = fmaxf(pb.y, A3.y);
    const float rbx = fminf(pb.z, A3.z), rby = fminf(pb.w, A3.w);
    const float iw = fmaxf(rbx - ltx, 0.f), ih = fmaxf(rby - lty, 0.f);
    const float inter = iw * ih;
    const float uni = areaA + areaB - inter;
    const float iou = inter / uni;
    const float eltx = fminf(pb.x, A3.x), elty = fminf(pb.y, A3.y);
    const float erbx = fmaxf(pb.z, A3.z), erby = fmaxf(pb.w, A3.w);
    const float ew = fmaxf(erbx - eltx, 0.f), eh = fmaxf(erby - elty, 0.f);
    const float earea = ew * eh;
    const float giou = iou - (earea - uni) / earea;
    const float cbb = fabsf(nb.x - A2.x) + fabsf(nb.y - A2.y)
                    + fabsf(nb.z - A2.z) + fabsf(nb.w - A2.w);
    const bool inb = (ax > A0.x) && (ax < A0.z) && (ay > A0.y) && (ay < A0.w);
    const bool inc = (ax > A1.x) && (ax < A1.y) && (ay > A1.z) && (ay < A1.w);
    const bool ibc = inb && inc;
    float cval = 5.0f * cbb + 2.0f * ccls[q];
    cval = cval + 2.0f * (-giou);
    cval = cval + (ibc ? 0.f : 100.f);
    cval = cval + fpen;
    crow[q] = cval;
    const unsigned bits = __float_as_uint(cval + 0.0f);  // canonicalize -0
    unsigned key = (bits & 0x80000000u) ? ~bits : (bits | 0x80000000u);
    int qi = q;
#pragma unroll
    for (int j = 0; j < 5; ++j) {   // stable branchless bubble (ties keep existing)
      const unsigned a = mk[j];
      const bool pr = key < a;
      mk[j] = pr ? key : a;
      const int ii = mi[j];
      mi[j] = pr ? qi : ii;
      key = pr ? a : key;
      qi = pr ? ii : qi;
    }
    float x = iou;
#pragma unroll
    for (int j = 0; j < 5; ++j) {   // sv sorted descending
      const float a = sv[j];
      sv[j] = fmaxf(a, x);
      x = fminf(a, x);
    }
  }

#pragma unroll
  for (int off = 32; off >= 1; off >>= 1) {
    unsigned ok[5]; int oi[5]; float ov[5];
#pragma unroll
    for (int j = 0; j < 5; ++j) {
      ok[j] = __shfl_down(mk[j], off);
      oi[j] = __shfl_down(mi[j], off);
      ov[j] = __shfl_down(sv[j], off);
    }
    kv_merge(mk, mi, ok, oi);
    merge5_iou(sv, ov);
  }

  __shared__ unsigned Lk[2][5];
  __shared__ int Li[2][5];
  __shared__ float Ls[2][5];
  if (lane == 0) {
#pragma unroll
    for (int j = 0; j < 5; ++j) { Lk[wave][j] = mk[j]; Li[wave][j] = mi[j]; Ls[wave][j] = sv[j]; }
  }
  __syncthreads();
  if (t == 0) {
    unsigned fk[5]; int fi[5]; float fs[5];
    unsigned o2[5]; int i2[5]; float s2[5];
#pragma unroll
    for (int j = 0; j < 5; ++j) {
      fk[j] = Lk[0][j]; fi[j] = Li[0][j]; fs[j] = Ls[0][j];
      o2[j] = Lk[1][j]; i2[j] = Li[1][j]; s2[j] = Ls[1][j];
    }
    kv_merge(fk, fi, o2, i2);
    merge5_iou(fs, s2);
    float s = fs[0]; s += fs[1]; s += fs[2]; s += fs[3]; s += fs[4];  // descending order sum
    int k = (int)s; if (k < 1) k = 1; if (k > 5) k = 5;
    for (int j = 0; j < k; ++j) {
      const int q = fi[j];
      mrow[q >> 5] |= 1u << (q & 31);
      atomicOr(&mbitsT[((size_t)(b*NQ + q)) * NGW + (g >> 5)], 1u << (g & 31));
      atomicAdd(&rcnt[b * NQ + q], 1);
    }
    ccov[b * NG + g] = k;
  }
}

// ---------------- K7: fused compact+gather+multifix + while-loop, one block per image ----------------
__global__ __launch_bounds__(1024) void loop_kernel(
    const float* __restrict__ cost, float* __restrict__ costM,
    unsigned* __restrict__ mbits, unsigned* __restrict__ mbitsT,
    const int* __restrict__ rcnt_g, const int* __restrict__ ccov_g,
    int* __restrict__ pen_g) {
  const int b = blockIdx.x, t = threadIdx.x;
  __shared__ int s_pen[NQ];
  __shared__ int s_rcnt[NQ];
  __shared__ short s_qmi[NQ];
  __shared__ int s_ccov[NG];
  __shared__ int s_unc[NG];
  __shared__ int s_pickq[NG];
  __shared__ int s_mq[MAXM];
  __shared__ unsigned s_mrow[MAXM][NGW];
  __shared__ int s_mn, s_n, s_fix, s_sticky;

  const int lane = t & 63, wave = t >> 6;
  unsigned* __restrict__ mb = mbits + b * NG * NQW;
  unsigned* __restrict__ mbT = mbitsT + (size_t)b * NQ * NGW;
  const float* __restrict__ cb = cost + (size_t)b * NG * NQ;
  float* __restrict__ cm = costM + (size_t)b * MAXM * NG;

  if (t == 0) { s_mn = 0; s_sticky = 0; }
  for (int q = t; q < NQ; q += 1024) {
    s_pen[q] = 0;
    s_rcnt[q] = rcnt_g[b * NQ + q];
    s_qmi[q] = -1;
  }
  for (int g = t; g < NG; g += 1024) s_ccov[g] = ccov_g[b * NG + g];
  __syncthreads();
  for (int q = t; q < NQ; q += 1024)
    if (s_rcnt[q] > 1) { const int i = atomicAdd(&s_mn, 1); if (i < MAXM) s_mq[i] = q; }
  __syncthreads();
  int m_n = s_mn; if (m_n > MAXM) m_n = MAXM;
  for (int i = t; i < m_n; i += 1024) s_qmi[s_mq[i]] = (short)i;
  for (int i = t; i < m_n * NG; i += 1024) {
    const int mi = i / NG, g = i - mi * NG;
    cm[i] = cb[(size_t)g * NQ + s_mq[mi]];
  }
  for (int i = t; i < m_n * NGW; i += 1024) {
    const int mi = i / NGW, w2 = i - mi * NGW;
    s_mrow[mi][w2] = mbT[(size_t)s_mq[mi] * NGW + w2];
  }
  __syncthreads();
  // multifix: one wave per multi row -> one-hot argmin_g
  for (int mi = wave; mi < m_n; mi += 16) {
    const int q = s_mq[mi];
    const float* __restrict__ row = cm + (size_t)mi * NG;
    float best = FLT_MAX; int bg = 0;
    for (int g = lane; g < NG; g += 64) {
      const float v = row[g];
      if (v < best) { best = v; bg = g; }
    }
    for (int off = 32; off; off >>= 1) {
      const float ov = __shfl_down(best, off);
      const int og = __shfl_down(bg, off);
      if (ov < best || (ov == best && og < bg)) { best = ov; bg = og; }
    }
    bg = __shfl(bg, 0);
    const unsigned qbit = 1u << (q & 31);
    const int qw = q >> 5;
    if (lane < NGW) {
      const unsigned wv = s_mrow[mi][lane];
      const unsigned want = ((bg >> 5) == lane) ? (1u << (bg & 31)) : 0u;
      unsigned clr = wv & ~want;
      while (clr) {
        const int gb = __ffs(clr) - 1; clr &= clr - 1;
        const int g = lane*32 + gb;
        atomicAnd(&mb[g * NQW + qw], ~qbit);
        atomicSub(&s_ccov[g], 1);
      }
      if (want & ~wv) {
        atomicOr(&mb[bg * NQW + qw], qbit);
        atomicAdd(&s_ccov[bg], 1);
      }
      s_mrow[mi][lane] = want;
    }
    if (lane == 0) s_rcnt[q] = 1;
  }
  __syncthreads();

  for (int iter = 0; iter < 100; ++iter) {
    if (t == 0) { s_n = 0; s_fix = s_sticky; }
    __syncthreads();
    for (int g = t; g < NG; g += 1024)
      if (s_ccov[g] == 0) { const int i = atomicAdd(&s_n, 1); s_unc[i] = g; }
    __syncthreads();
    const int n = s_n;
    if (n == 0) break;
    for (int q = t; q < NQ; q += 1024)
      if (s_rcnt[q] > 0) s_pen[q]++;
    __syncthreads();
    for (int ci = wave; ci < n; ci += 16) {
      const int g = s_unc[ci];
      const float* __restrict__ crow = cb + (size_t)g * NQ;
      float best = FLT_MAX; int bq = 0x7fffffff;
      for (int q = lane; q < NQ; q += 64) {
        if (s_pen[q] == 0) {
          const float v = crow[q];
          if (v < best) { best = v; bq = q; }
        }
      }
      for (int off = 32; off; off >>= 1) {
        const float ov = __shfl_down(best, off);
        const int oq = __shfl_down(bq, off);
        if (ov < best || (ov == best && oq < bq)) { best = ov; bq = oq; }
      }
      if (lane == 0) s_pickq[ci] = bq;
    }
    __syncthreads();
    if (t < n) {
      const int g = s_unc[t], q = s_pickq[t];
      atomicOr(&mb[g * NQW + (q >> 5)], 1u << (q & 31));
      const int mi2 = s_qmi[q];
      if (mi2 >= 0) atomicOr(&s_mrow[mi2][g >> 5], 1u << (g & 31));
      else atomicOr(&mbT[(size_t)q * NGW + (g >> 5)], 1u << (g & 31));
      const int nc = atomicAdd(&s_rcnt[q], 1) + 1;
      s_ccov[g] = 1;
      if (nc > 1) { s_fix = 1; if (s_qmi[q] < 0) s_sticky = 1; }
    }
    __syncthreads();
    if (s_fix) {
      for (int mi = wave; mi < m_n; mi += 16) {
        const int q = s_mq[mi];
        const int p = s_pen[q];
        const float* __restrict__ row = cm + (size_t)mi * NG;
        float best = FLT_MAX; int bg = 0;
        for (int g = lane; g < NG; g += 64) {
          const float v = penalized(row[g], p);
          if (v < best) { best = v; bg = g; }
        }
        for (int off = 32; off; off >>= 1) {
          const float ov = __shfl_down(best, off);
          const int og = __shfl_down(bg, off);
          if (ov < best || (ov == best && og < bg)) { best = ov; bg = og; }
        }
        bg = __shfl(bg, 0);
        const unsigned qbit = 1u << (q & 31);
        const int qw = q >> 5;
        if (lane < NGW) {
          const unsigned wv = s_mrow[mi][lane];
          const unsigned want = ((bg >> 5) == lane) ? (1u << (bg & 31)) : 0u;
          unsigned clr = wv & ~want;
          while (clr) {
            const int gb = __ffs(clr) - 1; clr &= clr - 1;
            const int g = lane * 32 + gb;
            atomicAnd(&mb[g * NQW + qw], ~qbit);
            atomicSub(&s_ccov[g], 1);
          }
          if (want & ~wv) {
            atomicOr(&mb[bg * NQW + qw], qbit);
            atomicAdd(&s_ccov[bg], 1);
          }
          s_mrow[mi][lane] = want;
        }
        if (lane == 0) s_rcnt[q] = 1;
      }
    }
    __syncthreads();
  }
  __syncthreads();
  for (int i = t; i < m_n * NGW; i += 1024) {
    const int mi = i / NGW, w2 = i - mi * NGW;
    mbT[(size_t)s_mq[mi] * NGW + w2] = s_mrow[mi][w2];
  }
  for (int q = t; q < NQ; q += 1024) pen_g[b * NQ + q] = s_pen[q];
}

// ---------------- K8: matched_qidx — bit-sparse, one wave per (b,g) ----------------
__global__ __launch_bounds__(256) void matched_kernel(
    const float* __restrict__ cost, const unsigned* __restrict__ mbits,
    const int* __restrict__ pen_g, float* __restrict__ out_mq) {
  const int b = blockIdx.y, t = threadIdx.x;
  const int g = blockIdx.x * 4 + (t >> 6);
  const int lane = t & 63;
  const float* __restrict__ crow = cost + ((size_t)(b*NG + g)) * NQ;
  const unsigned* __restrict__ mrow = mbits + (b*NG + g) * NQW;
  const int* __restrict__ pb = pen_g + b * NQ;
  float best = FLT_MAX; int bq = 0;
  for (int w = lane; w < NQW; w += 64) {
    unsigned word = mrow[w];
    while (word) {
      const int bit = __ffs(word) - 1; word &= word - 1;
      const int q = w * 32 + bit;
      const float v = penalized(crow[q], pb[q]);
      if (lexlt(v, q, best, bq)) { best = v; bq = q; }
    }
  }
  for (int off = 32; off; off >>= 1) {
    const float ov = __shfl_down(best, off);
    const int oq = __shfl_down(bq, off);
    if (lexlt(ov, oq, best, bq)) { best = ov; bq = oq; }
  }
  if (lane == 0) out_mq[b * NG + g] = (float)bq;
}

// ---------------- K9: expand mbitsT rows -> m floats (float4 stores), selected, gt_idx ----------------
__global__ void out_kernel(const unsigned* __restrict__ mbitsT, float* __restrict__ out_m,
                           float* __restrict__ out_sel, float* __restrict__ out_gti) {
  const int b = blockIdx.y, t = threadIdx.x;
  const int q0 = blockIdx.x * 8;
  __shared__ unsigned wds[8 * NGW];
  if (t < 8 * NGW) wds[t] = mbitsT[((size_t)(b*NQ + q0)) * NGW + t];
  __syncthreads();
  float4* __restrict__ om4 = reinterpret_cast<float4*>(out_m + ((size_t)(b*NQ + q0)) * NG);
  for (int j = t; j < 8 * (NG/4); j += 256) {
    const int qi = j / (NG/4);
    const int g0 = (j - qi * (NG/4)) * 4;
    const unsigned* wr = &wds[qi * NGW];
    float4 v;
    v.x = ((wr[(g0+0) >> 5] >> ((g0+0) & 31)) & 1u) ? 1.f : 0.f;
    v.y = ((wr[(g0+1) >> 5] >> ((g0+1) & 31)) & 1u) ? 1.f : 0.f;
    v.z = ((wr[(g0+2) >> 5] >> ((g0+2) & 31)) & 1u) ? 1.f : 0.f;
    v.w = ((wr[(g0+3) >> 5] >> ((g0+3) & 31)) & 1u) ? 1.f : 0.f;
    om4[j] = v;
  }
  if (t < 8) {
    int fgi = -1;
    for (int w = 0; w < NGW; ++w) {
      const unsigned v = wds[t*NGW + w];
      if (v) { fgi = w*32 + __ffs(v) - 1; break; }
    }
    out_sel[b*NQ + q0 + t] = (fgi >= 0) ? 1.f : 0.f;
    out_gti[b*NQ + q0 + t] = (fgi >= 0) ? (float)fgi : 0.f;
  }
}

extern "C" void kernel_launch(void* const* d_in, const int* in_sizes, int n_in,
                              void* d_out, int out_size, void* d_ws, size_t ws_size,
                              hipStream_t stream) {
  const float* logits = (const float*)d_in[0];
  const float* boxes  = (const float*)d_in[1];
  const int*   labels = (const int*)d_in[2];
  const float* gtb    = (const float*)d_in[3];
  const float* imgsz  = (const float*)d_in[4];

  float* out = (float*)d_out;
  float* out_m   = out;                                   // B*Q*G
  float* out_sel = out + (size_t)NB * NQ * NG;            // B*Q
  float* out_gti = out_sel + (size_t)NB * NQ;             // B*Q
  float* out_mq  = out_gti + (size_t)NB * NQ;             // B*G

  char* w = (char*)d_ws;
  const size_t szPrep = sizeof(float4) * (size_t)NB * NQ;
  const size_t szF    = sizeof(float) * (size_t)NB * NQ;
  const size_t szGp   = sizeof(float4) * (size_t)NB * NG * 5;
  const size_t szCct  = sizeof(float) * (size_t)NB * NC * NQ;
  const size_t szBits = sizeof(unsigned) * (size_t)NB * NG * NQW;
  const size_t szBitsT= sizeof(unsigned) * (size_t)NB * NQ * NGW;
  const size_t szIntQ = sizeof(int) * (size_t)NB * NQ;
  const size_t szIntG = sizeof(int) * (size_t)NB * NG;
  const size_t szCM   = sizeof(float) * (size_t)NB * MAXM * NG;
  const size_t need = szPrep + szF + szGp + szCct + szBits + szBitsT + 2*szIntQ + szIntG + szCM;
  if (ws_size < need) return;

  float4* prepN = (float4*)w; w += szPrep;
  float*  prepF = (float*)w;  w += szF;
  float4* gp    = (float4*)w; w += szGp;
  float*    cct   = (float*)w;    w += szCct;
  unsigned* mbits = (unsigned*)w; w += szBits;
  unsigned* mbitsT= (unsigned*)w; w += szBitsT;
  int* rcnt  = (int*)w; w += szIntQ;
  int* pen   = (int*)w; w += szIntQ;
  int* ccov  = (int*)w; w += szIntG;
  float* costM = (float*)w; w += szCM;

  float* cost = out_m;  // (B,G,Q) in the d_out m-region; overwritten by out_kernel at the end

  gprep_kernel<<<(NB * NG + 255) / 256, 256, 0, stream>>>(gtb, labels, imgsz, gp);
  prep_kernel<<<dim3((NQ + 255) / 256, NB), 256, 0, stream>>>(boxes, gp, imgsz, prepN, prepF, rcnt, mbitsT);
  cls_kernel<<<dim3((NQ + QT - 1) / QT, NB), 256, 0, stream>>>(logits, cct);
  cost_topk_kernel<<<dim3(NG, NB), 128, 0, stream>>>(boxes, prepN, prepF, gp, cct, cost, mbits, mbitsT, rcnt, ccov);
  loop_kernel<<<NB, 1024, 0, stream>>>(cost, costM, mbits, mbitsT, rcnt, ccov, pen);
  matched_kernel<<<dim3(NG/4, NB), 256, 0, stream>>>(cost, mbits, pen, out_mq);
  out_kernel<<<dim3(NQ / 8, NB), 256, 0, stream>>>(mbitsT, out_m, out_sel, out_gti);
}

// Round 11
// 238.773 us; speedup vs baseline: 1.8984x; 1.0224x over previous
//
#include <hip/hip_runtime.h>
#include <float.h>
#include <stdint.h>
#include <stddef.h>

#define NB 16
#define NQ 4000
#define NG 300
#define NC 81
#define NQW 125  // NQ/32
#define NGW 10   // ceil(NG/32)
#define MAXM 768 // multi rows per image <= sum(dyn_k)/2 <= 750 (provable bound)

__device__ __forceinline__ bool lexlt(float v1, int i1, float v2, int i2) {
  return (v1 < v2) || (v1 == v2 && i1 < i2);
}

// Exact replica of p sequential f32 adds of 1e5 (numpy semantics), in O(#binade crossings).
__device__ __forceinline__ float penalized(float v, int p) {
  if (p <= 0) return v;
  if (p <= 12) {
    float x = v;
    for (int r = 0; r < p; ++r) x += 100000.0f;
    return x;
  }
  double x = (double)v;
  x = (double)(float)(x + 100000.0);
  int k = 1;
  while (k < p) {
    double B = 131072.0;
    while (B <= x) B += B;
    double room = B - x;
    int j = (int)(room * 1e-5);
    while (j > 0 && x + (double)j * 100000.0 >= B) --j;
    if (j > p - k) j = p - k;
    if (j > 0) { x += (double)j * 100000.0; k += j; }
    if (k < p) { x = (double)(float)(x + 100000.0); ++k; }
  }
  return (float)x;
}

// ---------------- K0: per-gt derived params ----------------
__global__ void gprep_kernel(const float* __restrict__ gtb, const int* __restrict__ labels,
                             const float* __restrict__ imgsz, float4* __restrict__ gp) {
#pragma clang fp contract(off)
  const int idx = blockIdx.x * 256 + threadIdx.x;
  if (idx >= NB * NG) return;
  const int b = idx / NG;
  const float gx0 = gtb[idx*4 + 0];
  const float gy0 = gtb[idx*4 + 1];
  const float gx1 = gtb[idx*4 + 2];
  const float gy1 = gtb[idx*4 + 3];
  const float s0 = imgsz[b*4+0], s1 = imgsz[b*4+1], s2 = imgsz[b*4+2], s3 = imgsz[b*4+3];
  const float areaB = (gx1 - gx0) * (gy1 - gy0);
  const float gcx = (gx0 + gx1) * 0.5f, gcy = (gy0 + gy1) * 0.5f;
  const float gw0 = gx1 - gx0, gh0 = gy1 - gy0;
  const float xg0 = gcx - 0.5f*gw0, yg0 = gcy - 0.5f*gh0;
  const float xg1 = gcx + 0.5f*gw0, yg1 = gcy + 0.5f*gh0;
  const float cw = xg1 - xg0, ch = yg1 - yg0;
  gp[idx*5+0] = make_float4(xg0, yg0, xg1, yg1);
  gp[idx*5+1] = make_float4(gcx - 2.5f*cw, gcx + 2.5f*cw, gcy - 2.5f*ch, gcy + 2.5f*ch);
  gp[idx*5+2] = make_float4(gx0 / s0, gy0 / s1, gx1 / s2, gy1 / s3);
  gp[idx*5+3] = make_float4(gx0, gy0, gx1, gy1);
  gp[idx*5+4] = make_float4(areaB, __int_as_float(labels[idx]), 0.f, 0.f);
}

// ---------------- K1: prep — fg penalty via gp (early break), normalized box; zero rcnt/mbitsT ----------------
__global__ void prep_kernel(const float* __restrict__ boxes, const float4* __restrict__ gp,
                            const float* __restrict__ imgsz,
                            float4* __restrict__ prepN, float* __restrict__ prepF,
                            int* __restrict__ rcnt, unsigned* __restrict__ mbitsT) {
#pragma clang fp contract(off)
  const int b = blockIdx.y;
  const int q = blockIdx.x * 256 + threadIdx.x;
  const int tid = (blockIdx.y * gridDim.x + blockIdx.x) * 256 + threadIdx.x;
  const int nthreads = gridDim.x * gridDim.y * 256;
  for (int i = tid; i < NB * NQ * NGW; i += nthreads) mbitsT[i] = 0u;
  __shared__ float4 sA0[NG];
  __shared__ float4 sA1[NG];
  for (int i = threadIdx.x; i < NG; i += 256) {
    sA0[i] = gp[(size_t)(b*NG + i)*5 + 0];
    sA1[i] = gp[(size_t)(b*NG + i)*5 + 1];
  }
  __syncthreads();
  if (q >= NQ) return;
  const float4 pb = reinterpret_cast<const float4*>(boxes)[b * NQ + q];
  const float s0 = imgsz[b*4+0], s1 = imgsz[b*4+1], s2 = imgsz[b*4+2], s3 = imgsz[b*4+3];
  const float ax = (pb.x + pb.z) * 0.5f;
  const float ay = (pb.y + pb.w) * 0.5f;
  bool fg = false;
  for (int g = 0; g < NG; ++g) {
    const float4 A0 = sA0[g];
    const float4 A1 = sA1[g];
    const bool inb = (ax > A0.x) && (ax < A0.z) && (ay > A0.y) && (ay < A0.w);
    const bool inc = (ax > A1.x) && (ax < A1.y) && (ay > A1.z) && (ay < A1.w);
    if (inb || inc) { fg = true; break; }   // fg = any(in_box) | any(in_ctr)
  }
  const int idx = b * NQ + q;
  prepN[idx] = make_float4(pb.x / s0, pb.y / s1, pb.z / s2, pb.w / s3);
  prepF[idx] = fg ? 0.f : 10000.f;
  rcnt[idx] = 0;
}

// ---------------- K2: focal class cost table, transposed (B,C,Q), tiled ----------------
#define QT 64
__global__ void cls_kernel(const float* __restrict__ logits, float* __restrict__ cct) {
#pragma clang fp contract(off)
  const int b = blockIdx.y, q0 = blockIdx.x * QT, t = threadIdx.x;
  __shared__ float tile[QT * NC];
  const int nq = (NQ - q0 < QT) ? (NQ - q0) : QT;
  const float* __restrict__ src = logits + ((size_t)(b * NQ + q0)) * NC;
  for (int i = t; i < nq * NC; i += 256) {
    const float x = src[i];
    float p;
    if (x >= 0.f) p = 1.f / (1.f + expf(-x));
    else { const float e = expf(x); p = e / (1.f + e); }
    const float pos = 0.25f * ((1.f - p) * (1.f - p)) * (-logf(p + 1e-8f));
    const float neg = 0.75f * (p * p) * (-logf(1.f - p + 1e-8f));
    tile[i] = pos - neg;
  }
  __syncthreads();
  for (int i = t; i < NC * QT; i += 256) {
    const int c = i >> 6;
    const int ql = i & (QT - 1);
    if (ql < nq) cct[((size_t)(b * NC + c)) * NQ + q0 + ql] = tile[ql * NC + c];
  }
}

// ---------------- K3: FUSED cost + per-(b,g) top-5 (1 GT per block, 128 thr) ----------------
__device__ __forceinline__ void kv_sortnet(unsigned* k, int* i) {
#define CE(a,b) { \
    const bool pr = (k[b] < k[a]) || (k[b] == k[a] && i[b] < i[a]); \
    const unsigned tk = pr ? k[b] : k[a]; const unsigned uk = pr ? k[a] : k[b]; \
    const int ti = pr ? i[b] : i[a]; const int ui = pr ? i[a] : i[b]; \
    k[a] = tk; k[b] = uk; i[a] = ti; i[b] = ui; }
  CE(0,1)
  CE(1,2) CE(0,1)
  CE(2,3) CE(1,2) CE(0,1)
  CE(3,4) CE(2,3) CE(1,2) CE(0,1)
#undef CE
}
__device__ __forceinline__ void kv_merge(unsigned* ak, int* ai, const unsigned* bk, const int* bi) {
  unsigned ck[5]; int ci[5];
#pragma unroll
  for (int j = 0; j < 5; ++j) {
    const unsigned ka = ak[j], kb = bk[4 - j];
    const int ia = ai[j], ib = bi[4 - j];
    const bool pr = (kb < ka) || (kb == ka && ib < ia);
    ck[j] = pr ? kb : ka; ci[j] = pr ? ib : ia;
  }
  kv_sortnet(ck, ci);
#pragma unroll
  for (int j = 0; j < 5; ++j) { ak[j] = ck[j]; ai[j] = ci[j]; }
}
__device__ __forceinline__ void sort5_desc(float* c) {
#define CED(a,b) { const float hi = fmaxf(c[a], c[b]); c[b] = fminf(c[a], c[b]); c[a] = hi; }
  CED(0,1)
  CED(1,2) CED(0,1)
  CED(2,3) CED(1,2) CED(0,1)
  CED(3,4) CED(2,3) CED(1,2) CED(0,1)
#undef CED
}
__device__ __forceinline__ void merge5_iou(float* a, const float* o) {
  float c[5];
#pragma unroll
  for (int j = 0; j < 5; ++j) c[j] = fmaxf(a[j], o[4 - j]);
  sort5_desc(c);
#pragma unroll
  for (int j = 0; j < 5; ++j) a[j] = c[j];
}

__global__ __launch_bounds__(128, 4) void cost_topk_kernel(
    const float* __restrict__ boxes, const float4* __restrict__ prepN,
    const float* __restrict__ prepF, const float4* __restrict__ gp,
    const float* __restrict__ cct, float* __restrict__ cost,
    unsigned* __restrict__ mbits, unsigned* __restrict__ mbitsT,
    int* __restrict__ rcnt, int* __restrict__ ccov) {
#pragma clang fp contract(off)
  const int g = blockIdx.x, b = blockIdx.y, t = threadIdx.x;
  const int lane = t & 63, wave = t >> 6;
  const float4 A0 = gp[(size_t)(b*NG + g) * 5 + 0];
  const float4 A1 = gp[(size_t)(b*NG + g) * 5 + 1];
  const float4 A2 = gp[(size_t)(b*NG + g) * 5 + 2];
  const float4 A3 = gp[(size_t)(b*NG + g) * 5 + 3];
  const float4 A4 = gp[(size_t)(b*NG + g) * 5 + 4];
  const int lab = __float_as_int(A4.y);
  const float areaB = A4.x;
  const float* __restrict__ ccls = cct + ((size_t)(b*NC + lab)) * NQ;
  float* __restrict__ crow = cost + ((size_t)(b*NG + g)) * NQ;
  unsigned* __restrict__ mrow = mbits + (b*NG + g) * NQW;
  for (int i = t; i < NQW; i += 128) mrow[i] = 0u;

  unsigned mk[5]; int mi[5]; float sv[5];
#pragma unroll
  for (int j = 0; j < 5; ++j) { mk[j] = 0xffffffffu; mi[j] = 0x7fffffff; sv[j] = -1.f; }

  for (int q = t; q < NQ; q += 128) {
    const float4 pb = reinterpret_cast<const float4*>(boxes)[b*NQ + q];
    const float4 nb = prepN[b*NQ + q];
    const float fpen = prepF[b*NQ + q];
    const float ax = (pb.x + pb.z) * 0.5f;
    const float ay = (pb.y + pb.w) * 0.5f;
    const float areaA = (pb.z - pb.x) * (pb.w - pb.y);
    const float ltx = fmaxf(pb.x, A3.x), lty = fmaxf(pb.y, A3.y);
    const float rbx = fminf(pb.z, A3.z), rby = fminf(pb.w, A3.w);
    const float iw = fmaxf(rbx - ltx, 0.f), ih = fmaxf(rby - lty, 0.f);
    const float inter = iw * ih;
    const float uni = areaA + areaB - inter;
    const float iou = inter / uni;
    const float eltx = fminf(pb.x, A3.x), elty = fminf(pb.y, A3.y);
    const float erbx = fmaxf(pb.z, A3.z), erby = fmaxf(pb.w, A3.w);
    const float ew = fmaxf(erbx - eltx, 0.f), eh = fmaxf(erby - elty, 0.f);
    const float earea = ew * eh;
    const float giou = iou - (earea - uni) / earea;
    const float cbb = fabsf(nb.x - A2.x) + fabsf(nb.y - A2.y)
                    + fabsf(nb.z - A2.z) + fabsf(nb.w - A2.w);
    const bool inb = (ax > A0.x) && (ax < A0.z) && (ay > A0.y) && (ay < A0.w);
    const bool inc = (ax > A1.x) && (ax < A1.y) && (ay > A1.z) && (ay < A1.w);
    const bool ibc = inb && inc;
    float cval = 5.0f * cbb + 2.0f * ccls[q];
    cval = cval + 2.0f * (-giou);
    cval = cval + (ibc ? 0.f : 100.f);
    cval = cval + fpen;
    crow[q] = cval;
    const unsigned bits = __float_as_uint(cval + 0.0f);  // canonicalize -0
    unsigned key = (bits & 0x80000000u) ? ~bits : (bits | 0x80000000u);
    int qi = q;
#pragma unroll
    for (int j = 0; j < 5; ++j) {   // stable branchless bubble (ties keep existing)
      const unsigned a = mk[j];
      const bool pr = key < a;
      mk[j] = pr ? key : a;
      const int ii = mi[j];
      mi[j] = pr ? qi : ii;
      key = pr ? a : key;
      qi = pr ? ii : qi;
    }
    float x = iou;
#pragma unroll
    for (int j = 0; j < 5; ++j) {   // sv sorted descending
      const float a = sv[j];
      sv[j] = fmaxf(a, x);
      x = fminf(a, x);
    }
  }

#pragma unroll
  for (int off = 32; off >= 1; off >>= 1) {
    unsigned ok[5]; int oi[5]; float ov[5];
#pragma unroll
    for (int j = 0; j < 5; ++j) {
      ok[j] = __shfl_down(mk[j], off);
      oi[j] = __shfl_down(mi[j], off);
      ov[j] = __shfl_down(sv[j], off);
    }
    kv_merge(mk, mi, ok, oi);
    merge5_iou(sv, ov);
  }

  __shared__ unsigned Lk[2][5];
  __shared__ int Li[2][5];
  __shared__ float Ls[2][5];
  if (lane == 0) {
#pragma unroll
    for (int j = 0; j < 5; ++j) { Lk[wave][j] = mk[j]; Li[wave][j] = mi[j]; Ls[wave][j] = sv[j]; }
  }
  __syncthreads();
  if (t == 0) {
    unsigned fk[5]; int fi[5]; float fs[5];
    unsigned o2[5]; int i2[5]; float s2[5];
#pragma unroll
    for (int j = 0; j < 5; ++j) {
      fk[j] = Lk[0][j]; fi[j] = Li[0][j]; fs[j] = Ls[0][j];
      o2[j] = Lk[1][j]; i2[j] = Li[1][j]; s2[j] = Ls[1][j];
    }
    kv_merge(fk, fi, o2, i2);
    merge5_iou(fs, s2);
    float s = fs[0]; s += fs[1]; s += fs[2]; s += fs[3]; s += fs[4];  // descending order sum
    int k = (int)s; if (k < 1) k = 1; if (k > 5) k = 5;
    for (int j = 0; j < k; ++j) {
      const int q = fi[j];
      mrow[q >> 5] |= 1u << (q & 31);
      atomicOr(&mbitsT[((size_t)(b*NQ + q)) * NGW + (g >> 5)], 1u << (g & 31));
      atomicAdd(&rcnt[b * NQ + q], 1);
    }
    ccov[b * NG + g] = k;
  }
}

// ---------------- K7: fused compact+gather+multifix + while-loop, one block per image ----------------
// costM holds the multi rows' cost slices and is incremented by 1e5 every loop iteration —
// an EXACT replica of the reference's sequential f32 "c += 1e5" for always-assigned rows.
__global__ __launch_bounds__(1024) void loop_kernel(
    const float* __restrict__ cost, float* __restrict__ costM,
    unsigned* __restrict__ mbits, unsigned* __restrict__ mbitsT,
    const int* __restrict__ rcnt_g, const int* __restrict__ ccov_g,
    int* __restrict__ pen_g) {
  const int b = blockIdx.x, t = threadIdx.x;
  __shared__ int s_pen[NQ];
  __shared__ int s_rcnt[NQ];
  __shared__ short s_qmi[NQ];
  __shared__ int s_ccov[NG];
  __shared__ int s_unc[NG];
  __shared__ int s_pickq[NG];
  __shared__ int s_mq[MAXM];
  __shared__ unsigned s_mrow[MAXM][NGW];
  __shared__ int s_mn, s_n, s_fix, s_sticky;

  const int lane = t & 63, wave = t >> 6;
  unsigned* __restrict__ mb = mbits + b * NG * NQW;
  unsigned* __restrict__ mbT = mbitsT + (size_t)b * NQ * NGW;
  const float* __restrict__ cb = cost + (size_t)b * NG * NQ;
  float* __restrict__ cm = costM + (size_t)b * MAXM * NG;

  if (t == 0) { s_mn = 0; s_sticky = 0; }
  for (int q = t; q < NQ; q += 1024) {
    s_pen[q] = 0;
    s_rcnt[q] = rcnt_g[b * NQ + q];
    s_qmi[q] = -1;
  }
  for (int g = t; g < NG; g += 1024) s_ccov[g] = ccov_g[b * NG + g];
  __syncthreads();
  for (int q = t; q < NQ; q += 1024)
    if (s_rcnt[q] > 1) { const int i = atomicAdd(&s_mn, 1); if (i < MAXM) s_mq[i] = q; }
  __syncthreads();
  int m_n = s_mn; if (m_n > MAXM) m_n = MAXM;
  for (int i = t; i < m_n; i += 1024) s_qmi[s_mq[i]] = (short)i;
  for (int i = t; i < m_n * NG; i += 1024) {
    const int mi = i / NG, g = i - mi * NG;
    cm[i] = cb[(size_t)g * NQ + s_mq[mi]];
  }
  for (int i = t; i < m_n * NGW; i += 1024) {
    const int mi = i / NGW, w2 = i - mi * NGW;
    s_mrow[mi][w2] = mbT[(size_t)s_mq[mi] * NGW + w2];
  }
  __syncthreads();
  // multifix: one wave per multi row -> one-hot argmin_g (raw cost)
  for (int mi = wave; mi < m_n; mi += 16) {
    const int q = s_mq[mi];
    const float* __restrict__ row = cm + (size_t)mi * NG;
    float best = FLT_MAX; int bg = 0;
    for (int g = lane; g < NG; g += 64) {
      const float v = row[g];
      if (v < best) { best = v; bg = g; }
    }
    for (int off = 32; off; off >>= 1) {
      const float ov = __shfl_down(best, off);
      const int og = __shfl_down(bg, off);
      if (ov < best || (ov == best && og < bg)) { best = ov; bg = og; }
    }
    bg = __shfl(bg, 0);
    const unsigned qbit = 1u << (q & 31);
    const int qw = q >> 5;
    if (lane < NGW) {
      const unsigned wv = s_mrow[mi][lane];
      const unsigned want = ((bg >> 5) == lane) ? (1u << (bg & 31)) : 0u;
      unsigned clr = wv & ~want;
      while (clr) {
        const int gb = __ffs(clr) - 1; clr &= clr - 1;
        const int g = lane*32 + gb;
        atomicAnd(&mb[g * NQW + qw], ~qbit);
        atomicSub(&s_ccov[g], 1);
      }
      if (want & ~wv) {
        atomicOr(&mb[bg * NQW + qw], qbit);
        atomicAdd(&s_ccov[bg], 1);
      }
      s_mrow[mi][lane] = want;
    }
    if (lane == 0) s_rcnt[q] = 1;
  }
  __syncthreads();

  for (int iter = 0; iter < 100; ++iter) {
    if (t == 0) { s_n = 0; s_fix = s_sticky; }
    __syncthreads();
    for (int g = t; g < NG; g += 1024)
      if (s_ccov[g] == 0) { const int i = atomicAdd(&s_n, 1); s_unc[i] = g; }
    __syncthreads();
    const int n = s_n;
    if (n == 0) break;
    for (int q = t; q < NQ; q += 1024)
      if (s_rcnt[q] > 0) s_pen[q]++;
    // incremental penalty: multi rows are assigned every iteration from multifix onward,
    // so cm += 1e5 each iteration == reference's sequential f32 adds, EXACT.
    for (int i = t; i < m_n * NG; i += 1024) cm[i] += 100000.0f;
    __syncthreads();
    // argmin_q per uncovered column — pen==0 rows at raw cost (penalized >= 99989 > max raw);
    // branchless: penalized rows pushed to 1e30
    for (int ci = wave; ci < n; ci += 16) {
      const int g = s_unc[ci];
      const float* __restrict__ crow = cb + (size_t)g * NQ;
      float best = FLT_MAX; int bq = 0x7fffffff;
      for (int q = lane; q < NQ; q += 64) {
        const float v = crow[q] + (s_pen[q] ? 1e30f : 0.0f);
        const bool pr = v < best;
        best = pr ? v : best;
        bq = pr ? q : bq;
      }
      for (int off = 32; off; off >>= 1) {
        const float ov = __shfl_down(best, off);
        const int oq = __shfl_down(bq, off);
        if (ov < best || (ov == best && oq < bq)) { best = ov; bq = oq; }
      }
      if (lane == 0) s_pickq[ci] = bq;
    }
    __syncthreads();
    if (t < n) {
      const int g = s_unc[t], q = s_pickq[t];
      atomicOr(&mb[g * NQW + (q >> 5)], 1u << (q & 31));
      const int mi2 = s_qmi[q];
      if (mi2 >= 0) atomicOr(&s_mrow[mi2][g >> 5], 1u << (g & 31));
      else atomicOr(&mbT[(size_t)q * NGW + (g >> 5)], 1u << (g & 31));
      const int nc = atomicAdd(&s_rcnt[q], 1) + 1;
      s_ccov[g] = 1;
      if (nc > 1) { s_fix = 1; if (s_qmi[q] < 0) s_sticky = 1; }
    }
    __syncthreads();
    if (s_fix) {
      for (int mi = wave; mi < m_n; mi += 16) {
        const int q = s_mq[mi];
        const float* __restrict__ row = cm + (size_t)mi * NG;
        float best = FLT_MAX; int bg = 0;
        for (int g = lane; g < NG; g += 64) {
          const float v = row[g];  // already penalized (incremental, exact)
          if (v < best) { best = v; bg = g; }
        }
        for (int off = 32; off; off >>= 1) {
          const float ov = __shfl_down(best, off);
          const int og = __shfl_down(bg, off);
          if (ov < best || (ov == best && og < bg)) { best = ov; bg = og; }
        }
        bg = __shfl(bg, 0);
        const unsigned qbit = 1u << (q & 31);
        const int qw = q >> 5;
        if (lane < NGW) {
          const unsigned wv = s_mrow[mi][lane];
          const unsigned want = ((bg >> 5) == lane) ? (1u << (bg & 31)) : 0u;
          unsigned clr = wv & ~want;
          while (clr) {
            const int gb = __ffs(clr) - 1; clr &= clr - 1;
            const int g = lane * 32 + gb;
            atomicAnd(&mb[g * NQW + qw], ~qbit);
            atomicSub(&s_ccov[g], 1);
          }
          if (want & ~wv) {
            atomicOr(&mb[bg * NQW + qw], qbit);
            atomicAdd(&s_ccov[bg], 1);
          }
          s_mrow[mi][lane] = want;
        }
        if (lane == 0) s_rcnt[q] = 1;
      }
    }
    __syncthreads();
  }
  __syncthreads();
  for (int i = t; i < m_n * NGW; i += 1024) {
    const int mi = i / NGW, w2 = i - mi * NGW;
    mbT[(size_t)s_mq[mi] * NGW + w2] = s_mrow[mi][w2];
  }
  for (int q = t; q < NQ; q += 1024) pen_g[b * NQ + q] = s_pen[q];
}

// ---------------- K8: matched_qidx — bit-sparse, one wave per (b,g) ----------------
__global__ __launch_bounds__(256) void matched_kernel(
    const float* __restrict__ cost, const unsigned* __restrict__ mbits,
    const int* __restrict__ pen_g, float* __restrict__ out_mq) {
  const int b = blockIdx.y, t = threadIdx.x;
  const int g = blockIdx.x * 4 + (t >> 6);
  const int lane = t & 63;
  const float* __restrict__ crow = cost + ((size_t)(b*NG + g)) * NQ;
  const unsigned* __restrict__ mrow = mbits + (b*NG + g) * NQW;
  const int* __restrict__ pb = pen_g + b * NQ;
  float best = FLT_MAX; int bq = 0;
  for (int w = lane; w < NQW; w += 64) {
    unsigned word = mrow[w];
    while (word) {
      const int bit = __ffs(word) - 1; word &= word - 1;
      const int q = w * 32 + bit;
      const float v = penalized(crow[q], pb[q]);
      if (lexlt(v, q, best, bq)) { best = v; bq = q; }
    }
  }
  for (int off = 32; off; off >>= 1) {
    const float ov = __shfl_down(best, off);
    const int oq = __shfl_down(bq, off);
    if (lexlt(ov, oq, best, bq)) { best = ov; bq = oq; }
  }
  if (lane == 0) out_mq[b * NG + g] = (float)bq;
}

// ---------------- K9: expand mbitsT rows -> m floats (float4 stores), selected, gt_idx ----------------
__global__ void out_kernel(const unsigned* __restrict__ mbitsT, float* __restrict__ out_m,
                           float* __restrict__ out_sel, float* __restrict__ out_gti) {
  const int b = blockIdx.y, t = threadIdx.x;
  const int q0 = blockIdx.x * 8;
  __shared__ unsigned wds[8 * NGW];
  if (t < 8 * NGW) wds[t] = mbitsT[((size_t)(b*NQ + q0)) * NGW + t];
  __syncthreads();
  float4* __restrict__ om4 = reinterpret_cast<float4*>(out_m + ((size_t)(b*NQ + q0)) * NG);
  for (int j = t; j < 8 * (NG/4); j += 256) {
    const int qi = j / (NG/4);
    const int g0 = (j - qi * (NG/4)) * 4;
    const unsigned* wr = &wds[qi * NGW];
    float4 v;
    v.x = ((wr[(g0+0) >> 5] >> ((g0+0) & 31)) & 1u) ? 1.f : 0.f;
    v.y = ((wr[(g0+1) >> 5] >> ((g0+1) & 31)) & 1u) ? 1.f : 0.f;
    v.z = ((wr[(g0+2) >> 5] >> ((g0+2) & 31)) & 1u) ? 1.f : 0.f;
    v.w = ((wr[(g0+3) >> 5] >> ((g0+3) & 31)) & 1u) ? 1.f : 0.f;
    om4[j] = v;
  }
  if (t < 8) {
    int fgi = -1;
    for (int w = 0; w < NGW; ++w) {
      const unsigned v = wds[t*NGW + w];
      if (v) { fgi = w*32 + __ffs(v) - 1; break; }
    }
    out_sel[b*NQ + q0 + t] = (fgi >= 0) ? 1.f : 0.f;
    out_gti[b*NQ + q0 + t] = (fgi >= 0) ? (float)fgi : 0.f;
  }
}

extern "C" void kernel_launch(void* const* d_in, const int* in_sizes, int n_in,
                              void* d_out, int out_size, void* d_ws, size_t ws_size,
                              hipStream_t stream) {
  const float* logits = (const float*)d_in[0];
  const float* boxes  = (const float*)d_in[1];
  const int*   labels = (const int*)d_in[2];
  const float* gtb    = (const float*)d_in[3];
  const float* imgsz  = (const float*)d_in[4];

  float* out = (float*)d_out;
  float* out_m   = out;                                   // B*Q*G
  float* out_sel = out + (size_t)NB * NQ * NG;            // B*Q
  float* out_gti = out_sel + (size_t)NB * NQ;             // B*Q
  float* out_mq  = out_gti + (size_t)NB * NQ;             // B*G

  char* w = (char*)d_ws;
  const size_t szPrep = sizeof(float4) * (size_t)NB * NQ;
  const size_t szF    = sizeof(float) * (size_t)NB * NQ;
  const size_t szGp   = sizeof(float4) * (size_t)NB * NG * 5;
  const size_t szCct  = sizeof(float) * (size_t)NB * NC * NQ;
  const size_t szBits = sizeof(unsigned) * (size_t)NB * NG * NQW;
  const size_t szBitsT= sizeof(unsigned) * (size_t)NB * NQ * NGW;
  const size_t szIntQ = sizeof(int) * (size_t)NB * NQ;
  const size_t szIntG = sizeof(int) * (size_t)NB * NG;
  const size_t szCM   = sizeof(float) * (size_t)NB * MAXM * NG;
  const size_t need = szPrep + szF + szGp + szCct + szBits + szBitsT + 2*szIntQ + szIntG + szCM;
  if (ws_size < need) return;

  float4* prepN = (float4*)w; w += szPrep;
  float*  prepF = (float*)w;  w += szF;
  float4* gp    = (float4*)w; w += szGp;
  float*    cct   = (float*)w;    w += szCct;
  unsigned* mbits = (unsigned*)w; w += szBits;
  unsigned* mbitsT= (unsigned*)w; w += szBitsT;
  int* rcnt  = (int*)w; w += szIntQ;
  int* pen   = (int*)w; w += szIntQ;
  int* ccov  = (int*)w; w += szIntG;
  float* costM = (float*)w; w += szCM;

  float* cost = out_m;  // (B,G,Q) in the d_out m-region; overwritten by out_kernel at the end

  gprep_kernel<<<(NB * NG + 255) / 256, 256, 0, stream>>>(gtb, labels, imgsz, gp);
  prep_kernel<<<dim3((NQ + 255) / 256, NB), 256, 0, stream>>>(boxes, gp, imgsz, prepN, prepF, rcnt, mbitsT);
  cls_kernel<<<dim3((NQ + QT - 1) / QT, NB), 256, 0, stream>>>(logits, cct);
  cost_topk_kernel<<<dim3(NG, NB), 128, 0, stream>>>(boxes, prepN, prepF, gp, cct, cost, mbits, mbitsT, rcnt, ccov);
  loop_kernel<<<NB, 1024, 0, stream>>>(cost, costM, mbits, mbitsT, rcnt, ccov, pen);
  matched_kernel<<<dim3(NG/4, NB), 256, 0, stream>>>(cost, mbits, pen, out_mq);
  out_kernel<<<dim3(NQ / 8, NB), 256, 0, stream>>>(mbitsT, out_m, out_sel, out_gti);
}

// Round 12
// 238.321 us; speedup vs baseline: 1.9020x; 1.0019x over previous
//
#include <hip/hip_runtime.h>
#include <float.h>
#include <stdint.h>
#include <stddef.h>

#define NB 16
#define NQ 4000
#define NG 300
#define NC 81
#define NQW 125  // NQ/32
#define NGW 10   // ceil(NG/32)
#define MAXM 768 // multi rows per image <= sum(dyn_k)/2 <= 750 (provable bound)

__device__ __forceinline__ bool lexlt(float v1, int i1, float v2, int i2) {
  return (v1 < v2) || (v1 == v2 && i1 < i2);
}

// Exact replica of p sequential f32 adds of 1e5 (numpy semantics), in O(#binade crossings).
__device__ __forceinline__ float penalized(float v, int p) {
  if (p <= 0) return v;
  if (p <= 12) {
    float x = v;
    for (int r = 0; r < p; ++r) x += 100000.0f;
    return x;
  }
  double x = (double)v;
  x = (double)(float)(x + 100000.0);
  int k = 1;
  while (k < p) {
    double B = 131072.0;
    while (B <= x) B += B;
    double room = B - x;
    int j = (int)(room * 1e-5);
    while (j > 0 && x + (double)j * 100000.0 >= B) --j;
    if (j > p - k) j = p - k;
    if (j > 0) { x += (double)j * 100000.0; k += j; }
    if (k < p) { x = (double)(float)(x + 100000.0); ++k; }
  }
  return (float)x;
}

// ---------------- K0: per-gt derived params ----------------
__global__ void gprep_kernel(const float* __restrict__ gtb, const int* __restrict__ labels,
                             const float* __restrict__ imgsz, float4* __restrict__ gp) {
#pragma clang fp contract(off)
  const int idx = blockIdx.x * 256 + threadIdx.x;
  if (idx >= NB * NG) return;
  const int b = idx / NG;
  const float gx0 = gtb[idx*4 + 0];
  const float gy0 = gtb[idx*4 + 1];
  const float gx1 = gtb[idx*4 + 2];
  const float gy1 = gtb[idx*4 + 3];
  const float s0 = imgsz[b*4+0], s1 = imgsz[b*4+1], s2 = imgsz[b*4+2], s3 = imgsz[b*4+3];
  const float areaB = (gx1 - gx0) * (gy1 - gy0);
  const float gcx = (gx0 + gx1) * 0.5f, gcy = (gy0 + gy1) * 0.5f;
  const float gw0 = gx1 - gx0, gh0 = gy1 - gy0;
  const float xg0 = gcx - 0.5f*gw0, yg0 = gcy - 0.5f*gh0;
  const float xg1 = gcx + 0.5f*gw0, yg1 = gcy + 0.5f*gh0;
  const float cw = xg1 - xg0, ch = yg1 - yg0;
  gp[idx*5+0] = make_float4(xg0, yg0, xg1, yg1);
  gp[idx*5+1] = make_float4(gcx - 2.5f*cw, gcx + 2.5f*cw, gcy - 2.5f*ch, gcy + 2.5f*ch);
  gp[idx*5+2] = make_float4(gx0 / s0, gy0 / s1, gx1 / s2, gy1 / s3);
  gp[idx*5+3] = make_float4(gx0, gy0, gx1, gy1);
  gp[idx*5+4] = make_float4(areaB, __int_as_float(labels[idx]), 0.f, 0.f);
}

// ---------------- K1: prep — fg penalty via gp (early break), normalized box; zero rcnt/mbitsT ----------------
__global__ void prep_kernel(const float* __restrict__ boxes, const float4* __restrict__ gp,
                            const float* __restrict__ imgsz,
                            float4* __restrict__ prepN, float* __restrict__ prepF,
                            int* __restrict__ rcnt, unsigned* __restrict__ mbitsT) {
#pragma clang fp contract(off)
  const int b = blockIdx.y;
  const int q = blockIdx.x * 256 + threadIdx.x;
  const int tid = (blockIdx.y * gridDim.x + blockIdx.x) * 256 + threadIdx.x;
  const int nthreads = gridDim.x * gridDim.y * 256;
  for (int i = tid; i < NB * NQ * NGW; i += nthreads) mbitsT[i] = 0u;
  __shared__ float4 sA0[NG];
  __shared__ float4 sA1[NG];
  for (int i = threadIdx.x; i < NG; i += 256) {
    sA0[i] = gp[(size_t)(b*NG + i)*5 + 0];
    sA1[i] = gp[(size_t)(b*NG + i)*5 + 1];
  }
  __syncthreads();
  if (q >= NQ) return;
  const float4 pb = reinterpret_cast<const float4*>(boxes)[b * NQ + q];
  const float s0 = imgsz[b*4+0], s1 = imgsz[b*4+1], s2 = imgsz[b*4+2], s3 = imgsz[b*4+3];
  const float ax = (pb.x + pb.z) * 0.5f;
  const float ay = (pb.y + pb.w) * 0.5f;
  bool fg = false;
  for (int g = 0; g < NG; ++g) {
    const float4 A0 = sA0[g];
    const float4 A1 = sA1[g];
    const bool inb = (ax > A0.x) && (ax < A0.z) && (ay > A0.y) && (ay < A0.w);
    const bool inc = (ax > A1.x) && (ax < A1.y) && (ay > A1.z) && (ay < A1.w);
    if (inb || inc) { fg = true; break; }   // fg = any(in_box) | any(in_ctr)
  }
  const int idx = b * NQ + q;
  prepN[idx] = make_float4(pb.x / s0, pb.y / s1, pb.z / s2, pb.w / s3);
  prepF[idx] = fg ? 0.f : 10000.f;
  rcnt[idx] = 0;
}

// ---------------- K2: focal class cost table, transposed (B,C,Q), tiled ----------------
#define QT 64
__global__ void cls_kernel(const float* __restrict__ logits, float* __restrict__ cct) {
#pragma clang fp contract(off)
  const int b = blockIdx.y, q0 = blockIdx.x * QT, t = threadIdx.x;
  __shared__ float tile[QT * NC];
  const int nq = (NQ - q0 < QT) ? (NQ - q0) : QT;
  const float* __restrict__ src = logits + ((size_t)(b * NQ + q0)) * NC;
  for (int i = t; i < nq * NC; i += 256) {
    const float x = src[i];
    float p;
    if (x >= 0.f) p = 1.f / (1.f + expf(-x));
    else { const float e = expf(x); p = e / (1.f + e); }
    const float pos = 0.25f * ((1.f - p) * (1.f - p)) * (-logf(p + 1e-8f));
    const float neg = 0.75f * (p * p) * (-logf(1.f - p + 1e-8f));
    tile[i] = pos - neg;
  }
  __syncthreads();
  for (int i = t; i < NC * QT; i += 256) {
    const int c = i >> 6;
    const int ql = i & (QT - 1);
    if (ql < nq) cct[((size_t)(b * NC + c)) * NQ + q0 + ql] = tile[ql * NC + c];
  }
}

// ---------------- K3: FUSED cost + per-(b,g) top-5 (1 GT per block, 128 thr) ----------------
__device__ __forceinline__ void kv_sortnet(unsigned* k, int* i) {
#define CE(a,b) { \
    const bool pr = (k[b] < k[a]) || (k[b] == k[a] && i[b] < i[a]); \
    const unsigned tk = pr ? k[b] : k[a]; const unsigned uk = pr ? k[a] : k[b]; \
    const int ti = pr ? i[b] : i[a]; const int ui = pr ? i[a] : i[b]; \
    k[a] = tk; k[b] = uk; i[a] = ti; i[b] = ui; }
  CE(0,1)
  CE(1,2) CE(0,1)
  CE(2,3) CE(1,2) CE(0,1)
  CE(3,4) CE(2,3) CE(1,2) CE(0,1)
#undef CE
}
__device__ __forceinline__ void kv_merge(unsigned* ak, int* ai, const unsigned* bk, const int* bi) {
  unsigned ck[5]; int ci[5];
#pragma unroll
  for (int j = 0; j < 5; ++j) {
    const unsigned ka = ak[j], kb = bk[4 - j];
    const int ia = ai[j], ib = bi[4 - j];
    const bool pr = (kb < ka) || (kb == ka && ib < ia);
    ck[j] = pr ? kb : ka; ci[j] = pr ? ib : ia;
  }
  kv_sortnet(ck, ci);
#pragma unroll
  for (int j = 0; j < 5; ++j) { ak[j] = ck[j]; ai[j] = ci[j]; }
}
__device__ __forceinline__ void sort5_desc(float* c) {
#define CED(a,b) { const float hi = fmaxf(c[a], c[b]); c[b] = fminf(c[a], c[b]); c[a] = hi; }
  CED(0,1)
  CED(1,2) CED(0,1)
  CED(2,3) CED(1,2) CED(0,1)
  CED(3,4) CED(2,3) CED(1,2) CED(0,1)
#undef CED
}
__device__ __forceinline__ void merge5_iou(float* a, const float* o) {
  float c[5];
#pragma unroll
  for (int j = 0; j < 5; ++j) c[j] = fmaxf(a[j], o[4 - j]);
  sort5_desc(c);
#pragma unroll
  for (int j = 0; j < 5; ++j) a[j] = c[j];
}

__global__ __launch_bounds__(128, 4) void cost_topk_kernel(
    const float* __restrict__ boxes, const float4* __restrict__ prepN,
    const float* __restrict__ prepF, const float4* __restrict__ gp,
    const float* __restrict__ cct, float* __restrict__ cost,
    unsigned* __restrict__ mbits, unsigned* __restrict__ mbitsT,
    int* __restrict__ rcnt, int* __restrict__ ccov) {
#pragma clang fp contract(off)
  const int g = blockIdx.x, b = blockIdx.y, t = threadIdx.x;
  const int lane = t & 63, wave = t >> 6;
  const float4 A0 = gp[(size_t)(b*NG + g) * 5 + 0];
  const float4 A1 = gp[(size_t)(b*NG + g) * 5 + 1];
  const float4 A2 = gp[(size_t)(b*NG + g) * 5 + 2];
  const float4 A3 = gp[(size_t)(b*NG + g) * 5 + 3];
  const float4 A4 = gp[(size_t)(b*NG + g) * 5 + 4];
  const int lab = __float_as_int(A4.y);
  const float areaB = A4.x;
  const float* __restrict__ ccls = cct + ((size_t)(b*NC + lab)) * NQ;
  float* __restrict__ crow = cost + ((size_t)(b*NG + g)) * NQ;
  unsigned* __restrict__ mrow = mbits + (b*NG + g) * NQW;
  for (int i = t; i < NQW; i += 128) mrow[i] = 0u;

  unsigned mk[5]; int mi[5]; float sv[5];
#pragma unroll
  for (int j = 0; j < 5; ++j) { mk[j] = 0xffffffffu; mi[j] = 0x7fffffff; sv[j] = -1.f; }

  for (int q = t; q < NQ; q += 128) {
    const float4 pb = reinterpret_cast<const float4*>(boxes)[b*NQ + q];
    const float4 nb = prepN[b*NQ + q];
    const float fpen = prepF[b*NQ + q];
    const float ax = (pb.x + pb.z) * 0.5f;
    const float ay = (pb.y + pb.w) * 0.5f;
    const float areaA = (pb.z - pb.x) * (pb.w - pb.y);
    const float ltx = fmaxf(pb.x, A3.x), lty = fmaxf(pb.y, A3.y);
    const float rbx = fminf(pb.z, A3.z), rby = fminf(pb.w, A3.w);
    const float iw = fmaxf(rbx - ltx, 0.f), ih = fmaxf(rby - lty, 0.f);
    const float inter = iw * ih;
    const float uni = areaA + areaB - inter;
    const float iou = inter / uni;
    const float eltx = fminf(pb.x, A3.x), elty = fminf(pb.y, A3.y);
    const float erbx = fmaxf(pb.z, A3.z), erby = fmaxf(pb.w, A3.w);
    const float ew = fmaxf(erbx - eltx, 0.f), eh = fmaxf(erby - elty, 0.f);
    const float earea = ew * eh;
    const float giou = iou - (earea - uni) / earea;
    const float cbb = fabsf(nb.x - A2.x) + fabsf(nb.y - A2.y)
                    + fabsf(nb.z - A2.z) + fabsf(nb.w - A2.w);
    const bool inb = (ax > A0.x) && (ax < A0.z) && (ay > A0.y) && (ay < A0.w);
    const bool inc = (ax > A1.x) && (ax < A1.y) && (ay > A1.z) && (ay < A1.w);
    const bool ibc = inb && inc;
    float cval = 5.0f * cbb + 2.0f * ccls[q];
    cval = cval + 2.0f * (-giou);
    cval = cval + (ibc ? 0.f : 100.f);
    cval = cval + fpen;
    crow[q] = cval;
    const unsigned bits = __float_as_uint(cval + 0.0f);  // canonicalize -0
    unsigned key = (bits & 0x80000000u) ? ~bits : (bits | 0x80000000u);
    int qi = q;
#pragma unroll
    for (int j = 0; j < 5; ++j) {   // stable branchless bubble (ties keep existing)
      const unsigned a = mk[j];
      const bool pr = key < a;
      mk[j] = pr ? key : a;
      const int ii = mi[j];
      mi[j] = pr ? qi : ii;
      key = pr ? a : key;
      qi = pr ? ii : qi;
    }
    float x = iou;
#pragma unroll
    for (int j = 0; j < 5; ++j) {   // sv sorted descending
      const float a = sv[j];
      sv[j] = fmaxf(a, x);
      x = fminf(a, x);
    }
  }

#pragma unroll
  for (int off = 32; off >= 1; off >>= 1) {
    unsigned ok[5]; int oi[5]; float ov[5];
#pragma unroll
    for (int j = 0; j < 5; ++j) {
      ok[j] = __shfl_down(mk[j], off);
      oi[j] = __shfl_down(mi[j], off);
      ov[j] = __shfl_down(sv[j], off);
    }
    kv_merge(mk, mi, ok, oi);
    merge5_iou(sv, ov);
  }

  __shared__ unsigned Lk[2][5];
  __shared__ int Li[2][5];
  __shared__ float Ls[2][5];
  if (lane == 0) {
#pragma unroll
    for (int j = 0; j < 5; ++j) { Lk[wave][j] = mk[j]; Li[wave][j] = mi[j]; Ls[wave][j] = sv[j]; }
  }
  __syncthreads();
  if (t == 0) {
    unsigned fk[5]; int fi[5]; float fs[5];
    unsigned o2[5]; int i2[5]; float s2[5];
#pragma unroll
    for (int j = 0; j < 5; ++j) {
      fk[j] = Lk[0][j]; fi[j] = Li[0][j]; fs[j] = Ls[0][j];
      o2[j] = Lk[1][j]; i2[j] = Li[1][j]; s2[j] = Ls[1][j];
    }
    kv_merge(fk, fi, o2, i2);
    merge5_iou(fs, s2);
    float s = fs[0]; s += fs[1]; s += fs[2]; s += fs[3]; s += fs[4];  // descending order sum
    int k = (int)s; if (k < 1) k = 1; if (k > 5) k = 5;
    for (int j = 0; j < k; ++j) {
      const int q = fi[j];
      mrow[q >> 5] |= 1u << (q & 31);
      atomicOr(&mbitsT[((size_t)(b*NQ + q)) * NGW + (g >> 5)], 1u << (g & 31));
      atomicAdd(&rcnt[b * NQ + q], 1);
    }
    ccov[b * NG + g] = k;
  }
}

// ---------------- K7: fused compact+gather+multifix + while-loop, one block per image ----------------
// costM holds the multi rows' cost slices; exactly one +1e5 is applied per loop iteration
// (fused into the fix pass when fix runs, flat pass otherwise) — an EXACT replica of the
// reference's sequential f32 "c += 1e5" for always-assigned rows (fix reads post-add values,
// matching the reference's order: c update precedes the fix argmin).
__global__ __launch_bounds__(1024) void loop_kernel(
    const float* __restrict__ cost, float* __restrict__ costM,
    unsigned* __restrict__ mbits, unsigned* __restrict__ mbitsT,
    const int* __restrict__ rcnt_g, const int* __restrict__ ccov_g,
    int* __restrict__ pen_g) {
  const int b = blockIdx.x, t = threadIdx.x;
  __shared__ int s_pen[NQ];
  __shared__ int s_rcnt[NQ];
  __shared__ short s_qmi[NQ];
  __shared__ int s_ccov[NG];
  __shared__ int s_unc[NG];
  __shared__ int s_pickq[NG];
  __shared__ int s_mq[MAXM];
  __shared__ unsigned s_mrow[MAXM][NGW];
  __shared__ float s_pwv[16];
  __shared__ int s_pwq[16];
  __shared__ int s_mn, s_n, s_fix, s_sticky;

  const int lane = t & 63, wave = t >> 6;
  unsigned* __restrict__ mb = mbits + b * NG * NQW;
  unsigned* __restrict__ mbT = mbitsT + (size_t)b * NQ * NGW;
  const float* __restrict__ cb = cost + (size_t)b * NG * NQ;
  float* __restrict__ cm = costM + (size_t)b * MAXM * NG;

  if (t == 0) { s_mn = 0; s_sticky = 0; }
  for (int q = t; q < NQ; q += 1024) {
    s_pen[q] = 0;
    s_rcnt[q] = rcnt_g[b * NQ + q];
    s_qmi[q] = -1;
  }
  for (int g = t; g < NG; g += 1024) s_ccov[g] = ccov_g[b * NG + g];
  __syncthreads();
  for (int q = t; q < NQ; q += 1024)
    if (s_rcnt[q] > 1) { const int i = atomicAdd(&s_mn, 1); if (i < MAXM) s_mq[i] = q; }
  __syncthreads();
  int m_n = s_mn; if (m_n > MAXM) m_n = MAXM;
  for (int i = t; i < m_n; i += 1024) s_qmi[s_mq[i]] = (short)i;
  for (int i = t; i < m_n * NG; i += 1024) {
    const int mi = i / NG, g = i - mi * NG;
    cm[i] = cb[(size_t)g * NQ + s_mq[mi]];
  }
  for (int i = t; i < m_n * NGW; i += 1024) {
    const int mi = i / NGW, w2 = i - mi * NGW;
    s_mrow[mi][w2] = mbT[(size_t)s_mq[mi] * NGW + w2];
  }
  __syncthreads();
  // multifix: one wave per multi row -> one-hot argmin_g (raw cost)
  for (int mi = wave; mi < m_n; mi += 16) {
    const int q = s_mq[mi];
    const float* __restrict__ row = cm + (size_t)mi * NG;
    float best = FLT_MAX; int bg = 0;
    for (int g = lane; g < NG; g += 64) {
      const float v = row[g];
      if (v < best) { best = v; bg = g; }
    }
    for (int off = 32; off; off >>= 1) {
      const float ov = __shfl_down(best, off);
      const int og = __shfl_down(bg, off);
      if (ov < best || (ov == best && og < bg)) { best = ov; bg = og; }
    }
    bg = __shfl(bg, 0);
    const unsigned qbit = 1u << (q & 31);
    const int qw = q >> 5;
    if (lane < NGW) {
      const unsigned wv = s_mrow[mi][lane];
      const unsigned want = ((bg >> 5) == lane) ? (1u << (bg & 31)) : 0u;
      unsigned clr = wv & ~want;
      while (clr) {
        const int gb = __ffs(clr) - 1; clr &= clr - 1;
        const int g = lane*32 + gb;
        atomicAnd(&mb[g * NQW + qw], ~qbit);
        atomicSub(&s_ccov[g], 1);
      }
      if (want & ~wv) {
        atomicOr(&mb[bg * NQW + qw], qbit);
        atomicAdd(&s_ccov[bg], 1);
      }
      s_mrow[mi][lane] = want;
    }
    if (lane == 0) s_rcnt[q] = 1;
  }
  __syncthreads();

  for (int iter = 0; iter < 100; ++iter) {
    if (t == 0) { s_n = 0; s_fix = s_sticky; }
    __syncthreads();
    for (int g = t; g < NG; g += 1024)
      if (s_ccov[g] == 0) { const int i = atomicAdd(&s_n, 1); s_unc[i] = g; }
    __syncthreads();
    const int n = s_n;
    if (n == 0) break;
    for (int q = t; q < NQ; q += 1024)
      if (s_rcnt[q] > 0) s_pen[q]++;
    __syncthreads();
    // argmin_q per uncovered column — pen==0 rows at raw cost (penalized >= 99989 > max raw)
    if (n >= 16) {
      for (int ci = wave; ci < n; ci += 16) {
        const int g = s_unc[ci];
        const float* __restrict__ crow = cb + (size_t)g * NQ;
        float best = FLT_MAX; int bq = 0x7fffffff;
        for (int q = lane; q < NQ; q += 64) {
          const float v = crow[q] + (s_pen[q] ? 1e30f : 0.0f);
          const bool pr = v < best;
          best = pr ? v : best;
          bq = pr ? q : bq;
        }
        for (int off = 32; off; off >>= 1) {
          const float ov = __shfl_down(best, off);
          const int oq = __shfl_down(bq, off);
          if (ov < best || (ov == best && oq < bq)) { best = ov; bq = oq; }
        }
        if (lane == 0) s_pickq[ci] = bq;
      }
      __syncthreads();
    } else {
      // n < 16: split each column across wpc waves over disjoint q-segments
      const int wpc = 16 / n;
      const int ci = wave / wpc, seg = wave - ci * wpc;
      float best = FLT_MAX; int bq = 0x7fffffff;
      if (ci < n) {
        const int g = s_unc[ci];
        const float* __restrict__ crow = cb + (size_t)g * NQ;
        const int qlo = (NQ * seg) / wpc, qhi = (NQ * (seg + 1)) / wpc;
        for (int q = qlo + lane; q < qhi; q += 64) {
          const float v = crow[q] + (s_pen[q] ? 1e30f : 0.0f);
          const bool pr = v < best;
          best = pr ? v : best;
          bq = pr ? q : bq;
        }
        for (int off = 32; off; off >>= 1) {
          const float ov = __shfl_down(best, off);
          const int oq = __shfl_down(bq, off);
          if (ov < best || (ov == best && oq < bq)) { best = ov; bq = oq; }
        }
      }
      if (lane == 0) { s_pwv[wave] = best; s_pwq[wave] = bq; }
      __syncthreads();
      if (t < n) {
        float fb = FLT_MAX; int fq = 0x7fffffff;
        for (int s2 = 0; s2 < wpc; ++s2) {
          const float ov = s_pwv[t * wpc + s2];
          const int oq = s_pwq[t * wpc + s2];
          if (lexlt(ov, oq, fb, fq)) { fb = ov; fq = oq; }
        }
        s_pickq[t] = fq;
      }
      __syncthreads();
    }
    if (t < n) {
      const int g = s_unc[t], q = s_pickq[t];
      atomicOr(&mb[g * NQW + (q >> 5)], 1u << (q & 31));
      const int mi2 = s_qmi[q];
      if (mi2 >= 0) atomicOr(&s_mrow[mi2][g >> 5], 1u << (g & 31));
      else atomicOr(&mbT[(size_t)q * NGW + (g >> 5)], 1u << (g & 31));
      const int nc = atomicAdd(&s_rcnt[q], 1) + 1;
      s_ccov[g] = 1;
      if (nc > 1) { s_fix = 1; if (s_qmi[q] < 0) s_sticky = 1; }
    }
    __syncthreads();
    if (s_fix) {
      // fused: cm += 1e5 (this iteration's add) then argmin of the updated values — exact
      for (int mi = wave; mi < m_n; mi += 16) {
        const int q = s_mq[mi];
        float* __restrict__ row = cm + (size_t)mi * NG;
        float best = FLT_MAX; int bg = 0;
        for (int g = lane; g < NG; g += 64) {
          const float v = row[g] + 100000.0f;
          row[g] = v;
          if (v < best) { best = v; bg = g; }
        }
        for (int off = 32; off; off >>= 1) {
          const float ov = __shfl_down(best, off);
          const int og = __shfl_down(bg, off);
          if (ov < best || (ov == best && og < bg)) { best = ov; bg = og; }
        }
        bg = __shfl(bg, 0);
        const unsigned qbit = 1u << (q & 31);
        const int qw = q >> 5;
        if (lane < NGW) {
          const unsigned wv = s_mrow[mi][lane];
          const unsigned want = ((bg >> 5) == lane) ? (1u << (bg & 31)) : 0u;
          unsigned clr = wv & ~want;
          while (clr) {
            const int gb = __ffs(clr) - 1; clr &= clr - 1;
            const int g = lane * 32 + gb;
            atomicAnd(&mb[g * NQW + qw], ~qbit);
            atomicSub(&s_ccov[g], 1);
          }
          if (want & ~wv) {
            atomicOr(&mb[bg * NQW + qw], qbit);
            atomicAdd(&s_ccov[bg], 1);
          }
          s_mrow[mi][lane] = want;
        }
        if (lane == 0) s_rcnt[q] = 1;
      }
    } else {
      // no fix this iteration: flat penalty accumulation (exact sequential f32 add)
      for (int i = t; i < m_n * NG; i += 1024) cm[i] += 100000.0f;
    }
    __syncthreads();
  }
  __syncthreads();
  for (int i = t; i < m_n * NGW; i += 1024) {
    const int mi = i / NGW, w2 = i - mi * NGW;
    mbT[(size_t)s_mq[mi] * NGW + w2] = s_mrow[mi][w2];
  }
  for (int q = t; q < NQ; q += 1024) pen_g[b * NQ + q] = s_pen[q];
}

// ---------------- K8: matched_qidx — bit-sparse, one wave per (b,g) ----------------
__global__ __launch_bounds__(256) void matched_kernel(
    const float* __restrict__ cost, const unsigned* __restrict__ mbits,
    const int* __restrict__ pen_g, float* __restrict__ out_mq) {
  const int b = blockIdx.y, t = threadIdx.x;
  const int g = blockIdx.x * 4 + (t >> 6);
  const int lane = t & 63;
  const float* __restrict__ crow = cost + ((size_t)(b*NG + g)) * NQ;
  const unsigned* __restrict__ mrow = mbits + (b*NG + g) * NQW;
  const int* __restrict__ pb = pen_g + b * NQ;
  float best = FLT_MAX; int bq = 0;
  for (int w = lane; w < NQW; w += 64) {
    unsigned word = mrow[w];
    while (word) {
      const int bit = __ffs(word) - 1; word &= word - 1;
      const int q = w * 32 + bit;
      const float v = penalized(crow[q], pb[q]);
      if (lexlt(v, q, best, bq)) { best = v; bq = q; }
    }
  }
  for (int off = 32; off; off >>= 1) {
    const float ov = __shfl_down(best, off);
    const int oq = __shfl_down(bq, off);
    if (lexlt(ov, oq, best, bq)) { best = ov; bq = oq; }
  }
  if (lane == 0) out_mq[b * NG + g] = (float)bq;
}

// ---------------- K9: expand mbitsT rows -> m floats (float4 stores), selected, gt_idx ----------------
__global__ void out_kernel(const unsigned* __restrict__ mbitsT, float* __restrict__ out_m,
                           float* __restrict__ out_sel, float* __restrict__ out_gti) {
  const int b = blockIdx.y, t = threadIdx.x;
  const int q0 = blockIdx.x * 16;
  __shared__ unsigned wds[16 * NGW];
  if (t < 16 * NGW) wds[t] = mbitsT[((size_t)(b*NQ + q0)) * NGW + t];
  __syncthreads();
  float4* __restrict__ om4 = reinterpret_cast<float4*>(out_m + ((size_t)(b*NQ + q0)) * NG);
  for (int j = t; j < 16 * (NG/4); j += 256) {
    const int qi = j / (NG/4);
    const int g0 = (j - qi * (NG/4)) * 4;
    const unsigned* wr = &wds[qi * NGW];
    float4 v;
    v.x = ((wr[(g0+0) >> 5] >> ((g0+0) & 31)) & 1u) ? 1.f : 0.f;
    v.y = ((wr[(g0+1) >> 5] >> ((g0+1) & 31)) & 1u) ? 1.f : 0.f;
    v.z = ((wr[(g0+2) >> 5] >> ((g0+2) & 31)) & 1u) ? 1.f : 0.f;
    v.w = ((wr[(g0+3) >> 5] >> ((g0+3) & 31)) & 1u) ? 1.f : 0.f;
    om4[j] = v;
  }
  if (t < 16) {
    int fgi = -1;
    for (int w = 0; w < NGW; ++w) {
      const unsigned v = wds[t*NGW + w];
      if (v) { fgi = w*32 + __ffs(v) - 1; break; }
    }
    out_sel[b*NQ + q0 + t] = (fgi >= 0) ? 1.f : 0.f;
    out_gti[b*NQ + q0 + t] = (fgi >= 0) ? (float)fgi : 0.f;
  }
}

extern "C" void kernel_launch(void* const* d_in, const int* in_sizes, int n_in,
                              void* d_out, int out_size, void* d_ws, size_t ws_size,
                              hipStream_t stream) {
  const float* logits = (const float*)d_in[0];
  const float* boxes  = (const float*)d_in[1];
  const int*   labels = (const int*)d_in[2];
  const float* gtb    = (const float*)d_in[3];
  const float* imgsz  = (const float*)d_in[4];

  float* out = (float*)d_out;
  float* out_m   = out;                                   // B*Q*G
  float* out_sel = out + (size_t)NB * NQ * NG;            // B*Q
  float* out_gti = out_sel + (size_t)NB * NQ;             // B*Q
  float* out_mq  = out_gti + (size_t)NB * NQ;             // B*G

  char* w = (char*)d_ws;
  const size_t szPrep = sizeof(float4) * (size_t)NB * NQ;
  const size_t szF    = sizeof(float) * (size_t)NB * NQ;
  const size_t szGp   = sizeof(float4) * (size_t)NB * NG * 5;
  const size_t szCct  = sizeof(float) * (size_t)NB * NC * NQ;
  const size_t szBits = sizeof(unsigned) * (size_t)NB * NG * NQW;
  const size_t szBitsT= sizeof(unsigned) * (size_t)NB * NQ * NGW;
  const size_t szIntQ = sizeof(int) * (size_t)NB * NQ;
  const size_t szIntG = sizeof(int) * (size_t)NB * NG;
  const size_t szCM   = sizeof(float) * (size_t)NB * MAXM * NG;
  const size_t need = szPrep + szF + szGp + szCct + szBits + szBitsT + 2*szIntQ + szIntG + szCM;
  if (ws_size < need) return;

  float4* prepN = (float4*)w; w += szPrep;
  float*  prepF = (float*)w;  w += szF;
  float4* gp    = (float4*)w; w += szGp;
  float*    cct   = (float*)w;    w += szCct;
  unsigned* mbits = (unsigned*)w; w += szBits;
  unsigned* mbitsT= (unsigned*)w; w += szBitsT;
  int* rcnt  = (int*)w; w += szIntQ;
  int* pen   = (int*)w; w += szIntQ;
  int* ccov  = (int*)w; w += szIntG;
  float* costM = (float*)w; w += szCM;

  float* cost = out_m;  // (B,G,Q) in the d_out m-region; overwritten by out_kernel at the end

  gprep_kernel<<<(NB * NG + 255) / 256, 256, 0, stream>>>(gtb, labels, imgsz, gp);
  prep_kernel<<<dim3((NQ + 255) / 256, NB), 256, 0, stream>>>(boxes, gp, imgsz, prepN, prepF, rcnt, mbitsT);
  cls_kernel<<<dim3((NQ + QT - 1) / QT, NB), 256, 0, stream>>>(logits, cct);
  cost_topk_kernel<<<dim3(NG, NB), 128, 0, stream>>>(boxes, prepN, prepF, gp, cct, cost, mbits, mbitsT, rcnt, ccov);
  loop_kernel<<<NB, 1024, 0, stream>>>(cost, costM, mbits, mbitsT, rcnt, ccov, pen);
  matched_kernel<<<dim3(NG/4, NB), 256, 0, stream>>>(cost, mbits, pen, out_mq);
  out_kernel<<<dim3(NQ / 16, NB), 256, 0, stream>>>(mbitsT, out_m, out_sel, out_gti);
}

// Round 14
// 231.027 us; speedup vs baseline: 1.9620x; 1.0316x over previous
//
#include <hip/hip_runtime.h>
#include <float.h>
#include <stdint.h>
#include <stddef.h>

#define NB 16
#define NQ 4000
#define NG 300
#define NC 81
#define NQW 125  // NQ/32
#define NGW 10   // ceil(NG/32)
#define MAXM 768 // multi rows per image <= sum(dyn_k)/2 <= 750 (provable bound)

__device__ __forceinline__ bool lexlt(float v1, int i1, float v2, int i2) {
  return (v1 < v2) || (v1 == v2 && i1 < i2);
}

// Exact replica of p sequential f32 adds of 1e5 (numpy semantics), in O(#binade crossings).
__device__ __forceinline__ float penalized(float v, int p) {
  if (p <= 0) return v;
  if (p <= 12) {
    float x = v;
    for (int r = 0; r < p; ++r) x += 100000.0f;
    return x;
  }
  double x = (double)v;
  x = (double)(float)(x + 100000.0);
  int k = 1;
  while (k < p) {
    double B = 131072.0;
    while (B <= x) B += B;
    double room = B - x;
    int j = (int)(room * 1e-5);
    while (j > 0 && x + (double)j * 100000.0 >= B) --j;
    if (j > p - k) j = p - k;
    if (j > 0) { x += (double)j * 100000.0; k += j; }
    if (k < p) { x = (double)(float)(x + 100000.0); ++k; }
  }
  return (float)x;
}

// ---------------- K0: per-gt derived params ----------------
__global__ void gprep_kernel(const float* __restrict__ gtb, const int* __restrict__ labels,
                             const float* __restrict__ imgsz, float4* __restrict__ gp) {
#pragma clang fp contract(off)
  const int idx = blockIdx.x * 256 + threadIdx.x;
  if (idx >= NB * NG) return;
  const int b = idx / NG;
  const float gx0 = gtb[idx*4 + 0];
  const float gy0 = gtb[idx*4 + 1];
  const float gx1 = gtb[idx*4 + 2];
  const float gy1 = gtb[idx*4 + 3];
  const float s0 = imgsz[b*4+0], s1 = imgsz[b*4+1], s2 = imgsz[b*4+2], s3 = imgsz[b*4+3];
  const float areaB = (gx1 - gx0) * (gy1 - gy0);
  const float gcx = (gx0 + gx1) * 0.5f, gcy = (gy0 + gy1) * 0.5f;
  const float gw0 = gx1 - gx0, gh0 = gy1 - gy0;
  const float xg0 = gcx - 0.5f*gw0, yg0 = gcy - 0.5f*gh0;
  const float xg1 = gcx + 0.5f*gw0, yg1 = gcy + 0.5f*gh0;
  const float cw = xg1 - xg0, ch = yg1 - yg0;
  gp[idx*5+0] = make_float4(xg0, yg0, xg1, yg1);
  gp[idx*5+1] = make_float4(gcx - 2.5f*cw, gcx + 2.5f*cw, gcy - 2.5f*ch, gcy + 2.5f*ch);
  gp[idx*5+2] = make_float4(gx0 / s0, gy0 / s1, gx1 / s2, gy1 / s3);
  gp[idx*5+3] = make_float4(gx0, gy0, gx1, gy1);
  gp[idx*5+4] = make_float4(areaB, __int_as_float(labels[idx]), 0.f, 0.f);
}

// ---------------- K1: prep — fg via in_ctr only (inb => inc, provable), normalized box ----------------
__global__ void prep_kernel(const float* __restrict__ boxes, const float4* __restrict__ gp,
                            const float* __restrict__ imgsz,
                            float4* __restrict__ prepN, float* __restrict__ prepF,
                            int* __restrict__ rcnt, unsigned* __restrict__ mbitsT) {
#pragma clang fp contract(off)
  const int b = blockIdx.y;
  const int q = blockIdx.x * 256 + threadIdx.x;
  const int tid = (blockIdx.y * gridDim.x + blockIdx.x) * 256 + threadIdx.x;
  const int nthreads = gridDim.x * gridDim.y * 256;
  for (int i = tid; i < NB * NQ * NGW; i += nthreads) mbitsT[i] = 0u;
  __shared__ float4 sA1[NG];
  for (int i = threadIdx.x; i < NG; i += 256)
    sA1[i] = gp[(size_t)(b*NG + i)*5 + 1];
  __syncthreads();
  if (q >= NQ) return;
  const float4 pb = reinterpret_cast<const float4*>(boxes)[b * NQ + q];
  const float s0 = imgsz[b*4+0], s1 = imgsz[b*4+1], s2 = imgsz[b*4+2], s3 = imgsz[b*4+3];
  const float ax = (pb.x + pb.z) * 0.5f;
  const float ay = (pb.y + pb.w) * 0.5f;
  // fg = any(in_box)|any(in_ctr) == any(in_ctr): whenever a float lies strictly inside the
  // roundtripped box (xg0,xg1), cw = xg1-xg0 is Sterbenz-exact and fl(2.5*cw) >= 0.5*gw,
  // so the in_ctr interval contains the in_box interval -> inb implies inc pointwise.
  bool fg = false;
  for (int g = 0; g < NG; ++g) {
    const float4 A1 = sA1[g];
    if ((ax > A1.x) && (ax < A1.y) && (ay > A1.z) && (ay < A1.w)) { fg = true; break; }
  }
  const int idx = b * NQ + q;
  prepN[idx] = make_float4(pb.x / s0, pb.y / s1, pb.z / s2, pb.w / s3);
  prepF[idx] = fg ? 0.f : 10000.f;
  rcnt[idx] = 0;
}

// ---------------- K2: focal class cost table, transposed (B,C,Q), tiled ----------------
#define QT 64
__global__ void cls_kernel(const float* __restrict__ logits, float* __restrict__ cct) {
#pragma clang fp contract(off)
  const int b = blockIdx.y, q0 = blockIdx.x * QT, t = threadIdx.x;
  __shared__ float tile[QT * NC];
  const int nq = (NQ - q0 < QT) ? (NQ - q0) : QT;
  const float* __restrict__ src = logits + ((size_t)(b * NQ + q0)) * NC;
  for (int i = t; i < nq * NC; i += 256) {
    const float x = src[i];
    float p;
    if (x >= 0.f) p = 1.f / (1.f + expf(-x));
    else { const float e = expf(x); p = e / (1.f + e); }
    const float pos = 0.25f * ((1.f - p) * (1.f - p)) * (-logf(p + 1e-8f));
    const float neg = 0.75f * (p * p) * (-logf(1.f - p + 1e-8f));
    tile[i] = pos - neg;
  }
  __syncthreads();
  for (int i = t; i < NC * QT; i += 256) {
    const int c = i >> 6;
    const int ql = i & (QT - 1);
    if (ql < nq) cct[((size_t)(b * NC + c)) * NQ + q0 + ql] = tile[ql * NC + c];
  }
}

// ---------------- K3: FUSED cost + per-(b,g) top-5 (1 GT per block, 128 thr) ----------------
__device__ __forceinline__ void kv_sortnet(unsigned* k, int* i) {
#define CE(a,b) { \
    const bool pr = (k[b] < k[a]) || (k[b] == k[a] && i[b] < i[a]); \
    const unsigned tk = pr ? k[b] : k[a]; const unsigned uk = pr ? k[a] : k[b]; \
    const int ti = pr ? i[b] : i[a]; const int ui = pr ? i[a] : i[b]; \
    k[a] = tk; k[b] = uk; i[a] = ti; i[b] = ui; }
  CE(0,1)
  CE(1,2) CE(0,1)
  CE(2,3) CE(1,2) CE(0,1)
  CE(3,4) CE(2,3) CE(1,2) CE(0,1)
#undef CE
}
__device__ __forceinline__ void kv_merge(unsigned* ak, int* ai, const unsigned* bk, const int* bi) {
  unsigned ck[5]; int ci[5];
#pragma unroll
  for (int j = 0; j < 5; ++j) {
    const unsigned ka = ak[j], kb = bk[4 - j];
    const int ia = ai[j], ib = bi[4 - j];
    const bool pr = (kb < ka) || (kb == ka && ib < ia);
    ck[j] = pr ? kb : ka; ci[j] = pr ? ib : ia;
  }
  kv_sortnet(ck, ci);
#pragma unroll
  for (int j = 0; j < 5; ++j) { ak[j] = ck[j]; ai[j] = ci[j]; }
}
__device__ __forceinline__ void sort5_desc(float* c) {
#define CED(a,b) { const float hi = fmaxf(c[a], c[b]); c[b] = fminf(c[a], c[b]); c[a] = hi; }
  CED(0,1)
  CED(1,2) CED(0,1)
  CED(2,3) CED(1,2) CED(0,1)
  CED(3,4) CED(2,3) CED(1,2) CED(0,1)
#undef CED
}
__device__ __forceinline__ void merge5_iou(float* a, const float* o) {
  float c[5];
#pragma unroll
  for (int j = 0; j < 5; ++j) c[j] = fmaxf(a[j], o[4 - j]);
  sort5_desc(c);
#pragma unroll
  for (int j = 0; j < 5; ++j) a[j] = c[j];
}

__global__ __launch_bounds__(128, 4) void cost_topk_kernel(
    const float* __restrict__ boxes, const float4* __restrict__ prepN,
    const float* __restrict__ prepF, const float4* __restrict__ gp,
    const float* __restrict__ cct, float* __restrict__ cost,
    unsigned* __restrict__ mbits, unsigned* __restrict__ mbitsT,
    int* __restrict__ rcnt, int* __restrict__ ccov) {
#pragma clang fp contract(off)
  const int g = blockIdx.x, b = blockIdx.y, t = threadIdx.x;
  const int lane = t & 63, wave = t >> 6;
  const float4 A0 = gp[(size_t)(b*NG + g) * 5 + 0];
  const float4 A1 = gp[(size_t)(b*NG + g) * 5 + 1];
  const float4 A2 = gp[(size_t)(b*NG + g) * 5 + 2];
  const float4 A3 = gp[(size_t)(b*NG + g) * 5 + 3];
  const float4 A4 = gp[(size_t)(b*NG + g) * 5 + 4];
  const int lab = __float_as_int(A4.y);
  const float areaB = A4.x;
  const float* __restrict__ ccls = cct + ((size_t)(b*NC + lab)) * NQ;
  float* __restrict__ crow = cost + ((size_t)(b*NG + g)) * NQ;
  unsigned* __restrict__ mrow = mbits + (b*NG + g) * NQW;
  for (int i = t; i < NQW; i += 128) mrow[i] = 0u;

  unsigned mk[5]; int mi[5]; float sv[5];
#pragma unroll
  for (int j = 0; j < 5; ++j) { mk[j] = 0xffffffffu; mi[j] = 0x7fffffff; sv[j] = -1.f; }

#pragma unroll 2
  for (int q = t; q < NQ; q += 128) {
    const float4 pb = reinterpret_cast<const float4*>(boxes)[b*NQ + q];
    const float4 nb = prepN[b*NQ + q];
    const float fpen = prepF[b*NQ + q];
    const float ax = (pb.x + pb.z) * 0.5f;
    const float ay = (pb.y + pb.w) * 0.5f;
    const float areaA = (pb.z - pb.x) * (pb.w - pb.y);
    const float ltx = fmaxf(pb.x, A3.x), lty = fmaxf(pb.y, A3.y);
    const float rbx = fminf(pb.z, A3.z), rby = fminf(pb.w, A3.w);
    const float iw = fmaxf(rbx - ltx, 0.f), ih = fmaxf(rby - lty, 0.f);
    const float inter = iw * ih;
    const float uni = areaA + areaB - inter;
    const float iou = inter / uni;
    const float eltx = fminf(pb.x, A3.x), elty = fminf(pb.y, A3.y);
    const float erbx = fmaxf(pb.z, A3.z), erby = fmaxf(pb.w, A3.w);
    const float ew = fmaxf(erbx - eltx, 0.f), eh = fmaxf(erby - elty, 0.f);
    const float earea = ew * eh;
    const float giou = iou - (earea - uni) / earea;
    const float cbb = fabsf(nb.x - A2.x) + fabsf(nb.y - A2.y)
                    + fabsf(nb.z - A2.z) + fabsf(nb.w - A2.w);
    const bool inb = (ax > A0.x) && (ax < A0.z) && (ay > A0.y) && (ay < A0.w);
    const bool inc = (ax > A1.x) && (ax < A1.y) && (ay > A1.z) && (ay < A1.w);
    const bool ibc = inb && inc;
    float cval = 5.0f * cbb + 2.0f * ccls[q];
    cval = cval + 2.0f * (-giou);
    cval = cval + (ibc ? 0.f : 100.f);
    cval = cval + fpen;
    crow[q] = cval;
    const unsigned bits = __float_as_uint(cval + 0.0f);  // canonicalize -0
    unsigned key = (bits & 0x80000000u) ? ~bits : (bits | 0x80000000u);
    int qi = q;
#pragma unroll
    for (int j = 0; j < 5; ++j) {   // stable branchless bubble (ties keep existing)
      const unsigned a = mk[j];
      const bool pr = key < a;
      mk[j] = pr ? key : a;
      const int ii = mi[j];
      mi[j] = pr ? qi : ii;
      key = pr ? a : key;
      qi = pr ? ii : qi;
    }
    float x = iou;
#pragma unroll
    for (int j = 0; j < 5; ++j) {   // sv sorted descending
      const float a = sv[j];
      sv[j] = fmaxf(a, x);
      x = fminf(a, x);
    }
  }

#pragma unroll
  for (int off = 32; off >= 1; off >>= 1) {
    unsigned ok[5]; int oi[5]; float ov[5];
#pragma unroll
    for (int j = 0; j < 5; ++j) {
      ok[j] = __shfl_down(mk[j], off);
      oi[j] = __shfl_down(mi[j], off);
      ov[j] = __shfl_down(sv[j], off);
    }
    kv_merge(mk, mi, ok, oi);
    merge5_iou(sv, ov);
  }

  __shared__ unsigned Lk[2][5];
  __shared__ int Li[2][5];
  __shared__ float Ls[2][5];
  if (lane == 0) {
#pragma unroll
    for (int j = 0; j < 5; ++j) { Lk[wave][j] = mk[j]; Li[wave][j] = mi[j]; Ls[wave][j] = sv[j]; }
  }
  __syncthreads();
  if (t == 0) {
    unsigned fk[5]; int fi[5]; float fs[5];
    unsigned o2[5]; int i2[5]; float s2[5];
#pragma unroll
    for (int j = 0; j < 5; ++j) {
      fk[j] = Lk[0][j]; fi[j] = Li[0][j]; fs[j] = Ls[0][j];
      o2[j] = Lk[1][j]; i2[j] = Li[1][j]; s2[j] = Ls[1][j];
    }
    kv_merge(fk, fi, o2, i2);
    merge5_iou(fs, s2);
    float s = fs[0]; s += fs[1]; s += fs[2]; s += fs[3]; s += fs[4];  // descending order sum
    int k = (int)s; if (k < 1) k = 1; if (k > 5) k = 5;
    for (int j = 0; j < k; ++j) {
      const int q = fi[j];
      mrow[q >> 5] |= 1u << (q & 31);
      atomicOr(&mbitsT[((size_t)(b*NQ + q)) * NGW + (g >> 5)], 1u << (g & 31));
      atomicAdd(&rcnt[b * NQ + q], 1);
    }
    ccov[b * NG + g] = k;
  }
}

// ---------------- K7: fused compact+gather+multifix + while-loop, one block per image ----------------
__global__ __launch_bounds__(1024) void loop_kernel(
    const float* __restrict__ cost, float* __restrict__ costM,
    unsigned* __restrict__ mbits, unsigned* __restrict__ mbitsT,
    const int* __restrict__ rcnt_g, const int* __restrict__ ccov_g,
    int* __restrict__ pen_g) {
  const int b = blockIdx.x, t = threadIdx.x;
  __shared__ int s_pen[NQ];
  __shared__ int s_rcnt[NQ];
  __shared__ short s_qmi[NQ];
  __shared__ int s_ccov[NG];
  __shared__ int s_unc[NG];
  __shared__ int s_pickq[NG];
  __shared__ int s_mq[MAXM];
  __shared__ unsigned s_mrow[MAXM][NGW];
  __shared__ float s_pwv[16];
  __shared__ int s_pwq[16];
  __shared__ int s_mn, s_n, s_fix, s_sticky;

  const int lane = t & 63, wave = t >> 6;
  unsigned* __restrict__ mb = mbits + b * NG * NQW;
  unsigned* __restrict__ mbT = mbitsT + (size_t)b * NQ * NGW;
  const float* __restrict__ cb = cost + (size_t)b * NG * NQ;
  float* __restrict__ cm = costM + (size_t)b * MAXM * NG;

  if (t == 0) { s_mn = 0; s_sticky = 0; }
  for (int q = t; q < NQ; q += 1024) {
    s_pen[q] = 0;
    s_rcnt[q] = rcnt_g[b * NQ + q];
    s_qmi[q] = -1;
  }
  for (int g = t; g < NG; g += 1024) s_ccov[g] = ccov_g[b * NG + g];
  __syncthreads();
  for (int q = t; q < NQ; q += 1024)
    if (s_rcnt[q] > 1) { const int i = atomicAdd(&s_mn, 1); if (i < MAXM) s_mq[i] = q; }
  __syncthreads();
  int m_n = s_mn; if (m_n > MAXM) m_n = MAXM;
  for (int i = t; i < m_n; i += 1024) s_qmi[s_mq[i]] = (short)i;
  for (int i = t; i < m_n * NG; i += 1024) {
    const int mi = i / NG, g = i - mi * NG;
    cm[i] = cb[(size_t)g * NQ + s_mq[mi]];
  }
  for (int i = t; i < m_n * NGW; i += 1024) {
    const int mi = i / NGW, w2 = i - mi * NGW;
    s_mrow[mi][w2] = mbT[(size_t)s_mq[mi] * NGW + w2];
  }
  __syncthreads();
  // multifix: one wave per multi row -> one-hot argmin_g (raw cost)
  for (int mi = wave; mi < m_n; mi += 16) {
    const int q = s_mq[mi];
    const float* __restrict__ row = cm + (size_t)mi * NG;
    float best = FLT_MAX; int bg = 0;
    for (int g = lane; g < NG; g += 64) {
      const float v = row[g];
      if (v < best) { best = v; bg = g; }
    }
    for (int off = 32; off; off >>= 1) {
      const float ov = __shfl_down(best, off);
      const int og = __shfl_down(bg, off);
      if (ov < best || (ov == best && og < bg)) { best = ov; bg = og; }
    }
    bg = __shfl(bg, 0);
    const unsigned qbit = 1u << (q & 31);
    const int qw = q >> 5;
    if (lane < NGW) {
      const unsigned wv = s_mrow[mi][lane];
      const unsigned want = ((bg >> 5) == lane) ? (1u << (bg & 31)) : 0u;
      unsigned clr = wv & ~want;
      while (clr) {
        const int gb = __ffs(clr) - 1; clr &= clr - 1;
        const int g = lane*32 + gb;
        atomicAnd(&mb[g * NQW + qw], ~qbit);
        atomicSub(&s_ccov[g], 1);
      }
      if (want & ~wv) {
        atomicOr(&mb[bg * NQW + qw], qbit);
        atomicAdd(&s_ccov[bg], 1);
      }
      s_mrow[mi][lane] = want;
    }
    if (lane == 0) s_rcnt[q] = 1;
  }
  __syncthreads();

  for (int iter = 0; iter < 100; ++iter) {
    if (t == 0) { s_n = 0; s_fix = s_sticky; }
    __syncthreads();
    for (int g = t; g < NG; g += 1024)
      if (s_ccov[g] == 0) { const int i = atomicAdd(&s_n, 1); s_unc[i] = g; }
    __syncthreads();
    const int n = s_n;
    if (n == 0) break;
    for (int q = t; q < NQ; q += 1024)
      if (s_rcnt[q] > 0) s_pen[q]++;
    __syncthreads();
    if (n >= 16) {
      for (int ci = wave; ci < n; ci += 16) {
        const int g = s_unc[ci];
        const float* __restrict__ crow = cb + (size_t)g * NQ;
        float best = FLT_MAX; int bq = 0x7fffffff;
        for (int q = lane; q < NQ; q += 64) {
          const float v = crow[q] + (s_pen[q] ? 1e30f : 0.0f);
          const bool pr = v < best;
          best = pr ? v : best;
          bq = pr ? q : bq;
        }
        for (int off = 32; off; off >>= 1) {
          const float ov = __shfl_down(best, off);
          const int oq = __shfl_down(bq, off);
          if (ov < best || (ov == best && oq < bq)) { best = ov; bq = oq; }
        }
        if (lane == 0) s_pickq[ci] = bq;
      }
      __syncthreads();
    } else {
      const int wpc = 16 / n;
      const int ci = wave / wpc, seg = wave - ci * wpc;
      float best = FLT_MAX; int bq = 0x7fffffff;
      if (ci < n) {
        const int g = s_unc[ci];
        const float* __restrict__ crow = cb + (size_t)g * NQ;
        const int qlo = (NQ * seg) / wpc, qhi = (NQ * (seg + 1)) / wpc;
        for (int q = qlo + lane; q < qhi; q += 64) {
          const float v = crow[q] + (s_pen[q] ? 1e30f : 0.0f);
          const bool pr = v < best;
          best = pr ? v : best;
          bq = pr ? q : bq;
        }
        for (int off = 32; off; off >>= 1) {
          const float ov = __shfl_down(best, off);
          const int oq = __shfl_down(bq, off);
          if (ov < best || (ov == best && oq < bq)) { best = ov; bq = oq; }
        }
      }
      if (lane == 0) { s_pwv[wave] = best; s_pwq[wave] = bq; }
      __syncthreads();
      if (t < n) {
        float fb = FLT_MAX; int fq = 0x7fffffff;
        for (int s2 = 0; s2 < wpc; ++s2) {
          const float ov = s_pwv[t * wpc + s2];
          const int oq = s_pwq[t * wpc + s2];
          if (lexlt(ov, oq, fb, fq)) { fb = ov; fq = oq; }
        }
        s_pickq[t] = fq;
      }
      __syncthreads();
    }
    if (t < n) {
      const int g = s_unc[t], q = s_pickq[t];
      atomicOr(&mb[g * NQW + (q >> 5)], 1u << (q & 31));
      const int mi2 = s_qmi[q];
      if (mi2 >= 0) atomicOr(&s_mrow[mi2][g >> 5], 1u << (g & 31));
      else atomicOr(&mbT[(size_t)q * NGW + (g >> 5)], 1u << (g & 31));
      const int nc = atomicAdd(&s_rcnt[q], 1) + 1;
      s_ccov[g] = 1;
      if (nc > 1) { s_fix = 1; if (s_qmi[q] < 0) s_sticky = 1; }
    }
    __syncthreads();
    if (s_fix) {
      for (int mi = wave; mi < m_n; mi += 16) {
        const int q = s_mq[mi];
        float* __restrict__ row = cm + (size_t)mi * NG;
        float best = FLT_MAX; int bg = 0;
        for (int g = lane; g < NG; g += 64) {
          const float v = row[g] + 100000.0f;
          row[g] = v;
          if (v < best) { best = v; bg = g; }
        }
        for (int off = 32; off; off >>= 1) {
          const float ov = __shfl_down(best, off);
          const int og = __shfl_down(bg, off);
          if (ov < best || (ov == best && og < bg)) { best = ov; bg = og; }
        }
        bg = __shfl(bg, 0);
        const unsigned qbit = 1u << (q & 31);
        const int qw = q >> 5;
        if (lane < NGW) {
          const unsigned wv = s_mrow[mi][lane];
          const unsigned want = ((bg >> 5) == lane) ? (1u << (bg & 31)) : 0u;
          unsigned clr = wv & ~want;
          while (clr) {
            const int gb = __ffs(clr) - 1; clr &= clr - 1;
            const int g = lane * 32 + gb;
            atomicAnd(&mb[g * NQW + qw], ~qbit);
            atomicSub(&s_ccov[g], 1);
          }
          if (want & ~wv) {
            atomicOr(&mb[bg * NQW + qw], qbit);
            atomicAdd(&s_ccov[bg], 1);
          }
          s_mrow[mi][lane] = want;
        }
        if (lane == 0) s_rcnt[q] = 1;
      }
    } else {
      for (int i = t; i < m_n * NG; i += 1024) cm[i] += 100000.0f;
    }
    __syncthreads();
  }
  __syncthreads();
  for (int i = t; i < m_n * NGW; i += 1024) {
    const int mi = i / NGW, w2 = i - mi * NGW;
    mbT[(size_t)s_mq[mi] * NGW + w2] = s_mrow[mi][w2];
  }
  for (int q = t; q < NQ; q += 1024) pen_g[b * NQ + q] = s_pen[q];
}

// ---------------- K8: matched_qidx — bit-sparse, one wave per (b,g) ----------------
__global__ __launch_bounds__(256) void matched_kernel(
    const float* __restrict__ cost, const unsigned* __restrict__ mbits,
    const int* __restrict__ pen_g, float* __restrict__ out_mq) {
  const int b = blockIdx.y, t = threadIdx.x;
  const int g = blockIdx.x * 4 + (t >> 6);
  const int lane = t & 63;
  const float* __restrict__ crow = cost + ((size_t)(b*NG + g)) * NQ;
  const unsigned* __restrict__ mrow = mbits + (b*NG + g) * NQW;
  const int* __restrict__ pb = pen_g + b * NQ;
  float best = FLT_MAX; int bq = 0;
  for (int w = lane; w < NQW; w += 64) {
    unsigned word = mrow[w];
    while (word) {
      const int bit = __ffs(word) - 1; word &= word - 1;
      const int q = w * 32 + bit;
      const float v = penalized(crow[q], pb[q]);
      if (lexlt(v, q, best, bq)) { best = v; bq = q; }
    }
  }
  for (int off = 32; off; off >>= 1) {
    const float ov = __shfl_down(best, off);
    const int oq = __shfl_down(bq, off);
    if (lexlt(ov, oq, best, bq)) { best = ov; bq = oq; }
  }
  if (lane == 0) out_mq[b * NG + g] = (float)bq;
}

// ---------------- K9: expand mbitsT rows -> m floats (float4 stores), selected, gt_idx ----------------
__global__ void out_kernel(const unsigned* __restrict__ mbitsT, float* __restrict__ out_m,
                           float* __restrict__ out_sel, float* __restrict__ out_gti) {
  const int b = blockIdx.y, t = threadIdx.x;
  const int q0 = blockIdx.x * 32;
  __shared__ unsigned wds[32 * NGW];
  for (int i = t; i < 32 * NGW; i += 256)   // strided: 320 words > 256 threads
    wds[i] = mbitsT[((size_t)(b*NQ + q0)) * NGW + i];
  __syncthreads();
  float4* __restrict__ om4 = reinterpret_cast<float4*>(out_m + ((size_t)(b*NQ + q0)) * NG);
  for (int j = t; j < 32 * (NG/4); j += 256) {
    const int qi = j / (NG/4);
    const int g0 = (j - qi * (NG/4)) * 4;
    const unsigned* wr = &wds[qi * NGW];
    float4 v;
    v.x = ((wr[(g0+0) >> 5] >> ((g0+0) & 31)) & 1u) ? 1.f : 0.f;
    v.y = ((wr[(g0+1) >> 5] >> ((g0+1) & 31)) & 1u) ? 1.f : 0.f;
    v.z = ((wr[(g0+2) >> 5] >> ((g0+2) & 31)) & 1u) ? 1.f : 0.f;
    v.w = ((wr[(g0+3) >> 5] >> ((g0+3) & 31)) & 1u) ? 1.f : 0.f;
    om4[j] = v;
  }
  if (t < 32) {
    int fgi = -1;
    for (int w = 0; w < NGW; ++w) {
      const unsigned v = wds[t*NGW + w];
      if (v) { fgi = w*32 + __ffs(v) - 1; break; }
    }
    out_sel[b*NQ + q0 + t] = (fgi >= 0) ? 1.f : 0.f;
    out_gti[b*NQ + q0 + t] = (fgi >= 0) ? (float)fgi : 0.f;
  }
}

extern "C" void kernel_launch(void* const* d_in, const int* in_sizes, int n_in,
                              void* d_out, int out_size, void* d_ws, size_t ws_size,
                              hipStream_t stream) {
  const float* logits = (const float*)d_in[0];
  const float* boxes  = (const float*)d_in[1];
  const int*   labels = (const int*)d_in[2];
  const float* gtb    = (const float*)d_in[3];
  const float* imgsz  = (const float*)d_in[4];

  float* out = (float*)d_out;
  float* out_m   = out;                                   // B*Q*G
  float* out_sel = out + (size_t)NB * NQ * NG;            // B*Q
  float* out_gti = out_sel + (size_t)NB * NQ;             // B*Q
  float* out_mq  = out_gti + (size_t)NB * NQ;             // B*G

  char* w = (char*)d_ws;
  const size_t szPrep = sizeof(float4) * (size_t)NB * NQ;
  const size_t szF    = sizeof(float) * (size_t)NB * NQ;
  const size_t szGp   = sizeof(float4) * (size_t)NB * NG * 5;
  const size_t szCct  = sizeof(float) * (size_t)NB * NC * NQ;
  const size_t szBits = sizeof(unsigned) * (size_t)NB * NG * NQW;
  const size_t szBitsT= sizeof(unsigned) * (size_t)NB * NQ * NGW;
  const size_t szIntQ = sizeof(int) * (size_t)NB * NQ;
  const size_t szIntG = sizeof(int) * (size_t)NB * NG;
  const size_t szCM   = sizeof(float) * (size_t)NB * MAXM * NG;
  const size_t need = szPrep + szF + szGp + szCct + szBits + szBitsT + 2*szIntQ + szIntG + szCM;
  if (ws_size < need) return;

  float4* prepN = (float4*)w; w += szPrep;
  float*  prepF = (float*)w;  w += szF;
  float4* gp    = (float4*)w; w += szGp;
  float*    cct   = (float*)w;    w += szCct;
  unsigned* mbits = (unsigned*)w; w += szBits;
  unsigned* mbitsT= (unsigned*)w; w += szBitsT;
  int* rcnt  = (int*)w; w += szIntQ;
  int* pen   = (int*)w; w += szIntQ;
  int* ccov  = (int*)w; w += szIntG;
  float* costM = (float*)w; w += szCM;

  float* cost = out_m;  // (B,G,Q) in the d_out m-region; overwritten by out_kernel at the end

  gprep_kernel<<<(NB * NG + 255) / 256, 256, 0, stream>>>(gtb, labels, imgsz, gp);
  prep_kernel<<<dim3((NQ + 255) / 256, NB), 256, 0, stream>>>(boxes, gp, imgsz, prepN, prepF, rcnt, mbitsT);
  cls_kernel<<<dim3((NQ + QT - 1) / QT, NB), 256, 0, stream>>>(logits, cct);
  cost_topk_kernel<<<dim3(NG, NB), 128, 0, stream>>>(boxes, prepN, prepF, gp, cct, cost, mbits, mbitsT, rcnt, ccov);
  loop_kernel<<<NB, 1024, 0, stream>>>(cost, costM, mbits, mbitsT, rcnt, ccov, pen);
  matched_kernel<<<dim3(NG/4, NB), 256, 0, stream>>>(cost, mbits, pen, out_mq);
  out_kernel<<<dim3(NQ / 32, NB), 256, 0, stream>>>(mbitsT, out_m, out_sel, out_gti);
}

// Round 15
// 230.389 us; speedup vs baseline: 1.9675x; 1.0028x over previous
//
#include <hip/hip_runtime.h>
#include <float.h>
#include <stdint.h>
#include <stddef.h>

#define NB 16
#define NQ 4000
#define NG 300
#define NC 81
#define NQW 125  // NQ/32
#define NGW 10   // ceil(NG/32)
#define MAXM 768 // multi rows per image <= sum(dyn_k)/2 <= 750 (provable bound)

__device__ __forceinline__ bool lexlt(float v1, int i1, float v2, int i2) {
  return (v1 < v2) || (v1 == v2 && i1 < i2);
}

// Exact replica of p sequential f32 adds of 1e5 (numpy semantics), in O(#binade crossings).
__device__ __forceinline__ float penalized(float v, int p) {
  if (p <= 0) return v;
  if (p <= 12) {
    float x = v;
    for (int r = 0; r < p; ++r) x += 100000.0f;
    return x;
  }
  double x = (double)v;
  x = (double)(float)(x + 100000.0);
  int k = 1;
  while (k < p) {
    double B = 131072.0;
    while (B <= x) B += B;
    double room = B - x;
    int j = (int)(room * 1e-5);
    while (j > 0 && x + (double)j * 100000.0 >= B) --j;
    if (j > p - k) j = p - k;
    if (j > 0) { x += (double)j * 100000.0; k += j; }
    if (k < p) { x = (double)(float)(x + 100000.0); ++k; }
  }
  return (float)x;
}

// ---------------- K0: per-gt derived params ----------------
__global__ void gprep_kernel(const float* __restrict__ gtb, const int* __restrict__ labels,
                             const float* __restrict__ imgsz, float4* __restrict__ gp) {
#pragma clang fp contract(off)
  const int idx = blockIdx.x * 256 + threadIdx.x;
  if (idx >= NB * NG) return;
  const int b = idx / NG;
  const float gx0 = gtb[idx*4 + 0];
  const float gy0 = gtb[idx*4 + 1];
  const float gx1 = gtb[idx*4 + 2];
  const float gy1 = gtb[idx*4 + 3];
  const float s0 = imgsz[b*4+0], s1 = imgsz[b*4+1], s2 = imgsz[b*4+2], s3 = imgsz[b*4+3];
  const float areaB = (gx1 - gx0) * (gy1 - gy0);
  const float gcx = (gx0 + gx1) * 0.5f, gcy = (gy0 + gy1) * 0.5f;
  const float gw0 = gx1 - gx0, gh0 = gy1 - gy0;
  const float xg0 = gcx - 0.5f*gw0, yg0 = gcy - 0.5f*gh0;
  const float xg1 = gcx + 0.5f*gw0, yg1 = gcy + 0.5f*gh0;
  const float cw = xg1 - xg0, ch = yg1 - yg0;
  gp[idx*5+0] = make_float4(xg0, yg0, xg1, yg1);
  gp[idx*5+1] = make_float4(gcx - 2.5f*cw, gcx + 2.5f*cw, gcy - 2.5f*ch, gcy + 2.5f*ch);
  gp[idx*5+2] = make_float4(gx0 / s0, gy0 / s1, gx1 / s2, gy1 / s3);
  gp[idx*5+3] = make_float4(gx0, gy0, gx1, gy1);
  gp[idx*5+4] = make_float4(areaB, __int_as_float(labels[idx]), 0.f, 0.f);
}

// ---------------- K1: prep — fg via in_ctr only (inb => inc, provable); independent of gprep ----------------
__global__ void prep_kernel(const float* __restrict__ boxes, const float* __restrict__ gtb,
                            const float* __restrict__ imgsz,
                            float4* __restrict__ prepN, float* __restrict__ prepF,
                            int* __restrict__ rcnt, unsigned* __restrict__ mbitsT) {
#pragma clang fp contract(off)
  const int b = blockIdx.y;
  const int q = blockIdx.x * 256 + threadIdx.x;
  const int tid = (blockIdx.y * gridDim.x + blockIdx.x) * 256 + threadIdx.x;
  const int nthreads = gridDim.x * gridDim.y * 256;
  for (int i = tid; i < NB * NQ * NGW; i += nthreads) mbitsT[i] = 0u;
  __shared__ float4 sA1[NG];
  for (int i = threadIdx.x; i < NG; i += 256) {
    // same FP ops as gprep (bit-exact); computed locally to decouple from gprep's launch
    const float gx0 = gtb[(b*NG + i)*4 + 0];
    const float gy0 = gtb[(b*NG + i)*4 + 1];
    const float gx1 = gtb[(b*NG + i)*4 + 2];
    const float gy1 = gtb[(b*NG + i)*4 + 3];
    const float gcx = (gx0 + gx1) * 0.5f, gcy = (gy0 + gy1) * 0.5f;
    const float gw0 = gx1 - gx0, gh0 = gy1 - gy0;
    const float xg0 = gcx - 0.5f*gw0, yg0 = gcy - 0.5f*gh0;
    const float xg1 = gcx + 0.5f*gw0, yg1 = gcy + 0.5f*gh0;
    const float cw = xg1 - xg0, ch = yg1 - yg0;
    sA1[i] = make_float4(gcx - 2.5f*cw, gcx + 2.5f*cw, gcy - 2.5f*ch, gcy + 2.5f*ch);
  }
  __syncthreads();
  if (q >= NQ) return;
  const float4 pb = reinterpret_cast<const float4*>(boxes)[b * NQ + q];
  const float s0 = imgsz[b*4+0], s1 = imgsz[b*4+1], s2 = imgsz[b*4+2], s3 = imgsz[b*4+3];
  const float ax = (pb.x + pb.z) * 0.5f;
  const float ay = (pb.y + pb.w) * 0.5f;
  // fg = any(in_box)|any(in_ctr) == any(in_ctr): in_ctr interval contains in_box interval
  // (cw Sterbenz-exact when a float lies strictly inside, fl(2.5*cw) >= 0.5*gw).
  bool fg = false;
  for (int g = 0; g < NG; ++g) {
    const float4 A1 = sA1[g];
    if ((ax > A1.x) && (ax < A1.y) && (ay > A1.z) && (ay < A1.w)) { fg = true; break; }
  }
  const int idx = b * NQ + q;
  prepN[idx] = make_float4(pb.x / s0, pb.y / s1, pb.z / s2, pb.w / s3);
  prepF[idx] = fg ? 0.f : 10000.f;
  rcnt[idx] = 0;
}

// ---------------- K2: focal class cost table, transposed (B,C,Q), tiled ----------------
#define QT 64
__global__ void cls_kernel(const float* __restrict__ logits, float* __restrict__ cct) {
#pragma clang fp contract(off)
  const int b = blockIdx.y, q0 = blockIdx.x * QT, t = threadIdx.x;
  __shared__ float tile[QT * NC];
  const int nq = (NQ - q0 < QT) ? (NQ - q0) : QT;
  const float* __restrict__ src = logits + ((size_t)(b * NQ + q0)) * NC;
  for (int i = t; i < nq * NC; i += 256) {
    const float x = src[i];
    float p;
    if (x >= 0.f) p = 1.f / (1.f + expf(-x));
    else { const float e = expf(x); p = e / (1.f + e); }
    const float pos = 0.25f * ((1.f - p) * (1.f - p)) * (-logf(p + 1e-8f));
    const float neg = 0.75f * (p * p) * (-logf(1.f - p + 1e-8f));
    tile[i] = pos - neg;
  }
  __syncthreads();
  for (int i = t; i < NC * QT; i += 256) {
    const int c = i >> 6;
    const int ql = i & (QT - 1);
    if (ql < nq) cct[((size_t)(b * NC + c)) * NQ + q0 + ql] = tile[ql * NC + c];
  }
}

// ---------------- K3: FUSED cost + per-(b,g) top-5 (1 GT per block, 128 thr) ----------------
__device__ __forceinline__ void kv_sortnet(unsigned* k, int* i) {
#define CE(a,b) { \
    const bool pr = (k[b] < k[a]) || (k[b] == k[a] && i[b] < i[a]); \
    const unsigned tk = pr ? k[b] : k[a]; const unsigned uk = pr ? k[a] : k[b]; \
    const int ti = pr ? i[b] : i[a]; const int ui = pr ? i[a] : i[b]; \
    k[a] = tk; k[b] = uk; i[a] = ti; i[b] = ui; }
  CE(0,1)
  CE(1,2) CE(0,1)
  CE(2,3) CE(1,2) CE(0,1)
  CE(3,4) CE(2,3) CE(1,2) CE(0,1)
#undef CE
}
__device__ __forceinline__ void kv_merge(unsigned* ak, int* ai, const unsigned* bk, const int* bi) {
  unsigned ck[5]; int ci[5];
#pragma unroll
  for (int j = 0; j < 5; ++j) {
    const unsigned ka = ak[j], kb = bk[4 - j];
    const int ia = ai[j], ib = bi[4 - j];
    const bool pr = (kb < ka) || (kb == ka && ib < ia);
    ck[j] = pr ? kb : ka; ci[j] = pr ? ib : ia;
  }
  kv_sortnet(ck, ci);
#pragma unroll
  for (int j = 0; j < 5; ++j) { ak[j] = ck[j]; ai[j] = ci[j]; }
}
__device__ __forceinline__ void sort5_desc(float* c) {
#define CED(a,b) { const float hi = fmaxf(c[a], c[b]); c[b] = fminf(c[a], c[b]); c[a] = hi; }
  CED(0,1)
  CED(1,2) CED(0,1)
  CED(2,3) CED(1,2) CED(0,1)
  CED(3,4) CED(2,3) CED(1,2) CED(0,1)
#undef CED
}
__device__ __forceinline__ void merge5_iou(float* a, const float* o) {
  float c[5];
#pragma unroll
  for (int j = 0; j < 5; ++j) c[j] = fmaxf(a[j], o[4 - j]);
  sort5_desc(c);
#pragma unroll
  for (int j = 0; j < 5; ++j) a[j] = c[j];
}

__global__ __launch_bounds__(128, 4) void cost_topk_kernel(
    const float* __restrict__ boxes, const float4* __restrict__ prepN,
    const float* __restrict__ prepF, const float4* __restrict__ gp,
    const float* __restrict__ cct, float* __restrict__ cost,
    unsigned* __restrict__ mbits, unsigned* __restrict__ mbitsT,
    int* __restrict__ rcnt, int* __restrict__ ccov) {
#pragma clang fp contract(off)
  const int g = blockIdx.x, b = blockIdx.y, t = threadIdx.x;
  const int lane = t & 63, wave = t >> 6;
  const float4 A0 = gp[(size_t)(b*NG + g) * 5 + 0];
  const float4 A1 = gp[(size_t)(b*NG + g) * 5 + 1];
  const float4 A2 = gp[(size_t)(b*NG + g) * 5 + 2];
  const float4 A3 = gp[(size_t)(b*NG + g) * 5 + 3];
  const float4 A4 = gp[(size_t)(b*NG + g) * 5 + 4];
  const int lab = __float_as_int(A4.y);
  const float areaB = A4.x;
  const float* __restrict__ ccls = cct + ((size_t)(b*NC + lab)) * NQ;
  float* __restrict__ crow = cost + ((size_t)(b*NG + g)) * NQ;
  unsigned* __restrict__ mrow = mbits + (b*NG + g) * NQW;
  for (int i = t; i < NQW; i += 128) mrow[i] = 0u;

  unsigned mk[5]; int mi[5]; float sv[5];
#pragma unroll
  for (int j = 0; j < 5; ++j) { mk[j] = 0xffffffffu; mi[j] = 0x7fffffff; sv[j] = -1.f; }

#pragma unroll 4
  for (int q = t; q < NQ; q += 128) {
    const float4 pb = reinterpret_cast<const float4*>(boxes)[b*NQ + q];
    const float4 nb = prepN[b*NQ + q];
    const float fpen = prepF[b*NQ + q];
    const float ax = (pb.x + pb.z) * 0.5f;
    const float ay = (pb.y + pb.w) * 0.5f;
    const float areaA = (pb.z - pb.x) * (pb.w - pb.y);
    const float ltx = fmaxf(pb.x, A3.x), lty = fmaxf(pb.y, A3.y);
    const float rbx = fminf(pb.z, A3.z), rby = fminf(pb.w, A3.w);
    const float iw = fmaxf(rbx - ltx, 0.f), ih = fmaxf(rby - lty, 0.f);
    const float inter = iw * ih;
    const float uni = areaA + areaB - inter;
    const float iou = inter / uni;
    const float eltx = fminf(pb.x, A3.x), elty = fminf(pb.y, A3.y);
    const float erbx = fmaxf(pb.z, A3.z), erby = fmaxf(pb.w, A3.w);
    const float ew = fmaxf(erbx - eltx, 0.f), eh = fmaxf(erby - elty, 0.f);
    const float earea = ew * eh;
    const float giou = iou - (earea - uni) / earea;
    const float cbb = fabsf(nb.x - A2.x) + fabsf(nb.y - A2.y)
                    + fabsf(nb.z - A2.z) + fabsf(nb.w - A2.w);
    const bool inb = (ax > A0.x) && (ax < A0.z) && (ay > A0.y) && (ay < A0.w);
    const bool inc = (ax > A1.x) && (ax < A1.y) && (ay > A1.z) && (ay < A1.w);
    const bool ibc = inb && inc;
    float cval = 5.0f * cbb + 2.0f * ccls[q];
    cval = cval + 2.0f * (-giou);
    cval = cval + (ibc ? 0.f : 100.f);
    cval = cval + fpen;
    crow[q] = cval;
    const unsigned bits = __float_as_uint(cval + 0.0f);  // canonicalize -0
    unsigned key = (bits & 0x80000000u) ? ~bits : (bits | 0x80000000u);
    int qi = q;
#pragma unroll
    for (int j = 0; j < 5; ++j) {   // stable branchless bubble (ties keep existing)
      const unsigned a = mk[j];
      const bool pr = key < a;
      mk[j] = pr ? key : a;
      const int ii = mi[j];
      mi[j] = pr ? qi : ii;
      key = pr ? a : key;
      qi = pr ? ii : qi;
    }
    float x = iou;
#pragma unroll
    for (int j = 0; j < 5; ++j) {   // sv sorted descending
      const float a = sv[j];
      sv[j] = fmaxf(a, x);
      x = fminf(a, x);
    }
  }

#pragma unroll
  for (int off = 32; off >= 1; off >>= 1) {
    unsigned ok[5]; int oi[5]; float ov[5];
#pragma unroll
    for (int j = 0; j < 5; ++j) {
      ok[j] = __shfl_down(mk[j], off);
      oi[j] = __shfl_down(mi[j], off);
      ov[j] = __shfl_down(sv[j], off);
    }
    kv_merge(mk, mi, ok, oi);
    merge5_iou(sv, ov);
  }

  __shared__ unsigned Lk[2][5];
  __shared__ int Li[2][5];
  __shared__ float Ls[2][5];
  if (lane == 0) {
#pragma unroll
    for (int j = 0; j < 5; ++j) { Lk[wave][j] = mk[j]; Li[wave][j] = mi[j]; Ls[wave][j] = sv[j]; }
  }
  __syncthreads();
  if (t == 0) {
    unsigned fk[5]; int fi[5]; float fs[5];
    unsigned o2[5]; int i2[5]; float s2[5];
#pragma unroll
    for (int j = 0; j < 5; ++j) {
      fk[j] = Lk[0][j]; fi[j] = Li[0][j]; fs[j] = Ls[0][j];
      o2[j] = Lk[1][j]; i2[j] = Li[1][j]; s2[j] = Ls[1][j];
    }
    kv_merge(fk, fi, o2, i2);
    merge5_iou(fs, s2);
    float s = fs[0]; s += fs[1]; s += fs[2]; s += fs[3]; s += fs[4];  // descending order sum
    int k = (int)s; if (k < 1) k = 1; if (k > 5) k = 5;
    for (int j = 0; j < k; ++j) {
      const int q = fi[j];
      mrow[q >> 5] |= 1u << (q & 31);
      atomicOr(&mbitsT[((size_t)(b*NQ + q)) * NGW + (g >> 5)], 1u << (g & 31));
      atomicAdd(&rcnt[b * NQ + q], 1);
    }
    ccov[b * NG + g] = k;
  }
}

// ---------------- K7: fused compact+gather+multifix + while-loop, one block per image ----------------
__global__ __launch_bounds__(1024) void loop_kernel(
    const float* __restrict__ cost, float* __restrict__ costM,
    unsigned* __restrict__ mbits, unsigned* __restrict__ mbitsT,
    const int* __restrict__ rcnt_g, const int* __restrict__ ccov_g,
    int* __restrict__ pen_g) {
  const int b = blockIdx.x, t = threadIdx.x;
  __shared__ int s_pen[NQ];
  __shared__ int s_rcnt[NQ];
  __shared__ short s_qmi[NQ];
  __shared__ int s_ccov[NG];
  __shared__ int s_unc[NG];
  __shared__ int s_pickq[NG];
  __shared__ int s_mq[MAXM];
  __shared__ unsigned s_mrow[MAXM][NGW];
  __shared__ float s_pwv[16];
  __shared__ int s_pwq[16];
  __shared__ int s_mn, s_n, s_fix, s_sticky;

  const int lane = t & 63, wave = t >> 6;
  unsigned* __restrict__ mb = mbits + b * NG * NQW;
  unsigned* __restrict__ mbT = mbitsT + (size_t)b * NQ * NGW;
  const float* __restrict__ cb = cost + (size_t)b * NG * NQ;
  float* __restrict__ cm = costM + (size_t)b * MAXM * NG;

  if (t == 0) { s_mn = 0; s_sticky = 0; }
  for (int q = t; q < NQ; q += 1024) {
    s_pen[q] = 0;
    s_rcnt[q] = rcnt_g[b * NQ + q];
    s_qmi[q] = -1;
  }
  for (int g = t; g < NG; g += 1024) s_ccov[g] = ccov_g[b * NG + g];
  __syncthreads();
  for (int q = t; q < NQ; q += 1024)
    if (s_rcnt[q] > 1) { const int i = atomicAdd(&s_mn, 1); if (i < MAXM) s_mq[i] = q; }
  __syncthreads();
  int m_n = s_mn; if (m_n > MAXM) m_n = MAXM;
  for (int i = t; i < m_n; i += 1024) s_qmi[s_mq[i]] = (short)i;
  for (int i = t; i < m_n * NG; i += 1024) {
    const int mi = i / NG, g = i - mi * NG;
    cm[i] = cb[(size_t)g * NQ + s_mq[mi]];
  }
  for (int i = t; i < m_n * NGW; i += 1024) {
    const int mi = i / NGW, w2 = i - mi * NGW;
    s_mrow[mi][w2] = mbT[(size_t)s_mq[mi] * NGW + w2];
  }
  __syncthreads();
  // multifix: one wave per multi row -> one-hot argmin_g (raw cost)
  for (int mi = wave; mi < m_n; mi += 16) {
    const int q = s_mq[mi];
    const float* __restrict__ row = cm + (size_t)mi * NG;
    float best = FLT_MAX; int bg = 0;
    for (int g = lane; g < NG; g += 64) {
      const float v = row[g];
      if (v < best) { best = v; bg = g; }
    }
    for (int off = 32; off; off >>= 1) {
      const float ov = __shfl_down(best, off);
      const int og = __shfl_down(bg, off);
      if (ov < best || (ov == best && og < bg)) { best = ov; bg = og; }
    }
    bg = __shfl(bg, 0);
    const unsigned qbit = 1u << (q & 31);
    const int qw = q >> 5;
    if (lane < NGW) {
      const unsigned wv = s_mrow[mi][lane];
      const unsigned want = ((bg >> 5) == lane) ? (1u << (bg & 31)) : 0u;
      unsigned clr = wv & ~want;
      while (clr) {
        const int gb = __ffs(clr) - 1; clr &= clr - 1;
        const int g = lane*32 + gb;
        atomicAnd(&mb[g * NQW + qw], ~qbit);
        atomicSub(&s_ccov[g], 1);
      }
      if (want & ~wv) {
        atomicOr(&mb[bg * NQW + qw], qbit);
        atomicAdd(&s_ccov[bg], 1);
      }
      s_mrow[mi][lane] = want;
    }
    if (lane == 0) s_rcnt[q] = 1;
  }
  __syncthreads();

  for (int iter = 0; iter < 100; ++iter) {
    if (t == 0) { s_n = 0; s_fix = s_sticky; }
    __syncthreads();
    for (int g = t; g < NG; g += 1024)
      if (s_ccov[g] == 0) { const int i = atomicAdd(&s_n, 1); s_unc[i] = g; }
    __syncthreads();
    const int n = s_n;
    if (n == 0) break;
    for (int q = t; q < NQ; q += 1024)
      if (s_rcnt[q] > 0) s_pen[q]++;
    __syncthreads();
    if (n >= 16) {
      for (int ci = wave; ci < n; ci += 16) {
        const int g = s_unc[ci];
        const float* __restrict__ crow = cb + (size_t)g * NQ;
        float best = FLT_MAX; int bq = 0x7fffffff;
        for (int q = lane; q < NQ; q += 64) {
          const float v = crow[q] + (s_pen[q] ? 1e30f : 0.0f);
          const bool pr = v < best;
          best = pr ? v : best;
          bq = pr ? q : bq;
        }
        for (int off = 32; off; off >>= 1) {
          const float ov = __shfl_down(best, off);
          const int oq = __shfl_down(bq, off);
          if (ov < best || (ov == best && oq < bq)) { best = ov; bq = oq; }
        }
        if (lane == 0) s_pickq[ci] = bq;
      }
      __syncthreads();
    } else {
      const int wpc = 16 / n;
      const int ci = wave / wpc, seg = wave - ci * wpc;
      float best = FLT_MAX; int bq = 0x7fffffff;
      if (ci < n) {
        const int g = s_unc[ci];
        const float* __restrict__ crow = cb + (size_t)g * NQ;
        const int qlo = (NQ * seg) / wpc, qhi = (NQ * (seg + 1)) / wpc;
        for (int q = qlo + lane; q < qhi; q += 64) {
          const float v = crow[q] + (s_pen[q] ? 1e30f : 0.0f);
          const bool pr = v < best;
          best = pr ? v : best;
          bq = pr ? q : bq;
        }
        for (int off = 32; off; off >>= 1) {
          const float ov = __shfl_down(best, off);
          const int oq = __shfl_down(bq, off);
          if (ov < best || (ov == best && oq < bq)) { best = ov; bq = oq; }
        }
      }
      if (lane == 0) { s_pwv[wave] = best; s_pwq[wave] = bq; }
      __syncthreads();
      if (t < n) {
        float fb = FLT_MAX; int fq = 0x7fffffff;
        for (int s2 = 0; s2 < wpc; ++s2) {
          const float ov = s_pwv[t * wpc + s2];
          const int oq = s_pwq[t * wpc + s2];
          if (lexlt(ov, oq, fb, fq)) { fb = ov; fq = oq; }
        }
        s_pickq[t] = fq;
      }
      __syncthreads();
    }
    if (t < n) {
      const int g = s_unc[t], q = s_pickq[t];
      atomicOr(&mb[g * NQW + (q >> 5)], 1u << (q & 31));
      const int mi2 = s_qmi[q];
      if (mi2 >= 0) atomicOr(&s_mrow[mi2][g >> 5], 1u << (g & 31));
      else atomicOr(&mbT[(size_t)q * NGW + (g >> 5)], 1u << (g & 31));
      const int nc = atomicAdd(&s_rcnt[q], 1) + 1;
      s_ccov[g] = 1;
      if (nc > 1) { s_fix = 1; if (s_qmi[q] < 0) s_sticky = 1; }
    }
    __syncthreads();
    if (s_fix) {
      for (int mi = wave; mi < m_n; mi += 16) {
        const int q = s_mq[mi];
        float* __restrict__ row = cm + (size_t)mi * NG;
        float best = FLT_MAX; int bg = 0;
        for (int g = lane; g < NG; g += 64) {
          const float v = row[g] + 100000.0f;
          row[g] = v;
          if (v < best) { best = v; bg = g; }
        }
        for (int off = 32; off; off >>= 1) {
          const float ov = __shfl_down(best, off);
          const int og = __shfl_down(bg, off);
          if (ov < best || (ov == best && og < bg)) { best = ov; bg = og; }
        }
        bg = __shfl(bg, 0);
        const unsigned qbit = 1u << (q & 31);
        const int qw = q >> 5;
        if (lane < NGW) {
          const unsigned wv = s_mrow[mi][lane];
          const unsigned want = ((bg >> 5) == lane) ? (1u << (bg & 31)) : 0u;
          unsigned clr = wv & ~want;
          while (clr) {
            const int gb = __ffs(clr) - 1; clr &= clr - 1;
            const int g = lane * 32 + gb;
            atomicAnd(&mb[g * NQW + qw], ~qbit);
            atomicSub(&s_ccov[g], 1);
          }
          if (want & ~wv) {
            atomicOr(&mb[bg * NQW + qw], qbit);
            atomicAdd(&s_ccov[bg], 1);
          }
          s_mrow[mi][lane] = want;
        }
        if (lane == 0) s_rcnt[q] = 1;
      }
    } else {
      for (int i = t; i < m_n * NG; i += 1024) cm[i] += 100000.0f;
    }
    __syncthreads();
  }
  __syncthreads();
  for (int i = t; i < m_n * NGW; i += 1024) {
    const int mi = i / NGW, w2 = i - mi * NGW;
    mbT[(size_t)s_mq[mi] * NGW + w2] = s_mrow[mi][w2];
  }
  for (int q = t; q < NQ; q += 1024) pen_g[b * NQ + q] = s_pen[q];
}

// ---------------- K8: matched_qidx — bit-sparse, one wave per (b,g) ----------------
__global__ __launch_bounds__(256) void matched_kernel(
    const float* __restrict__ cost, const unsigned* __restrict__ mbits,
    const int* __restrict__ pen_g, float* __restrict__ out_mq) {
  const int b = blockIdx.y, t = threadIdx.x;
  const int g = blockIdx.x * 4 + (t >> 6);
  const int lane = t & 63;
  const float* __restrict__ crow = cost + ((size_t)(b*NG + g)) * NQ;
  const unsigned* __restrict__ mrow = mbits + (b*NG + g) * NQW;
  const int* __restrict__ pb = pen_g + b * NQ;
  float best = FLT_MAX; int bq = 0;
  for (int w = lane; w < NQW; w += 64) {
    unsigned word = mrow[w];
    while (word) {
      const int bit = __ffs(word) - 1; word &= word - 1;
      const int q = w * 32 + bit;
      const float v = penalized(crow[q], pb[q]);
      if (lexlt(v, q, best, bq)) { best = v; bq = q; }
    }
  }
  for (int off = 32; off; off >>= 1) {
    const float ov = __shfl_down(best, off);
    const int oq = __shfl_down(bq, off);
    if (lexlt(ov, oq, best, bq)) { best = ov; bq = oq; }
  }
  if (lane == 0) out_mq[b * NG + g] = (float)bq;
}

// ---------------- K9: expand mbitsT rows -> m floats (float4 stores), selected, gt_idx ----------------
__global__ void out_kernel(const unsigned* __restrict__ mbitsT, float* __restrict__ out_m,
                           float* __restrict__ out_sel, float* __restrict__ out_gti) {
  const int b = blockIdx.y, t = threadIdx.x;
  const int q0 = blockIdx.x * 32;
  __shared__ unsigned wds[32 * NGW];
  for (int i = t; i < 32 * NGW; i += 256)   // strided: 320 words > 256 threads
    wds[i] = mbitsT[((size_t)(b*NQ + q0)) * NGW + i];
  __syncthreads();
  float4* __restrict__ om4 = reinterpret_cast<float4*>(out_m + ((size_t)(b*NQ + q0)) * NG);
  for (int j = t; j < 32 * (NG/4); j += 256) {
    const int qi = j / (NG/4);
    const int g0 = (j - qi * (NG/4)) * 4;
    const unsigned* wr = &wds[qi * NGW];
    float4 v;
    v.x = ((wr[(g0+0) >> 5] >> ((g0+0) & 31)) & 1u) ? 1.f : 0.f;
    v.y = ((wr[(g0+1) >> 5] >> ((g0+1) & 31)) & 1u) ? 1.f : 0.f;
    v.z = ((wr[(g0+2) >> 5] >> ((g0+2) & 31)) & 1u) ? 1.f : 0.f;
    v.w = ((wr[(g0+3) >> 5] >> ((g0+3) & 31)) & 1u) ? 1.f : 0.f;
    om4[j] = v;
  }
  if (t < 32) {
    int fgi = -1;
    for (int w = 0; w < NGW; ++w) {
      const unsigned v = wds[t*NGW + w];
      if (v) { fgi = w*32 + __ffs(v) - 1; break; }
    }
    out_sel[b*NQ + q0 + t] = (fgi >= 0) ? 1.f : 0.f;
    out_gti[b*NQ + q0 + t] = (fgi >= 0) ? (float)fgi : 0.f;
  }
}

extern "C" void kernel_launch(void* const* d_in, const int* in_sizes, int n_in,
                              void* d_out, int out_size, void* d_ws, size_t ws_size,
                              hipStream_t stream) {
  const float* logits = (const float*)d_in[0];
  const float* boxes  = (const float*)d_in[1];
  const int*   labels = (const int*)d_in[2];
  const float* gtb    = (const float*)d_in[3];
  const float* imgsz  = (const float*)d_in[4];

  float* out = (float*)d_out;
  float* out_m   = out;                                   // B*Q*G
  float* out_sel = out + (size_t)NB * NQ * NG;            // B*Q
  float* out_gti = out_sel + (size_t)NB * NQ;             // B*Q
  float* out_mq  = out_gti + (size_t)NB * NQ;             // B*G

  char* w = (char*)d_ws;
  const size_t szPrep = sizeof(float4) * (size_t)NB * NQ;
  const size_t szF    = sizeof(float) * (size_t)NB * NQ;
  const size_t szGp   = sizeof(float4) * (size_t)NB * NG * 5;
  const size_t szCct  = sizeof(float) * (size_t)NB * NC * NQ;
  const size_t szBits = sizeof(unsigned) * (size_t)NB * NG * NQW;
  const size_t szBitsT= sizeof(unsigned) * (size_t)NB * NQ * NGW;
  const size_t szIntQ = sizeof(int) * (size_t)NB * NQ;
  const size_t szIntG = sizeof(int) * (size_t)NB * NG;
  const size_t szCM   = sizeof(float) * (size_t)NB * MAXM * NG;
  const size_t need = szPrep + szF + szGp + szCct + szBits + szBitsT + 2*szIntQ + szIntG + szCM;
  if (ws_size < need) return;

  float4* prepN = (float4*)w; w += szPrep;
  float*  prepF = (float*)w;  w += szF;
  float4* gp    = (float4*)w; w += szGp;
  float*    cct   = (float*)w;    w += szCct;
  unsigned* mbits = (unsigned*)w; w += szBits;
  unsigned* mbitsT= (unsigned*)w; w += szBitsT;
  int* rcnt  = (int*)w; w += szIntQ;
  int* pen   = (int*)w; w += szIntQ;
  int* ccov  = (int*)w; w += szIntG;
  float* costM = (float*)w; w += szCM;

  float* cost = out_m;  // (B,G,Q) in the d_out m-region; overwritten by out_kernel at the end

  prep_kernel<<<dim3((NQ + 255) / 256, NB), 256, 0, stream>>>(boxes, gtb, imgsz, prepN, prepF, rcnt, mbitsT);
  gprep_kernel<<<(NB * NG + 255) / 256, 256, 0, stream>>>(gtb, labels, imgsz, gp);
  cls_kernel<<<dim3((NQ + QT - 1) / QT, NB), 256, 0, stream>>>(logits, cct);
  cost_topk_kernel<<<dim3(NG, NB), 128, 0, stream>>>(boxes, prepN, prepF, gp, cct, cost, mbits, mbitsT, rcnt, ccov);
  loop_kernel<<<NB, 1024, 0, stream>>>(cost, costM, mbits, mbitsT, rcnt, ccov, pen);
  matched_kernel<<<dim3(NG/4, NB), 256, 0, stream>>>(cost, mbits, pen, out_mq);
  out_kernel<<<dim3(NQ / 32, NB), 256, 0, stream>>>(mbitsT, out_m, out_sel, out_gti);
}

// Round 16
// 228.346 us; speedup vs baseline: 1.9851x; 1.0089x over previous
//
#include <hip/hip_runtime.h>
#include <float.h>
#include <stdint.h>
#include <stddef.h>

#define NB 16
#define NQ 4000
#define NG 300
#define NC 81
#define NQW 125  // NQ/32
#define NGW 10   // ceil(NG/32)
#define MAXM 768 // multi rows per image <= sum(dyn_k)/2 <= 750 (provable bound)

__device__ __forceinline__ bool lexlt(float v1, int i1, float v2, int i2) {
  return (v1 < v2) || (v1 == v2 && i1 < i2);
}

// Exact replica of p sequential f32 adds of 1e5 (numpy semantics), in O(#binade crossings).
__device__ __forceinline__ float penalized(float v, int p) {
  if (p <= 0) return v;
  if (p <= 12) {
    float x = v;
    for (int r = 0; r < p; ++r) x += 100000.0f;
    return x;
  }
  double x = (double)v;
  x = (double)(float)(x + 100000.0);
  int k = 1;
  while (k < p) {
    double B = 131072.0;
    while (B <= x) B += B;
    double room = B - x;
    int j = (int)(room * 1e-5);
    while (j > 0 && x + (double)j * 100000.0 >= B) --j;
    if (j > p - k) j = p - k;
    if (j > 0) { x += (double)j * 100000.0; k += j; }
    if (k < p) { x = (double)(float)(x + 100000.0); ++k; }
  }
  return (float)x;
}

// ---------------- K0: per-gt derived params ----------------
__global__ void gprep_kernel(const float* __restrict__ gtb, const int* __restrict__ labels,
                             const float* __restrict__ imgsz, float4* __restrict__ gp) {
#pragma clang fp contract(off)
  const int idx = blockIdx.x * 256 + threadIdx.x;
  if (idx >= NB * NG) return;
  const int b = idx / NG;
  const float gx0 = gtb[idx*4 + 0];
  const float gy0 = gtb[idx*4 + 1];
  const float gx1 = gtb[idx*4 + 2];
  const float gy1 = gtb[idx*4 + 3];
  const float s0 = imgsz[b*4+0], s1 = imgsz[b*4+1], s2 = imgsz[b*4+2], s3 = imgsz[b*4+3];
  const float areaB = (gx1 - gx0) * (gy1 - gy0);
  const float gcx = (gx0 + gx1) * 0.5f, gcy = (gy0 + gy1) * 0.5f;
  const float gw0 = gx1 - gx0, gh0 = gy1 - gy0;
  const float xg0 = gcx - 0.5f*gw0, yg0 = gcy - 0.5f*gh0;
  const float xg1 = gcx + 0.5f*gw0, yg1 = gcy + 0.5f*gh0;
  const float cw = xg1 - xg0, ch = yg1 - yg0;
  gp[idx*5+0] = make_float4(xg0, yg0, xg1, yg1);
  gp[idx*5+1] = make_float4(gcx - 2.5f*cw, gcx + 2.5f*cw, gcy - 2.5f*ch, gcy + 2.5f*ch);
  gp[idx*5+2] = make_float4(gx0 / s0, gy0 / s1, gx1 / s2, gy1 / s3);
  gp[idx*5+3] = make_float4(gx0, gy0, gx1, gy1);
  gp[idx*5+4] = make_float4(areaB, __int_as_float(labels[idx]), 0.f, 0.f);
}

// ---------------- K1: prep — fg via in_ctr only (inb => inc, provable); independent of gprep ----------------
__global__ void prep_kernel(const float* __restrict__ boxes, const float* __restrict__ gtb,
                            const float* __restrict__ imgsz,
                            float4* __restrict__ prepN, float* __restrict__ prepF,
                            int* __restrict__ rcnt, unsigned* __restrict__ mbitsT) {
#pragma clang fp contract(off)
  const int b = blockIdx.y;
  const int q = blockIdx.x * 256 + threadIdx.x;
  const int tid = (blockIdx.y * gridDim.x + blockIdx.x) * 256 + threadIdx.x;
  const int nthreads = gridDim.x * gridDim.y * 256;
  for (int i = tid; i < NB * NQ * NGW; i += nthreads) mbitsT[i] = 0u;
  __shared__ float4 sA1[NG];
  for (int i = threadIdx.x; i < NG; i += 256) {
    // same FP ops as gprep (bit-exact); computed locally to decouple from gprep's launch
    const float gx0 = gtb[(b*NG + i)*4 + 0];
    const float gy0 = gtb[(b*NG + i)*4 + 1];
    const float gx1 = gtb[(b*NG + i)*4 + 2];
    const float gy1 = gtb[(b*NG + i)*4 + 3];
    const float gcx = (gx0 + gx1) * 0.5f, gcy = (gy0 + gy1) * 0.5f;
    const float gw0 = gx1 - gx0, gh0 = gy1 - gy0;
    const float xg0 = gcx - 0.5f*gw0, yg0 = gcy - 0.5f*gh0;
    const float xg1 = gcx + 0.5f*gw0, yg1 = gcy + 0.5f*gh0;
    const float cw = xg1 - xg0, ch = yg1 - yg0;
    sA1[i] = make_float4(gcx - 2.5f*cw, gcx + 2.5f*cw, gcy - 2.5f*ch, gcy + 2.5f*ch);
  }
  __syncthreads();
  if (q >= NQ) return;
  const float4 pb = reinterpret_cast<const float4*>(boxes)[b * NQ + q];
  const float s0 = imgsz[b*4+0], s1 = imgsz[b*4+1], s2 = imgsz[b*4+2], s3 = imgsz[b*4+3];
  const float ax = (pb.x + pb.z) * 0.5f;
  const float ay = (pb.y + pb.w) * 0.5f;
  // fg = any(in_box)|any(in_ctr) == any(in_ctr): in_ctr interval contains in_box interval
  // (cw Sterbenz-exact when a float lies strictly inside, fl(2.5*cw) >= 0.5*gw).
  bool fg = false;
  for (int g = 0; g < NG; ++g) {
    const float4 A1 = sA1[g];
    if ((ax > A1.x) && (ax < A1.y) && (ay > A1.z) && (ay < A1.w)) { fg = true; break; }
  }
  const int idx = b * NQ + q;
  prepN[idx] = make_float4(pb.x / s0, pb.y / s1, pb.z / s2, pb.w / s3);
  prepF[idx] = fg ? 0.f : 10000.f;
  rcnt[idx] = 0;
}

// ---------------- K2: focal class cost table, transposed (B,C,Q), tiled ----------------
#define QT 64
__global__ void cls_kernel(const float* __restrict__ logits, float* __restrict__ cct) {
#pragma clang fp contract(off)
  const int b = blockIdx.y, q0 = blockIdx.x * QT, t = threadIdx.x;
  __shared__ float tile[QT * NC];
  const int nq = (NQ - q0 < QT) ? (NQ - q0) : QT;
  const float* __restrict__ src = logits + ((size_t)(b * NQ + q0)) * NC;
  for (int i = t; i < nq * NC; i += 256) {
    const float x = src[i];
    float p;
    if (x >= 0.f) p = 1.f / (1.f + expf(-x));
    else { const float e = expf(x); p = e / (1.f + e); }
    const float pos = 0.25f * ((1.f - p) * (1.f - p)) * (-logf(p + 1e-8f));
    const float neg = 0.75f * (p * p) * (-logf(1.f - p + 1e-8f));
    tile[i] = pos - neg;
  }
  __syncthreads();
  for (int i = t; i < NC * QT; i += 256) {
    const int c = i >> 6;
    const int ql = i & (QT - 1);
    if (ql < nq) cct[((size_t)(b * NC + c)) * NQ + q0 + ql] = tile[ql * NC + c];
  }
}

// ---------------- K3: FUSED cost + per-(b,g) top-5 (1 GT per block, 128 thr) ----------------
__device__ __forceinline__ void kv_sortnet(unsigned* k, int* i) {
#define CE(a,b) { \
    const bool pr = (k[b] < k[a]) || (k[b] == k[a] && i[b] < i[a]); \
    const unsigned tk = pr ? k[b] : k[a]; const unsigned uk = pr ? k[a] : k[b]; \
    const int ti = pr ? i[b] : i[a]; const int ui = pr ? i[a] : i[b]; \
    k[a] = tk; k[b] = uk; i[a] = ti; i[b] = ui; }
  CE(0,1)
  CE(1,2) CE(0,1)
  CE(2,3) CE(1,2) CE(0,1)
  CE(3,4) CE(2,3) CE(1,2) CE(0,1)
#undef CE
}
__device__ __forceinline__ void kv_merge(unsigned* ak, int* ai, const unsigned* bk, const int* bi) {
  unsigned ck[5]; int ci[5];
#pragma unroll
  for (int j = 0; j < 5; ++j) {
    const unsigned ka = ak[j], kb = bk[4 - j];
    const int ia = ai[j], ib = bi[4 - j];
    const bool pr = (kb < ka) || (kb == ka && ib < ia);
    ck[j] = pr ? kb : ka; ci[j] = pr ? ib : ia;
  }
  kv_sortnet(ck, ci);
#pragma unroll
  for (int j = 0; j < 5; ++j) { ak[j] = ck[j]; ai[j] = ci[j]; }
}
__device__ __forceinline__ void sort5_desc(float* c) {
#define CED(a,b) { const float hi = fmaxf(c[a], c[b]); c[b] = fminf(c[a], c[b]); c[a] = hi; }
  CED(0,1)
  CED(1,2) CED(0,1)
  CED(2,3) CED(1,2) CED(0,1)
  CED(3,4) CED(2,3) CED(1,2) CED(0,1)
#undef CED
}
__device__ __forceinline__ void merge5_iou(float* a, const float* o) {
  float c[5];
#pragma unroll
  for (int j = 0; j < 5; ++j) c[j] = fmaxf(a[j], o[4 - j]);
  sort5_desc(c);
#pragma unroll
  for (int j = 0; j < 5; ++j) a[j] = c[j];
}

__global__ __launch_bounds__(128, 4) void cost_topk_kernel(
    const float* __restrict__ boxes, const float4* __restrict__ prepN,
    const float* __restrict__ prepF, const float4* __restrict__ gp,
    const float* __restrict__ cct, float* __restrict__ cost,
    unsigned* __restrict__ mbits, unsigned* __restrict__ mbitsT,
    int* __restrict__ rcnt, int* __restrict__ ccov) {
#pragma clang fp contract(off)
  const int g = blockIdx.x, b = blockIdx.y, t = threadIdx.x;
  const int lane = t & 63, wave = t >> 6;
  const float4 A0 = gp[(size_t)(b*NG + g) * 5 + 0];
  const float4 A1 = gp[(size_t)(b*NG + g) * 5 + 1];
  const float4 A2 = gp[(size_t)(b*NG + g) * 5 + 2];
  const float4 A3 = gp[(size_t)(b*NG + g) * 5 + 3];
  const float4 A4 = gp[(size_t)(b*NG + g) * 5 + 4];
  const int lab = __float_as_int(A4.y);
  const float areaB = A4.x;
  const float* __restrict__ ccls = cct + ((size_t)(b*NC + lab)) * NQ;
  float* __restrict__ crow = cost + ((size_t)(b*NG + g)) * NQ;
  unsigned* __restrict__ mrow = mbits + (b*NG + g) * NQW;
  for (int i = t; i < NQW; i += 128) mrow[i] = 0u;

  unsigned mk[5]; int mi[5]; float sv[5];
#pragma unroll
  for (int j = 0; j < 5; ++j) { mk[j] = 0xffffffffu; mi[j] = 0x7fffffff; sv[j] = -1.f; }

#pragma unroll 2
  for (int q = t; q < NQ; q += 128) {
    const float4 pb = reinterpret_cast<const float4*>(boxes)[b*NQ + q];
    const float4 nb = prepN[b*NQ + q];
    const float fpen = prepF[b*NQ + q];
    const float ax = (pb.x + pb.z) * 0.5f;
    const float ay = (pb.y + pb.w) * 0.5f;
    const float areaA = (pb.z - pb.x) * (pb.w - pb.y);
    const float ltx = fmaxf(pb.x, A3.x), lty = fmaxf(pb.y, A3.y);
    const float rbx = fminf(pb.z, A3.z), rby = fminf(pb.w, A3.w);
    const float iw = fmaxf(rbx - ltx, 0.f), ih = fmaxf(rby - lty, 0.f);
    const float inter = iw * ih;
    const float uni = areaA + areaB - inter;
    const float iou = inter / uni;
    const float eltx = fminf(pb.x, A3.x), elty = fminf(pb.y, A3.y);
    const float erbx = fmaxf(pb.z, A3.z), erby = fmaxf(pb.w, A3.w);
    const float ew = fmaxf(erbx - eltx, 0.f), eh = fmaxf(erby - elty, 0.f);
    const float earea = ew * eh;
    const float giou = iou - (earea - uni) / earea;
    const float cbb = fabsf(nb.x - A2.x) + fabsf(nb.y - A2.y)
                    + fabsf(nb.z - A2.z) + fabsf(nb.w - A2.w);
    const bool inb = (ax > A0.x) && (ax < A0.z) && (ay > A0.y) && (ay < A0.w);
    const bool inc = (ax > A1.x) && (ax < A1.y) && (ay > A1.z) && (ay < A1.w);
    const bool ibc = inb && inc;
    float cval = 5.0f * cbb + 2.0f * ccls[q];
    cval = cval + 2.0f * (-giou);
    cval = cval + (ibc ? 0.f : 100.f);
    cval = cval + fpen;
    crow[q] = cval;
    const unsigned bits = __float_as_uint(cval + 0.0f);  // canonicalize -0
    unsigned key = (bits & 0x80000000u) ? ~bits : (bits | 0x80000000u);
    int qi = q;
#pragma unroll
    for (int j = 0; j < 5; ++j) {   // stable branchless bubble (ties keep existing)
      const unsigned a = mk[j];
      const bool pr = key < a;
      mk[j] = pr ? key : a;
      const int ii = mi[j];
      mi[j] = pr ? qi : ii;
      key = pr ? a : key;
      qi = pr ? ii : qi;
    }
    float x = iou;
#pragma unroll
    for (int j = 0; j < 5; ++j) {   // sv sorted descending
      const float a = sv[j];
      sv[j] = fmaxf(a, x);
      x = fminf(a, x);
    }
  }

#pragma unroll
  for (int off = 32; off >= 1; off >>= 1) {
    unsigned ok[5]; int oi[5]; float ov[5];
#pragma unroll
    for (int j = 0; j < 5; ++j) {
      ok[j] = __shfl_down(mk[j], off);
      oi[j] = __shfl_down(mi[j], off);
      ov[j] = __shfl_down(sv[j], off);
    }
    kv_merge(mk, mi, ok, oi);
    merge5_iou(sv, ov);
  }

  __shared__ unsigned Lk[2][5];
  __shared__ int Li[2][5];
  __shared__ float Ls[2][5];
  if (lane == 0) {
#pragma unroll
    for (int j = 0; j < 5; ++j) { Lk[wave][j] = mk[j]; Li[wave][j] = mi[j]; Ls[wave][j] = sv[j]; }
  }
  __syncthreads();
  if (t == 0) {
    unsigned fk[5]; int fi[5]; float fs[5];
    unsigned o2[5]; int i2[5]; float s2[5];
#pragma unroll
    for (int j = 0; j < 5; ++j) {
      fk[j] = Lk[0][j]; fi[j] = Li[0][j]; fs[j] = Ls[0][j];
      o2[j] = Lk[1][j]; i2[j] = Li[1][j]; s2[j] = Ls[1][j];
    }
    kv_merge(fk, fi, o2, i2);
    merge5_iou(fs, s2);
    float s = fs[0]; s += fs[1]; s += fs[2]; s += fs[3]; s += fs[4];  // descending order sum
    int k = (int)s; if (k < 1) k = 1; if (k > 5) k = 5;
    for (int j = 0; j < k; ++j) {
      const int q = fi[j];
      mrow[q >> 5] |= 1u << (q & 31);
      atomicOr(&mbitsT[((size_t)(b*NQ + q)) * NGW + (g >> 5)], 1u << (g & 31));
      atomicAdd(&rcnt[b * NQ + q], 1);
    }
    ccov[b * NG + g] = k;
  }
}

// ---------------- K7: fused compact+gather+multifix + while-loop, one block per image ----------------
__global__ __launch_bounds__(1024) void loop_kernel(
    const float* __restrict__ cost, float* __restrict__ costM,
    unsigned* __restrict__ mbits, unsigned* __restrict__ mbitsT,
    const int* __restrict__ rcnt_g, const int* __restrict__ ccov_g,
    int* __restrict__ pen_g) {
  const int b = blockIdx.x, t = threadIdx.x;
  __shared__ int s_pen[NQ];
  __shared__ int s_rcnt[NQ];
  __shared__ short s_qmi[NQ];
  __shared__ int s_ccov[NG];
  __shared__ int s_unc[NG];
  __shared__ int s_pickq[NG];
  __shared__ int s_mq[MAXM];
  __shared__ unsigned s_mrow[MAXM][NGW];
  __shared__ float s_pwv[16];
  __shared__ int s_pwq[16];
  __shared__ int s_mn, s_n, s_fix, s_sticky;

  const int lane = t & 63, wave = t >> 6;
  unsigned* __restrict__ mb = mbits + b * NG * NQW;
  unsigned* __restrict__ mbT = mbitsT + (size_t)b * NQ * NGW;
  const float* __restrict__ cb = cost + (size_t)b * NG * NQ;
  float* __restrict__ cm = costM + (size_t)b * MAXM * NG;

  if (t == 0) { s_mn = 0; s_sticky = 0; }
  for (int q = t; q < NQ; q += 1024) {
    s_pen[q] = 0;
    s_rcnt[q] = rcnt_g[b * NQ + q];
    s_qmi[q] = -1;
  }
  for (int g = t; g < NG; g += 1024) s_ccov[g] = ccov_g[b * NG + g];
  __syncthreads();
  for (int q = t; q < NQ; q += 1024)
    if (s_rcnt[q] > 1) { const int i = atomicAdd(&s_mn, 1); if (i < MAXM) s_mq[i] = q; }
  __syncthreads();
  int m_n = s_mn; if (m_n > MAXM) m_n = MAXM;
  for (int i = t; i < m_n; i += 1024) s_qmi[s_mq[i]] = (short)i;
  for (int i = t; i < m_n * NG; i += 1024) {
    const int mi = i / NG, g = i - mi * NG;
    cm[i] = cb[(size_t)g * NQ + s_mq[mi]];
  }
  for (int i = t; i < m_n * NGW; i += 1024) {
    const int mi = i / NGW, w2 = i - mi * NGW;
    s_mrow[mi][w2] = mbT[(size_t)s_mq[mi] * NGW + w2];
  }
  __syncthreads();
  // multifix: one wave per multi row -> one-hot argmin_g (raw cost)
  for (int mi = wave; mi < m_n; mi += 16) {
    const int q = s_mq[mi];
    const float* __restrict__ row = cm + (size_t)mi * NG;
    float best = FLT_MAX; int bg = 0;
    for (int g = lane; g < NG; g += 64) {
      const float v = row[g];
      if (v < best) { best = v; bg = g; }
    }
    for (int off = 32; off; off >>= 1) {
      const float ov = __shfl_down(best, off);
      const int og = __shfl_down(bg, off);
      if (ov < best || (ov == best && og < bg)) { best = ov; bg = og; }
    }
    bg = __shfl(bg, 0);
    const unsigned qbit = 1u << (q & 31);
    const int qw = q >> 5;
    if (lane < NGW) {
      const unsigned wv = s_mrow[mi][lane];
      const unsigned want = ((bg >> 5) == lane) ? (1u << (bg & 31)) : 0u;
      unsigned clr = wv & ~want;
      while (clr) {
        const int gb = __ffs(clr) - 1; clr &= clr - 1;
        const int g = lane*32 + gb;
        atomicAnd(&mb[g * NQW + qw], ~qbit);
        atomicSub(&s_ccov[g], 1);
      }
      if (want & ~wv) {
        atomicOr(&mb[bg * NQW + qw], qbit);
        atomicAdd(&s_ccov[bg], 1);
      }
      s_mrow[mi][lane] = want;
    }
    if (lane == 0) s_rcnt[q] = 1;
  }
  __syncthreads();

  for (int iter = 0; iter < 100; ++iter) {
    if (t == 0) { s_n = 0; s_fix = s_sticky; }
    __syncthreads();
    for (int g = t; g < NG; g += 1024)
      if (s_ccov[g] == 0) { const int i = atomicAdd(&s_n, 1); s_unc[i] = g; }
    __syncthreads();
    const int n = s_n;
    if (n == 0) break;
    for (int q = t; q < NQ; q += 1024)
      if (s_rcnt[q] > 0) s_pen[q]++;
    __syncthreads();
    if (n >= 16) {
      for (int ci = wave; ci < n; ci += 16) {
        const int g = s_unc[ci];
        const float* __restrict__ crow = cb + (size_t)g * NQ;
        float best = FLT_MAX; int bq = 0x7fffffff;
        for (int q = lane; q < NQ; q += 64) {
          const float v = crow[q] + (s_pen[q] ? 1e30f : 0.0f);
          const bool pr = v < best;
          best = pr ? v : best;
          bq = pr ? q : bq;
        }
        for (int off = 32; off; off >>= 1) {
          const float ov = __shfl_down(best, off);
          const int oq = __shfl_down(bq, off);
          if (ov < best || (ov == best && oq < bq)) { best = ov; bq = oq; }
        }
        if (lane == 0) s_pickq[ci] = bq;
      }
      __syncthreads();
    } else {
      const int wpc = 16 / n;
      const int ci = wave / wpc, seg = wave - ci * wpc;
      float best = FLT_MAX; int bq = 0x7fffffff;
      if (ci < n) {
        const int g = s_unc[ci];
        const float* __restrict__ crow = cb + (size_t)g * NQ;
        const int qlo = (NQ * seg) / wpc, qhi = (NQ * (seg + 1)) / wpc;
        for (int q = qlo + lane; q < qhi; q += 64) {
          const float v = crow[q] + (s_pen[q] ? 1e30f : 0.0f);
          const bool pr = v < best;
          best = pr ? v : best;
          bq = pr ? q : bq;
        }
        for (int off = 32; off; off >>= 1) {
          const float ov = __shfl_down(best, off);
          const int oq = __shfl_down(bq, off);
          if (ov < best || (ov == best && oq < bq)) { best = ov; bq = oq; }
        }
      }
      if (lane == 0) { s_pwv[wave] = best; s_pwq[wave] = bq; }
      __syncthreads();
      if (t < n) {
        float fb = FLT_MAX; int fq = 0x7fffffff;
        for (int s2 = 0; s2 < wpc; ++s2) {
          const float ov = s_pwv[t * wpc + s2];
          const int oq = s_pwq[t * wpc + s2];
          if (lexlt(ov, oq, fb, fq)) { fb = ov; fq = oq; }
        }
        s_pickq[t] = fq;
      }
      __syncthreads();
    }
    if (t < n) {
      const int g = s_unc[t], q = s_pickq[t];
      atomicOr(&mb[g * NQW + (q >> 5)], 1u << (q & 31));
      const int mi2 = s_qmi[q];
      if (mi2 >= 0) atomicOr(&s_mrow[mi2][g >> 5], 1u << (g & 31));
      else atomicOr(&mbT[(size_t)q * NGW + (g >> 5)], 1u << (g & 31));
      const int nc = atomicAdd(&s_rcnt[q], 1) + 1;
      s_ccov[g] = 1;
      if (nc > 1) { s_fix = 1; if (s_qmi[q] < 0) s_sticky = 1; }
    }
    __syncthreads();
    if (s_fix) {
      for (int mi = wave; mi < m_n; mi += 16) {
        const int q = s_mq[mi];
        float* __restrict__ row = cm + (size_t)mi * NG;
        float best = FLT_MAX; int bg = 0;
        for (int g = lane; g < NG; g += 64) {
          const float v = row[g] + 100000.0f;
          row[g] = v;
          if (v < best) { best = v; bg = g; }
        }
        for (int off = 32; off; off >>= 1) {
          const float ov = __shfl_down(best, off);
          const int og = __shfl_down(bg, off);
          if (ov < best || (ov == best && og < bg)) { best = ov; bg = og; }
        }
        bg = __shfl(bg, 0);
        const unsigned qbit = 1u << (q & 31);
        const int qw = q >> 5;
        if (lane < NGW) {
          const unsigned wv = s_mrow[mi][lane];
          const unsigned want = ((bg >> 5) == lane) ? (1u << (bg & 31)) : 0u;
          unsigned clr = wv & ~want;
          while (clr) {
            const int gb = __ffs(clr) - 1; clr &= clr - 1;
            const int g = lane * 32 + gb;
            atomicAnd(&mb[g * NQW + qw], ~qbit);
            atomicSub(&s_ccov[g], 1);
          }
          if (want & ~wv) {
            atomicOr(&mb[bg * NQW + qw], qbit);
            atomicAdd(&s_ccov[bg], 1);
          }
          s_mrow[mi][lane] = want;
        }
        if (lane == 0) s_rcnt[q] = 1;
      }
    } else {
      for (int i = t; i < m_n * NG; i += 1024) cm[i] += 100000.0f;
    }
    __syncthreads();
  }
  __syncthreads();
  for (int i = t; i < m_n * NGW; i += 1024) {
    const int mi = i / NGW, w2 = i - mi * NGW;
    mbT[(size_t)s_mq[mi] * NGW + w2] = s_mrow[mi][w2];
  }
  for (int q = t; q < NQ; q += 1024) pen_g[b * NQ + q] = s_pen[q];
}

// ---------------- K8: matched_qidx — bit-sparse, one wave per (b,g) ----------------
__global__ __launch_bounds__(256) void matched_kernel(
    const float* __restrict__ cost, const unsigned* __restrict__ mbits,
    const int* __restrict__ pen_g, float* __restrict__ out_mq) {
  const int b = blockIdx.y, t = threadIdx.x;
  const int g = blockIdx.x * 4 + (t >> 6);
  const int lane = t & 63;
  const float* __restrict__ crow = cost + ((size_t)(b*NG + g)) * NQ;
  const unsigned* __restrict__ mrow = mbits + (b*NG + g) * NQW;
  const int* __restrict__ pb = pen_g + b * NQ;
  float best = FLT_MAX; int bq = 0;
  for (int w = lane; w < NQW; w += 64) {
    unsigned word = mrow[w];
    while (word) {
      const int bit = __ffs(word) - 1; word &= word - 1;
      const int q = w * 32 + bit;
      const float v = penalized(crow[q], pb[q]);
      if (lexlt(v, q, best, bq)) { best = v; bq = q; }
    }
  }
  for (int off = 32; off; off >>= 1) {
    const float ov = __shfl_down(best, off);
    const int oq = __shfl_down(bq, off);
    if (lexlt(ov, oq, best, bq)) { best = ov; bq = oq; }
  }
  if (lane == 0) out_mq[b * NG + g] = (float)bq;
}

// ---------------- K9: expand mbitsT rows -> m floats (float4 stores), selected, gt_idx ----------------
__global__ void out_kernel(const unsigned* __restrict__ mbitsT, float* __restrict__ out_m,
                           float* __restrict__ out_sel, float* __restrict__ out_gti) {
  const int b = blockIdx.y, t = threadIdx.x;
  const int q0 = blockIdx.x * 32;
  __shared__ unsigned wds[32 * NGW];
  for (int i = t; i < 32 * NGW; i += 256)   // strided: 320 words > 256 threads
    wds[i] = mbitsT[((size_t)(b*NQ + q0)) * NGW + i];
  __syncthreads();
  float4* __restrict__ om4 = reinterpret_cast<float4*>(out_m + ((size_t)(b*NQ + q0)) * NG);
  for (int j = t; j < 32 * (NG/4); j += 256) {
    const int qi = j / (NG/4);
    const int g0 = (j - qi * (NG/4)) * 4;
    const unsigned* wr = &wds[qi * NGW];
    float4 v;
    v.x = ((wr[(g0+0) >> 5] >> ((g0+0) & 31)) & 1u) ? 1.f : 0.f;
    v.y = ((wr[(g0+1) >> 5] >> ((g0+1) & 31)) & 1u) ? 1.f : 0.f;
    v.z = ((wr[(g0+2) >> 5] >> ((g0+2) & 31)) & 1u) ? 1.f : 0.f;
    v.w = ((wr[(g0+3) >> 5] >> ((g0+3) & 31)) & 1u) ? 1.f : 0.f;
    om4[j] = v;
  }
  if (t < 32) {
    int fgi = -1;
    for (int w = 0; w < NGW; ++w) {
      const unsigned v = wds[t*NGW + w];
      if (v) { fgi = w*32 + __ffs(v) - 1; break; }
    }
    out_sel[b*NQ + q0 + t] = (fgi >= 0) ? 1.f : 0.f;
    out_gti[b*NQ + q0 + t] = (fgi >= 0) ? (float)fgi : 0.f;
  }
}

extern "C" void kernel_launch(void* const* d_in, const int* in_sizes, int n_in,
                              void* d_out, int out_size, void* d_ws, size_t ws_size,
                              hipStream_t stream) {
  const float* logits = (const float*)d_in[0];
  const float* boxes  = (const float*)d_in[1];
  const int*   labels = (const int*)d_in[2];
  const float* gtb    = (const float*)d_in[3];
  const float* imgsz  = (const float*)d_in[4];

  float* out = (float*)d_out;
  float* out_m   = out;                                   // B*Q*G
  float* out_sel = out + (size_t)NB * NQ * NG;            // B*Q
  float* out_gti = out_sel + (size_t)NB * NQ;             // B*Q
  float* out_mq  = out_gti + (size_t)NB * NQ;             // B*G

  char* w = (char*)d_ws;
  const size_t szPrep = sizeof(float4) * (size_t)NB * NQ;
  const size_t szF    = sizeof(float) * (size_t)NB * NQ;
  const size_t szGp   = sizeof(float4) * (size_t)NB * NG * 5;
  const size_t szCct  = sizeof(float) * (size_t)NB * NC * NQ;
  const size_t szBits = sizeof(unsigned) * (size_t)NB * NG * NQW;
  const size_t szBitsT= sizeof(unsigned) * (size_t)NB * NQ * NGW;
  const size_t szIntQ = sizeof(int) * (size_t)NB * NQ;
  const size_t szIntG = sizeof(int) * (size_t)NB * NG;
  const size_t szCM   = sizeof(float) * (size_t)NB * MAXM * NG;
  const size_t need = szPrep + szF + szGp + szCct + szBits + szBitsT + 2*szIntQ + szIntG + szCM;
  if (ws_size < need) return;

  float4* prepN = (float4*)w; w += szPrep;
  float*  prepF = (float*)w;  w += szF;
  float4* gp    = (float4*)w; w += szGp;
  float*    cct   = (float*)w;    w += szCct;
  unsigned* mbits = (unsigned*)w; w += szBits;
  unsigned* mbitsT= (unsigned*)w; w += szBitsT;
  int* rcnt  = (int*)w; w += szIntQ;
  int* pen   = (int*)w; w += szIntQ;
  int* ccov  = (int*)w; w += szIntG;
  float* costM = (float*)w; w += szCM;

  float* cost = out_m;  // (B,G,Q) in the d_out m-region; overwritten by out_kernel at the end

  prep_kernel<<<dim3((NQ + 255) / 256, NB), 256, 0, stream>>>(boxes, gtb, imgsz, prepN, prepF, rcnt, mbitsT);
  gprep_kernel<<<(NB * NG + 255) / 256, 256, 0, stream>>>(gtb, labels, imgsz, gp);
  cls_kernel<<<dim3((NQ + QT - 1) / QT, NB), 256, 0, stream>>>(logits, cct);
  cost_topk_kernel<<<dim3(NG, NB), 128, 0, stream>>>(boxes, prepN, prepF, gp, cct, cost, mbits, mbitsT, rcnt, ccov);
  loop_kernel<<<NB, 1024, 0, stream>>>(cost, costM, mbits, mbitsT, rcnt, ccov, pen);
  matched_kernel<<<dim3(NG/4, NB), 256, 0, stream>>>(cost, mbits, pen, out_mq);
  out_kernel<<<dim3(NQ / 32, NB), 256, 0, stream>>>(mbitsT, out_m, out_sel, out_gti);
}